// Round 4
// baseline (773.261 us; speedup 1.0000x reference)
//
#include <hip/hip_runtime.h>
#include <hip/hip_bf16.h>

#define NN_ 30000
#define NE_ 480000
#define DIM 128
#define EINF 16
#define EOUTF 16
#define NG 64
#define RSQRT_DH 0.17677669529663687f

typedef unsigned short u16;
typedef __attribute__((ext_vector_type(8))) short short8;
typedef __attribute__((ext_vector_type(8))) unsigned short ushort8v;
typedef __attribute__((ext_vector_type(4))) float floatx4;

// ---------------- workspace layout (32-bit word offsets) ----------------
#define W_DEG     0
#define W_CUR     30000
#define W_GSUM1   60000
#define W_GSQ1    68192
#define W_GSUM2   76384
#define W_GSQ2    84576
#define W_ZEND    92768
#define W_OFF     92768
#define W_BSUM    122772
#define W_GSTART  122900
#define W_EID     122968
#define W_JC      602968
#define W_SCORES  1082968
#define W_SRCB    3002968
#define W_DSTB    4922968
#define W_VALB    6842968
#define W_A       8762968
#define W_B       12602968
#define W_C       16442968
#define W_WGC     20282968
#define W_WE2B    20315736

static __device__ __forceinline__ u16 f2bf(float x) {
  __hip_bfloat16 h = __float2bfloat16(x);
  return *reinterpret_cast<u16*>(&h);
}
static __device__ __forceinline__ float bf2f(u16 v) {
  unsigned int b = ((unsigned int)v) << 16;
  return __uint_as_float(b);
}

// ---------------- GEMM building blocks (K=128, 32-row tile, 256 thr) ----
static __device__ __forceinline__ void stage32(const float* __restrict__ X,
                                               float* xsb, int row0, int tid) {
#pragma unroll
  for (int t = 0; t < 4; ++t) {
    int idx = tid + t * 256;
    int r = idx >> 5, c4 = (idx & 31) * 4;
    int row = row0 + r;
    float4 v; v.x = v.y = v.z = v.w = 0.f;
    if (row < NN_) v = *(const float4*)&X[(size_t)row * DIM + c4];
    *(float4*)&xsb[r * DIM + c4] = v;
  }
}

static __device__ __forceinline__ void mm_k128(const float* xsb, int ld,
                                               const float* __restrict__ W,
                                               float acc[4][4], int tid) {
  int cg = tid & 31, rg = tid >> 5;
  int c0 = cg * 4, r0 = rg * 4;
  for (int k = 0; k < 128; k += 4) {
    float4 w0 = *(const float4*)&W[(size_t)(k + 0) * DIM + c0];
    float4 w1 = *(const float4*)&W[(size_t)(k + 1) * DIM + c0];
    float4 w2 = *(const float4*)&W[(size_t)(k + 2) * DIM + c0];
    float4 w3 = *(const float4*)&W[(size_t)(k + 3) * DIM + c0];
#pragma unroll
    for (int u = 0; u < 4; ++u) {
      float4 xv = *(const float4*)&xsb[(r0 + u) * ld + k];
      acc[u][0] += xv.x * w0.x + xv.y * w1.x + xv.z * w2.x + xv.w * w3.x;
      acc[u][1] += xv.x * w0.y + xv.y * w1.y + xv.z * w2.y + xv.w * w3.y;
      acc[u][2] += xv.x * w0.z + xv.y * w1.z + xv.z * w2.z + xv.w * w3.z;
      acc[u][3] += xv.x * w0.w + xv.y * w1.w + xv.z * w2.w + xv.w * w3.w;
    }
  }
}

// bf16 variant for the projection outputs
static __device__ __forceinline__ void epi_store_bf(float acc[4][4],
    const float* __restrict__ bias, u16* __restrict__ Y,
    int row0, int tid) {
  int cg = tid & 31, rg = tid >> 5;
  int c0 = cg * 4, r0 = rg * 4;
  float4 bv = *(const float4*)&bias[c0];
#pragma unroll
  for (int u = 0; u < 4; ++u) {
    int row = row0 + r0 + u;
    if (row >= NN_) continue;
    ushort4 pk;
    pk.x = f2bf(acc[u][0] + bv.x); pk.y = f2bf(acc[u][1] + bv.y);
    pk.z = f2bf(acc[u][2] + bv.z); pk.w = f2bf(acc[u][3] + bv.w);
    *(ushort4*)&Y[(size_t)row * DIM + c0] = pk;
  }
}

// ---------------- small utility kernels ----------------
__global__ void zero_kernel(int* p, int n) {
  int i = blockIdx.x * 256 + threadIdx.x;
  if (i < n) p[i] = 0;
}

__global__ void gstart_kernel(const int* __restrict__ batch, int* __restrict__ gstart) {
  int g = threadIdx.x;
  if (g > NG) return;
  int lo = 0, hi = NN_;
  while (lo < hi) { int mid = (lo + hi) >> 1; if (batch[mid] < g) lo = mid + 1; else hi = mid; }
  gstart[g] = lo;
}

__global__ void prep_wg_kernel(const float* __restrict__ Wg, float* __restrict__ Wgc) {
  int idx = blockIdx.x * 256 + threadIdx.x;  // 256*128
  int k = idx >> 7, c = idx & 127;
  float v;
  if (k < 128) v = Wg[(size_t)k * DIM + c] + Wg[(size_t)(256 + k) * DIM + c];
  else { int kk = k - 128; v = Wg[(size_t)(128 + kk) * DIM + c] - Wg[(size_t)(256 + kk) * DIM + c]; }
  Wgc[idx] = v;
}

// We2 -> bf16, fragment-linear B layout for mfma_f32_16x16x32_bf16
__global__ void prep_we2_kernel(const float* __restrict__ We2, u16* __restrict__ out) {
  int idx = blockIdx.x * 256 + threadIdx.x;   // 64 blocks -> 16384
  if (idx >= 16384) return;
  int j = idx & 7, lane = (idx >> 3) & 63, s = (idx >> 9) & 3, T = idx >> 11;
  int k = s * 32 + ((lane >> 4) << 3) + j;
  int n = T * 16 + (lane & 15);
  out[idx] = f2bf(We2[(size_t)k * DIM + n]);
}

__global__ void deg_kernel(const int* __restrict__ EI, int* __restrict__ deg) {
  int e = blockIdx.x * 256 + threadIdx.x;
  if (e < NE_) atomicAdd(&deg[EI[e]], 1);
}

// ---------------- node projections: src,dst,value (bf16 outputs) -------
__global__ void __launch_bounds__(256) proj_kernel(
    const float* __restrict__ node,
    const float* __restrict__ Ws, const float* __restrict__ bs,
    const float* __restrict__ Wd, const float* __restrict__ bd,
    const float* __restrict__ Wv, const float* __restrict__ bv,
    u16* __restrict__ srcb, u16* __restrict__ dstb, u16* __restrict__ valb) {
  __shared__ __align__(16) float xs[32 * DIM];
  int tid = threadIdx.x, row0 = blockIdx.x * 32;
  stage32(node, xs, row0, tid);
  __syncthreads();
  const float* Wt[3] = {Ws, Wd, Wv};
  const float* Bt[3] = {bs, bd, bv};
  u16* Yt[3] = {srcb, dstb, valb};
#pragma unroll
  for (int w3 = 0; w3 < 3; ++w3) {
    float acc[4][4] = {};
    mm_k128(xs, DIM, Wt[w3], acc, tid);
    epi_store_bf(acc, Bt[w3], Yt[w3], row0, tid);
  }
}

// ---------------- fused node_new GEMM + gate ----------------
// A-tile: nnew = agg@Wun+bun stays in LDS; then g = sigmoid(nnew@Wgc0 +
// node@Wgc1 + bg); x1 = g*nnew + node. Saves one 15.4MB write + read.
__global__ void __launch_bounds__(256) nnew_gate_kernel(
    const float* __restrict__ AGG, const float* __restrict__ NODE,
    const float* __restrict__ Wun, const float* __restrict__ bun,
    const float* __restrict__ Wgc, const float* __restrict__ bg,
    float* __restrict__ G, float* __restrict__ X1) {
  __shared__ __align__(16) float xs0[32 * DIM];   // agg -> nnew
  __shared__ __align__(16) float xs1[32 * DIM];   // node
  int tid = threadIdx.x, row0 = blockIdx.x * 32;
  stage32(AGG, xs0, row0, tid);
  stage32(NODE, xs1, row0, tid);
  __syncthreads();
  int cg = tid & 31, rg = tid >> 5, c0 = cg * 4, r0 = rg * 4;
  {
    float acc[4][4] = {};
    mm_k128(xs0, DIM, Wun, acc, tid);
    __syncthreads();            // all xs0 (agg) reads done
    float4 bv = *(const float4*)&bun[c0];
#pragma unroll
    for (int u = 0; u < 4; ++u) {
      float4 ov; ov.x = acc[u][0] + bv.x; ov.y = acc[u][1] + bv.y;
      ov.z = acc[u][2] + bv.z; ov.w = acc[u][3] + bv.w;
      *(float4*)&xs0[(r0 + u) * DIM + c0] = ov;   // nnew tile
    }
  }
  __syncthreads();
  float acc[4][4] = {};
  mm_k128(xs0, DIM, Wgc, acc, tid);
  mm_k128(xs1, DIM, Wgc + 128 * DIM, acc, tid);
  float4 bv = *(const float4*)&bg[c0];
#pragma unroll
  for (int u = 0; u < 4; ++u) {
    int row = row0 + r0 + u;
    if (row >= NN_) continue;
    float z0 = acc[u][0] + bv.x, z1 = acc[u][1] + bv.y;
    float z2 = acc[u][2] + bv.z, z3 = acc[u][3] + bv.w;
    float g0 = 1.f / (1.f + __expf(-z0));
    float g1 = 1.f / (1.f + __expf(-z1));
    float g2 = 1.f / (1.f + __expf(-z2));
    float g3 = 1.f / (1.f + __expf(-z3));
    float4 nn4 = *(const float4*)&xs0[(r0 + u) * DIM + c0];
    float4 nd4 = *(const float4*)&xs1[(r0 + u) * DIM + c0];
    float4 gv; gv.x = g0; gv.y = g1; gv.z = g2; gv.w = g3;
    float4 xv; xv.x = g0 * nn4.x + nd4.x; xv.y = g1 * nn4.y + nd4.y;
    xv.z = g2 * nn4.z + nd4.z; xv.w = g3 * nn4.w + nd4.w;
    *(float4*)&G[(size_t)row * DIM + c0] = gv;
    *(float4*)&X1[(size_t)row * DIM + c0] = xv;
  }
}

// ---------------- fused fix_node: t = leaky(n1@Wf1+bf1); x2 = g*(t@Wf2+bf2)+n1
__global__ void __launch_bounds__(256) fx_kernel(
    const float* __restrict__ N1, const float* __restrict__ Wf1,
    const float* __restrict__ bf1, const float* __restrict__ Wf2,
    const float* __restrict__ bf2, const float* __restrict__ G,
    float* __restrict__ X2) {
  __shared__ __align__(16) float xs0[32 * DIM];   // n1
  __shared__ __align__(16) float xs1[32 * DIM];   // t
  int tid = threadIdx.x, row0 = blockIdx.x * 32;
  stage32(N1, xs0, row0, tid);
  __syncthreads();
  int cg = tid & 31, rg = tid >> 5, c0 = cg * 4, r0 = rg * 4;
  {
    float acc[4][4] = {};
    mm_k128(xs0, DIM, Wf1, acc, tid);
    float4 bv = *(const float4*)&bf1[c0];
#pragma unroll
    for (int u = 0; u < 4; ++u) {
      float t0 = acc[u][0] + bv.x, t1 = acc[u][1] + bv.y;
      float t2 = acc[u][2] + bv.z, t3 = acc[u][3] + bv.w;
      t0 = t0 > 0.f ? t0 : 0.01f * t0; t1 = t1 > 0.f ? t1 : 0.01f * t1;
      t2 = t2 > 0.f ? t2 : 0.01f * t2; t3 = t3 > 0.f ? t3 : 0.01f * t3;
      float4 ov; ov.x = t0; ov.y = t1; ov.z = t2; ov.w = t3;
      *(float4*)&xs1[(r0 + u) * DIM + c0] = ov;
    }
  }
  __syncthreads();
  float acc[4][4] = {};
  mm_k128(xs1, DIM, Wf2, acc, tid);
  float4 bv = *(const float4*)&bf2[c0];
#pragma unroll
  for (int u = 0; u < 4; ++u) {
    int row = row0 + r0 + u;
    if (row >= NN_) continue;
    float4 gv = *(const float4*)&G[(size_t)row * DIM + c0];
    float4 nv = *(const float4*)&xs0[(r0 + u) * DIM + c0];
    float4 ov;
    ov.x = gv.x * (acc[u][0] + bv.x) + nv.x;
    ov.y = gv.y * (acc[u][1] + bv.y) + nv.y;
    ov.z = gv.z * (acc[u][2] + bv.z) + nv.z;
    ov.w = gv.w * (acc[u][3] + bv.w) + nv.w;
    *(float4*)&X2[(size_t)row * DIM + c0] = ov;
  }
}

// ---------------- CSR build ----------------
__global__ void scanA_kernel(const int* __restrict__ deg, int* __restrict__ off,
                             int* __restrict__ bsum) {
  __shared__ int buf[256];
  int tid = threadIdx.x;
  int i = blockIdx.x * 256 + tid;
  int v = (i < NN_) ? deg[i] : 0;
  buf[tid] = v;
  __syncthreads();
  for (int s = 1; s < 256; s <<= 1) {
    int t = (tid >= s) ? buf[tid - s] : 0;
    __syncthreads();
    buf[tid] += t;
    __syncthreads();
  }
  if (i < NN_) off[i] = buf[tid] - v;
  if (tid == 255) bsum[blockIdx.x] = buf[255];
}

__global__ void scanB_kernel(int* __restrict__ bsum) {
  const int NBLK = (NN_ + 255) / 256;
  __shared__ int buf[128];
  int tid = threadIdx.x;
  int v = (tid < NBLK) ? bsum[tid] : 0;
  buf[tid] = v;
  __syncthreads();
  for (int s = 1; s < 128; s <<= 1) {
    int t = (tid >= s) ? buf[tid - s] : 0;
    __syncthreads();
    buf[tid] += t;
    __syncthreads();
  }
  if (tid < NBLK) bsum[tid] = buf[tid] - v;
}

__global__ void scanC_kernel(int* __restrict__ off, const int* __restrict__ bsum) {
  int i = blockIdx.x * 256 + threadIdx.x;
  if (i < NN_) off[i] += bsum[i >> 8];
  if (i == 0) off[NN_] = NE_;
}

__global__ void fill_kernel(const int* __restrict__ EI, const int* __restrict__ off,
                            int* __restrict__ cur, int* __restrict__ eidb,
                            int* __restrict__ jcsr) {
  int e = blockIdx.x * 256 + threadIdx.x;
  if (e >= NE_) return;
  int i = EI[e];
  int p = atomicAdd(&cur[i], 1);
  int pos = off[i] + p;
  eidb[pos] = e;
  jcsr[pos] = EI[NE_ + e];
}

// ---------------- fused edge kernel, CSR order ----------------
// LDS 28608 B -> 5 blocks/CU. Epilogue v2: MFMA output parked in ers as
// e2+be2; second pass remaps threads to (edge, 16 contiguous cols) so the
// dst/src gathers are 4x16B vector loads issued at kernel START (latency
// hidden under h-GEMM + MFMA), instead of 32x2B scalar gathers post-MFMA.
__global__ void __launch_bounds__(256, 5) edge_kernel(
    const float* __restrict__ edgef, const float* __restrict__ coords,
    const int* __restrict__ EI, const int* __restrict__ eidb,
    const float* __restrict__ We1, const float* __restrict__ be1,
    const float* __restrict__ be2, const u16* __restrict__ we2b,
    const float* __restrict__ Wue, const float* __restrict__ bue,
    const u16* __restrict__ srcb, const u16* __restrict__ dstb,
    float* __restrict__ scores, float* __restrict__ outE) {
  __shared__ __align__(16) float regA[2816];
  __shared__ __align__(16) float ers[32 * 132];
  __shared__ float bue_s[EOUTF];
  __shared__ int ii[32], jj[32], ee[32];

  float* xs   = regA;                 // [32][20], cols 0..16 used
  u16*   hbf  = (u16*)(regA + 640);   // [32][136]
  float* wue_s= regA;                 // [16][132], valid after overlay barrier

  int tid = threadIdx.x;
  // XCD chunk swizzle: 15000 blocks % 8 == 0 -> bijective.
  int bid = blockIdx.x;
  int bswz = (bid & 7) * (NE_ / 32 / 8) + (bid >> 3);
  int p0 = bswz * 32;

  if (tid < 32) {
    int p = p0 + tid;
    int e = eidb[p];
    ee[tid] = e;
    int i = EI[e], j = EI[NE_ + e];
    ii[tid] = i; jj[tid] = j;
    float dx = coords[i * 3 + 0] - coords[j * 3 + 0];
    float dy = coords[i * 3 + 1] - coords[j * 3 + 1];
    float dz = coords[i * 3 + 2] - coords[j * 3 + 2];
    float dist = sqrtf(dx * dx + dy * dy + dz * dz + 1e-12f) * 0.1f;
    xs[tid * 20 + 16] = dist;
  }
  if (tid < EOUTF) bue_s[tid] = bue[tid];
  __syncthreads();

  // issue the epilogue's dst/src gathers NOW (T14 async split): thread ->
  // (edge el2 = tid>>3, col block cb2*16). Consumed after the MFMA phase.
  int el2 = tid >> 3, cb2 = tid & 7;
  int c0b = cb2 * 16;
  int irow = ii[el2], jrow = jj[el2];
  ushort8v dv8a = *(const ushort8v*)&dstb[(size_t)irow * DIM + c0b];
  ushort8v dv8b = *(const ushort8v*)&dstb[(size_t)irow * DIM + c0b + 8];
  ushort8v sv8a = *(const ushort8v*)&srcb[(size_t)jrow * DIM + c0b];
  ushort8v sv8b = *(const ushort8v*)&srcb[(size_t)jrow * DIM + c0b + 8];

  if (tid < 128) {                      // stage 32x16 edge feats (gathered rows)
    int r = tid >> 2, c4 = (tid & 3) * 4;
    *(float4*)&xs[r * 20 + c4] = *(const float4*)&edgef[(size_t)ee[r] * EINF + c4];
  }
  __syncthreads();

  int cg = tid & 31, rg = tid >> 5, c0 = cg * 4, r0 = rg * 4;

  // h = leaky(x @ We1 + be1), K=17; We1 read directly from global (L1-hot).
  {
    float acc[4][4] = {};
    for (int k = 0; k < 16; k += 4) {
      float4 w0 = *(const float4*)&We1[(size_t)(k + 0) * DIM + c0];
      float4 w1 = *(const float4*)&We1[(size_t)(k + 1) * DIM + c0];
      float4 w2 = *(const float4*)&We1[(size_t)(k + 2) * DIM + c0];
      float4 w3 = *(const float4*)&We1[(size_t)(k + 3) * DIM + c0];
#pragma unroll
      for (int u = 0; u < 4; ++u) {
        float4 xv = *(const float4*)&xs[(r0 + u) * 20 + k];
        acc[u][0] += xv.x * w0.x + xv.y * w1.x + xv.z * w2.x + xv.w * w3.x;
        acc[u][1] += xv.x * w0.y + xv.y * w1.y + xv.z * w2.y + xv.w * w3.y;
        acc[u][2] += xv.x * w0.z + xv.y * w1.z + xv.z * w2.z + xv.w * w3.z;
        acc[u][3] += xv.x * w0.w + xv.y * w1.w + xv.z * w2.w + xv.w * w3.w;
      }
    }
    {   // k = 16: the dist column
      float4 w4 = *(const float4*)&We1[(size_t)16 * DIM + c0];
#pragma unroll
      for (int u = 0; u < 4; ++u) {
        float xd = xs[(r0 + u) * 20 + 16];
        acc[u][0] += xd * w4.x; acc[u][1] += xd * w4.y;
        acc[u][2] += xd * w4.z; acc[u][3] += xd * w4.w;
      }
    }
    float4 b1 = *(const float4*)&be1[c0];
#pragma unroll
    for (int u = 0; u < 4; ++u) {
      float h0 = acc[u][0] + b1.x, h1 = acc[u][1] + b1.y;
      float h2 = acc[u][2] + b1.z, h3 = acc[u][3] + b1.w;
      h0 = h0 > 0.f ? h0 : 0.01f * h0; h1 = h1 > 0.f ? h1 : 0.01f * h1;
      h2 = h2 > 0.f ? h2 : 0.01f * h2; h3 = h3 > 0.f ? h3 : 0.01f * h3;
      ushort4 pk; pk.x = f2bf(h0); pk.y = f2bf(h1); pk.z = f2bf(h2); pk.w = f2bf(h3);
      *(ushort4*)&hbf[(r0 + u) * 136 + c0] = pk;
    }
  }
  __syncthreads();

  // e2 = h @ We2 via MFMA. wave -> (mtile = w&1, nhalf = w>>1)
  int wv = tid >> 6, lane = tid & 63;
  int mtile = wv & 1, nhalf = wv >> 1;
  int quad = lane >> 4, lrow = lane & 15;
  int m0 = mtile * 16;

  short8 afrag[4];
#pragma unroll
  for (int s = 0; s < 4; ++s)
    afrag[s] = *(const short8*)&hbf[(m0 + lrow) * 136 + s * 32 + quad * 8];
  __syncthreads();   // hbf reads done -> regA reusable for wue_s

  // stage Wue^T into the now-dead xs/hbf region (2 barriers before use)
  for (int idx = tid; idx < 16 * DIM; idx += 256) {
    int oc = idx >> 7, k = idx & 127;
    wue_s[oc * 132 + k] = Wue[(size_t)k * EOUTF + oc];
  }

  floatx4 dacc[4];
#pragma unroll
  for (int t = 0; t < 4; ++t) dacc[t] = (floatx4){0.f, 0.f, 0.f, 0.f};
#pragma unroll
  for (int s = 0; s < 4; ++s) {
#pragma unroll
    for (int t = 0; t < 4; ++t) {
      int T = nhalf * 4 + t;
      short8 bfrg = *(const short8*)&we2b[(size_t)((T * 4 + s) * 64 + lane) * 8];
      dacc[t] = __builtin_amdgcn_mfma_f32_16x16x32_bf16(afrag[s], bfrg, dacc[t], 0, 0, 0);
    }
  }

  // pass 1: park e2 + be2 in ers (MFMA C layout)
#pragma unroll
  for (int t = 0; t < 4; ++t) {
    int col = nhalf * 64 + t * 16 + lrow;
    float b2v = be2[col];
#pragma unroll
    for (int r = 0; r < 4; ++r) {
      int erow = m0 + quad * 4 + r;
      ers[erow * 132 + col] = dacc[t][r] + b2v;
    }
  }
  __syncthreads();

  // pass 2: er = dst_i * src_j * e2 / sqrt(DH) with vectorized gathers
  {
    float ef[16];
#pragma unroll
    for (int q = 0; q < 4; ++q) {
      float4 v = *(const float4*)&ers[el2 * 132 + c0b + q * 4];
      ef[q * 4 + 0] = v.x; ef[q * 4 + 1] = v.y;
      ef[q * 4 + 2] = v.z; ef[q * 4 + 3] = v.w;
    }
    float asum = 0.f;
#pragma unroll
    for (int k = 0; k < 8; ++k) {
      float er = bf2f((u16)dv8a[k]) * bf2f((u16)sv8a[k]) * ef[k] * RSQRT_DH;
      ef[k] = er; asum += fabsf(er);
    }
#pragma unroll
    for (int k = 0; k < 8; ++k) {
      float er = bf2f((u16)dv8b[k]) * bf2f((u16)sv8b[k]) * ef[8 + k] * RSQRT_DH;
      ef[8 + k] = er; asum += fabsf(er);
    }
#pragma unroll
    for (int q = 0; q < 4; ++q) {
      float4 v; v.x = ef[q * 4 + 0]; v.y = ef[q * 4 + 1];
      v.z = ef[q * 4 + 2]; v.w = ef[q * 4 + 3];
      *(float4*)&ers[el2 * 132 + c0b + q * 4] = v;
    }
    // head = cb2>>1 (32 cols per head); partner thread tid^1 has other half
    asum += __shfl_xor(asum, 1);
    if ((cb2 & 1) == 0)
      scores[(size_t)(p0 + el2) * 4 + (cb2 >> 1)] = asum;
  }
  __syncthreads();   // er + wue_s fully in LDS

  // edge_new = er @ Wue + bue  -> scatter by original edge id
  int el = tid >> 3, oc2 = (tid & 7) * 2;
  float a0 = 0.f, a1 = 0.f;
  for (int k = 0; k < DIM; k += 4) {
    float4 e4 = *(const float4*)&ers[el * 132 + k];
    float4 w0 = *(const float4*)&wue_s[oc2 * 132 + k];
    float4 w1 = *(const float4*)&wue_s[(oc2 + 1) * 132 + k];
    a0 += e4.x * w0.x + e4.y * w0.y + e4.z * w0.z + e4.w * w0.w;
    a1 += e4.x * w1.x + e4.y * w1.y + e4.z * w1.z + e4.w * w1.w;
  }
  size_t ob = (size_t)ee[el] * EOUTF + oc2;
  float2 o2; o2.x = a0 + bue_s[oc2]; o2.y = a1 + bue_s[oc2 + 1];
  *(float2*)&outE[ob] = o2;
}

// ---------------- per-node softmax + aggregation (CSR gather) -----------
__global__ void __launch_bounds__(256) agg_kernel(
    const u16* __restrict__ valb, const float* __restrict__ scores,
    const int* __restrict__ off, const int* __restrict__ jcsr,
    float* __restrict__ agg) {
  int n = blockIdx.x * 4 + (threadIdx.x >> 6);
  int lane = threadIdx.x & 63;
  if (n >= NN_) return;
  int s = off[n], e_end = off[n + 1];

  float m0 = -1e30f, m1 = -1e30f, m2 = -1e30f, m3 = -1e30f;
  for (int p = s + lane; p < e_end; p += 64) {
    float4 sc = *(const float4*)&scores[(size_t)p * 4];
    m0 = fmaxf(m0, sc.x); m1 = fmaxf(m1, sc.y);
    m2 = fmaxf(m2, sc.z); m3 = fmaxf(m3, sc.w);
  }
#pragma unroll
  for (int d = 1; d < 64; d <<= 1) {
    m0 = fmaxf(m0, __shfl_xor(m0, d)); m1 = fmaxf(m1, __shfl_xor(m1, d));
    m2 = fmaxf(m2, __shfl_xor(m2, d)); m3 = fmaxf(m3, __shfl_xor(m3, d));
  }
  int h0 = lane >> 5;
  float mh0 = h0 ? m1 : m0;
  float mh1 = h0 ? m3 : m2;

  // 2-way unrolled: two independent jcsr->valb chains per iteration
  float acc0 = 0.f, acc1 = 0.f, den0 = 0.f, den1 = 0.f;
  int p = s;
  for (; p + 2 <= e_end; p += 2) {
    int j0 = jcsr[p], j1 = jcsr[p + 1];
    float s00 = scores[(size_t)p * 4 + h0];
    float s01 = scores[(size_t)p * 4 + 2 + h0];
    float s10 = scores[(size_t)(p + 1) * 4 + h0];
    float s11 = scores[(size_t)(p + 1) * 4 + 2 + h0];
    float v00 = bf2f(valb[(size_t)j0 * DIM + lane]);
    float v01 = bf2f(valb[(size_t)j0 * DIM + 64 + lane]);
    float v10 = bf2f(valb[(size_t)j1 * DIM + lane]);
    float v11 = bf2f(valb[(size_t)j1 * DIM + 64 + lane]);
    float ex00 = __expf(s00 - mh0), ex01 = __expf(s01 - mh1);
    float ex10 = __expf(s10 - mh0), ex11 = __expf(s11 - mh1);
    den0 += ex00 + ex10; den1 += ex01 + ex11;
    acc0 += ex00 * v00 + ex10 * v10;
    acc1 += ex01 * v01 + ex11 * v11;
  }
  if (p < e_end) {
    int j = jcsr[p];
    float s0 = scores[(size_t)p * 4 + h0];
    float s1 = scores[(size_t)p * 4 + 2 + h0];
    float ex0 = __expf(s0 - mh0), ex1 = __expf(s1 - mh1);
    den0 += ex0; den1 += ex1;
    acc0 += ex0 * bf2f(valb[(size_t)j * DIM + lane]);
    acc1 += ex1 * bf2f(valb[(size_t)j * DIM + 64 + lane]);
  }
  if (e_end > s) {
    agg[(size_t)n * DIM + lane]      = acc0 / den0;
    agg[(size_t)n * DIM + 64 + lane] = acc1 / den1;
  } else {
    agg[(size_t)n * DIM + lane] = 0.f;
    agg[(size_t)n * DIM + 64 + lane] = 0.f;
  }
}

// ---------------- GraphNorm ----------------
__global__ void gn_stats_kernel(const float* __restrict__ X, const int* __restrict__ gstart,
                                float* __restrict__ gsum, float* __restrict__ gsq) {
  int g = blockIdx.x, slice = blockIdx.y;
  int s = gstart[g], e = gstart[g + 1];
  int c = threadIdx.x & 127, half = threadIdx.x >> 7;
  float sm = 0.f, sq = 0.f;
  for (int n = s + slice * 2 + half; n < e; n += 16) {
    float v = X[(size_t)n * DIM + c];
    sm += v; sq += v * v;
  }
  __shared__ float bsm[2][DIM], bsq[2][DIM];
  bsm[half][c] = sm; bsq[half][c] = sq;
  __syncthreads();
  if (half == 0) {
    atomicAdd(&gsum[g * DIM + c], bsm[0][c] + bsm[1][c]);
    atomicAdd(&gsq[g * DIM + c],  bsq[0][c] + bsq[1][c]);
  }
}

__global__ void gn_apply_kernel(const float* __restrict__ X, const int* __restrict__ batch,
    const int* __restrict__ gstart, const float* __restrict__ gsum,
    const float* __restrict__ gsq, const float* __restrict__ w,
    const float* __restrict__ b, const float* __restrict__ a,
    float* __restrict__ Y) {
  int idx = blockIdx.x * 256 + threadIdx.x;
  if (idx >= NN_ * 32) return;
  int n = idx >> 5, c4 = (idx & 31) * 4;
  int g = batch[n];
  float cnt = fmaxf((float)(gstart[g + 1] - gstart[g]), 1.f);
  float inv = 1.f / cnt;
  float4 xv = *(const float4*)&X[(size_t)n * DIM + c4];
  float4 sm = *(const float4*)&gsum[g * DIM + c4];
  float4 sq = *(const float4*)&gsq[g * DIM + c4];
  float4 av = *(const float4*)&a[c4];
  float4 wv = *(const float4*)&w[c4];
  float4 bv = *(const float4*)&b[c4];
  float4 ov;
  {
    float mean = sm.x * inv, msq = sq.x * inv, am = av.x * mean;
    float var = msq - 2.f * am * mean + am * am;
    ov.x = wv.x * (xv.x - am) * rsqrtf(var + 1e-5f) + bv.x;
  }
  {
    float mean = sm.y * inv, msq = sq.y * inv, am = av.y * mean;
    float var = msq - 2.f * am * mean + am * am;
    ov.y = wv.y * (xv.y - am) * rsqrtf(var + 1e-5f) + bv.y;
  }
  {
    float mean = sm.z * inv, msq = sq.z * inv, am = av.z * mean;
    float var = msq - 2.f * am * mean + am * am;
    ov.z = wv.z * (xv.z - am) * rsqrtf(var + 1e-5f) + bv.z;
  }
  {
    float mean = sm.w * inv, msq = sq.w * inv, am = av.w * mean;
    float var = msq - 2.f * am * mean + am * am;
    ov.w = wv.w * (xv.w - am) * rsqrtf(var + 1e-5f) + bv.w;
  }
  *(float4*)&Y[(size_t)n * DIM + c4] = ov;
}

__global__ void coords_kernel(const float* __restrict__ C, float* __restrict__ O) {
  int i = blockIdx.x * 256 + threadIdx.x;
  if (i < NN_ * 3) O[i] = C[i];
}

// ---------------- launcher ----------------
extern "C" void kernel_launch(void* const* d_in, const int* in_sizes, int n_in,
                              void* d_out, int out_size, void* d_ws, size_t ws_size,
                              hipStream_t stream) {
  (void)in_sizes; (void)n_in; (void)out_size; (void)ws_size;
  const float* node  = (const float*)d_in[0];
  const float* edgef = (const float*)d_in[1];
  const float* coords= (const float*)d_in[2];
  const float* Ws  = (const float*)d_in[3];  const float* bs  = (const float*)d_in[4];
  const float* Wd  = (const float*)d_in[5];  const float* bd  = (const float*)d_in[6];
  const float* Wv  = (const float*)d_in[7];  const float* bv  = (const float*)d_in[8];
  const float* We1 = (const float*)d_in[9];  const float* be1 = (const float*)d_in[10];
  const float* We2 = (const float*)d_in[11]; const float* be2 = (const float*)d_in[12];
  const float* Wun = (const float*)d_in[13]; const float* bun = (const float*)d_in[14];
  const float* Wue = (const float*)d_in[15]; const float* bue = (const float*)d_in[16];
  const float* Wg  = (const float*)d_in[17]; const float* bg  = (const float*)d_in[18];
  const float* Wf1 = (const float*)d_in[19]; const float* bf1 = (const float*)d_in[20];
  const float* Wf2 = (const float*)d_in[21]; const float* bf2 = (const float*)d_in[22];
  const float* g1w = (const float*)d_in[23]; const float* g1b = (const float*)d_in[24];
  const float* g1a = (const float*)d_in[25];
  const float* g2w = (const float*)d_in[26]; const float* g2b = (const float*)d_in[27];
  const float* g2a = (const float*)d_in[28];
  const int* EI    = (const int*)d_in[29];
  const int* batch = (const int*)d_in[30];
  float* out = (float*)d_out;

  int*   wsi = (int*)d_ws;
  float* wsf = (float*)d_ws;
  int* deg    = wsi + W_DEG;
  int* cur    = wsi + W_CUR;
  int* offs   = wsi + W_OFF;
  int* bsum   = wsi + W_BSUM;
  int* gstart = wsi + W_GSTART;
  int* eidb   = wsi + W_EID;
  int* jcsr   = wsi + W_JC;
  float* gsum1 = wsf + W_GSUM1; float* gsq1 = wsf + W_GSQ1;
  float* gsum2 = wsf + W_GSUM2; float* gsq2 = wsf + W_GSQ2;
  float* scores_ = wsf + W_SCORES;
  u16* srcb = (u16*)(wsf + W_SRCB);
  u16* dstb = (u16*)(wsf + W_DSTB);
  u16* valb = (u16*)(wsf + W_VALB);
  float* A = wsf + W_A;   // agg -> x1 -> x2
  float* B = wsf + W_B;   // g
  float* C = wsf + W_C;   // n1
  float* wgc_ = wsf + W_WGC;
  u16*   we2b = (u16*)(wsf + W_WE2B);

  float* outE = out + (size_t)NN_ * DIM;
  float* outC = out + (size_t)NN_ * DIM + (size_t)NE_ * EOUTF;

  zero_kernel<<<(W_ZEND + 255) / 256, 256, 0, stream>>>(wsi, W_ZEND);
  gstart_kernel<<<1, 128, 0, stream>>>(batch, gstart);
  prep_wg_kernel<<<128, 256, 0, stream>>>(Wg, wgc_);
  prep_we2_kernel<<<64, 256, 0, stream>>>(We2, we2b);
  // CSR build (independent of projections)
  deg_kernel<<<(NE_ + 255) / 256, 256, 0, stream>>>(EI, deg);
  scanA_kernel<<<(NN_ + 255) / 256, 256, 0, stream>>>(deg, offs, bsum);
  scanB_kernel<<<1, 128, 0, stream>>>(bsum);
  scanC_kernel<<<(NN_ + 255) / 256, 256, 0, stream>>>(offs, bsum);
  fill_kernel<<<(NE_ + 255) / 256, 256, 0, stream>>>(EI, offs, cur, eidb, jcsr);
  // projections (bf16)
  proj_kernel<<<(NN_ + 31) / 32, 256, 0, stream>>>(node, Ws, bs, Wd, bd, Wv, bv,
                                                   srcb, dstb, valb);
  // edge pipeline in CSR order
  edge_kernel<<<NE_ / 32, 256, 0, stream>>>(edgef, coords, EI, eidb, We1, be1,
                                            be2, we2b, Wue, bue,
                                            srcb, dstb, scores_, outE);
  // A := agg
  agg_kernel<<<NN_ / 4, 256, 0, stream>>>(valb, scores_, offs, jcsr, A);
  // fused: nnew = A@Wun+bun (LDS); B := g, A := x1
  nnew_gate_kernel<<<(NN_ + 31) / 32, 256, 0, stream>>>(A, node, Wun, bun,
                                                        wgc_, bg, B, A);
  gn_stats_kernel<<<dim3(NG, 8), 256, 0, stream>>>(A, gstart, gsum1, gsq1);
  // C := n1
  gn_apply_kernel<<<(NN_ * 32 + 255) / 256, 256, 0, stream>>>(
      A, batch, gstart, gsum1, gsq1, g1w, g1b, g1a, C);
  // fused: t = leaky(C@Wf1+bf1) (LDS); A := x2 = g*(t@Wf2+bf2) + n1
  fx_kernel<<<(NN_ + 31) / 32, 256, 0, stream>>>(C, Wf1, bf1, Wf2, bf2, B, A);
  gn_stats_kernel<<<dim3(NG, 8), 256, 0, stream>>>(A, gstart, gsum2, gsq2);
  gn_apply_kernel<<<(NN_ * 32 + 255) / 256, 256, 0, stream>>>(
      A, batch, gstart, gsum2, gsq2, g2w, g2b, g2a, out);
  coords_kernel<<<(NN_ * 3 + 255) / 256, 256, 0, stream>>>(coords, outC);
}

// Round 6
// 667.091 us; speedup vs baseline: 1.1592x; 1.1592x over previous
//
#include <hip/hip_runtime.h>
#include <hip/hip_bf16.h>

#define NN_ 30000
#define NE_ 480000
#define DIM 128
#define EINF 16
#define EOUTF 16
#define NG 64
#define RSQRT_DH 0.17677669529663687f

typedef unsigned short u16;
typedef __attribute__((ext_vector_type(8))) short short8;
typedef __attribute__((ext_vector_type(8))) unsigned short ushort8v;
typedef __attribute__((ext_vector_type(4))) float floatx4;

// ---------------- workspace layout (32-bit word offsets) ----------------
#define W_DEG     0
#define W_CUR     30000
#define W_GSUM1   60000
#define W_GSQ1    68192
#define W_GSUM2   76384
#define W_GSQ2    84576
#define W_ZEND    92768
#define W_OFF     92768
#define W_BSUM    122772
#define W_GSTART  122900
#define W_EID     122968
#define W_JC      602968
#define W_SCORES  1082968
#define W_SRCB    3002968
#define W_DSTB    4922968
#define W_VALB    6842968
#define W_A       8762968
#define W_B       12602968
#define W_C       16442968
#define W_WGC     20282968
#define W_WE2B    20315736

static __device__ __forceinline__ u16 f2bf(float x) {
  __hip_bfloat16 h = __float2bfloat16(x);
  return *reinterpret_cast<u16*>(&h);
}
static __device__ __forceinline__ float bf2f(u16 v) {
  unsigned int b = ((unsigned int)v) << 16;
  return __uint_as_float(b);
}

// ---------------- GEMM building blocks (K=128, 32-row tile, 256 thr) ----
static __device__ __forceinline__ void stage32(const float* __restrict__ X,
                                               float* xsb, int row0, int tid) {
#pragma unroll
  for (int t = 0; t < 4; ++t) {
    int idx = tid + t * 256;
    int r = idx >> 5, c4 = (idx & 31) * 4;
    int row = row0 + r;
    float4 v; v.x = v.y = v.z = v.w = 0.f;
    if (row < NN_) v = *(const float4*)&X[(size_t)row * DIM + c4];
    *(float4*)&xsb[r * DIM + c4] = v;
  }
}

static __device__ __forceinline__ void mm_k128(const float* xsb, int ld,
                                               const float* __restrict__ W,
                                               float acc[4][4], int tid) {
  int cg = tid & 31, rg = tid >> 5;
  int c0 = cg * 4, r0 = rg * 4;
  for (int k = 0; k < 128; k += 4) {
    float4 w0 = *(const float4*)&W[(size_t)(k + 0) * DIM + c0];
    float4 w1 = *(const float4*)&W[(size_t)(k + 1) * DIM + c0];
    float4 w2 = *(const float4*)&W[(size_t)(k + 2) * DIM + c0];
    float4 w3 = *(const float4*)&W[(size_t)(k + 3) * DIM + c0];
#pragma unroll
    for (int u = 0; u < 4; ++u) {
      float4 xv = *(const float4*)&xsb[(r0 + u) * ld + k];
      acc[u][0] += xv.x * w0.x + xv.y * w1.x + xv.z * w2.x + xv.w * w3.x;
      acc[u][1] += xv.x * w0.y + xv.y * w1.y + xv.z * w2.y + xv.w * w3.y;
      acc[u][2] += xv.x * w0.z + xv.y * w1.z + xv.z * w2.z + xv.w * w3.z;
      acc[u][3] += xv.x * w0.w + xv.y * w1.w + xv.z * w2.w + xv.w * w3.w;
    }
  }
}

// bf16 variant for the projection outputs
static __device__ __forceinline__ void epi_store_bf(float acc[4][4],
    const float* __restrict__ bias, u16* __restrict__ Y,
    int row0, int tid) {
  int cg = tid & 31, rg = tid >> 5;
  int c0 = cg * 4, r0 = rg * 4;
  float4 bv = *(const float4*)&bias[c0];
#pragma unroll
  for (int u = 0; u < 4; ++u) {
    int row = row0 + r0 + u;
    if (row >= NN_) continue;
    ushort4 pk;
    pk.x = f2bf(acc[u][0] + bv.x); pk.y = f2bf(acc[u][1] + bv.y);
    pk.z = f2bf(acc[u][2] + bv.z); pk.w = f2bf(acc[u][3] + bv.w);
    *(ushort4*)&Y[(size_t)row * DIM + c0] = pk;
  }
}

// ---------------- small utility kernels ----------------
__global__ void zero_kernel(int* p, int n) {
  int i = blockIdx.x * 256 + threadIdx.x;
  if (i < n) p[i] = 0;
}

__global__ void gstart_kernel(const int* __restrict__ batch, int* __restrict__ gstart) {
  int g = threadIdx.x;
  if (g > NG) return;
  int lo = 0, hi = NN_;
  while (lo < hi) { int mid = (lo + hi) >> 1; if (batch[mid] < g) lo = mid + 1; else hi = mid; }
  gstart[g] = lo;
}

__global__ void prep_wg_kernel(const float* __restrict__ Wg, float* __restrict__ Wgc) {
  int idx = blockIdx.x * 256 + threadIdx.x;  // 256*128
  int k = idx >> 7, c = idx & 127;
  float v;
  if (k < 128) v = Wg[(size_t)k * DIM + c] + Wg[(size_t)(256 + k) * DIM + c];
  else { int kk = k - 128; v = Wg[(size_t)(128 + kk) * DIM + c] - Wg[(size_t)(256 + kk) * DIM + c]; }
  Wgc[idx] = v;
}

// We2 -> bf16, fragment-linear B layout for mfma_f32_16x16x32_bf16
__global__ void prep_we2_kernel(const float* __restrict__ We2, u16* __restrict__ out) {
  int idx = blockIdx.x * 256 + threadIdx.x;   // 64 blocks -> 16384
  if (idx >= 16384) return;
  int j = idx & 7, lane = (idx >> 3) & 63, s = (idx >> 9) & 3, T = idx >> 11;
  int k = s * 32 + ((lane >> 4) << 3) + j;
  int n = T * 16 + (lane & 15);
  out[idx] = f2bf(We2[(size_t)k * DIM + n]);
}

__global__ void deg_kernel(const int* __restrict__ EI, int* __restrict__ deg) {
  int e = blockIdx.x * 256 + threadIdx.x;
  if (e < NE_) atomicAdd(&deg[EI[e]], 1);
}

// ---------------- node projections: src,dst,value (bf16 outputs) -------
__global__ void __launch_bounds__(256) proj_kernel(
    const float* __restrict__ node,
    const float* __restrict__ Ws, const float* __restrict__ bs,
    const float* __restrict__ Wd, const float* __restrict__ bd,
    const float* __restrict__ Wv, const float* __restrict__ bv,
    u16* __restrict__ srcb, u16* __restrict__ dstb, u16* __restrict__ valb) {
  __shared__ __align__(16) float xs[32 * DIM];
  int tid = threadIdx.x, row0 = blockIdx.x * 32;
  stage32(node, xs, row0, tid);
  __syncthreads();
  const float* Wt[3] = {Ws, Wd, Wv};
  const float* Bt[3] = {bs, bd, bv};
  u16* Yt[3] = {srcb, dstb, valb};
#pragma unroll
  for (int w3 = 0; w3 < 3; ++w3) {
    float acc[4][4] = {};
    mm_k128(xs, DIM, Wt[w3], acc, tid);
    epi_store_bf(acc, Bt[w3], Yt[w3], row0, tid);
  }
}

// ---------------- fused node_new GEMM + gate ----------------
// A-tile: nnew = agg@Wun+bun stays in LDS; then g = sigmoid(nnew@Wgc0 +
// node@Wgc1 + bg); x1 = g*nnew + node. Saves one 15.4MB write + read.
__global__ void __launch_bounds__(256) nnew_gate_kernel(
    const float* __restrict__ AGG, const float* __restrict__ NODE,
    const float* __restrict__ Wun, const float* __restrict__ bun,
    const float* __restrict__ Wgc, const float* __restrict__ bg,
    float* __restrict__ G, float* __restrict__ X1) {
  __shared__ __align__(16) float xs0[32 * DIM];   // agg -> nnew
  __shared__ __align__(16) float xs1[32 * DIM];   // node
  int tid = threadIdx.x, row0 = blockIdx.x * 32;
  stage32(AGG, xs0, row0, tid);
  stage32(NODE, xs1, row0, tid);
  __syncthreads();
  int cg = tid & 31, rg = tid >> 5, c0 = cg * 4, r0 = rg * 4;
  {
    float acc[4][4] = {};
    mm_k128(xs0, DIM, Wun, acc, tid);
    __syncthreads();            // all xs0 (agg) reads done
    float4 bv = *(const float4*)&bun[c0];
#pragma unroll
    for (int u = 0; u < 4; ++u) {
      float4 ov; ov.x = acc[u][0] + bv.x; ov.y = acc[u][1] + bv.y;
      ov.z = acc[u][2] + bv.z; ov.w = acc[u][3] + bv.w;
      *(float4*)&xs0[(r0 + u) * DIM + c0] = ov;   // nnew tile
    }
  }
  __syncthreads();
  float acc[4][4] = {};
  mm_k128(xs0, DIM, Wgc, acc, tid);
  mm_k128(xs1, DIM, Wgc + 128 * DIM, acc, tid);
  float4 bv = *(const float4*)&bg[c0];
#pragma unroll
  for (int u = 0; u < 4; ++u) {
    int row = row0 + r0 + u;
    if (row >= NN_) continue;
    float z0 = acc[u][0] + bv.x, z1 = acc[u][1] + bv.y;
    float z2 = acc[u][2] + bv.z, z3 = acc[u][3] + bv.w;
    float g0 = 1.f / (1.f + __expf(-z0));
    float g1 = 1.f / (1.f + __expf(-z1));
    float g2 = 1.f / (1.f + __expf(-z2));
    float g3 = 1.f / (1.f + __expf(-z3));
    float4 nn4 = *(const float4*)&xs0[(r0 + u) * DIM + c0];
    float4 nd4 = *(const float4*)&xs1[(r0 + u) * DIM + c0];
    float4 gv; gv.x = g0; gv.y = g1; gv.z = g2; gv.w = g3;
    float4 xv; xv.x = g0 * nn4.x + nd4.x; xv.y = g1 * nn4.y + nd4.y;
    xv.z = g2 * nn4.z + nd4.z; xv.w = g3 * nn4.w + nd4.w;
    *(float4*)&G[(size_t)row * DIM + c0] = gv;
    *(float4*)&X1[(size_t)row * DIM + c0] = xv;
  }
}

// ---------------- fused fix_node: t = leaky(n1@Wf1+bf1); x2 = g*(t@Wf2+bf2)+n1
__global__ void __launch_bounds__(256) fx_kernel(
    const float* __restrict__ N1, const float* __restrict__ Wf1,
    const float* __restrict__ bf1, const float* __restrict__ Wf2,
    const float* __restrict__ bf2, const float* __restrict__ G,
    float* __restrict__ X2) {
  __shared__ __align__(16) float xs0[32 * DIM];   // n1
  __shared__ __align__(16) float xs1[32 * DIM];   // t
  int tid = threadIdx.x, row0 = blockIdx.x * 32;
  stage32(N1, xs0, row0, tid);
  __syncthreads();
  int cg = tid & 31, rg = tid >> 5, c0 = cg * 4, r0 = rg * 4;
  {
    float acc[4][4] = {};
    mm_k128(xs0, DIM, Wf1, acc, tid);
    float4 bv = *(const float4*)&bf1[c0];
#pragma unroll
    for (int u = 0; u < 4; ++u) {
      float t0 = acc[u][0] + bv.x, t1 = acc[u][1] + bv.y;
      float t2 = acc[u][2] + bv.z, t3 = acc[u][3] + bv.w;
      t0 = t0 > 0.f ? t0 : 0.01f * t0; t1 = t1 > 0.f ? t1 : 0.01f * t1;
      t2 = t2 > 0.f ? t2 : 0.01f * t2; t3 = t3 > 0.f ? t3 : 0.01f * t3;
      float4 ov; ov.x = t0; ov.y = t1; ov.z = t2; ov.w = t3;
      *(float4*)&xs1[(r0 + u) * DIM + c0] = ov;
    }
  }
  __syncthreads();
  float acc[4][4] = {};
  mm_k128(xs1, DIM, Wf2, acc, tid);
  float4 bv = *(const float4*)&bf2[c0];
#pragma unroll
  for (int u = 0; u < 4; ++u) {
    int row = row0 + r0 + u;
    if (row >= NN_) continue;
    float4 gv = *(const float4*)&G[(size_t)row * DIM + c0];
    float4 nv = *(const float4*)&xs0[(r0 + u) * DIM + c0];
    float4 ov;
    ov.x = gv.x * (acc[u][0] + bv.x) + nv.x;
    ov.y = gv.y * (acc[u][1] + bv.y) + nv.y;
    ov.z = gv.z * (acc[u][2] + bv.z) + nv.z;
    ov.w = gv.w * (acc[u][3] + bv.w) + nv.w;
    *(float4*)&X2[(size_t)row * DIM + c0] = ov;
  }
}

// ---------------- CSR build ----------------
__global__ void scanA_kernel(const int* __restrict__ deg, int* __restrict__ off,
                             int* __restrict__ bsum) {
  __shared__ int buf[256];
  int tid = threadIdx.x;
  int i = blockIdx.x * 256 + tid;
  int v = (i < NN_) ? deg[i] : 0;
  buf[tid] = v;
  __syncthreads();
  for (int s = 1; s < 256; s <<= 1) {
    int t = (tid >= s) ? buf[tid - s] : 0;
    __syncthreads();
    buf[tid] += t;
    __syncthreads();
  }
  if (i < NN_) off[i] = buf[tid] - v;
  if (tid == 255) bsum[blockIdx.x] = buf[255];
}

__global__ void scanB_kernel(int* __restrict__ bsum) {
  const int NBLK = (NN_ + 255) / 256;
  __shared__ int buf[128];
  int tid = threadIdx.x;
  int v = (tid < NBLK) ? bsum[tid] : 0;
  buf[tid] = v;
  __syncthreads();
  for (int s = 1; s < 128; s <<= 1) {
    int t = (tid >= s) ? buf[tid - s] : 0;
    __syncthreads();
    buf[tid] += t;
    __syncthreads();
  }
  if (tid < NBLK) bsum[tid] = buf[tid] - v;
}

__global__ void scanC_kernel(int* __restrict__ off, const int* __restrict__ bsum) {
  int i = blockIdx.x * 256 + threadIdx.x;
  if (i < NN_) off[i] += bsum[i >> 8];
  if (i == 0) off[NN_] = NE_;
}

__global__ void fill_kernel(const int* __restrict__ EI, const int* __restrict__ off,
                            int* __restrict__ cur, int* __restrict__ eidb,
                            int* __restrict__ jcsr) {
  int e = blockIdx.x * 256 + threadIdx.x;
  if (e >= NE_) return;
  int i = EI[e];
  int p = atomicAdd(&cur[i], 1);
  int pos = off[i] + p;
  eidb[pos] = e;
  jcsr[pos] = EI[NE_ + e];
}

// ---------------- fused edge kernel, CSR order ----------------
// LDS 28608 B -> 5 blocks/CU. Two-pass epilogue, gathers at USE site:
// pass 1 parks e2+be2 in ers (MFMA C layout); pass 2 remaps threads to
// (edge, 16 contiguous cols) and loads dst/src as 4x16B vector loads
// consumed immediately (short liveness -> no scratch spill; R4's
// early-issue variant spilled 64B/thread to scratch = +480MB HBM).
__global__ void __launch_bounds__(256, 5) edge_kernel(
    const float* __restrict__ edgef, const float* __restrict__ coords,
    const int* __restrict__ EI, const int* __restrict__ eidb,
    const float* __restrict__ We1, const float* __restrict__ be1,
    const float* __restrict__ be2, const u16* __restrict__ we2b,
    const float* __restrict__ Wue, const float* __restrict__ bue,
    const u16* __restrict__ srcb, const u16* __restrict__ dstb,
    float* __restrict__ scores, float* __restrict__ outE) {
  __shared__ __align__(16) float regA[2816];
  __shared__ __align__(16) float ers[32 * 132];
  __shared__ float bue_s[EOUTF];
  __shared__ int ii[32], jj[32], ee[32];

  float* xs   = regA;                 // [32][20], cols 0..16 used
  u16*   hbf  = (u16*)(regA + 640);   // [32][136]
  float* wue_s= regA;                 // [16][132], valid after overlay barrier

  int tid = threadIdx.x;
  // XCD chunk swizzle: 15000 blocks % 8 == 0 -> bijective.
  int bid = blockIdx.x;
  int bswz = (bid & 7) * (NE_ / 32 / 8) + (bid >> 3);
  int p0 = bswz * 32;

  if (tid < 32) {
    int p = p0 + tid;
    int e = eidb[p];
    ee[tid] = e;
    int i = EI[e], j = EI[NE_ + e];
    ii[tid] = i; jj[tid] = j;
    float dx = coords[i * 3 + 0] - coords[j * 3 + 0];
    float dy = coords[i * 3 + 1] - coords[j * 3 + 1];
    float dz = coords[i * 3 + 2] - coords[j * 3 + 2];
    float dist = sqrtf(dx * dx + dy * dy + dz * dz + 1e-12f) * 0.1f;
    xs[tid * 20 + 16] = dist;
  }
  if (tid < EOUTF) bue_s[tid] = bue[tid];
  __syncthreads();

  if (tid < 128) {                      // stage 32x16 edge feats (gathered rows)
    int r = tid >> 2, c4 = (tid & 3) * 4;
    *(float4*)&xs[r * 20 + c4] = *(const float4*)&edgef[(size_t)ee[r] * EINF + c4];
  }
  __syncthreads();

  int cg = tid & 31, rg = tid >> 5, c0 = cg * 4, r0 = rg * 4;

  // h = leaky(x @ We1 + be1), K=17; We1 read directly from global (L1-hot).
  {
    float acc[4][4] = {};
    for (int k = 0; k < 16; k += 4) {
      float4 w0 = *(const float4*)&We1[(size_t)(k + 0) * DIM + c0];
      float4 w1 = *(const float4*)&We1[(size_t)(k + 1) * DIM + c0];
      float4 w2 = *(const float4*)&We1[(size_t)(k + 2) * DIM + c0];
      float4 w3 = *(const float4*)&We1[(size_t)(k + 3) * DIM + c0];
#pragma unroll
      for (int u = 0; u < 4; ++u) {
        float4 xv = *(const float4*)&xs[(r0 + u) * 20 + k];
        acc[u][0] += xv.x * w0.x + xv.y * w1.x + xv.z * w2.x + xv.w * w3.x;
        acc[u][1] += xv.x * w0.y + xv.y * w1.y + xv.z * w2.y + xv.w * w3.y;
        acc[u][2] += xv.x * w0.z + xv.y * w1.z + xv.z * w2.z + xv.w * w3.z;
        acc[u][3] += xv.x * w0.w + xv.y * w1.w + xv.z * w2.w + xv.w * w3.w;
      }
    }
    {   // k = 16: the dist column
      float4 w4 = *(const float4*)&We1[(size_t)16 * DIM + c0];
#pragma unroll
      for (int u = 0; u < 4; ++u) {
        float xd = xs[(r0 + u) * 20 + 16];
        acc[u][0] += xd * w4.x; acc[u][1] += xd * w4.y;
        acc[u][2] += xd * w4.z; acc[u][3] += xd * w4.w;
      }
    }
    float4 b1 = *(const float4*)&be1[c0];
#pragma unroll
    for (int u = 0; u < 4; ++u) {
      float h0 = acc[u][0] + b1.x, h1 = acc[u][1] + b1.y;
      float h2 = acc[u][2] + b1.z, h3 = acc[u][3] + b1.w;
      h0 = h0 > 0.f ? h0 : 0.01f * h0; h1 = h1 > 0.f ? h1 : 0.01f * h1;
      h2 = h2 > 0.f ? h2 : 0.01f * h2; h3 = h3 > 0.f ? h3 : 0.01f * h3;
      ushort4 pk; pk.x = f2bf(h0); pk.y = f2bf(h1); pk.z = f2bf(h2); pk.w = f2bf(h3);
      *(ushort4*)&hbf[(r0 + u) * 136 + c0] = pk;
    }
  }
  __syncthreads();

  // e2 = h @ We2 via MFMA. wave -> (mtile = w&1, nhalf = w>>1)
  int wv = tid >> 6, lane = tid & 63;
  int mtile = wv & 1, nhalf = wv >> 1;
  int quad = lane >> 4, lrow = lane & 15;
  int m0 = mtile * 16;

  short8 afrag[4];
#pragma unroll
  for (int s = 0; s < 4; ++s)
    afrag[s] = *(const short8*)&hbf[(m0 + lrow) * 136 + s * 32 + quad * 8];
  __syncthreads();   // hbf reads done -> regA reusable for wue_s

  // stage Wue^T into the now-dead xs/hbf region (2 barriers before use)
  for (int idx = tid; idx < 16 * DIM; idx += 256) {
    int oc = idx >> 7, k = idx & 127;
    wue_s[oc * 132 + k] = Wue[(size_t)k * EOUTF + oc];
  }

  floatx4 dacc[4];
#pragma unroll
  for (int t = 0; t < 4; ++t) dacc[t] = (floatx4){0.f, 0.f, 0.f, 0.f};
#pragma unroll
  for (int s = 0; s < 4; ++s) {
#pragma unroll
    for (int t = 0; t < 4; ++t) {
      int T = nhalf * 4 + t;
      short8 bfrg = *(const short8*)&we2b[(size_t)((T * 4 + s) * 64 + lane) * 8];
      dacc[t] = __builtin_amdgcn_mfma_f32_16x16x32_bf16(afrag[s], bfrg, dacc[t], 0, 0, 0);
    }
  }

  // pass 1: park e2 + be2 in ers (MFMA C layout)
#pragma unroll
  for (int t = 0; t < 4; ++t) {
    int col = nhalf * 64 + t * 16 + lrow;
    float b2v = be2[col];
#pragma unroll
    for (int r = 0; r < 4; ++r) {
      int erow = m0 + quad * 4 + r;
      ers[erow * 132 + col] = dacc[t][r] + b2v;
    }
  }
  __syncthreads();

  // pass 2: er = dst_i * src_j * e2 / sqrt(DH); gathers loaded AT USE
  // (4x16B vector loads, consumed within ~10 instrs -> no spill)
  {
    int el2 = tid >> 3, cb2 = tid & 7;
    int c0b = cb2 * 16;
    int irow = ii[el2], jrow = jj[el2];
    ushort8v dv8a = *(const ushort8v*)&dstb[(size_t)irow * DIM + c0b];
    ushort8v dv8b = *(const ushort8v*)&dstb[(size_t)irow * DIM + c0b + 8];
    ushort8v sv8a = *(const ushort8v*)&srcb[(size_t)jrow * DIM + c0b];
    ushort8v sv8b = *(const ushort8v*)&srcb[(size_t)jrow * DIM + c0b + 8];

    float ef[16];
#pragma unroll
    for (int q = 0; q < 4; ++q) {
      float4 v = *(const float4*)&ers[el2 * 132 + c0b + q * 4];
      ef[q * 4 + 0] = v.x; ef[q * 4 + 1] = v.y;
      ef[q * 4 + 2] = v.z; ef[q * 4 + 3] = v.w;
    }
    float asum = 0.f;
#pragma unroll
    for (int k = 0; k < 8; ++k) {
      float er = bf2f((u16)dv8a[k]) * bf2f((u16)sv8a[k]) * ef[k] * RSQRT_DH;
      ef[k] = er; asum += fabsf(er);
    }
#pragma unroll
    for (int k = 0; k < 8; ++k) {
      float er = bf2f((u16)dv8b[k]) * bf2f((u16)sv8b[k]) * ef[8 + k] * RSQRT_DH;
      ef[8 + k] = er; asum += fabsf(er);
    }
#pragma unroll
    for (int q = 0; q < 4; ++q) {
      float4 v; v.x = ef[q * 4 + 0]; v.y = ef[q * 4 + 1];
      v.z = ef[q * 4 + 2]; v.w = ef[q * 4 + 3];
      *(float4*)&ers[el2 * 132 + c0b + q * 4] = v;
    }
    // head = cb2>>1 (32 cols per head); partner thread tid^1 has other half
    asum += __shfl_xor(asum, 1);
    if ((cb2 & 1) == 0)
      scores[(size_t)(p0 + el2) * 4 + (cb2 >> 1)] = asum;
  }
  __syncthreads();   // er + wue_s fully in LDS

  // edge_new = er @ Wue + bue  -> scatter by original edge id
  int el = tid >> 3, oc2 = (tid & 7) * 2;
  float a0 = 0.f, a1 = 0.f;
  for (int k = 0; k < DIM; k += 4) {
    float4 e4 = *(const float4*)&ers[el * 132 + k];
    float4 w0 = *(const float4*)&wue_s[oc2 * 132 + k];
    float4 w1 = *(const float4*)&wue_s[(oc2 + 1) * 132 + k];
    a0 += e4.x * w0.x + e4.y * w0.y + e4.z * w0.z + e4.w * w0.w;
    a1 += e4.x * w1.x + e4.y * w1.y + e4.z * w1.z + e4.w * w1.w;
  }
  size_t ob = (size_t)ee[el] * EOUTF + oc2;
  float2 o2; o2.x = a0 + bue_s[oc2]; o2.y = a1 + bue_s[oc2 + 1];
  *(float2*)&outE[ob] = o2;
}

// ---------------- per-node softmax + aggregation (CSR gather) -----------
__global__ void __launch_bounds__(256) agg_kernel(
    const u16* __restrict__ valb, const float* __restrict__ scores,
    const int* __restrict__ off, const int* __restrict__ jcsr,
    float* __restrict__ agg) {
  int n = blockIdx.x * 4 + (threadIdx.x >> 6);
  int lane = threadIdx.x & 63;
  if (n >= NN_) return;
  int s = off[n], e_end = off[n + 1];

  float m0 = -1e30f, m1 = -1e30f, m2 = -1e30f, m3 = -1e30f;
  for (int p = s + lane; p < e_end; p += 64) {
    float4 sc = *(const float4*)&scores[(size_t)p * 4];
    m0 = fmaxf(m0, sc.x); m1 = fmaxf(m1, sc.y);
    m2 = fmaxf(m2, sc.z); m3 = fmaxf(m3, sc.w);
  }
#pragma unroll
  for (int d = 1; d < 64; d <<= 1) {
    m0 = fmaxf(m0, __shfl_xor(m0, d)); m1 = fmaxf(m1, __shfl_xor(m1, d));
    m2 = fmaxf(m2, __shfl_xor(m2, d)); m3 = fmaxf(m3, __shfl_xor(m3, d));
  }
  int h0 = lane >> 5;
  float mh0 = h0 ? m1 : m0;
  float mh1 = h0 ? m3 : m2;

  // 2-way unrolled: two independent jcsr->valb chains per iteration
  float acc0 = 0.f, acc1 = 0.f, den0 = 0.f, den1 = 0.f;
  int p = s;
  for (; p + 2 <= e_end; p += 2) {
    int j0 = jcsr[p], j1 = jcsr[p + 1];
    float s00 = scores[(size_t)p * 4 + h0];
    float s01 = scores[(size_t)p * 4 + 2 + h0];
    float s10 = scores[(size_t)(p + 1) * 4 + h0];
    float s11 = scores[(size_t)(p + 1) * 4 + 2 + h0];
    float v00 = bf2f(valb[(size_t)j0 * DIM + lane]);
    float v01 = bf2f(valb[(size_t)j0 * DIM + 64 + lane]);
    float v10 = bf2f(valb[(size_t)j1 * DIM + lane]);
    float v11 = bf2f(valb[(size_t)j1 * DIM + 64 + lane]);
    float ex00 = __expf(s00 - mh0), ex01 = __expf(s01 - mh1);
    float ex10 = __expf(s10 - mh0), ex11 = __expf(s11 - mh1);
    den0 += ex00 + ex10; den1 += ex01 + ex11;
    acc0 += ex00 * v00 + ex10 * v10;
    acc1 += ex01 * v01 + ex11 * v11;
  }
  if (p < e_end) {
    int j = jcsr[p];
    float s0 = scores[(size_t)p * 4 + h0];
    float s1 = scores[(size_t)p * 4 + 2 + h0];
    float ex0 = __expf(s0 - mh0), ex1 = __expf(s1 - mh1);
    den0 += ex0; den1 += ex1;
    acc0 += ex0 * bf2f(valb[(size_t)j * DIM + lane]);
    acc1 += ex1 * bf2f(valb[(size_t)j * DIM + 64 + lane]);
  }
  if (e_end > s) {
    agg[(size_t)n * DIM + lane]      = acc0 / den0;
    agg[(size_t)n * DIM + 64 + lane] = acc1 / den1;
  } else {
    agg[(size_t)n * DIM + lane] = 0.f;
    agg[(size_t)n * DIM + 64 + lane] = 0.f;
  }
}

// ---------------- GraphNorm ----------------
__global__ void gn_stats_kernel(const float* __restrict__ X, const int* __restrict__ gstart,
                                float* __restrict__ gsum, float* __restrict__ gsq) {
  int g = blockIdx.x, slice = blockIdx.y;
  int s = gstart[g], e = gstart[g + 1];
  int c = threadIdx.x & 127, half = threadIdx.x >> 7;
  float sm = 0.f, sq = 0.f;
  for (int n = s + slice * 2 + half; n < e; n += 16) {
    float v = X[(size_t)n * DIM + c];
    sm += v; sq += v * v;
  }
  __shared__ float bsm[2][DIM], bsq[2][DIM];
  bsm[half][c] = sm; bsq[half][c] = sq;
  __syncthreads();
  if (half == 0) {
    atomicAdd(&gsum[g * DIM + c], bsm[0][c] + bsm[1][c]);
    atomicAdd(&gsq[g * DIM + c],  bsq[0][c] + bsq[1][c]);
  }
}

__global__ void gn_apply_kernel(const float* __restrict__ X, const int* __restrict__ batch,
    const int* __restrict__ gstart, const float* __restrict__ gsum,
    const float* __restrict__ gsq, const float* __restrict__ w,
    const float* __restrict__ b, const float* __restrict__ a,
    float* __restrict__ Y) {
  int idx = blockIdx.x * 256 + threadIdx.x;
  if (idx >= NN_ * 32) return;
  int n = idx >> 5, c4 = (idx & 31) * 4;
  int g = batch[n];
  float cnt = fmaxf((float)(gstart[g + 1] - gstart[g]), 1.f);
  float inv = 1.f / cnt;
  float4 xv = *(const float4*)&X[(size_t)n * DIM + c4];
  float4 sm = *(const float4*)&gsum[g * DIM + c4];
  float4 sq = *(const float4*)&gsq[g * DIM + c4];
  float4 av = *(const float4*)&a[c4];
  float4 wv = *(const float4*)&w[c4];
  float4 bv = *(const float4*)&b[c4];
  float4 ov;
  {
    float mean = sm.x * inv, msq = sq.x * inv, am = av.x * mean;
    float var = msq - 2.f * am * mean + am * am;
    ov.x = wv.x * (xv.x - am) * rsqrtf(var + 1e-5f) + bv.x;
  }
  {
    float mean = sm.y * inv, msq = sq.y * inv, am = av.y * mean;
    float var = msq - 2.f * am * mean + am * am;
    ov.y = wv.y * (xv.y - am) * rsqrtf(var + 1e-5f) + bv.y;
  }
  {
    float mean = sm.z * inv, msq = sq.z * inv, am = av.z * mean;
    float var = msq - 2.f * am * mean + am * am;
    ov.z = wv.z * (xv.z - am) * rsqrtf(var + 1e-5f) + bv.z;
  }
  {
    float mean = sm.w * inv, msq = sq.w * inv, am = av.w * mean;
    float var = msq - 2.f * am * mean + am * am;
    ov.w = wv.w * (xv.w - am) * rsqrtf(var + 1e-5f) + bv.w;
  }
  *(float4*)&Y[(size_t)n * DIM + c4] = ov;
}

__global__ void coords_kernel(const float* __restrict__ C, float* __restrict__ O) {
  int i = blockIdx.x * 256 + threadIdx.x;
  if (i < NN_ * 3) O[i] = C[i];
}

// ---------------- launcher ----------------
extern "C" void kernel_launch(void* const* d_in, const int* in_sizes, int n_in,
                              void* d_out, int out_size, void* d_ws, size_t ws_size,
                              hipStream_t stream) {
  (void)in_sizes; (void)n_in; (void)out_size; (void)ws_size;
  const float* node  = (const float*)d_in[0];
  const float* edgef = (const float*)d_in[1];
  const float* coords= (const float*)d_in[2];
  const float* Ws  = (const float*)d_in[3];  const float* bs  = (const float*)d_in[4];
  const float* Wd  = (const float*)d_in[5];  const float* bd  = (const float*)d_in[6];
  const float* Wv  = (const float*)d_in[7];  const float* bv  = (const float*)d_in[8];
  const float* We1 = (const float*)d_in[9];  const float* be1 = (const float*)d_in[10];
  const float* We2 = (const float*)d_in[11]; const float* be2 = (const float*)d_in[12];
  const float* Wun = (const float*)d_in[13]; const float* bun = (const float*)d_in[14];
  const float* Wue = (const float*)d_in[15]; const float* bue = (const float*)d_in[16];
  const float* Wg  = (const float*)d_in[17]; const float* bg  = (const float*)d_in[18];
  const float* Wf1 = (const float*)d_in[19]; const float* bf1 = (const float*)d_in[20];
  const float* Wf2 = (const float*)d_in[21]; const float* bf2 = (const float*)d_in[22];
  const float* g1w = (const float*)d_in[23]; const float* g1b = (const float*)d_in[24];
  const float* g1a = (const float*)d_in[25];
  const float* g2w = (const float*)d_in[26]; const float* g2b = (const float*)d_in[27];
  const float* g2a = (const float*)d_in[28];
  const int* EI    = (const int*)d_in[29];
  const int* batch = (const int*)d_in[30];
  float* out = (float*)d_out;

  int*   wsi = (int*)d_ws;
  float* wsf = (float*)d_ws;
  int* deg    = wsi + W_DEG;
  int* cur    = wsi + W_CUR;
  int* offs   = wsi + W_OFF;
  int* bsum   = wsi + W_BSUM;
  int* gstart = wsi + W_GSTART;
  int* eidb   = wsi + W_EID;
  int* jcsr   = wsi + W_JC;
  float* gsum1 = wsf + W_GSUM1; float* gsq1 = wsf + W_GSQ1;
  float* gsum2 = wsf + W_GSUM2; float* gsq2 = wsf + W_GSQ2;
  float* scores_ = wsf + W_SCORES;
  u16* srcb = (u16*)(wsf + W_SRCB);
  u16* dstb = (u16*)(wsf + W_DSTB);
  u16* valb = (u16*)(wsf + W_VALB);
  float* A = wsf + W_A;   // agg -> x1 -> x2
  float* B = wsf + W_B;   // g
  float* C = wsf + W_C;   // n1
  float* wgc_ = wsf + W_WGC;
  u16*   we2b = (u16*)(wsf + W_WE2B);

  float* outE = out + (size_t)NN_ * DIM;
  float* outC = out + (size_t)NN_ * DIM + (size_t)NE_ * EOUTF;

  zero_kernel<<<(W_ZEND + 255) / 256, 256, 0, stream>>>(wsi, W_ZEND);
  gstart_kernel<<<1, 128, 0, stream>>>(batch, gstart);
  prep_wg_kernel<<<128, 256, 0, stream>>>(Wg, wgc_);
  prep_we2_kernel<<<64, 256, 0, stream>>>(We2, we2b);
  // CSR build (independent of projections)
  deg_kernel<<<(NE_ + 255) / 256, 256, 0, stream>>>(EI, deg);
  scanA_kernel<<<(NN_ + 255) / 256, 256, 0, stream>>>(deg, offs, bsum);
  scanB_kernel<<<1, 128, 0, stream>>>(bsum);
  scanC_kernel<<<(NN_ + 255) / 256, 256, 0, stream>>>(offs, bsum);
  fill_kernel<<<(NE_ + 255) / 256, 256, 0, stream>>>(EI, offs, cur, eidb, jcsr);
  // projections (bf16)
  proj_kernel<<<(NN_ + 31) / 32, 256, 0, stream>>>(node, Ws, bs, Wd, bd, Wv, bv,
                                                   srcb, dstb, valb);
  // edge pipeline in CSR order
  edge_kernel<<<NE_ / 32, 256, 0, stream>>>(edgef, coords, EI, eidb, We1, be1,
                                            be2, we2b, Wue, bue,
                                            srcb, dstb, scores_, outE);
  // A := agg
  agg_kernel<<<NN_ / 4, 256, 0, stream>>>(valb, scores_, offs, jcsr, A);
  // fused: nnew = A@Wun+bun (LDS); B := g, A := x1
  nnew_gate_kernel<<<(NN_ + 31) / 32, 256, 0, stream>>>(A, node, Wun, bun,
                                                        wgc_, bg, B, A);
  gn_stats_kernel<<<dim3(NG, 8), 256, 0, stream>>>(A, gstart, gsum1, gsq1);
  // C := n1
  gn_apply_kernel<<<(NN_ * 32 + 255) / 256, 256, 0, stream>>>(
      A, batch, gstart, gsum1, gsq1, g1w, g1b, g1a, C);
  // fused: t = leaky(C@Wf1+bf1) (LDS); A := x2 = g*(t@Wf2+bf2) + n1
  fx_kernel<<<(NN_ + 31) / 32, 256, 0, stream>>>(C, Wf1, bf1, Wf2, bf2, B, A);
  gn_stats_kernel<<<dim3(NG, 8), 256, 0, stream>>>(A, gstart, gsum2, gsq2);
  gn_apply_kernel<<<(NN_ * 32 + 255) / 256, 256, 0, stream>>>(
      A, batch, gstart, gsum2, gsq2, g2w, g2b, g2a, out);
  coords_kernel<<<(NN_ * 3 + 255) / 256, 256, 0, stream>>>(coords, outC);
}

// Round 7
// 605.837 us; speedup vs baseline: 1.2764x; 1.1011x over previous
//
#include <hip/hip_runtime.h>
#include <hip/hip_bf16.h>

#define NN_ 30000
#define NE_ 480000
#define DIM 128
#define EINF 16
#define EOUTF 16
#define NG 64
#define RSQRT_DH 0.17677669529663687f

typedef unsigned short u16;
typedef __attribute__((ext_vector_type(8))) short short8;
typedef __attribute__((ext_vector_type(8))) unsigned short ushort8v;
typedef __attribute__((ext_vector_type(4))) float floatx4;

// ---------------- workspace layout (32-bit word offsets) ----------------
#define W_DEG     0
#define W_CUR     30000
#define W_GSUM1   60000
#define W_GSQ1    68192
#define W_GSUM2   76384
#define W_GSQ2    84576
#define W_ZEND    92768
#define W_OFF     92768
#define W_BSUM    122772
#define W_GSTART  122900
#define W_EID     122968
#define W_JC      602968
#define W_SCORES  1082968
#define W_SRCB    3002968
#define W_DSTB    4922968
#define W_VALB    6842968
#define W_A       8762968
#define W_B       12602968
#define W_C       16442968
#define W_WGC     20282968
#define W_WE2B    20315736

static __device__ __forceinline__ u16 f2bf(float x) {
  __hip_bfloat16 h = __float2bfloat16(x);
  return *reinterpret_cast<u16*>(&h);
}
static __device__ __forceinline__ float bf2f(u16 v) {
  unsigned int b = ((unsigned int)v) << 16;
  return __uint_as_float(b);
}

// ---------------- GEMM building blocks (K=128, 32-row tile, 256 thr) ----
static __device__ __forceinline__ void stage32(const float* __restrict__ X,
                                               float* xsb, int row0, int tid) {
#pragma unroll
  for (int t = 0; t < 4; ++t) {
    int idx = tid + t * 256;
    int r = idx >> 5, c4 = (idx & 31) * 4;
    int row = row0 + r;
    float4 v; v.x = v.y = v.z = v.w = 0.f;
    if (row < NN_) v = *(const float4*)&X[(size_t)row * DIM + c4];
    *(float4*)&xsb[r * DIM + c4] = v;
  }
}

static __device__ __forceinline__ void mm_k128(const float* xsb, int ld,
                                               const float* __restrict__ W,
                                               float acc[4][4], int tid) {
  int cg = tid & 31, rg = tid >> 5;
  int c0 = cg * 4, r0 = rg * 4;
  for (int k = 0; k < 128; k += 4) {
    float4 w0 = *(const float4*)&W[(size_t)(k + 0) * DIM + c0];
    float4 w1 = *(const float4*)&W[(size_t)(k + 1) * DIM + c0];
    float4 w2 = *(const float4*)&W[(size_t)(k + 2) * DIM + c0];
    float4 w3 = *(const float4*)&W[(size_t)(k + 3) * DIM + c0];
#pragma unroll
    for (int u = 0; u < 4; ++u) {
      float4 xv = *(const float4*)&xsb[(r0 + u) * ld + k];
      acc[u][0] += xv.x * w0.x + xv.y * w1.x + xv.z * w2.x + xv.w * w3.x;
      acc[u][1] += xv.x * w0.y + xv.y * w1.y + xv.z * w2.y + xv.w * w3.y;
      acc[u][2] += xv.x * w0.z + xv.y * w1.z + xv.z * w2.z + xv.w * w3.z;
      acc[u][3] += xv.x * w0.w + xv.y * w1.w + xv.z * w2.w + xv.w * w3.w;
    }
  }
}

// bf16 variant for the projection outputs
static __device__ __forceinline__ void epi_store_bf(float acc[4][4],
    const float* __restrict__ bias, u16* __restrict__ Y,
    int row0, int tid) {
  int cg = tid & 31, rg = tid >> 5;
  int c0 = cg * 4, r0 = rg * 4;
  float4 bv = *(const float4*)&bias[c0];
#pragma unroll
  for (int u = 0; u < 4; ++u) {
    int row = row0 + r0 + u;
    if (row >= NN_) continue;
    ushort4 pk;
    pk.x = f2bf(acc[u][0] + bv.x); pk.y = f2bf(acc[u][1] + bv.y);
    pk.z = f2bf(acc[u][2] + bv.z); pk.w = f2bf(acc[u][3] + bv.w);
    *(ushort4*)&Y[(size_t)row * DIM + c0] = pk;
  }
}

// per-tile column reduce of a 32xDIM LDS tile into per-graph sum/sumsq
// (2 threads per column; rows sorted by graph; <=1 boundary per tile)
static __device__ __forceinline__ void tile_gn_stats(const float* xsb,
    const int* bg_s, int row0, int tid,
    float* __restrict__ gsum, float* __restrict__ gsq) {
  int c = tid & 127, half = tid >> 7;
  float sm = 0.f, sq = 0.f;
  int gcur = -1;
  for (int r = 0; r < 16; ++r) {
    int rl = half * 16 + r;
    int row = row0 + rl;
    if (row >= NN_) break;
    int g = bg_s[rl];
    float v = xsb[rl * DIM + c];
    if (g != gcur) {
      if (gcur >= 0) {
        atomicAdd(&gsum[gcur * DIM + c], sm);
        atomicAdd(&gsq[gcur * DIM + c], sq);
      }
      gcur = g; sm = 0.f; sq = 0.f;
    }
    sm += v; sq += v * v;
  }
  if (gcur >= 0) {
    atomicAdd(&gsum[gcur * DIM + c], sm);
    atomicAdd(&gsq[gcur * DIM + c], sq);
  }
}

// ---------------- consolidated setup kernel ----------------
// blocks 0..362: zero wsi[0..W_ZEND); 363: gstart; 364..491: Wgc; 492..555: we2b
__global__ void setup_kernel(int* __restrict__ wsi, const int* __restrict__ batch,
                             int* __restrict__ gstart,
                             const float* __restrict__ Wg, float* __restrict__ Wgc,
                             const float* __restrict__ We2, u16* __restrict__ we2b) {
  int b = blockIdx.x, tid = threadIdx.x;
  if (b < 363) {
    int i = b * 256 + tid;
    if (i < W_ZEND) wsi[i] = 0;
  } else if (b == 363) {
    int g = tid;
    if (g <= NG) {
      int lo = 0, hi = NN_;
      while (lo < hi) { int mid = (lo + hi) >> 1; if (batch[mid] < g) lo = mid + 1; else hi = mid; }
      gstart[g] = lo;
    }
  } else if (b < 492) {
    int idx = (b - 364) * 256 + tid;   // 32768 elems
    int k = idx >> 7, c = idx & 127;
    float v;
    if (k < 128) v = Wg[(size_t)k * DIM + c] + Wg[(size_t)(256 + k) * DIM + c];
    else { int kk = k - 128; v = Wg[(size_t)(128 + kk) * DIM + c] - Wg[(size_t)(256 + kk) * DIM + c]; }
    Wgc[idx] = v;
  } else {
    int idx = (b - 492) * 256 + tid;   // 16384 elems
    if (idx < 16384) {
      int j = idx & 7, lane = (idx >> 3) & 63, s = (idx >> 9) & 3, T = idx >> 11;
      int k = s * 32 + ((lane >> 4) << 3) + j;
      int n = T * 16 + (lane & 15);
      we2b[idx] = f2bf(We2[(size_t)k * DIM + n]);
    }
  }
}

__global__ void deg_kernel(const int* __restrict__ EI, int* __restrict__ deg) {
  int e = blockIdx.x * 256 + threadIdx.x;
  if (e < NE_) atomicAdd(&deg[EI[e]], 1);
}

// ---------------- node projections: src,dst,value (bf16 outputs) -------
__global__ void __launch_bounds__(256) proj_kernel(
    const float* __restrict__ node,
    const float* __restrict__ Ws, const float* __restrict__ bs,
    const float* __restrict__ Wd, const float* __restrict__ bd,
    const float* __restrict__ Wv, const float* __restrict__ bv,
    u16* __restrict__ srcb, u16* __restrict__ dstb, u16* __restrict__ valb) {
  __shared__ __align__(16) float xs[32 * DIM];
  int tid = threadIdx.x, row0 = blockIdx.x * 32;
  stage32(node, xs, row0, tid);
  __syncthreads();
  const float* Wt[3] = {Ws, Wd, Wv};
  const float* Bt[3] = {bs, bd, bv};
  u16* Yt[3] = {srcb, dstb, valb};
#pragma unroll
  for (int w3 = 0; w3 < 3; ++w3) {
    float acc[4][4] = {};
    mm_k128(xs, DIM, Wt[w3], acc, tid);
    epi_store_bf(acc, Bt[w3], Yt[w3], row0, tid);
  }
}

// ---------------- fused node_new GEMM + gate + gn1 stats ----------------
// nnew = agg@Wun+bun (LDS); g = sigmoid(nnew@Wgc0 + node@Wgc1 + bg);
// x1 = g*nnew + node -> global AND back into xs1 for the per-tile gn1
// stats reduce (removes gn_stats1's 15.4MB re-read + launch).
__global__ void __launch_bounds__(256) nnew_gate_kernel(
    const float* __restrict__ AGG, const float* __restrict__ NODE,
    const int* __restrict__ batch,
    const float* __restrict__ Wun, const float* __restrict__ bun,
    const float* __restrict__ Wgc, const float* __restrict__ bg,
    float* __restrict__ gsum1, float* __restrict__ gsq1,
    float* __restrict__ G, float* __restrict__ X1) {
  __shared__ __align__(16) float xs0[32 * DIM];   // agg -> nnew
  __shared__ __align__(16) float xs1[32 * DIM];   // node -> x1
  __shared__ int bg_s[32];
  int tid = threadIdx.x, row0 = blockIdx.x * 32;
  stage32(AGG, xs0, row0, tid);
  stage32(NODE, xs1, row0, tid);
  if (tid < 32) {
    int row = row0 + tid;
    bg_s[tid] = (row < NN_) ? batch[row] : 0;
  }
  __syncthreads();
  int cg = tid & 31, rg = tid >> 5, c0 = cg * 4, r0 = rg * 4;
  {
    float acc[4][4] = {};
    mm_k128(xs0, DIM, Wun, acc, tid);
    __syncthreads();            // all xs0 (agg) reads done
    float4 bv = *(const float4*)&bun[c0];
#pragma unroll
    for (int u = 0; u < 4; ++u) {
      float4 ov; ov.x = acc[u][0] + bv.x; ov.y = acc[u][1] + bv.y;
      ov.z = acc[u][2] + bv.z; ov.w = acc[u][3] + bv.w;
      *(float4*)&xs0[(r0 + u) * DIM + c0] = ov;   // nnew tile
    }
  }
  __syncthreads();
  float acc[4][4] = {};
  mm_k128(xs0, DIM, Wgc, acc, tid);
  mm_k128(xs1, DIM, Wgc + 128 * DIM, acc, tid);
  float4 bv = *(const float4*)&bg[c0];
  float4 xvv[4];
#pragma unroll
  for (int u = 0; u < 4; ++u) {
    int row = row0 + r0 + u;
    float z0 = acc[u][0] + bv.x, z1 = acc[u][1] + bv.y;
    float z2 = acc[u][2] + bv.z, z3 = acc[u][3] + bv.w;
    float g0 = 1.f / (1.f + __expf(-z0));
    float g1 = 1.f / (1.f + __expf(-z1));
    float g2 = 1.f / (1.f + __expf(-z2));
    float g3 = 1.f / (1.f + __expf(-z3));
    float4 nn4 = *(const float4*)&xs0[(r0 + u) * DIM + c0];
    float4 nd4 = *(const float4*)&xs1[(r0 + u) * DIM + c0];
    float4 gv; gv.x = g0; gv.y = g1; gv.z = g2; gv.w = g3;
    float4 xv; xv.x = g0 * nn4.x + nd4.x; xv.y = g1 * nn4.y + nd4.y;
    xv.z = g2 * nn4.z + nd4.z; xv.w = g3 * nn4.w + nd4.w;
    xvv[u] = xv;
    if (row < NN_) {
      *(float4*)&G[(size_t)row * DIM + c0] = gv;
      *(float4*)&X1[(size_t)row * DIM + c0] = xv;
    }
  }
  __syncthreads();   // all xs1 (node) reads done -> reuse for x1 tile
#pragma unroll
  for (int u = 0; u < 4; ++u)
    *(float4*)&xs1[(r0 + u) * DIM + c0] = xvv[u];
  __syncthreads();
  tile_gn_stats(xs1, bg_s, row0, tid, gsum1, gsq1);
}

// ---------------- fused fix_node + gn_apply1(inline) + gn2 stats --------
// n1 = GN1(x1) computed inline from stats (removes gn_apply1 + C buffer);
// t = leaky(n1@Wf1+bf1); x2 = g*(t@Wf2+bf2)+n1 -> global AND xs1 for the
// gn2 stats reduce (removes gn_stats2's re-read + launch).
__global__ void __launch_bounds__(256) fx_kernel(
    const float* __restrict__ X1, const int* __restrict__ batch,
    const int* __restrict__ gstart,
    const float* __restrict__ gsum1, const float* __restrict__ gsq1,
    const float* __restrict__ g1w, const float* __restrict__ g1b,
    const float* __restrict__ g1a,
    const float* __restrict__ Wf1, const float* __restrict__ bf1,
    const float* __restrict__ Wf2, const float* __restrict__ bf2,
    const float* __restrict__ G,
    float* __restrict__ gsum2, float* __restrict__ gsq2,
    float* __restrict__ X2) {
  __shared__ __align__(16) float xs0[32 * DIM];   // x1 -> n1
  __shared__ __align__(16) float xs1[32 * DIM];   // t -> x2
  __shared__ int bg_s[32];
  int tid = threadIdx.x, row0 = blockIdx.x * 32;
  stage32(X1, xs0, row0, tid);
  if (tid < 32) {
    int row = row0 + tid;
    bg_s[tid] = (row < NN_) ? batch[row] : 0;
  }
  __syncthreads();
  int cg = tid & 31, rg = tid >> 5, c0 = cg * 4, r0 = rg * 4;
  // inline GN1 on own 4x4 slice: n1 = w*(x1 - a*mean)*rsqrt(var+eps) + b
#pragma unroll
  for (int u = 0; u < 4; ++u) {
    int rl = r0 + u, row = row0 + rl;
    if (row >= NN_) continue;
    int g = bg_s[rl];
    float cnt = fmaxf((float)(gstart[g + 1] - gstart[g]), 1.f);
    float inv = 1.f / cnt;
    float4 xv = *(const float4*)&xs0[rl * DIM + c0];
    float4 sm = *(const float4*)&gsum1[g * DIM + c0];
    float4 sq = *(const float4*)&gsq1[g * DIM + c0];
    float4 av = *(const float4*)&g1a[c0];
    float4 wv = *(const float4*)&g1w[c0];
    float4 bvv = *(const float4*)&g1b[c0];
    float4 ov;
    {
      float mean = sm.x * inv, msq = sq.x * inv, am = av.x * mean;
      float var = msq - 2.f * am * mean + am * am;
      ov.x = wv.x * (xv.x - am) * rsqrtf(var + 1e-5f) + bvv.x;
    }
    {
      float mean = sm.y * inv, msq = sq.y * inv, am = av.y * mean;
      float var = msq - 2.f * am * mean + am * am;
      ov.y = wv.y * (xv.y - am) * rsqrtf(var + 1e-5f) + bvv.y;
    }
    {
      float mean = sm.z * inv, msq = sq.z * inv, am = av.z * mean;
      float var = msq - 2.f * am * mean + am * am;
      ov.z = wv.z * (xv.z - am) * rsqrtf(var + 1e-5f) + bvv.z;
    }
    {
      float mean = sm.w * inv, msq = sq.w * inv, am = av.w * mean;
      float var = msq - 2.f * am * mean + am * am;
      ov.w = wv.w * (xv.w - am) * rsqrtf(var + 1e-5f) + bvv.w;
    }
    *(float4*)&xs0[rl * DIM + c0] = ov;   // n1 tile
  }
  __syncthreads();
  {
    float acc[4][4] = {};
    mm_k128(xs0, DIM, Wf1, acc, tid);
    float4 bv = *(const float4*)&bf1[c0];
#pragma unroll
    for (int u = 0; u < 4; ++u) {
      float t0 = acc[u][0] + bv.x, t1 = acc[u][1] + bv.y;
      float t2 = acc[u][2] + bv.z, t3 = acc[u][3] + bv.w;
      t0 = t0 > 0.f ? t0 : 0.01f * t0; t1 = t1 > 0.f ? t1 : 0.01f * t1;
      t2 = t2 > 0.f ? t2 : 0.01f * t2; t3 = t3 > 0.f ? t3 : 0.01f * t3;
      float4 ov; ov.x = t0; ov.y = t1; ov.z = t2; ov.w = t3;
      *(float4*)&xs1[(r0 + u) * DIM + c0] = ov;
    }
  }
  __syncthreads();
  float acc[4][4] = {};
  mm_k128(xs1, DIM, Wf2, acc, tid);
  float4 bv = *(const float4*)&bf2[c0];
  float4 x2v[4];
#pragma unroll
  for (int u = 0; u < 4; ++u) {
    int row = row0 + r0 + u;
    float4 nv = *(const float4*)&xs0[(r0 + u) * DIM + c0];
    float4 gv; gv.x = gv.y = gv.z = gv.w = 0.f;
    if (row < NN_) gv = *(const float4*)&G[(size_t)row * DIM + c0];
    float4 ov;
    ov.x = gv.x * (acc[u][0] + bv.x) + nv.x;
    ov.y = gv.y * (acc[u][1] + bv.y) + nv.y;
    ov.z = gv.z * (acc[u][2] + bv.z) + nv.z;
    ov.w = gv.w * (acc[u][3] + bv.w) + nv.w;
    x2v[u] = ov;
    if (row < NN_) *(float4*)&X2[(size_t)row * DIM + c0] = ov;
  }
  __syncthreads();   // all xs1 (t) reads done -> reuse for x2 tile
#pragma unroll
  for (int u = 0; u < 4; ++u)
    *(float4*)&xs1[(r0 + u) * DIM + c0] = x2v[u];
  __syncthreads();
  tile_gn_stats(xs1, bg_s, row0, tid, gsum2, gsq2);
}

// ---------------- CSR build ----------------
__global__ void scanA_kernel(const int* __restrict__ deg, int* __restrict__ off,
                             int* __restrict__ bsum) {
  __shared__ int buf[256];
  int tid = threadIdx.x;
  int i = blockIdx.x * 256 + tid;
  int v = (i < NN_) ? deg[i] : 0;
  buf[tid] = v;
  __syncthreads();
  for (int s = 1; s < 256; s <<= 1) {
    int t = (tid >= s) ? buf[tid - s] : 0;
    __syncthreads();
    buf[tid] += t;
    __syncthreads();
  }
  if (i < NN_) off[i] = buf[tid] - v;
  if (tid == 255) bsum[blockIdx.x] = buf[255];
}

__global__ void scanB_kernel(int* __restrict__ bsum) {
  const int NBLK = (NN_ + 255) / 256;
  __shared__ int buf[128];
  int tid = threadIdx.x;
  int v = (tid < NBLK) ? bsum[tid] : 0;
  buf[tid] = v;
  __syncthreads();
  for (int s = 1; s < 128; s <<= 1) {
    int t = (tid >= s) ? buf[tid - s] : 0;
    __syncthreads();
    buf[tid] += t;
    __syncthreads();
  }
  if (tid < NBLK) bsum[tid] = buf[tid] - v;
}

__global__ void scanC_kernel(int* __restrict__ off, const int* __restrict__ bsum) {
  int i = blockIdx.x * 256 + threadIdx.x;
  if (i < NN_) off[i] += bsum[i >> 8];
  if (i == 0) off[NN_] = NE_;
}

__global__ void fill_kernel(const int* __restrict__ EI, const int* __restrict__ off,
                            int* __restrict__ cur, int* __restrict__ eidb,
                            int* __restrict__ jcsr) {
  int e = blockIdx.x * 256 + threadIdx.x;
  if (e >= NE_) return;
  int i = EI[e];
  int p = atomicAdd(&cur[i], 1);
  int pos = off[i] + p;
  eidb[pos] = e;
  jcsr[pos] = EI[NE_ + e];
}

// ---------------- fused edge kernel, CSR order (UNCHANGED from R6) -----
__global__ void __launch_bounds__(256, 5) edge_kernel(
    const float* __restrict__ edgef, const float* __restrict__ coords,
    const int* __restrict__ EI, const int* __restrict__ eidb,
    const float* __restrict__ We1, const float* __restrict__ be1,
    const float* __restrict__ be2, const u16* __restrict__ we2b,
    const float* __restrict__ Wue, const float* __restrict__ bue,
    const u16* __restrict__ srcb, const u16* __restrict__ dstb,
    float* __restrict__ scores, float* __restrict__ outE) {
  __shared__ __align__(16) float regA[2816];
  __shared__ __align__(16) float ers[32 * 132];
  __shared__ float bue_s[EOUTF];
  __shared__ int ii[32], jj[32], ee[32];

  float* xs   = regA;                 // [32][20], cols 0..16 used
  u16*   hbf  = (u16*)(regA + 640);   // [32][136]
  float* wue_s= regA;                 // [16][132], valid after overlay barrier

  int tid = threadIdx.x;
  int bid = blockIdx.x;
  int bswz = (bid & 7) * (NE_ / 32 / 8) + (bid >> 3);
  int p0 = bswz * 32;

  if (tid < 32) {
    int p = p0 + tid;
    int e = eidb[p];
    ee[tid] = e;
    int i = EI[e], j = EI[NE_ + e];
    ii[tid] = i; jj[tid] = j;
    float dx = coords[i * 3 + 0] - coords[j * 3 + 0];
    float dy = coords[i * 3 + 1] - coords[j * 3 + 1];
    float dz = coords[i * 3 + 2] - coords[j * 3 + 2];
    float dist = sqrtf(dx * dx + dy * dy + dz * dz + 1e-12f) * 0.1f;
    xs[tid * 20 + 16] = dist;
  }
  if (tid < EOUTF) bue_s[tid] = bue[tid];
  __syncthreads();

  if (tid < 128) {
    int r = tid >> 2, c4 = (tid & 3) * 4;
    *(float4*)&xs[r * 20 + c4] = *(const float4*)&edgef[(size_t)ee[r] * EINF + c4];
  }
  __syncthreads();

  int cg = tid & 31, rg = tid >> 5, c0 = cg * 4, r0 = rg * 4;

  {
    float acc[4][4] = {};
    for (int k = 0; k < 16; k += 4) {
      float4 w0 = *(const float4*)&We1[(size_t)(k + 0) * DIM + c0];
      float4 w1 = *(const float4*)&We1[(size_t)(k + 1) * DIM + c0];
      float4 w2 = *(const float4*)&We1[(size_t)(k + 2) * DIM + c0];
      float4 w3 = *(const float4*)&We1[(size_t)(k + 3) * DIM + c0];
#pragma unroll
      for (int u = 0; u < 4; ++u) {
        float4 xv = *(const float4*)&xs[(r0 + u) * 20 + k];
        acc[u][0] += xv.x * w0.x + xv.y * w1.x + xv.z * w2.x + xv.w * w3.x;
        acc[u][1] += xv.x * w0.y + xv.y * w1.y + xv.z * w2.y + xv.w * w3.y;
        acc[u][2] += xv.x * w0.z + xv.y * w1.z + xv.z * w2.z + xv.w * w3.z;
        acc[u][3] += xv.x * w0.w + xv.y * w1.w + xv.z * w2.w + xv.w * w3.w;
      }
    }
    {   // k = 16: the dist column
      float4 w4 = *(const float4*)&We1[(size_t)16 * DIM + c0];
#pragma unroll
      for (int u = 0; u < 4; ++u) {
        float xd = xs[(r0 + u) * 20 + 16];
        acc[u][0] += xd * w4.x; acc[u][1] += xd * w4.y;
        acc[u][2] += xd * w4.z; acc[u][3] += xd * w4.w;
      }
    }
    float4 b1 = *(const float4*)&be1[c0];
#pragma unroll
    for (int u = 0; u < 4; ++u) {
      float h0 = acc[u][0] + b1.x, h1 = acc[u][1] + b1.y;
      float h2 = acc[u][2] + b1.z, h3 = acc[u][3] + b1.w;
      h0 = h0 > 0.f ? h0 : 0.01f * h0; h1 = h1 > 0.f ? h1 : 0.01f * h1;
      h2 = h2 > 0.f ? h2 : 0.01f * h2; h3 = h3 > 0.f ? h3 : 0.01f * h3;
      ushort4 pk; pk.x = f2bf(h0); pk.y = f2bf(h1); pk.z = f2bf(h2); pk.w = f2bf(h3);
      *(ushort4*)&hbf[(r0 + u) * 136 + c0] = pk;
    }
  }
  __syncthreads();

  int wv = tid >> 6, lane = tid & 63;
  int mtile = wv & 1, nhalf = wv >> 1;
  int quad = lane >> 4, lrow = lane & 15;
  int m0 = mtile * 16;

  short8 afrag[4];
#pragma unroll
  for (int s = 0; s < 4; ++s)
    afrag[s] = *(const short8*)&hbf[(m0 + lrow) * 136 + s * 32 + quad * 8];
  __syncthreads();

  for (int idx = tid; idx < 16 * DIM; idx += 256) {
    int oc = idx >> 7, k = idx & 127;
    wue_s[oc * 132 + k] = Wue[(size_t)k * EOUTF + oc];
  }

  floatx4 dacc[4];
#pragma unroll
  for (int t = 0; t < 4; ++t) dacc[t] = (floatx4){0.f, 0.f, 0.f, 0.f};
#pragma unroll
  for (int s = 0; s < 4; ++s) {
#pragma unroll
    for (int t = 0; t < 4; ++t) {
      int T = nhalf * 4 + t;
      short8 bfrg = *(const short8*)&we2b[(size_t)((T * 4 + s) * 64 + lane) * 8];
      dacc[t] = __builtin_amdgcn_mfma_f32_16x16x32_bf16(afrag[s], bfrg, dacc[t], 0, 0, 0);
    }
  }

#pragma unroll
  for (int t = 0; t < 4; ++t) {
    int col = nhalf * 64 + t * 16 + lrow;
    float b2v = be2[col];
#pragma unroll
    for (int r = 0; r < 4; ++r) {
      int erow = m0 + quad * 4 + r;
      ers[erow * 132 + col] = dacc[t][r] + b2v;
    }
  }
  __syncthreads();

  {
    int el2 = tid >> 3, cb2 = tid & 7;
    int c0b = cb2 * 16;
    int irow = ii[el2], jrow = jj[el2];
    ushort8v dv8a = *(const ushort8v*)&dstb[(size_t)irow * DIM + c0b];
    ushort8v dv8b = *(const ushort8v*)&dstb[(size_t)irow * DIM + c0b + 8];
    ushort8v sv8a = *(const ushort8v*)&srcb[(size_t)jrow * DIM + c0b];
    ushort8v sv8b = *(const ushort8v*)&srcb[(size_t)jrow * DIM + c0b + 8];

    float ef[16];
#pragma unroll
    for (int q = 0; q < 4; ++q) {
      float4 v = *(const float4*)&ers[el2 * 132 + c0b + q * 4];
      ef[q * 4 + 0] = v.x; ef[q * 4 + 1] = v.y;
      ef[q * 4 + 2] = v.z; ef[q * 4 + 3] = v.w;
    }
    float asum = 0.f;
#pragma unroll
    for (int k = 0; k < 8; ++k) {
      float er = bf2f((u16)dv8a[k]) * bf2f((u16)sv8a[k]) * ef[k] * RSQRT_DH;
      ef[k] = er; asum += fabsf(er);
    }
#pragma unroll
    for (int k = 0; k < 8; ++k) {
      float er = bf2f((u16)dv8b[k]) * bf2f((u16)sv8b[k]) * ef[8 + k] * RSQRT_DH;
      ef[8 + k] = er; asum += fabsf(er);
    }
#pragma unroll
    for (int q = 0; q < 4; ++q) {
      float4 v; v.x = ef[q * 4 + 0]; v.y = ef[q * 4 + 1];
      v.z = ef[q * 4 + 2]; v.w = ef[q * 4 + 3];
      *(float4*)&ers[el2 * 132 + c0b + q * 4] = v;
    }
    asum += __shfl_xor(asum, 1);
    if ((cb2 & 1) == 0)
      scores[(size_t)(p0 + el2) * 4 + (cb2 >> 1)] = asum;
  }
  __syncthreads();

  int el = tid >> 3, oc2 = (tid & 7) * 2;
  float a0 = 0.f, a1 = 0.f;
  for (int k = 0; k < DIM; k += 4) {
    float4 e4 = *(const float4*)&ers[el * 132 + k];
    float4 w0 = *(const float4*)&wue_s[oc2 * 132 + k];
    float4 w1 = *(const float4*)&wue_s[(oc2 + 1) * 132 + k];
    a0 += e4.x * w0.x + e4.y * w0.y + e4.z * w0.z + e4.w * w0.w;
    a1 += e4.x * w1.x + e4.y * w1.y + e4.z * w1.z + e4.w * w1.w;
  }
  size_t ob = (size_t)ee[el] * EOUTF + oc2;
  float2 o2; o2.x = a0 + bue_s[oc2]; o2.y = a1 + bue_s[oc2 + 1];
  *(float2*)&outE[ob] = o2;
}

// ---------------- per-node softmax + aggregation (CSR gather) -----------
// v2: lane covers column pair (2l, 2l+1) -- both always in head l>>4 --
// so the serial loop does 1 exp + 1 ushort2 load (was 2 exp + 2 scalar).
__global__ void __launch_bounds__(256) agg_kernel(
    const u16* __restrict__ valb, const float* __restrict__ scores,
    const int* __restrict__ off, const int* __restrict__ jcsr,
    float* __restrict__ agg) {
  int n = blockIdx.x * 4 + (threadIdx.x >> 6);
  int l = threadIdx.x & 63;
  if (n >= NN_) return;
  int s = off[n], e_end = off[n + 1];

  float m0 = -1e30f, m1 = -1e30f, m2 = -1e30f, m3 = -1e30f;
  for (int p = s + l; p < e_end; p += 64) {
    float4 sc = *(const float4*)&scores[(size_t)p * 4];
    m0 = fmaxf(m0, sc.x); m1 = fmaxf(m1, sc.y);
    m2 = fmaxf(m2, sc.z); m3 = fmaxf(m3, sc.w);
  }
#pragma unroll
  for (int d = 1; d < 64; d <<= 1) {
    m0 = fmaxf(m0, __shfl_xor(m0, d)); m1 = fmaxf(m1, __shfl_xor(m1, d));
    m2 = fmaxf(m2, __shfl_xor(m2, d)); m3 = fmaxf(m3, __shfl_xor(m3, d));
  }
  int hh = l >> 4;            // head of cols (2l, 2l+1)
  float mh = (hh == 0) ? m0 : (hh == 1) ? m1 : (hh == 2) ? m2 : m3;

  float acc0 = 0.f, acc1 = 0.f, den = 0.f;
  int p = s;
  for (; p + 2 <= e_end; p += 2) {
    int j0 = jcsr[p], j1 = jcsr[p + 1];
    float s0 = scores[(size_t)p * 4 + hh];
    float s1 = scores[(size_t)(p + 1) * 4 + hh];
    ushort2 u0 = *(const ushort2*)&valb[(size_t)j0 * DIM + 2 * l];
    ushort2 u1 = *(const ushort2*)&valb[(size_t)j1 * DIM + 2 * l];
    float e0 = __expf(s0 - mh), e1 = __expf(s1 - mh);
    den += e0 + e1;
    acc0 += e0 * bf2f(u0.x) + e1 * bf2f(u1.x);
    acc1 += e0 * bf2f(u0.y) + e1 * bf2f(u1.y);
  }
  if (p < e_end) {
    int j = jcsr[p];
    float s0 = scores[(size_t)p * 4 + hh];
    ushort2 u0 = *(const ushort2*)&valb[(size_t)j * DIM + 2 * l];
    float e0 = __expf(s0 - mh);
    den += e0;
    acc0 += e0 * bf2f(u0.x);
    acc1 += e0 * bf2f(u0.y);
  }
  float2 o;
  if (e_end > s) { o.x = acc0 / den; o.y = acc1 / den; }
  else { o.x = 0.f; o.y = 0.f; }
  *(float2*)&agg[(size_t)n * DIM + 2 * l] = o;
}

// ---------------- final GraphNorm apply ----------------
__global__ void gn_apply_kernel(const float* __restrict__ X, const int* __restrict__ batch,
    const int* __restrict__ gstart, const float* __restrict__ gsum,
    const float* __restrict__ gsq, const float* __restrict__ w,
    const float* __restrict__ b, const float* __restrict__ a,
    float* __restrict__ Y) {
  int idx = blockIdx.x * 256 + threadIdx.x;
  if (idx >= NN_ * 32) return;
  int n = idx >> 5, c4 = (idx & 31) * 4;
  int g = batch[n];
  float cnt = fmaxf((float)(gstart[g + 1] - gstart[g]), 1.f);
  float inv = 1.f / cnt;
  float4 xv = *(const float4*)&X[(size_t)n * DIM + c4];
  float4 sm = *(const float4*)&gsum[g * DIM + c4];
  float4 sq = *(const float4*)&gsq[g * DIM + c4];
  float4 av = *(const float4*)&a[c4];
  float4 wv = *(const float4*)&w[c4];
  float4 bv = *(const float4*)&b[c4];
  float4 ov;
  {
    float mean = sm.x * inv, msq = sq.x * inv, am = av.x * mean;
    float var = msq - 2.f * am * mean + am * am;
    ov.x = wv.x * (xv.x - am) * rsqrtf(var + 1e-5f) + bv.x;
  }
  {
    float mean = sm.y * inv, msq = sq.y * inv, am = av.y * mean;
    float var = msq - 2.f * am * mean + am * am;
    ov.y = wv.y * (xv.y - am) * rsqrtf(var + 1e-5f) + bv.y;
  }
  {
    float mean = sm.z * inv, msq = sq.z * inv, am = av.z * mean;
    float var = msq - 2.f * am * mean + am * am;
    ov.z = wv.z * (xv.z - am) * rsqrtf(var + 1e-5f) + bv.z;
  }
  {
    float mean = sm.w * inv, msq = sq.w * inv, am = av.w * mean;
    float var = msq - 2.f * am * mean + am * am;
    ov.w = wv.w * (xv.w - am) * rsqrtf(var + 1e-5f) + bv.w;
  }
  *(float4*)&Y[(size_t)n * DIM + c4] = ov;
}

__global__ void coords_kernel(const float* __restrict__ C, float* __restrict__ O) {
  int i = blockIdx.x * 256 + threadIdx.x;
  if (i < NN_ * 3) O[i] = C[i];
}

// ---------------- launcher ----------------
extern "C" void kernel_launch(void* const* d_in, const int* in_sizes, int n_in,
                              void* d_out, int out_size, void* d_ws, size_t ws_size,
                              hipStream_t stream) {
  (void)in_sizes; (void)n_in; (void)out_size; (void)ws_size;
  const float* node  = (const float*)d_in[0];
  const float* edgef = (const float*)d_in[1];
  const float* coords= (const float*)d_in[2];
  const float* Ws  = (const float*)d_in[3];  const float* bs  = (const float*)d_in[4];
  const float* Wd  = (const float*)d_in[5];  const float* bd  = (const float*)d_in[6];
  const float* Wv  = (const float*)d_in[7];  const float* bv  = (const float*)d_in[8];
  const float* We1 = (const float*)d_in[9];  const float* be1 = (const float*)d_in[10];
  const float* We2 = (const float*)d_in[11]; const float* be2 = (const float*)d_in[12];
  const float* Wun = (const float*)d_in[13]; const float* bun = (const float*)d_in[14];
  const float* Wue = (const float*)d_in[15]; const float* bue = (const float*)d_in[16];
  const float* Wg  = (const float*)d_in[17]; const float* bg  = (const float*)d_in[18];
  const float* Wf1 = (const float*)d_in[19]; const float* bf1 = (const float*)d_in[20];
  const float* Wf2 = (const float*)d_in[21]; const float* bf2 = (const float*)d_in[22];
  const float* g1w = (const float*)d_in[23]; const float* g1b = (const float*)d_in[24];
  const float* g1a = (const float*)d_in[25];
  const float* g2w = (const float*)d_in[26]; const float* g2b = (const float*)d_in[27];
  const float* g2a = (const float*)d_in[28];
  const int* EI    = (const int*)d_in[29];
  const int* batch = (const int*)d_in[30];
  float* out = (float*)d_out;

  int*   wsi = (int*)d_ws;
  float* wsf = (float*)d_ws;
  int* deg    = wsi + W_DEG;
  int* cur    = wsi + W_CUR;
  int* offs   = wsi + W_OFF;
  int* bsum   = wsi + W_BSUM;
  int* gstart = wsi + W_GSTART;
  int* eidb   = wsi + W_EID;
  int* jcsr   = wsi + W_JC;
  float* gsum1 = wsf + W_GSUM1; float* gsq1 = wsf + W_GSQ1;
  float* gsum2 = wsf + W_GSUM2; float* gsq2 = wsf + W_GSQ2;
  float* scores_ = wsf + W_SCORES;
  u16* srcb = (u16*)(wsf + W_SRCB);
  u16* dstb = (u16*)(wsf + W_DSTB);
  u16* valb = (u16*)(wsf + W_VALB);
  float* A = wsf + W_A;   // agg -> x1 -> x2
  float* B = wsf + W_B;   // g
  float* wgc_ = wsf + W_WGC;
  u16*   we2b = (u16*)(wsf + W_WE2B);

  float* outE = out + (size_t)NN_ * DIM;
  float* outC = out + (size_t)NN_ * DIM + (size_t)NE_ * EOUTF;

  // consolidated setup: zero + gstart + Wgc + we2b
  setup_kernel<<<556, 256, 0, stream>>>(wsi, batch, gstart, Wg, wgc_, We2, we2b);
  // CSR build
  deg_kernel<<<(NE_ + 255) / 256, 256, 0, stream>>>(EI, deg);
  scanA_kernel<<<(NN_ + 255) / 256, 256, 0, stream>>>(deg, offs, bsum);
  scanB_kernel<<<1, 128, 0, stream>>>(bsum);
  scanC_kernel<<<(NN_ + 255) / 256, 256, 0, stream>>>(offs, bsum);
  fill_kernel<<<(NE_ + 255) / 256, 256, 0, stream>>>(EI, offs, cur, eidb, jcsr);
  // projections (bf16)
  proj_kernel<<<(NN_ + 31) / 32, 256, 0, stream>>>(node, Ws, bs, Wd, bd, Wv, bv,
                                                   srcb, dstb, valb);
  // edge pipeline in CSR order
  edge_kernel<<<NE_ / 32, 256, 0, stream>>>(edgef, coords, EI, eidb, We1, be1,
                                            be2, we2b, Wue, bue,
                                            srcb, dstb, scores_, outE);
  // A := agg
  agg_kernel<<<NN_ / 4, 256, 0, stream>>>(valb, scores_, offs, jcsr, A);
  // fused: nnew (LDS); B := g, A := x1; gn1 stats accumulated
  nnew_gate_kernel<<<(NN_ + 31) / 32, 256, 0, stream>>>(A, node, batch, Wun, bun,
                                                        wgc_, bg, gsum1, gsq1, B, A);
  // fused: n1 = GN1(x1) inline; t; A := x2; gn2 stats accumulated
  fx_kernel<<<(NN_ + 31) / 32, 256, 0, stream>>>(A, batch, gstart, gsum1, gsq1,
                                                 g1w, g1b, g1a, Wf1, bf1, Wf2, bf2,
                                                 B, gsum2, gsq2, A);
  gn_apply_kernel<<<(NN_ * 32 + 255) / 256, 256, 0, stream>>>(
      A, batch, gstart, gsum2, gsq2, g2w, g2b, g2a, out);
  coords_kernel<<<(NN_ * 3 + 255) / 256, 256, 0, stream>>>(coords, outC);
}

// Round 10
// 573.967 us; speedup vs baseline: 1.3472x; 1.0555x over previous
//
#include <hip/hip_runtime.h>
#include <hip/hip_bf16.h>

#define NN_ 30000
#define NE_ 480000
#define DIM 128
#define EINF 16
#define EOUTF 16
#define NG 64
#define RSQRT_DH 0.17677669529663687f

typedef unsigned short u16;
typedef __attribute__((ext_vector_type(8))) short short8;
typedef __attribute__((ext_vector_type(8))) unsigned short ushort8v;
typedef __attribute__((ext_vector_type(4))) float floatx4;

// ---------------- workspace layout (32-bit word offsets) ----------------
#define W_DEG     0
#define W_CUR     30000
#define W_GSUM1   60000
#define W_GSQ1    68192
#define W_GSUM2   76384
#define W_GSQ2    84576
#define W_ZEND    92768
#define W_OFF     92768
#define W_BSUM    122772
#define W_GSTART  122900
#define W_EID     122968
#define W_JC      602968
#define W_SCORES  1082968
#define W_SRCB    3002968
#define W_DSTB    4922968
#define W_VALB    6842968
#define W_A       8762968
#define W_B       12602968
#define W_C       16442968
#define W_WGC     20282968
#define W_WE2B    20315736
#define W_WPROJ   20323928
// end 20373080 words = 81.5 MB (133 MB proven safe)

static __device__ __forceinline__ u16 f2bf(float x) {
  __hip_bfloat16 h = __float2bfloat16(x);
  return *reinterpret_cast<u16*>(&h);
}
static __device__ __forceinline__ float bf2f(u16 v) {
  unsigned int b = ((unsigned int)v) << 16;
  return __uint_as_float(b);
}

// ---------------- GEMM building blocks (K=128, 32-row tile, 256 thr) ----
static __device__ __forceinline__ void stage32(const float* __restrict__ X,
                                               float* xsb, int row0, int tid) {
#pragma unroll
  for (int t = 0; t < 4; ++t) {
    int idx = tid + t * 256;
    int r = idx >> 5, c4 = (idx & 31) * 4;
    int row = row0 + r;
    float4 v; v.x = v.y = v.z = v.w = 0.f;
    if (row < NN_) v = *(const float4*)&X[(size_t)row * DIM + c4];
    *(float4*)&xsb[r * DIM + c4] = v;
  }
}

static __device__ __forceinline__ void mm_k128(const float* xsb, int ld,
                                               const float* __restrict__ W,
                                               float acc[4][4], int tid) {
  int cg = tid & 31, rg = tid >> 5;
  int c0 = cg * 4, r0 = rg * 4;
  for (int k = 0; k < 128; k += 4) {
    float4 w0 = *(const float4*)&W[(size_t)(k + 0) * DIM + c0];
    float4 w1 = *(const float4*)&W[(size_t)(k + 1) * DIM + c0];
    float4 w2 = *(const float4*)&W[(size_t)(k + 2) * DIM + c0];
    float4 w3 = *(const float4*)&W[(size_t)(k + 3) * DIM + c0];
#pragma unroll
    for (int u = 0; u < 4; ++u) {
      float4 xv = *(const float4*)&xsb[(r0 + u) * ld + k];
      acc[u][0] += xv.x * w0.x + xv.y * w1.x + xv.z * w2.x + xv.w * w3.x;
      acc[u][1] += xv.x * w0.y + xv.y * w1.y + xv.z * w2.y + xv.w * w3.y;
      acc[u][2] += xv.x * w0.z + xv.y * w1.z + xv.z * w2.z + xv.w * w3.z;
      acc[u][3] += xv.x * w0.w + xv.y * w1.w + xv.z * w2.w + xv.w * w3.w;
    }
  }
}

// per-tile column reduce of a 32xDIM LDS tile into per-graph sum/sumsq
static __device__ __forceinline__ void tile_gn_stats(const float* xsb,
    const int* bg_s, int row0, int tid,
    float* __restrict__ gsum, float* __restrict__ gsq) {
  int c = tid & 127, half = tid >> 7;
  float sm = 0.f, sq = 0.f;
  int gcur = -1;
  for (int r = 0; r < 16; ++r) {
    int rl = half * 16 + r;
    int row = row0 + rl;
    if (row >= NN_) break;
    int g = bg_s[rl];
    float v = xsb[rl * DIM + c];
    if (g != gcur) {
      if (gcur >= 0) {
        atomicAdd(&gsum[gcur * DIM + c], sm);
        atomicAdd(&gsq[gcur * DIM + c], sq);
      }
      gcur = g; sm = 0.f; sq = 0.f;
    }
    sm += v; sq += v * v;
  }
  if (gcur >= 0) {
    atomicAdd(&gsum[gcur * DIM + c], sm);
    atomicAdd(&gsq[gcur * DIM + c], sq);
  }
}

// ---------------- consolidated setup kernel ----------------
// b0: gstart; b1..128: Wgc; b129..192: we2b; b193..576: proj W hi/lo frags
// (workspace zeroing moved to hipMemsetAsync)
__global__ void setup_kernel(const int* __restrict__ batch, int* __restrict__ gstart,
                             const float* __restrict__ Wg, float* __restrict__ Wgc,
                             const float* __restrict__ We2, u16* __restrict__ we2b,
                             const float* __restrict__ Ws, const float* __restrict__ Wd,
                             const float* __restrict__ Wv, u16* __restrict__ wproj) {
  int b = blockIdx.x, tid = threadIdx.x;
  if (b == 0) {
    int g = tid;
    if (g <= NG) {
      int lo = 0, hi = NN_;
      while (lo < hi) { int mid = (lo + hi) >> 1; if (batch[mid] < g) lo = mid + 1; else hi = mid; }
      gstart[g] = lo;
    }
  } else if (b < 129) {
    int idx = (b - 1) * 256 + tid;   // 32768 elems
    int k = idx >> 7, c = idx & 127;
    float v;
    if (k < 128) v = Wg[(size_t)k * DIM + c] + Wg[(size_t)(256 + k) * DIM + c];
    else { int kk = k - 128; v = Wg[(size_t)(128 + kk) * DIM + c] - Wg[(size_t)(256 + kk) * DIM + c]; }
    Wgc[idx] = v;
  } else if (b < 193) {
    int idx = (b - 129) * 256 + tid;   // 16384 elems
    int j = idx & 7, lane = (idx >> 3) & 63, s = (idx >> 9) & 3, T = idx >> 11;
    int k = s * 32 + ((lane >> 4) << 3) + j;
    int n = T * 16 + (lane & 15);
    we2b[idx] = f2bf(We2[(size_t)k * DIM + n]);
  } else {
    int idx = (b - 193) * 256 + tid;   // 98304 elems: 3 mats x {hi,lo} x 16384
    int which = idx >> 14;             // 0..5: (mat<<1)|lo
    int sub = idx & 16383;
    int j = sub & 7, lane = (sub >> 3) & 63, s = (sub >> 9) & 3, T = sub >> 11;
    int k = s * 32 + ((lane >> 4) << 3) + j;
    int n = T * 16 + (lane & 15);
    int mat = which >> 1;
    const float* Wsrc = (mat == 0) ? Ws : (mat == 1) ? Wd : Wv;
    float w = Wsrc[(size_t)k * DIM + n];
    u16 h = f2bf(w);
    u16 o = (which & 1) ? f2bf(w - bf2f(h)) : h;
    wproj[which * 16384 + sub] = o;
  }
}

__global__ void deg_kernel(const int* __restrict__ EI, int* __restrict__ deg) {
  int e = blockIdx.x * 256 + threadIdx.x;
  if (e < NE_) atomicAdd(&deg[EI[e]], 1);
}

// ---------------- node projections via MFMA (bf16x2 split) --------------
// Y = node @ W + b for W in {Ws,Wd,Wv}, outputs bf16. A split hi/lo in LDS;
// W prepped hi/lo in fragment-linear layout; 3-product MFMA (AhBh+AlBh+AhBl)
// keeps precision ~f32 before the final bf16 round. Fragment layouts are the
// ones proven in edge_kernel (A-frag / we2b B-frag / ers C-park).
__global__ void __launch_bounds__(256) proj_kernel(
    const float* __restrict__ node, const u16* __restrict__ wproj,
    const float* __restrict__ bs, const float* __restrict__ bd,
    const float* __restrict__ bv,
    u16* __restrict__ srcb, u16* __restrict__ dstb, u16* __restrict__ valb) {
  __shared__ __align__(16) u16 ah[32 * 136];
  __shared__ __align__(16) u16 al[32 * 136];
  __shared__ __align__(16) float park[32 * 132];
  int tid = threadIdx.x, row0 = blockIdx.x * 32;
  int r2 = tid >> 3, c16 = (tid & 7) * 16;

  // stage node tile + hi/lo split: thread -> (row r2, 16 cols at c16)
  {
    int row = row0 + r2;
    float v[16];
    if (row < NN_) {
#pragma unroll
      for (int q = 0; q < 4; ++q) {
        float4 x = *(const float4*)&node[(size_t)row * DIM + c16 + q * 4];
        v[q * 4 + 0] = x.x; v[q * 4 + 1] = x.y;
        v[q * 4 + 2] = x.z; v[q * 4 + 3] = x.w;
      }
    } else {
#pragma unroll
      for (int q = 0; q < 16; ++q) v[q] = 0.f;
    }
#pragma unroll
    for (int h2 = 0; h2 < 2; ++h2) {
      ushort8v hh, ll;
#pragma unroll
      for (int q = 0; q < 8; ++q) {
        float x = v[h2 * 8 + q];
        u16 h = f2bf(x);
        hh[q] = h;
        ll[q] = f2bf(x - bf2f(h));
      }
      *(ushort8v*)&ah[r2 * 136 + c16 + h2 * 8] = hh;
      *(ushort8v*)&al[r2 * 136 + c16 + h2 * 8] = ll;
    }
  }
  __syncthreads();

  int wv_ = tid >> 6, lane = tid & 63;
  int mtile = wv_ & 1, nhalf = wv_ >> 1;
  int quad = lane >> 4, lrow = lane & 15;
  int m0 = mtile * 16;

  short8 afh[4], afl[4];
#pragma unroll
  for (int s = 0; s < 4; ++s) {
    afh[s] = *(const short8*)&ah[(m0 + lrow) * 136 + s * 32 + quad * 8];
    afl[s] = *(const short8*)&al[(m0 + lrow) * 136 + s * 32 + quad * 8];
  }

  const float* Bt[3] = {bs, bd, bv};
  u16* Yt[3] = {srcb, dstb, valb};
#pragma unroll 1
  for (int g3 = 0; g3 < 3; ++g3) {
    const u16* wh = wproj + (size_t)(g3 * 2 + 0) * 16384;
    const u16* wl = wproj + (size_t)(g3 * 2 + 1) * 16384;
    floatx4 dacc[4];
#pragma unroll
    for (int t = 0; t < 4; ++t) dacc[t] = (floatx4){0.f, 0.f, 0.f, 0.f};
#pragma unroll
    for (int s = 0; s < 4; ++s) {
#pragma unroll
      for (int t = 0; t < 4; ++t) {
        int T = nhalf * 4 + t;
        size_t off = (size_t)((T * 4 + s) * 64 + lane) * 8;
        short8 bh = *(const short8*)&wh[off];
        short8 bl = *(const short8*)&wl[off];
        dacc[t] = __builtin_amdgcn_mfma_f32_16x16x32_bf16(afh[s], bh, dacc[t], 0, 0, 0);
        dacc[t] = __builtin_amdgcn_mfma_f32_16x16x32_bf16(afl[s], bh, dacc[t], 0, 0, 0);
        dacc[t] = __builtin_amdgcn_mfma_f32_16x16x32_bf16(afh[s], bl, dacc[t], 0, 0, 0);
      }
    }
    // park C (proven ers pattern: 2-way bank alias = free)
#pragma unroll
    for (int t = 0; t < 4; ++t) {
      int col = nhalf * 64 + t * 16 + lrow;
#pragma unroll
      for (int r = 0; r < 4; ++r)
        park[(m0 + quad * 4 + r) * 132 + col] = dacc[t][r];
    }
    __syncthreads();
    // pass 2: +bias, bf16, row-contiguous 16B stores
    {
      int row = row0 + r2;
      if (row < NN_) {
#pragma unroll
        for (int h2 = 0; h2 < 2; ++h2) {
          ushort8v o;
#pragma unroll
          for (int q = 0; q < 8; ++q) {
            float pv = park[r2 * 132 + c16 + h2 * 8 + q] + Bt[g3][c16 + h2 * 8 + q];
            o[q] = f2bf(pv);
          }
          *(ushort8v*)&Yt[g3][(size_t)row * DIM + c16 + h2 * 8] = o;
        }
      }
    }
    __syncthreads();
  }
}

// ---------------- fused node_new GEMM + gate + gn1 stats ----------------
__global__ void __launch_bounds__(256) nnew_gate_kernel(
    const float* __restrict__ AGG, const float* __restrict__ NODE,
    const int* __restrict__ batch,
    const float* __restrict__ Wun, const float* __restrict__ bun,
    const float* __restrict__ Wgc, const float* __restrict__ bg,
    float* __restrict__ gsum1, float* __restrict__ gsq1,
    float* __restrict__ G, float* __restrict__ X1) {
  __shared__ __align__(16) float xs0[32 * DIM];   // agg -> nnew
  __shared__ __align__(16) float xs1[32 * DIM];   // node -> x1
  __shared__ int bg_s[32];
  int tid = threadIdx.x, row0 = blockIdx.x * 32;
  stage32(AGG, xs0, row0, tid);
  stage32(NODE, xs1, row0, tid);
  if (tid < 32) {
    int row = row0 + tid;
    bg_s[tid] = (row < NN_) ? batch[row] : 0;
  }
  __syncthreads();
  int cg = tid & 31, rg = tid >> 5, c0 = cg * 4, r0 = rg * 4;
  {
    float acc[4][4] = {};
    mm_k128(xs0, DIM, Wun, acc, tid);
    __syncthreads();            // all xs0 (agg) reads done
    float4 bv = *(const float4*)&bun[c0];
#pragma unroll
    for (int u = 0; u < 4; ++u) {
      float4 ov; ov.x = acc[u][0] + bv.x; ov.y = acc[u][1] + bv.y;
      ov.z = acc[u][2] + bv.z; ov.w = acc[u][3] + bv.w;
      *(float4*)&xs0[(r0 + u) * DIM + c0] = ov;   // nnew tile
    }
  }
  __syncthreads();
  float acc[4][4] = {};
  mm_k128(xs0, DIM, Wgc, acc, tid);
  mm_k128(xs1, DIM, Wgc + 128 * DIM, acc, tid);
  float4 bv = *(const float4*)&bg[c0];
  float4 xvv[4];
#pragma unroll
  for (int u = 0; u < 4; ++u) {
    int row = row0 + r0 + u;
    float z0 = acc[u][0] + bv.x, z1 = acc[u][1] + bv.y;
    float z2 = acc[u][2] + bv.z, z3 = acc[u][3] + bv.w;
    float g0 = 1.f / (1.f + __expf(-z0));
    float g1 = 1.f / (1.f + __expf(-z1));
    float g2 = 1.f / (1.f + __expf(-z2));
    float g3 = 1.f / (1.f + __expf(-z3));
    float4 nn4 = *(const float4*)&xs0[(r0 + u) * DIM + c0];
    float4 nd4 = *(const float4*)&xs1[(r0 + u) * DIM + c0];
    float4 gv; gv.x = g0; gv.y = g1; gv.z = g2; gv.w = g3;
    float4 xv; xv.x = g0 * nn4.x + nd4.x; xv.y = g1 * nn4.y + nd4.y;
    xv.z = g2 * nn4.z + nd4.z; xv.w = g3 * nn4.w + nd4.w;
    xvv[u] = xv;
    if (row < NN_) {
      *(float4*)&G[(size_t)row * DIM + c0] = gv;
      *(float4*)&X1[(size_t)row * DIM + c0] = xv;
    }
  }
  __syncthreads();   // all xs1 (node) reads done -> reuse for x1 tile
#pragma unroll
  for (int u = 0; u < 4; ++u)
    *(float4*)&xs1[(r0 + u) * DIM + c0] = xvv[u];
  __syncthreads();
  tile_gn_stats(xs1, bg_s, row0, tid, gsum1, gsq1);
}

// ---------------- fused fix_node + gn_apply1(inline) + gn2 stats --------
__global__ void __launch_bounds__(256) fx_kernel(
    const float* __restrict__ X1, const int* __restrict__ batch,
    const int* __restrict__ gstart,
    const float* __restrict__ gsum1, const float* __restrict__ gsq1,
    const float* __restrict__ g1w, const float* __restrict__ g1b,
    const float* __restrict__ g1a,
    const float* __restrict__ Wf1, const float* __restrict__ bf1,
    const float* __restrict__ Wf2, const float* __restrict__ bf2,
    const float* __restrict__ G,
    float* __restrict__ gsum2, float* __restrict__ gsq2,
    float* __restrict__ X2) {
  __shared__ __align__(16) float xs0[32 * DIM];   // x1 -> n1
  __shared__ __align__(16) float xs1[32 * DIM];   // t -> x2
  __shared__ int bg_s[32];
  int tid = threadIdx.x, row0 = blockIdx.x * 32;
  stage32(X1, xs0, row0, tid);
  if (tid < 32) {
    int row = row0 + tid;
    bg_s[tid] = (row < NN_) ? batch[row] : 0;
  }
  __syncthreads();
  int cg = tid & 31, rg = tid >> 5, c0 = cg * 4, r0 = rg * 4;
#pragma unroll
  for (int u = 0; u < 4; ++u) {
    int rl = r0 + u, row = row0 + rl;
    if (row >= NN_) continue;
    int g = bg_s[rl];
    float cnt = fmaxf((float)(gstart[g + 1] - gstart[g]), 1.f);
    float inv = 1.f / cnt;
    float4 xv = *(const float4*)&xs0[rl * DIM + c0];
    float4 sm = *(const float4*)&gsum1[g * DIM + c0];
    float4 sq = *(const float4*)&gsq1[g * DIM + c0];
    float4 av = *(const float4*)&g1a[c0];
    float4 wv = *(const float4*)&g1w[c0];
    float4 bvv = *(const float4*)&g1b[c0];
    float4 ov;
    {
      float mean = sm.x * inv, msq = sq.x * inv, am = av.x * mean;
      float var = msq - 2.f * am * mean + am * am;
      ov.x = wv.x * (xv.x - am) * rsqrtf(var + 1e-5f) + bvv.x;
    }
    {
      float mean = sm.y * inv, msq = sq.y * inv, am = av.y * mean;
      float var = msq - 2.f * am * mean + am * am;
      ov.y = wv.y * (xv.y - am) * rsqrtf(var + 1e-5f) + bvv.y;
    }
    {
      float mean = sm.z * inv, msq = sq.z * inv, am = av.z * mean;
      float var = msq - 2.f * am * mean + am * am;
      ov.z = wv.z * (xv.z - am) * rsqrtf(var + 1e-5f) + bvv.z;
    }
    {
      float mean = sm.w * inv, msq = sq.w * inv, am = av.w * mean;
      float var = msq - 2.f * am * mean + am * am;
      ov.w = wv.w * (xv.w - am) * rsqrtf(var + 1e-5f) + bvv.w;
    }
    *(float4*)&xs0[rl * DIM + c0] = ov;   // n1 tile
  }
  __syncthreads();
  {
    float acc[4][4] = {};
    mm_k128(xs0, DIM, Wf1, acc, tid);
    float4 bv = *(const float4*)&bf1[c0];
#pragma unroll
    for (int u = 0; u < 4; ++u) {
      float t0 = acc[u][0] + bv.x, t1 = acc[u][1] + bv.y;
      float t2 = acc[u][2] + bv.z, t3 = acc[u][3] + bv.w;
      t0 = t0 > 0.f ? t0 : 0.01f * t0; t1 = t1 > 0.f ? t1 : 0.01f * t1;
      t2 = t2 > 0.f ? t2 : 0.01f * t2; t3 = t3 > 0.f ? t3 : 0.01f * t3;
      float4 ov; ov.x = t0; ov.y = t1; ov.z = t2; ov.w = t3;
      *(float4*)&xs1[(r0 + u) * DIM + c0] = ov;
    }
  }
  __syncthreads();
  float acc[4][4] = {};
  mm_k128(xs1, DIM, Wf2, acc, tid);
  float4 bv = *(const float4*)&bf2[c0];
  float4 x2v[4];
#pragma unroll
  for (int u = 0; u < 4; ++u) {
    int row = row0 + r0 + u;
    float4 nv = *(const float4*)&xs0[(r0 + u) * DIM + c0];
    float4 gv; gv.x = gv.y = gv.z = gv.w = 0.f;
    if (row < NN_) gv = *(const float4*)&G[(size_t)row * DIM + c0];
    float4 ov;
    ov.x = gv.x * (acc[u][0] + bv.x) + nv.x;
    ov.y = gv.y * (acc[u][1] + bv.y) + nv.y;
    ov.z = gv.z * (acc[u][2] + bv.z) + nv.z;
    ov.w = gv.w * (acc[u][3] + bv.w) + nv.w;
    x2v[u] = ov;
    if (row < NN_) *(float4*)&X2[(size_t)row * DIM + c0] = ov;
  }
  __syncthreads();   // all xs1 (t) reads done -> reuse for x2 tile
#pragma unroll
  for (int u = 0; u < 4; ++u)
    *(float4*)&xs1[(r0 + u) * DIM + c0] = x2v[u];
  __syncthreads();
  tile_gn_stats(xs1, bg_s, row0, tid, gsum2, gsq2);
}

// ---------------- CSR build ----------------
__global__ void scanA_kernel(const int* __restrict__ deg, int* __restrict__ off,
                             int* __restrict__ bsum) {
  __shared__ int buf[256];
  int tid = threadIdx.x;
  int i = blockIdx.x * 256 + tid;
  int v = (i < NN_) ? deg[i] : 0;
  buf[tid] = v;
  __syncthreads();
  for (int s = 1; s < 256; s <<= 1) {
    int t = (tid >= s) ? buf[tid - s] : 0;
    __syncthreads();
    buf[tid] += t;
    __syncthreads();
  }
  if (i < NN_) off[i] = buf[tid] - v;
  if (tid == 255) bsum[blockIdx.x] = buf[255];
}

__global__ void scanB_kernel(int* __restrict__ bsum) {
  const int NBLK = (NN_ + 255) / 256;
  __shared__ int buf[128];
  int tid = threadIdx.x;
  int v = (tid < NBLK) ? bsum[tid] : 0;
  buf[tid] = v;
  __syncthreads();
  for (int s = 1; s < 128; s <<= 1) {
    int t = (tid >= s) ? buf[tid - s] : 0;
    __syncthreads();
    buf[tid] += t;
    __syncthreads();
  }
  if (tid < NBLK) bsum[tid] = buf[tid] - v;
}

__global__ void scanC_kernel(int* __restrict__ off, const int* __restrict__ bsum) {
  int i = blockIdx.x * 256 + threadIdx.x;
  if (i < NN_) off[i] += bsum[i >> 8];
  if (i == 0) off[NN_] = NE_;
}

__global__ void fill_kernel(const int* __restrict__ EI, const int* __restrict__ off,
                            int* __restrict__ cur, int* __restrict__ eidb,
                            int* __restrict__ jcsr) {
  int e = blockIdx.x * 256 + threadIdx.x;
  if (e >= NE_) return;
  int i = EI[e];
  int p = atomicAdd(&cur[i], 1);
  int pos = off[i] + p;
  eidb[pos] = e;
  jcsr[pos] = EI[NE_ + e];
}

// ---------------- fused edge kernel, CSR order (UNCHANGED from R6) -----
__global__ void __launch_bounds__(256, 5) edge_kernel(
    const float* __restrict__ edgef, const float* __restrict__ coords,
    const int* __restrict__ EI, const int* __restrict__ eidb,
    const float* __restrict__ We1, const float* __restrict__ be1,
    const float* __restrict__ be2, const u16* __restrict__ we2b,
    const float* __restrict__ Wue, const float* __restrict__ bue,
    const u16* __restrict__ srcb, const u16* __restrict__ dstb,
    float* __restrict__ scores, float* __restrict__ outE) {
  __shared__ __align__(16) float regA[2816];
  __shared__ __align__(16) float ers[32 * 132];
  __shared__ float bue_s[EOUTF];
  __shared__ int ii[32], jj[32], ee[32];

  float* xs   = regA;                 // [32][20], cols 0..16 used
  u16*   hbf  = (u16*)(regA + 640);   // [32][136]
  float* wue_s= regA;                 // [16][132], valid after overlay barrier

  int tid = threadIdx.x;
  int bid = blockIdx.x;
  int bswz = (bid & 7) * (NE_ / 32 / 8) + (bid >> 3);
  int p0 = bswz * 32;

  if (tid < 32) {
    int p = p0 + tid;
    int e = eidb[p];
    ee[tid] = e;
    int i = EI[e], j = EI[NE_ + e];
    ii[tid] = i; jj[tid] = j;
    float dx = coords[i * 3 + 0] - coords[j * 3 + 0];
    float dy = coords[i * 3 + 1] - coords[j * 3 + 1];
    float dz = coords[i * 3 + 2] - coords[j * 3 + 2];
    float dist = sqrtf(dx * dx + dy * dy + dz * dz + 1e-12f) * 0.1f;
    xs[tid * 20 + 16] = dist;
  }
  if (tid < EOUTF) bue_s[tid] = bue[tid];
  __syncthreads();

  if (tid < 128) {
    int r = tid >> 2, c4 = (tid & 3) * 4;
    *(float4*)&xs[r * 20 + c4] = *(const float4*)&edgef[(size_t)ee[r] * EINF + c4];
  }
  __syncthreads();

  int cg = tid & 31, rg = tid >> 5, c0 = cg * 4, r0 = rg * 4;

  {
    float acc[4][4] = {};
    for (int k = 0; k < 16; k += 4) {
      float4 w0 = *(const float4*)&We1[(size_t)(k + 0) * DIM + c0];
      float4 w1 = *(const float4*)&We1[(size_t)(k + 1) * DIM + c0];
      float4 w2 = *(const float4*)&We1[(size_t)(k + 2) * DIM + c0];
      float4 w3 = *(const float4*)&We1[(size_t)(k + 3) * DIM + c0];
#pragma unroll
      for (int u = 0; u < 4; ++u) {
        float4 xv = *(const float4*)&xs[(r0 + u) * 20 + k];
        acc[u][0] += xv.x * w0.x + xv.y * w1.x + xv.z * w2.x + xv.w * w3.x;
        acc[u][1] += xv.x * w0.y + xv.y * w1.y + xv.z * w2.y + xv.w * w3.y;
        acc[u][2] += xv.x * w0.z + xv.y * w1.z + xv.z * w2.z + xv.w * w3.z;
        acc[u][3] += xv.x * w0.w + xv.y * w1.w + xv.z * w2.w + xv.w * w3.w;
      }
    }
    {   // k = 16: the dist column
      float4 w4 = *(const float4*)&We1[(size_t)16 * DIM + c0];
#pragma unroll
      for (int u = 0; u < 4; ++u) {
        float xd = xs[(r0 + u) * 20 + 16];
        acc[u][0] += xd * w4.x; acc[u][1] += xd * w4.y;
        acc[u][2] += xd * w4.z; acc[u][3] += xd * w4.w;
      }
    }
    float4 b1 = *(const float4*)&be1[c0];
#pragma unroll
    for (int u = 0; u < 4; ++u) {
      float h0 = acc[u][0] + b1.x, h1 = acc[u][1] + b1.y;
      float h2 = acc[u][2] + b1.z, h3 = acc[u][3] + b1.w;
      h0 = h0 > 0.f ? h0 : 0.01f * h0; h1 = h1 > 0.f ? h1 : 0.01f * h1;
      h2 = h2 > 0.f ? h2 : 0.01f * h2; h3 = h3 > 0.f ? h3 : 0.01f * h3;
      ushort4 pk; pk.x = f2bf(h0); pk.y = f2bf(h1); pk.z = f2bf(h2); pk.w = f2bf(h3);
      *(ushort4*)&hbf[(r0 + u) * 136 + c0] = pk;
    }
  }
  __syncthreads();

  int wv = tid >> 6, lane = tid & 63;
  int mtile = wv & 1, nhalf = wv >> 1;
  int quad = lane >> 4, lrow = lane & 15;
  int m0 = mtile * 16;

  short8 afrag[4];
#pragma unroll
  for (int s = 0; s < 4; ++s)
    afrag[s] = *(const short8*)&hbf[(m0 + lrow) * 136 + s * 32 + quad * 8];
  __syncthreads();

  for (int idx = tid; idx < 16 * DIM; idx += 256) {
    int oc = idx >> 7, k = idx & 127;
    wue_s[oc * 132 + k] = Wue[(size_t)k * EOUTF + oc];
  }

  floatx4 dacc[4];
#pragma unroll
  for (int t = 0; t < 4; ++t) dacc[t] = (floatx4){0.f, 0.f, 0.f, 0.f};
#pragma unroll
  for (int s = 0; s < 4; ++s) {
#pragma unroll
    for (int t = 0; t < 4; ++t) {
      int T = nhalf * 4 + t;
      short8 bfrg = *(const short8*)&we2b[(size_t)((T * 4 + s) * 64 + lane) * 8];
      dacc[t] = __builtin_amdgcn_mfma_f32_16x16x32_bf16(afrag[s], bfrg, dacc[t], 0, 0, 0);
    }
  }

#pragma unroll
  for (int t = 0; t < 4; ++t) {
    int col = nhalf * 64 + t * 16 + lrow;
    float b2v = be2[col];
#pragma unroll
    for (int r = 0; r < 4; ++r) {
      int erow = m0 + quad * 4 + r;
      ers[erow * 132 + col] = dacc[t][r] + b2v;
    }
  }
  __syncthreads();

  {
    int el2 = tid >> 3, cb2 = tid & 7;
    int c0b = cb2 * 16;
    int irow = ii[el2], jrow = jj[el2];
    ushort8v dv8a = *(const ushort8v*)&dstb[(size_t)irow * DIM + c0b];
    ushort8v dv8b = *(const ushort8v*)&dstb[(size_t)irow * DIM + c0b + 8];
    ushort8v sv8a = *(const ushort8v*)&srcb[(size_t)jrow * DIM + c0b];
    ushort8v sv8b = *(const ushort8v*)&srcb[(size_t)jrow * DIM + c0b + 8];

    float ef[16];
#pragma unroll
    for (int q = 0; q < 4; ++q) {
      float4 v = *(const float4*)&ers[el2 * 132 + c0b + q * 4];
      ef[q * 4 + 0] = v.x; ef[q * 4 + 1] = v.y;
      ef[q * 4 + 2] = v.z; ef[q * 4 + 3] = v.w;
    }
    float asum = 0.f;
#pragma unroll
    for (int k = 0; k < 8; ++k) {
      float er = bf2f((u16)dv8a[k]) * bf2f((u16)sv8a[k]) * ef[k] * RSQRT_DH;
      ef[k] = er; asum += fabsf(er);
    }
#pragma unroll
    for (int k = 0; k < 8; ++k) {
      float er = bf2f((u16)dv8b[k]) * bf2f((u16)sv8b[k]) * ef[8 + k] * RSQRT_DH;
      ef[8 + k] = er; asum += fabsf(er);
    }
#pragma unroll
    for (int q = 0; q < 4; ++q) {
      float4 v; v.x = ef[q * 4 + 0]; v.y = ef[q * 4 + 1];
      v.z = ef[q * 4 + 2]; v.w = ef[q * 4 + 3];
      *(float4*)&ers[el2 * 132 + c0b + q * 4] = v;
    }
    asum += __shfl_xor(asum, 1);
    if ((cb2 & 1) == 0)
      scores[(size_t)(p0 + el2) * 4 + (cb2 >> 1)] = asum;
  }
  __syncthreads();

  int el = tid >> 3, oc2 = (tid & 7) * 2;
  float a0 = 0.f, a1 = 0.f;
  for (int k = 0; k < DIM; k += 4) {
    float4 e4 = *(const float4*)&ers[el * 132 + k];
    float4 w0 = *(const float4*)&wue_s[oc2 * 132 + k];
    float4 w1 = *(const float4*)&wue_s[(oc2 + 1) * 132 + k];
    a0 += e4.x * w0.x + e4.y * w0.y + e4.z * w0.z + e4.w * w0.w;
    a1 += e4.x * w1.x + e4.y * w1.y + e4.z * w1.z + e4.w * w1.w;
  }
  size_t ob = (size_t)ee[el] * EOUTF + oc2;
  float2 o2; o2.x = a0 + bue_s[oc2]; o2.y = a1 + bue_s[oc2 + 1];
  *(float2*)&outE[ob] = o2;
}

// ---------------- per-node softmax + aggregation (CSR gather) -----------
// lane covers column pair (2l, 2l+1); 4-way unrolled serial loop (deeper
// MLP on the jcsr -> valb dependent-load chain).
__global__ void __launch_bounds__(256) agg_kernel(
    const u16* __restrict__ valb, const float* __restrict__ scores,
    const int* __restrict__ off, const int* __restrict__ jcsr,
    float* __restrict__ agg) {
  int n = blockIdx.x * 4 + (threadIdx.x >> 6);
  int l = threadIdx.x & 63;
  if (n >= NN_) return;
  int s = off[n], e_end = off[n + 1];

  float m0 = -1e30f, m1 = -1e30f, m2 = -1e30f, m3 = -1e30f;
  for (int p = s + l; p < e_end; p += 64) {
    float4 sc = *(const float4*)&scores[(size_t)p * 4];
    m0 = fmaxf(m0, sc.x); m1 = fmaxf(m1, sc.y);
    m2 = fmaxf(m2, sc.z); m3 = fmaxf(m3, sc.w);
  }
#pragma unroll
  for (int d = 1; d < 64; d <<= 1) {
    m0 = fmaxf(m0, __shfl_xor(m0, d)); m1 = fmaxf(m1, __shfl_xor(m1, d));
    m2 = fmaxf(m2, __shfl_xor(m2, d)); m3 = fmaxf(m3, __shfl_xor(m3, d));
  }
  int hh = l >> 4;            // head of cols (2l, 2l+1)
  float mh = (hh == 0) ? m0 : (hh == 1) ? m1 : (hh == 2) ? m2 : m3;

  float acc0 = 0.f, acc1 = 0.f, den = 0.f;
  int p = s;
  for (; p + 4 <= e_end; p += 4) {
    int j0 = jcsr[p], j1 = jcsr[p + 1], j2 = jcsr[p + 2], j3 = jcsr[p + 3];
    float s0 = scores[(size_t)p * 4 + hh];
    float s1 = scores[(size_t)(p + 1) * 4 + hh];
    float s2 = scores[(size_t)(p + 2) * 4 + hh];
    float s3 = scores[(size_t)(p + 3) * 4 + hh];
    ushort2 u0 = *(const ushort2*)&valb[(size_t)j0 * DIM + 2 * l];
    ushort2 u1 = *(const ushort2*)&valb[(size_t)j1 * DIM + 2 * l];
    ushort2 u2 = *(const ushort2*)&valb[(size_t)j2 * DIM + 2 * l];
    ushort2 u3 = *(const ushort2*)&valb[(size_t)j3 * DIM + 2 * l];
    float e0 = __expf(s0 - mh), e1 = __expf(s1 - mh);
    float e2 = __expf(s2 - mh), e3 = __expf(s3 - mh);
    den += (e0 + e1) + (e2 + e3);
    acc0 += e0 * bf2f(u0.x) + e1 * bf2f(u1.x) + e2 * bf2f(u2.x) + e3 * bf2f(u3.x);
    acc1 += e0 * bf2f(u0.y) + e1 * bf2f(u1.y) + e2 * bf2f(u2.y) + e3 * bf2f(u3.y);
  }
  for (; p < e_end; ++p) {
    int j = jcsr[p];
    float s0 = scores[(size_t)p * 4 + hh];
    ushort2 u0 = *(const ushort2*)&valb[(size_t)j * DIM + 2 * l];
    float e0 = __expf(s0 - mh);
    den += e0;
    acc0 += e0 * bf2f(u0.x);
    acc1 += e0 * bf2f(u0.y);
  }
  float2 o;
  if (e_end > s) { o.x = acc0 / den; o.y = acc1 / den; }
  else { o.x = 0.f; o.y = 0.f; }
  *(float2*)&agg[(size_t)n * DIM + 2 * l] = o;
}

// ---------------- final GraphNorm apply + coords copy (merged) ----------
__global__ void gn_apply_kernel(const float* __restrict__ X, const int* __restrict__ batch,
    const int* __restrict__ gstart, const float* __restrict__ gsum,
    const float* __restrict__ gsq, const float* __restrict__ w,
    const float* __restrict__ b, const float* __restrict__ a,
    float* __restrict__ Y,
    const float* __restrict__ C, float* __restrict__ OC) {
  int blk = blockIdx.x;
  if (blk >= (NN_ * 32) / 256) {            // 3750.. : coords copy
    int i = (blk - (NN_ * 32) / 256) * 256 + threadIdx.x;
    if (i < NN_ * 3) OC[i] = C[i];
    return;
  }
  int idx = blk * 256 + threadIdx.x;
  int n = idx >> 5, c4 = (idx & 31) * 4;
  int g = batch[n];
  float cnt = fmaxf((float)(gstart[g + 1] - gstart[g]), 1.f);
  float inv = 1.f / cnt;
  float4 xv = *(const float4*)&X[(size_t)n * DIM + c4];
  float4 sm = *(const float4*)&gsum[g * DIM + c4];
  float4 sq = *(const float4*)&gsq[g * DIM + c4];
  float4 av = *(const float4*)&a[c4];
  float4 wv = *(const float4*)&w[c4];
  float4 bv = *(const float4*)&b[c4];
  float4 ov;
  {
    float mean = sm.x * inv, msq = sq.x * inv, am = av.x * mean;
    float var = msq - 2.f * am * mean + am * am;
    ov.x = wv.x * (xv.x - am) * rsqrtf(var + 1e-5f) + bv.x;
  }
  {
    float mean = sm.y * inv, msq = sq.y * inv, am = av.y * mean;
    float var = msq - 2.f * am * mean + am * am;
    ov.y = wv.y * (xv.y - am) * rsqrtf(var + 1e-5f) + bv.y;
  }
  {
    float mean = sm.z * inv, msq = sq.z * inv, am = av.z * mean;
    float var = msq - 2.f * am * mean + am * am;
    ov.z = wv.z * (xv.z - am) * rsqrtf(var + 1e-5f) + bv.z;
  }
  {
    float mean = sm.w * inv, msq = sq.w * inv, am = av.w * mean;
    float var = msq - 2.f * am * mean + am * am;
    ov.w = wv.w * (xv.w - am) * rsqrtf(var + 1e-5f) + bv.w;
  }
  *(float4*)&Y[(size_t)n * DIM + c4] = ov;
}

// ---------------- launcher ----------------
extern "C" void kernel_launch(void* const* d_in, const int* in_sizes, int n_in,
                              void* d_out, int out_size, void* d_ws, size_t ws_size,
                              hipStream_t stream) {
  (void)in_sizes; (void)n_in; (void)out_size; (void)ws_size;
  const float* node  = (const float*)d_in[0];
  const float* edgef = (const float*)d_in[1];
  const float* coords= (const float*)d_in[2];
  const float* Ws  = (const float*)d_in[3];  const float* bs  = (const float*)d_in[4];
  const float* Wd  = (const float*)d_in[5];  const float* bd  = (const float*)d_in[6];
  const float* Wv  = (const float*)d_in[7];  const float* bv  = (const float*)d_in[8];
  const float* We1 = (const float*)d_in[9];  const float* be1 = (const float*)d_in[10];
  const float* We2 = (const float*)d_in[11]; const float* be2 = (const float*)d_in[12];
  const float* Wun = (const float*)d_in[13]; const float* bun = (const float*)d_in[14];
  const float* Wue = (const float*)d_in[15]; const float* bue = (const float*)d_in[16];
  const float* Wg  = (const float*)d_in[17]; const float* bg  = (const float*)d_in[18];
  const float* Wf1 = (const float*)d_in[19]; const float* bf1 = (const float*)d_in[20];
  const float* Wf2 = (const float*)d_in[21]; const float* bf2 = (const float*)d_in[22];
  const float* g1w = (const float*)d_in[23]; const float* g1b = (const float*)d_in[24];
  const float* g1a = (const float*)d_in[25];
  const float* g2w = (const float*)d_in[26]; const float* g2b = (const float*)d_in[27];
  const float* g2a = (const float*)d_in[28];
  const int* EI    = (const int*)d_in[29];
  const int* batch = (const int*)d_in[30];
  float* out = (float*)d_out;

  int*   wsi = (int*)d_ws;
  float* wsf = (float*)d_ws;
  int* deg    = wsi + W_DEG;
  int* cur    = wsi + W_CUR;
  int* offs   = wsi + W_OFF;
  int* bsum   = wsi + W_BSUM;
  int* gstart = wsi + W_GSTART;
  int* eidb   = wsi + W_EID;
  int* jcsr   = wsi + W_JC;
  float* gsum1 = wsf + W_GSUM1; float* gsq1 = wsf + W_GSQ1;
  float* gsum2 = wsf + W_GSUM2; float* gsq2 = wsf + W_GSQ2;
  float* scores_ = wsf + W_SCORES;
  u16* srcb = (u16*)(wsf + W_SRCB);
  u16* dstb = (u16*)(wsf + W_DSTB);
  u16* valb = (u16*)(wsf + W_VALB);
  float* A = wsf + W_A;   // agg -> x1 -> x2
  float* B = wsf + W_B;   // g
  float* wgc_ = wsf + W_WGC;
  u16*   we2b = (u16*)(wsf + W_WE2B);
  u16*   wproj = (u16*)(wsf + W_WPROJ);

  float* outE = out + (size_t)NN_ * DIM;
  float* outC = out + (size_t)NN_ * DIM + (size_t)NE_ * EOUTF;

  // zero the counter/stat prefix via DMA, not a kernel
  hipMemsetAsync(d_ws, 0, (size_t)W_ZEND * sizeof(int), stream);
  // consolidated setup: gstart + Wgc + we2b + proj W hi/lo fragments
  setup_kernel<<<577, 256, 0, stream>>>(batch, gstart, Wg, wgc_, We2, we2b,
                                        Ws, Wd, Wv, wproj);
  // CSR build
  deg_kernel<<<(NE_ + 255) / 256, 256, 0, stream>>>(EI, deg);
  scanA_kernel<<<(NN_ + 255) / 256, 256, 0, stream>>>(deg, offs, bsum);
  scanB_kernel<<<1, 128, 0, stream>>>(bsum);
  scanC_kernel<<<(NN_ + 255) / 256, 256, 0, stream>>>(offs, bsum);
  fill_kernel<<<(NE_ + 255) / 256, 256, 0, stream>>>(EI, offs, cur, eidb, jcsr);
  // projections via MFMA (bf16x2)
  proj_kernel<<<(NN_ + 31) / 32, 256, 0, stream>>>(node, wproj, bs, bd, bv,
                                                   srcb, dstb, valb);
  // edge pipeline in CSR order
  edge_kernel<<<NE_ / 32, 256, 0, stream>>>(edgef, coords, EI, eidb, We1, be1,
                                            be2, we2b, Wue, bue,
                                            srcb, dstb, scores_, outE);
  // A := agg
  agg_kernel<<<NN_ / 4, 256, 0, stream>>>(valb, scores_, offs, jcsr, A);
  // fused: nnew (LDS); B := g, A := x1; gn1 stats accumulated
  nnew_gate_kernel<<<(NN_ + 31) / 32, 256, 0, stream>>>(A, node, batch, Wun, bun,
                                                        wgc_, bg, gsum1, gsq1, B, A);
  // fused: n1 = GN1(x1) inline; t; A := x2; gn2 stats accumulated
  fx_kernel<<<(NN_ + 31) / 32, 256, 0, stream>>>(A, batch, gstart, gsum1, gsq1,
                                                 g1w, g1b, g1a, Wf1, bf1, Wf2, bf2,
                                                 B, gsum2, gsq2, A);
  // final GN apply + coords copy (merged)
  gn_apply_kernel<<<(NN_ * 32) / 256 + (NN_ * 3 + 255) / 256, 256, 0, stream>>>(
      A, batch, gstart, gsum2, gsq2, g2w, g2b, g2a, out, coords, outC);
}

// Round 11
// 531.901 us; speedup vs baseline: 1.4538x; 1.0791x over previous
//
#include <hip/hip_runtime.h>
#include <hip/hip_bf16.h>

#define NN_ 30000
#define NE_ 480000
#define DIM 128
#define EINF 16
#define EOUTF 16
#define NG 64
#define RSQRT_DH 0.17677669529663687f

typedef unsigned short u16;
typedef __attribute__((ext_vector_type(8))) short short8;
typedef __attribute__((ext_vector_type(8))) unsigned short ushort8v;
typedef __attribute__((ext_vector_type(4))) float floatx4;

// ---------------- workspace layout (32-bit word offsets) ----------------
#define W_DEG     0
#define W_CUR     30000
#define W_GSUM1   60000
#define W_GSQ1    68192
#define W_GSUM2   76384
#define W_GSQ2    84576
#define W_ZEND    92768
#define W_OFF     92768
#define W_BSUM    122772
#define W_GSTART  122900
#define W_EID     122968
#define W_JC      602968
#define W_SCORES  1082968
#define W_SRCB    3002968
#define W_DSTB    4922968
#define W_VALB    6842968
#define W_A       8762968
#define W_B       12602968
#define W_C       16442968
#define W_WGC     20282968
#define W_WE2B    20315736
#define W_WPROJ   20323928
// wfrag bank: 16 halves x 16384 u16 = 65536 words -> end 20389464 = 81.6 MB

static __device__ __forceinline__ u16 f2bf(float x) {
  __hip_bfloat16 h = __float2bfloat16(x);
  return *reinterpret_cast<u16*>(&h);
}
static __device__ __forceinline__ float bf2f(u16 v) {
  unsigned int b = ((unsigned int)v) << 16;
  return __uint_as_float(b);
}

// per-tile column reduce of a 32-row LDS tile (stride ld) into per-graph stats
static __device__ __forceinline__ void tile_gn_stats(const float* xsb, int ld,
    const int* bg_s, int row0, int tid,
    float* __restrict__ gsum, float* __restrict__ gsq) {
  int c = tid & 127, half = tid >> 7;
  float sm = 0.f, sq = 0.f;
  int gcur = -1;
  for (int r = 0; r < 16; ++r) {
    int rl = half * 16 + r;
    int row = row0 + rl;
    if (row >= NN_) break;
    int g = bg_s[rl];
    float v = xsb[rl * ld + c];
    if (g != gcur) {
      if (gcur >= 0) {
        atomicAdd(&gsum[gcur * DIM + c], sm);
        atomicAdd(&gsq[gcur * DIM + c], sq);
      }
      gcur = g; sm = 0.f; sq = 0.f;
    }
    sm += v; sq += v * v;
  }
  if (gcur >= 0) {
    atomicAdd(&gsum[gcur * DIM + c], sm);
    atomicAdd(&gsq[gcur * DIM + c], sq);
  }
}

// ---------------- consolidated setup kernel ----------------
// b0: gstart; b1..64: we2b; b65..1088: weight hi/lo fragments.
// wfrag half index = mat*2 + lo; mats: 0 Ws, 1 Wd, 2 Wv, 3 Wun,
// 4 Wgc0(=Wg[k]+Wg[256+k]), 5 Wgc1(=Wg[128+k]-Wg[256+k]), 6 Wf1, 7 Wf2.
__global__ void setup_kernel(const int* __restrict__ batch, int* __restrict__ gstart,
                             const float* __restrict__ Wg,
                             const float* __restrict__ We2, u16* __restrict__ we2b,
                             const float* __restrict__ Ws, const float* __restrict__ Wd,
                             const float* __restrict__ Wv, const float* __restrict__ Wun,
                             const float* __restrict__ Wf1, const float* __restrict__ Wf2,
                             u16* __restrict__ wfrag) {
  int b = blockIdx.x, tid = threadIdx.x;
  if (b == 0) {
    int g = tid;
    if (g <= NG) {
      int lo = 0, hi = NN_;
      while (lo < hi) { int mid = (lo + hi) >> 1; if (batch[mid] < g) lo = mid + 1; else hi = mid; }
      gstart[g] = lo;
    }
  } else if (b < 65) {
    int idx = (b - 1) * 256 + tid;   // 16384 elems
    int j = idx & 7, lane = (idx >> 3) & 63, s = (idx >> 9) & 3, T = idx >> 11;
    int k = s * 32 + ((lane >> 4) << 3) + j;
    int n = T * 16 + (lane & 15);
    we2b[idx] = f2bf(We2[(size_t)k * DIM + n]);
  } else {
    int idx = (b - 65) * 256 + tid;   // 262144 elems: 16 halves x 16384
    int which = idx >> 14;            // mat*2 + lo
    int sub = idx & 16383;
    int j = sub & 7, lane = (sub >> 3) & 63, s = (sub >> 9) & 3, T = sub >> 11;
    int k = s * 32 + ((lane >> 4) << 3) + j;
    int n = T * 16 + (lane & 15);
    int mat = which >> 1;
    float w;
    if (mat == 4) w = Wg[(size_t)k * DIM + n] + Wg[(size_t)(256 + k) * DIM + n];
    else if (mat == 5) w = Wg[(size_t)(128 + k) * DIM + n] - Wg[(size_t)(256 + k) * DIM + n];
    else {
      const float* Wsrc = (mat == 0) ? Ws : (mat == 1) ? Wd : (mat == 2) ? Wv
                        : (mat == 3) ? Wun : (mat == 6) ? Wf1 : Wf2;
      w = Wsrc[(size_t)k * DIM + n];
    }
    u16 h = f2bf(w);
    wfrag[(size_t)which * 16384 + sub] = (which & 1) ? f2bf(w - bf2f(h)) : h;
  }
}

__global__ void deg_kernel(const int* __restrict__ EI, int* __restrict__ deg) {
  int e = blockIdx.x * 256 + threadIdx.x;
  if (e < NE_) atomicAdd(&deg[EI[e]], 1);
}

// ---------------- node projections via MFMA (bf16x2 split) --------------
__global__ void __launch_bounds__(256) proj_kernel(
    const float* __restrict__ node, const u16* __restrict__ wfrag,
    const float* __restrict__ bs, const float* __restrict__ bd,
    const float* __restrict__ bv,
    u16* __restrict__ srcb, u16* __restrict__ dstb, u16* __restrict__ valb) {
  __shared__ __align__(16) u16 ah[32 * 136];
  __shared__ __align__(16) u16 al[32 * 136];
  __shared__ __align__(16) float park[32 * 132];
  int tid = threadIdx.x, row0 = blockIdx.x * 32;
  int r2 = tid >> 3, c16 = (tid & 7) * 16;

  {
    int row = row0 + r2;
    float v[16];
    if (row < NN_) {
#pragma unroll
      for (int q = 0; q < 4; ++q) {
        float4 x = *(const float4*)&node[(size_t)row * DIM + c16 + q * 4];
        v[q * 4 + 0] = x.x; v[q * 4 + 1] = x.y;
        v[q * 4 + 2] = x.z; v[q * 4 + 3] = x.w;
      }
    } else {
#pragma unroll
      for (int q = 0; q < 16; ++q) v[q] = 0.f;
    }
#pragma unroll
    for (int h2 = 0; h2 < 2; ++h2) {
      ushort8v hh, ll;
#pragma unroll
      for (int q = 0; q < 8; ++q) {
        float x = v[h2 * 8 + q];
        u16 h = f2bf(x);
        hh[q] = h;
        ll[q] = f2bf(x - bf2f(h));
      }
      *(ushort8v*)&ah[r2 * 136 + c16 + h2 * 8] = hh;
      *(ushort8v*)&al[r2 * 136 + c16 + h2 * 8] = ll;
    }
  }
  __syncthreads();

  int wv_ = tid >> 6, lane = tid & 63;
  int mtile = wv_ & 1, nhalf = wv_ >> 1;
  int quad = lane >> 4, lrow = lane & 15;
  int m0 = mtile * 16;

  short8 afh[4], afl[4];
#pragma unroll
  for (int s = 0; s < 4; ++s) {
    afh[s] = *(const short8*)&ah[(m0 + lrow) * 136 + s * 32 + quad * 8];
    afl[s] = *(const short8*)&al[(m0 + lrow) * 136 + s * 32 + quad * 8];
  }

  const float* Bt[3] = {bs, bd, bv};
  u16* Yt[3] = {srcb, dstb, valb};
#pragma unroll 1
  for (int g3 = 0; g3 < 3; ++g3) {
    const u16* wh = wfrag + (size_t)(g3 * 2 + 0) * 16384;
    const u16* wl = wfrag + (size_t)(g3 * 2 + 1) * 16384;
    floatx4 dacc[4];
#pragma unroll
    for (int t = 0; t < 4; ++t) dacc[t] = (floatx4){0.f, 0.f, 0.f, 0.f};
#pragma unroll
    for (int s = 0; s < 4; ++s) {
#pragma unroll
      for (int t = 0; t < 4; ++t) {
        int T = nhalf * 4 + t;
        size_t off = (size_t)((T * 4 + s) * 64 + lane) * 8;
        short8 bh = *(const short8*)&wh[off];
        short8 bl = *(const short8*)&wl[off];
        dacc[t] = __builtin_amdgcn_mfma_f32_16x16x32_bf16(afh[s], bh, dacc[t], 0, 0, 0);
        dacc[t] = __builtin_amdgcn_mfma_f32_16x16x32_bf16(afl[s], bh, dacc[t], 0, 0, 0);
        dacc[t] = __builtin_amdgcn_mfma_f32_16x16x32_bf16(afh[s], bl, dacc[t], 0, 0, 0);
      }
    }
#pragma unroll
    for (int t = 0; t < 4; ++t) {
      int col = nhalf * 64 + t * 16 + lrow;
#pragma unroll
      for (int r = 0; r < 4; ++r)
        park[(m0 + quad * 4 + r) * 132 + col] = dacc[t][r];
    }
    __syncthreads();
    {
      int row = row0 + r2;
      if (row < NN_) {
#pragma unroll
        for (int h2 = 0; h2 < 2; ++h2) {
          ushort8v o;
#pragma unroll
          for (int q = 0; q < 8; ++q) {
            float pv = park[r2 * 132 + c16 + h2 * 8 + q] + Bt[g3][c16 + h2 * 8 + q];
            o[q] = f2bf(pv);
          }
          *(ushort8v*)&Yt[g3][(size_t)row * DIM + c16 + h2 * 8] = o;
        }
      }
    }
    __syncthreads();
  }
}

// ---------------- nnew+gate via MFMA + gn1 stats ----------------
// nnew = AGG@Wun + bun (MFMA1, parked); nnew re-split hi/lo into the dead
// AGG-frag LDS; z = nnew@Wgc0 + NODE@Wgc1 (MFMA2, 6 ops/(s,t)); epilogue in
// C-layout: g = sigmoid(z+bg), x1 = g*nnew + node (node = hi+lo recon).
// x1 parked in place -> tile gn1 stats.
__global__ void __launch_bounds__(256) nnew_gate_kernel(
    const float* __restrict__ AGG, const float* __restrict__ NODE,
    const int* __restrict__ batch, const u16* __restrict__ wfrag,
    const float* __restrict__ bun, const float* __restrict__ bg,
    float* __restrict__ gsum1, float* __restrict__ gsq1,
    float* __restrict__ G, float* __restrict__ X1) {
  __shared__ __align__(16) u16 a_h[32 * 136];   // AGG frags -> nnew frags
  __shared__ __align__(16) u16 a_l[32 * 136];
  __shared__ __align__(16) u16 n_h[32 * 136];   // NODE frags
  __shared__ __align__(16) u16 n_l[32 * 136];
  __shared__ __align__(16) float park[32 * 132]; // nnew(raw) -> x1
  __shared__ int bg_s[32];
  int tid = threadIdx.x, row0 = blockIdx.x * 32;
  int r2 = tid >> 3, c16 = (tid & 7) * 16;
  if (tid < 32) bg_s[tid] = (row0 + tid < NN_) ? batch[row0 + tid] : 0;

  {
    int row = row0 + r2;
    float va[16], vn[16];
    if (row < NN_) {
#pragma unroll
      for (int q = 0; q < 4; ++q) {
        float4 xa = *(const float4*)&AGG[(size_t)row * DIM + c16 + q * 4];
        float4 xn = *(const float4*)&NODE[(size_t)row * DIM + c16 + q * 4];
        va[q * 4 + 0] = xa.x; va[q * 4 + 1] = xa.y; va[q * 4 + 2] = xa.z; va[q * 4 + 3] = xa.w;
        vn[q * 4 + 0] = xn.x; vn[q * 4 + 1] = xn.y; vn[q * 4 + 2] = xn.z; vn[q * 4 + 3] = xn.w;
      }
    } else {
#pragma unroll
      for (int q = 0; q < 16; ++q) { va[q] = 0.f; vn[q] = 0.f; }
    }
#pragma unroll
    for (int h2 = 0; h2 < 2; ++h2) {
      ushort8v ah8, al8, nh8, nl8;
#pragma unroll
      for (int q = 0; q < 8; ++q) {
        float x = va[h2 * 8 + q];
        u16 h = f2bf(x); ah8[q] = h; al8[q] = f2bf(x - bf2f(h));
        float y = vn[h2 * 8 + q];
        u16 hy = f2bf(y); nh8[q] = hy; nl8[q] = f2bf(y - bf2f(hy));
      }
      *(ushort8v*)&a_h[r2 * 136 + c16 + h2 * 8] = ah8;
      *(ushort8v*)&a_l[r2 * 136 + c16 + h2 * 8] = al8;
      *(ushort8v*)&n_h[r2 * 136 + c16 + h2 * 8] = nh8;
      *(ushort8v*)&n_l[r2 * 136 + c16 + h2 * 8] = nl8;
    }
  }
  __syncthreads();

  int wv_ = tid >> 6, lane = tid & 63;
  int mtile = wv_ & 1, nhalf = wv_ >> 1;
  int quad = lane >> 4, lrow = lane & 15;
  int m0 = mtile * 16;

  const u16* WunH = wfrag + (size_t)6 * 16384;
  const u16* WunL = wfrag + (size_t)7 * 16384;
  const u16* G0H  = wfrag + (size_t)8 * 16384;
  const u16* G0L  = wfrag + (size_t)9 * 16384;
  const u16* G1H  = wfrag + (size_t)10 * 16384;
  const u16* G1L  = wfrag + (size_t)11 * 16384;

  // MFMA1: nnew = AGG @ Wun (raw, bias added later)
  {
    short8 fh[4], fl[4];
#pragma unroll
    for (int s = 0; s < 4; ++s) {
      fh[s] = *(const short8*)&a_h[(m0 + lrow) * 136 + s * 32 + quad * 8];
      fl[s] = *(const short8*)&a_l[(m0 + lrow) * 136 + s * 32 + quad * 8];
    }
    floatx4 d1[4];
#pragma unroll
    for (int t = 0; t < 4; ++t) d1[t] = (floatx4){0.f, 0.f, 0.f, 0.f};
#pragma unroll
    for (int s = 0; s < 4; ++s) {
#pragma unroll
      for (int t = 0; t < 4; ++t) {
        int T = nhalf * 4 + t;
        size_t off = (size_t)((T * 4 + s) * 64 + lane) * 8;
        short8 bh = *(const short8*)&WunH[off];
        short8 bl = *(const short8*)&WunL[off];
        d1[t] = __builtin_amdgcn_mfma_f32_16x16x32_bf16(fh[s], bh, d1[t], 0, 0, 0);
        d1[t] = __builtin_amdgcn_mfma_f32_16x16x32_bf16(fl[s], bh, d1[t], 0, 0, 0);
        d1[t] = __builtin_amdgcn_mfma_f32_16x16x32_bf16(fh[s], bl, d1[t], 0, 0, 0);
      }
    }
#pragma unroll
    for (int t = 0; t < 4; ++t) {
      int col = nhalf * 64 + t * 16 + lrow;
#pragma unroll
      for (int r = 0; r < 4; ++r)
        park[(m0 + quad * 4 + r) * 132 + col] = d1[t][r];
    }
  }
  __syncthreads();

  // re-split nnew+bun into the dead AGG-frag region (A layout for MFMA2)
  {
#pragma unroll
    for (int h2 = 0; h2 < 2; ++h2) {
      ushort8v hh, ll;
#pragma unroll
      for (int q = 0; q < 8; ++q) {
        float x = park[r2 * 132 + c16 + h2 * 8 + q] + bun[c16 + h2 * 8 + q];
        u16 h = f2bf(x); hh[q] = h; ll[q] = f2bf(x - bf2f(h));
      }
      *(ushort8v*)&a_h[r2 * 136 + c16 + h2 * 8] = hh;
      *(ushort8v*)&a_l[r2 * 136 + c16 + h2 * 8] = ll;
    }
  }
  __syncthreads();

  // MFMA2: z = nnew@Wgc0 + NODE@Wgc1; epilogue in C-layout
  {
    short8 mh[4], ml[4], ph[4], pl[4];
#pragma unroll
    for (int s = 0; s < 4; ++s) {
      mh[s] = *(const short8*)&a_h[(m0 + lrow) * 136 + s * 32 + quad * 8];
      ml[s] = *(const short8*)&a_l[(m0 + lrow) * 136 + s * 32 + quad * 8];
      ph[s] = *(const short8*)&n_h[(m0 + lrow) * 136 + s * 32 + quad * 8];
      pl[s] = *(const short8*)&n_l[(m0 + lrow) * 136 + s * 32 + quad * 8];
    }
    floatx4 d2[4];
#pragma unroll
    for (int t = 0; t < 4; ++t) d2[t] = (floatx4){0.f, 0.f, 0.f, 0.f};
#pragma unroll
    for (int s = 0; s < 4; ++s) {
#pragma unroll
      for (int t = 0; t < 4; ++t) {
        int T = nhalf * 4 + t;
        size_t off = (size_t)((T * 4 + s) * 64 + lane) * 8;
        short8 g0h = *(const short8*)&G0H[off];
        short8 g0l = *(const short8*)&G0L[off];
        short8 g1h = *(const short8*)&G1H[off];
        short8 g1l = *(const short8*)&G1L[off];
        d2[t] = __builtin_amdgcn_mfma_f32_16x16x32_bf16(mh[s], g0h, d2[t], 0, 0, 0);
        d2[t] = __builtin_amdgcn_mfma_f32_16x16x32_bf16(ml[s], g0h, d2[t], 0, 0, 0);
        d2[t] = __builtin_amdgcn_mfma_f32_16x16x32_bf16(mh[s], g0l, d2[t], 0, 0, 0);
        d2[t] = __builtin_amdgcn_mfma_f32_16x16x32_bf16(ph[s], g1h, d2[t], 0, 0, 0);
        d2[t] = __builtin_amdgcn_mfma_f32_16x16x32_bf16(pl[s], g1h, d2[t], 0, 0, 0);
        d2[t] = __builtin_amdgcn_mfma_f32_16x16x32_bf16(ph[s], g1l, d2[t], 0, 0, 0);
      }
    }
#pragma unroll
    for (int t = 0; t < 4; ++t) {
      int col = nhalf * 64 + t * 16 + lrow;
      float bgv = bg[col], bunv = bun[col];
#pragma unroll
      for (int r = 0; r < 4; ++r) {
        int erow = m0 + quad * 4 + r;
        int row = row0 + erow;
        float z = d2[t][r] + bgv;
        float gg = 1.f / (1.f + __expf(-z));
        float nn = park[erow * 132 + col] + bunv;
        float nodev = bf2f(n_h[erow * 136 + col]) + bf2f(n_l[erow * 136 + col]);
        float x1 = gg * nn + nodev;
        park[erow * 132 + col] = x1;
        if (row < NN_) {
          G[(size_t)row * DIM + col] = gg;
          X1[(size_t)row * DIM + col] = x1;
        }
      }
    }
  }
  __syncthreads();
  tile_gn_stats(park, 132, bg_s, row0, tid, gsum1, gsq1);
}

// ---------------- fix_node via MFMA + inline GN1 + gn2 stats ------------
// n1 = GN1(x1) inline at staging; t = leaky(n1@Wf1+bf1) (MFMA1, C->A u16
// scatter); x2 = g*(t@Wf2+bf2) + n1 (MFMA2, C-layout epilogue). x2 parked
// in place -> tile gn2 stats.
__global__ void __launch_bounds__(256) fx_kernel(
    const float* __restrict__ X1, const int* __restrict__ batch,
    const int* __restrict__ gstart,
    const float* __restrict__ gsum1, const float* __restrict__ gsq1,
    const float* __restrict__ g1w, const float* __restrict__ g1b,
    const float* __restrict__ g1a, const u16* __restrict__ wfrag,
    const float* __restrict__ bf1, const float* __restrict__ bf2,
    const float* __restrict__ G,
    float* __restrict__ gsum2, float* __restrict__ gsq2,
    float* __restrict__ X2) {
  __shared__ __align__(16) u16 a_h[32 * 136];   // n1 frags -> t frags
  __shared__ __align__(16) u16 a_l[32 * 136];
  __shared__ __align__(16) float n1s[32 * 132]; // n1 -> x2
  __shared__ int bg_s[32];
  int tid = threadIdx.x, row0 = blockIdx.x * 32;
  int r2 = tid >> 3, c16 = (tid & 7) * 16;
  if (tid < 32) bg_s[tid] = (row0 + tid < NN_) ? batch[row0 + tid] : 0;

  // stage x1 + inline GN1 -> n1 (f32 tile + hi/lo frags)
  {
    int row = row0 + r2;
    int gi = (row < NN_) ? batch[row] : 0;
    float cnt = fmaxf((float)(gstart[gi + 1] - gstart[gi]), 1.f);
    float inv = 1.f / cnt;
    float v[16];
    if (row < NN_) {
#pragma unroll
      for (int q = 0; q < 4; ++q) {
        float4 x = *(const float4*)&X1[(size_t)row * DIM + c16 + q * 4];
        v[q * 4 + 0] = x.x; v[q * 4 + 1] = x.y;
        v[q * 4 + 2] = x.z; v[q * 4 + 3] = x.w;
      }
    } else {
#pragma unroll
      for (int q = 0; q < 16; ++q) v[q] = 0.f;
    }
#pragma unroll
    for (int q0 = 0; q0 < 16; ++q0) {
      int c = c16 + q0;
      float sm = gsum1[gi * DIM + c], sq = gsq1[gi * DIM + c];
      float mean = sm * inv, msq = sq * inv, am = g1a[c] * mean;
      float var = msq - 2.f * am * mean + am * am;
      v[q0] = g1w[c] * (v[q0] - am) * rsqrtf(var + 1e-5f) + g1b[c];
    }
#pragma unroll
    for (int q = 0; q < 4; ++q) {
      float4 o; o.x = v[q * 4 + 0]; o.y = v[q * 4 + 1];
      o.z = v[q * 4 + 2]; o.w = v[q * 4 + 3];
      *(float4*)&n1s[r2 * 132 + c16 + q * 4] = o;
    }
#pragma unroll
    for (int h2 = 0; h2 < 2; ++h2) {
      ushort8v hh, ll;
#pragma unroll
      for (int q = 0; q < 8; ++q) {
        float x = v[h2 * 8 + q];
        u16 h = f2bf(x); hh[q] = h; ll[q] = f2bf(x - bf2f(h));
      }
      *(ushort8v*)&a_h[r2 * 136 + c16 + h2 * 8] = hh;
      *(ushort8v*)&a_l[r2 * 136 + c16 + h2 * 8] = ll;
    }
  }
  __syncthreads();

  int wv_ = tid >> 6, lane = tid & 63;
  int mtile = wv_ & 1, nhalf = wv_ >> 1;
  int quad = lane >> 4, lrow = lane & 15;
  int m0 = mtile * 16;

  const u16* F1H = wfrag + (size_t)12 * 16384;
  const u16* F1L = wfrag + (size_t)13 * 16384;
  const u16* F2H = wfrag + (size_t)14 * 16384;
  const u16* F2L = wfrag + (size_t)15 * 16384;

  short8 fh[4], fl[4];
#pragma unroll
  for (int s = 0; s < 4; ++s) {
    fh[s] = *(const short8*)&a_h[(m0 + lrow) * 136 + s * 32 + quad * 8];
    fl[s] = *(const short8*)&a_l[(m0 + lrow) * 136 + s * 32 + quad * 8];
  }
  __syncthreads();   // all frags in regs before the t-scatter overwrites

  // MFMA1: t = leaky(n1 @ Wf1 + bf1); scatter hi/lo into a_h/a_l (C->A)
  {
    floatx4 d1[4];
#pragma unroll
    for (int t = 0; t < 4; ++t) d1[t] = (floatx4){0.f, 0.f, 0.f, 0.f};
#pragma unroll
    for (int s = 0; s < 4; ++s) {
#pragma unroll
      for (int t = 0; t < 4; ++t) {
        int T = nhalf * 4 + t;
        size_t off = (size_t)((T * 4 + s) * 64 + lane) * 8;
        short8 bh = *(const short8*)&F1H[off];
        short8 bl = *(const short8*)&F1L[off];
        d1[t] = __builtin_amdgcn_mfma_f32_16x16x32_bf16(fh[s], bh, d1[t], 0, 0, 0);
        d1[t] = __builtin_amdgcn_mfma_f32_16x16x32_bf16(fl[s], bh, d1[t], 0, 0, 0);
        d1[t] = __builtin_amdgcn_mfma_f32_16x16x32_bf16(fh[s], bl, d1[t], 0, 0, 0);
      }
    }
#pragma unroll
    for (int t = 0; t < 4; ++t) {
      int col = nhalf * 64 + t * 16 + lrow;
      float b1v = bf1[col];
#pragma unroll
      for (int r = 0; r < 4; ++r) {
        int erow = m0 + quad * 4 + r;
        float tt = d1[t][r] + b1v;
        tt = tt > 0.f ? tt : 0.01f * tt;
        u16 h = f2bf(tt);
        a_h[erow * 136 + col] = h;
        a_l[erow * 136 + col] = f2bf(tt - bf2f(h));
      }
    }
  }
  __syncthreads();

  // MFMA2: x2 = g*(t @ Wf2 + bf2) + n1
  {
    short8 th[4], tl[4];
#pragma unroll
    for (int s = 0; s < 4; ++s) {
      th[s] = *(const short8*)&a_h[(m0 + lrow) * 136 + s * 32 + quad * 8];
      tl[s] = *(const short8*)&a_l[(m0 + lrow) * 136 + s * 32 + quad * 8];
    }
    floatx4 d2[4];
#pragma unroll
    for (int t = 0; t < 4; ++t) d2[t] = (floatx4){0.f, 0.f, 0.f, 0.f};
#pragma unroll
    for (int s = 0; s < 4; ++s) {
#pragma unroll
      for (int t = 0; t < 4; ++t) {
        int T = nhalf * 4 + t;
        size_t off = (size_t)((T * 4 + s) * 64 + lane) * 8;
        short8 bh = *(const short8*)&F2H[off];
        short8 bl = *(const short8*)&F2L[off];
        d2[t] = __builtin_amdgcn_mfma_f32_16x16x32_bf16(th[s], bh, d2[t], 0, 0, 0);
        d2[t] = __builtin_amdgcn_mfma_f32_16x16x32_bf16(tl[s], bh, d2[t], 0, 0, 0);
        d2[t] = __builtin_amdgcn_mfma_f32_16x16x32_bf16(th[s], bl, d2[t], 0, 0, 0);
      }
    }
#pragma unroll
    for (int t = 0; t < 4; ++t) {
      int col = nhalf * 64 + t * 16 + lrow;
      float b2v = bf2[col];
#pragma unroll
      for (int r = 0; r < 4; ++r) {
        int erow = m0 + quad * 4 + r;
        int row = row0 + erow;
        float gg = (row < NN_) ? G[(size_t)row * DIM + col] : 0.f;
        float x2 = gg * (d2[t][r] + b2v) + n1s[erow * 132 + col];
        n1s[erow * 132 + col] = x2;
        if (row < NN_) X2[(size_t)row * DIM + col] = x2;
      }
    }
  }
  __syncthreads();
  tile_gn_stats(n1s, 132, bg_s, row0, tid, gsum2, gsq2);
}

// ---------------- CSR build ----------------
__global__ void scanA_kernel(const int* __restrict__ deg, int* __restrict__ off,
                             int* __restrict__ bsum) {
  __shared__ int buf[256];
  int tid = threadIdx.x;
  int i = blockIdx.x * 256 + tid;
  int v = (i < NN_) ? deg[i] : 0;
  buf[tid] = v;
  __syncthreads();
  for (int s = 1; s < 256; s <<= 1) {
    int t = (tid >= s) ? buf[tid - s] : 0;
    __syncthreads();
    buf[tid] += t;
    __syncthreads();
  }
  if (i < NN_) off[i] = buf[tid] - v;
  if (tid == 255) bsum[blockIdx.x] = buf[255];
}

__global__ void scanB_kernel(int* __restrict__ bsum) {
  const int NBLK = (NN_ + 255) / 256;
  __shared__ int buf[128];
  int tid = threadIdx.x;
  int v = (tid < NBLK) ? bsum[tid] : 0;
  buf[tid] = v;
  __syncthreads();
  for (int s = 1; s < 128; s <<= 1) {
    int t = (tid >= s) ? buf[tid - s] : 0;
    __syncthreads();
    buf[tid] += t;
    __syncthreads();
  }
  if (tid < NBLK) bsum[tid] = buf[tid] - v;
}

__global__ void scanC_kernel(int* __restrict__ off, const int* __restrict__ bsum) {
  int i = blockIdx.x * 256 + threadIdx.x;
  if (i < NN_) off[i] += bsum[i >> 8];
  if (i == 0) off[NN_] = NE_;
}

__global__ void fill_kernel(const int* __restrict__ EI, const int* __restrict__ off,
                            int* __restrict__ cur, int* __restrict__ eidb,
                            int* __restrict__ jcsr) {
  int e = blockIdx.x * 256 + threadIdx.x;
  if (e >= NE_) return;
  int i = EI[e];
  int p = atomicAdd(&cur[i], 1);
  int pos = off[i] + p;
  eidb[pos] = e;
  jcsr[pos] = EI[NE_ + e];
}

// ---------------- fused edge kernel, CSR order ----------------
// R11: single overlaid LDS buffer -> 25792 B -> 6 blocks/CU (was 5).
// Phase A: xs[0..640) + hbf[640..2816). Phase B (after afrag barrier):
// wue_s[0..2112) + ers[2112..6336). All disjoint-or-dead transitions are
// guarded by the existing barriers.
__global__ void __launch_bounds__(256, 6) edge_kernel(
    const float* __restrict__ edgef, const float* __restrict__ coords,
    const int* __restrict__ EI, const int* __restrict__ eidb,
    const float* __restrict__ We1, const float* __restrict__ be1,
    const float* __restrict__ be2, const u16* __restrict__ we2b,
    const float* __restrict__ Wue, const float* __restrict__ bue,
    const u16* __restrict__ srcb, const u16* __restrict__ dstb,
    float* __restrict__ scores, float* __restrict__ outE) {
  __shared__ __align__(16) float sbuf[6336];
  __shared__ float bue_s[EOUTF];
  __shared__ int ii[32], jj[32], ee[32];

  float* xs    = sbuf;                 // [32][20], cols 0..16 used
  u16*   hbf   = (u16*)(sbuf + 640);   // [32][136]
  float* wue_s = sbuf;                 // [16][132], phase B
  float* ers   = sbuf + 2112;          // [32][132], phase B

  int tid = threadIdx.x;
  int bid = blockIdx.x;
  int bswz = (bid & 7) * (NE_ / 32 / 8) + (bid >> 3);
  int p0 = bswz * 32;

  if (tid < 32) {
    int p = p0 + tid;
    int e = eidb[p];
    ee[tid] = e;
    int i = EI[e], j = EI[NE_ + e];
    ii[tid] = i; jj[tid] = j;
    float dx = coords[i * 3 + 0] - coords[j * 3 + 0];
    float dy = coords[i * 3 + 1] - coords[j * 3 + 1];
    float dz = coords[i * 3 + 2] - coords[j * 3 + 2];
    float dist = sqrtf(dx * dx + dy * dy + dz * dz + 1e-12f) * 0.1f;
    xs[tid * 20 + 16] = dist;
  }
  if (tid < EOUTF) bue_s[tid] = bue[tid];
  __syncthreads();

  if (tid < 128) {
    int r = tid >> 2, c4 = (tid & 3) * 4;
    *(float4*)&xs[r * 20 + c4] = *(const float4*)&edgef[(size_t)ee[r] * EINF + c4];
  }
  __syncthreads();

  int cg = tid & 31, rg = tid >> 5, c0 = cg * 4, r0 = rg * 4;

  {
    float acc[4][4] = {};
    for (int k = 0; k < 16; k += 4) {
      float4 w0 = *(const float4*)&We1[(size_t)(k + 0) * DIM + c0];
      float4 w1 = *(const float4*)&We1[(size_t)(k + 1) * DIM + c0];
      float4 w2 = *(const float4*)&We1[(size_t)(k + 2) * DIM + c0];
      float4 w3 = *(const float4*)&We1[(size_t)(k + 3) * DIM + c0];
#pragma unroll
      for (int u = 0; u < 4; ++u) {
        float4 xv = *(const float4*)&xs[(r0 + u) * 20 + k];
        acc[u][0] += xv.x * w0.x + xv.y * w1.x + xv.z * w2.x + xv.w * w3.x;
        acc[u][1] += xv.x * w0.y + xv.y * w1.y + xv.z * w2.y + xv.w * w3.y;
        acc[u][2] += xv.x * w0.z + xv.y * w1.z + xv.z * w2.z + xv.w * w3.z;
        acc[u][3] += xv.x * w0.w + xv.y * w1.w + xv.z * w2.w + xv.w * w3.w;
      }
    }
    {   // k = 16: the dist column
      float4 w4 = *(const float4*)&We1[(size_t)16 * DIM + c0];
#pragma unroll
      for (int u = 0; u < 4; ++u) {
        float xd = xs[(r0 + u) * 20 + 16];
        acc[u][0] += xd * w4.x; acc[u][1] += xd * w4.y;
        acc[u][2] += xd * w4.z; acc[u][3] += xd * w4.w;
      }
    }
    float4 b1 = *(const float4*)&be1[c0];
#pragma unroll
    for (int u = 0; u < 4; ++u) {
      float h0 = acc[u][0] + b1.x, h1 = acc[u][1] + b1.y;
      float h2 = acc[u][2] + b1.z, h3 = acc[u][3] + b1.w;
      h0 = h0 > 0.f ? h0 : 0.01f * h0; h1 = h1 > 0.f ? h1 : 0.01f * h1;
      h2 = h2 > 0.f ? h2 : 0.01f * h2; h3 = h3 > 0.f ? h3 : 0.01f * h3;
      ushort4 pk; pk.x = f2bf(h0); pk.y = f2bf(h1); pk.z = f2bf(h2); pk.w = f2bf(h3);
      *(ushort4*)&hbf[(r0 + u) * 136 + c0] = pk;
    }
  }
  __syncthreads();

  int wv = tid >> 6, lane = tid & 63;
  int mtile = wv & 1, nhalf = wv >> 1;
  int quad = lane >> 4, lrow = lane & 15;
  int m0 = mtile * 16;

  short8 afrag[4];
#pragma unroll
  for (int s = 0; s < 4; ++s)
    afrag[s] = *(const short8*)&hbf[(m0 + lrow) * 136 + s * 32 + quad * 8];
  __syncthreads();   // hbf/xs dead -> phase B overlay begins

  for (int idx = tid; idx < 16 * DIM; idx += 256) {
    int oc = idx >> 7, k = idx & 127;
    wue_s[oc * 132 + k] = Wue[(size_t)k * EOUTF + oc];
  }

  floatx4 dacc[4];
#pragma unroll
  for (int t = 0; t < 4; ++t) dacc[t] = (floatx4){0.f, 0.f, 0.f, 0.f};
#pragma unroll
  for (int s = 0; s < 4; ++s) {
#pragma unroll
    for (int t = 0; t < 4; ++t) {
      int T = nhalf * 4 + t;
      short8 bfrg = *(const short8*)&we2b[(size_t)((T * 4 + s) * 64 + lane) * 8];
      dacc[t] = __builtin_amdgcn_mfma_f32_16x16x32_bf16(afrag[s], bfrg, dacc[t], 0, 0, 0);
    }
  }

#pragma unroll
  for (int t = 0; t < 4; ++t) {
    int col = nhalf * 64 + t * 16 + lrow;
    float b2v = be2[col];
#pragma unroll
    for (int r = 0; r < 4; ++r) {
      int erow = m0 + quad * 4 + r;
      ers[erow * 132 + col] = dacc[t][r] + b2v;
    }
  }
  __syncthreads();

  {
    int el2 = tid >> 3, cb2 = tid & 7;
    int c0b = cb2 * 16;
    int irow = ii[el2], jrow = jj[el2];
    ushort8v dv8a = *(const ushort8v*)&dstb[(size_t)irow * DIM + c0b];
    ushort8v dv8b = *(const ushort8v*)&dstb[(size_t)irow * DIM + c0b + 8];
    ushort8v sv8a = *(const ushort8v*)&srcb[(size_t)jrow * DIM + c0b];
    ushort8v sv8b = *(const ushort8v*)&srcb[(size_t)jrow * DIM + c0b + 8];

    float ef[16];
#pragma unroll
    for (int q = 0; q < 4; ++q) {
      float4 v = *(const float4*)&ers[el2 * 132 + c0b + q * 4];
      ef[q * 4 + 0] = v.x; ef[q * 4 + 1] = v.y;
      ef[q * 4 + 2] = v.z; ef[q * 4 + 3] = v.w;
    }
    float asum = 0.f;
#pragma unroll
    for (int k = 0; k < 8; ++k) {
      float er = bf2f((u16)dv8a[k]) * bf2f((u16)sv8a[k]) * ef[k] * RSQRT_DH;
      ef[k] = er; asum += fabsf(er);
    }
#pragma unroll
    for (int k = 0; k < 8; ++k) {
      float er = bf2f((u16)dv8b[k]) * bf2f((u16)sv8b[k]) * ef[8 + k] * RSQRT_DH;
      ef[8 + k] = er; asum += fabsf(er);
    }
#pragma unroll
    for (int q = 0; q < 4; ++q) {
      float4 v; v.x = ef[q * 4 + 0]; v.y = ef[q * 4 + 1];
      v.z = ef[q * 4 + 2]; v.w = ef[q * 4 + 3];
      *(float4*)&ers[el2 * 132 + c0b + q * 4] = v;
    }
    asum += __shfl_xor(asum, 1);
    if ((cb2 & 1) == 0)
      scores[(size_t)(p0 + el2) * 4 + (cb2 >> 1)] = asum;
  }
  __syncthreads();

  int el = tid >> 3, oc2 = (tid & 7) * 2;
  float a0 = 0.f, a1 = 0.f;
  for (int k = 0; k < DIM; k += 4) {
    float4 e4 = *(const float4*)&ers[el * 132 + k];
    float4 w0 = *(const float4*)&wue_s[oc2 * 132 + k];
    float4 w1 = *(const float4*)&wue_s[(oc2 + 1) * 132 + k];
    a0 += e4.x * w0.x + e4.y * w0.y + e4.z * w0.z + e4.w * w0.w;
    a1 += e4.x * w1.x + e4.y * w1.y + e4.z * w1.z + e4.w * w1.w;
  }
  size_t ob = (size_t)ee[el] * EOUTF + oc2;
  float2 o2; o2.x = a0 + bue_s[oc2]; o2.y = a1 + bue_s[oc2 + 1];
  *(float2*)&outE[ob] = o2;
}

// ---------------- per-node softmax + aggregation (CSR gather) -----------
__global__ void __launch_bounds__(256) agg_kernel(
    const u16* __restrict__ valb, const float* __restrict__ scores,
    const int* __restrict__ off, const int* __restrict__ jcsr,
    float* __restrict__ agg) {
  int n = blockIdx.x * 4 + (threadIdx.x >> 6);
  int l = threadIdx.x & 63;
  if (n >= NN_) return;
  int s = off[n], e_end = off[n + 1];

  float m0 = -1e30f, m1 = -1e30f, m2 = -1e30f, m3 = -1e30f;
  for (int p = s + l; p < e_end; p += 64) {
    float4 sc = *(const float4*)&scores[(size_t)p * 4];
    m0 = fmaxf(m0, sc.x); m1 = fmaxf(m1, sc.y);
    m2 = fmaxf(m2, sc.z); m3 = fmaxf(m3, sc.w);
  }
#pragma unroll
  for (int d = 1; d < 64; d <<= 1) {
    m0 = fmaxf(m0, __shfl_xor(m0, d)); m1 = fmaxf(m1, __shfl_xor(m1, d));
    m2 = fmaxf(m2, __shfl_xor(m2, d)); m3 = fmaxf(m3, __shfl_xor(m3, d));
  }
  int hh = l >> 4;
  float mh = (hh == 0) ? m0 : (hh == 1) ? m1 : (hh == 2) ? m2 : m3;

  float acc0 = 0.f, acc1 = 0.f, den = 0.f;
  int p = s;
  for (; p + 4 <= e_end; p += 4) {
    int j0 = jcsr[p], j1 = jcsr[p + 1], j2 = jcsr[p + 2], j3 = jcsr[p + 3];
    float s0 = scores[(size_t)p * 4 + hh];
    float s1 = scores[(size_t)(p + 1) * 4 + hh];
    float s2 = scores[(size_t)(p + 2) * 4 + hh];
    float s3 = scores[(size_t)(p + 3) * 4 + hh];
    ushort2 u0 = *(const ushort2*)&valb[(size_t)j0 * DIM + 2 * l];
    ushort2 u1 = *(const ushort2*)&valb[(size_t)j1 * DIM + 2 * l];
    ushort2 u2 = *(const ushort2*)&valb[(size_t)j2 * DIM + 2 * l];
    ushort2 u3 = *(const ushort2*)&valb[(size_t)j3 * DIM + 2 * l];
    float e0 = __expf(s0 - mh), e1 = __expf(s1 - mh);
    float e2 = __expf(s2 - mh), e3 = __expf(s3 - mh);
    den += (e0 + e1) + (e2 + e3);
    acc0 += e0 * bf2f(u0.x) + e1 * bf2f(u1.x) + e2 * bf2f(u2.x) + e3 * bf2f(u3.x);
    acc1 += e0 * bf2f(u0.y) + e1 * bf2f(u1.y) + e2 * bf2f(u2.y) + e3 * bf2f(u3.y);
  }
  for (; p < e_end; ++p) {
    int j = jcsr[p];
    float s0 = scores[(size_t)p * 4 + hh];
    ushort2 u0 = *(const ushort2*)&valb[(size_t)j * DIM + 2 * l];
    float e0 = __expf(s0 - mh);
    den += e0;
    acc0 += e0 * bf2f(u0.x);
    acc1 += e0 * bf2f(u0.y);
  }
  float2 o;
  if (e_end > s) { o.x = acc0 / den; o.y = acc1 / den; }
  else { o.x = 0.f; o.y = 0.f; }
  *(float2*)&agg[(size_t)n * DIM + 2 * l] = o;
}

// ---------------- final GraphNorm apply + coords copy (merged) ----------
__global__ void gn_apply_kernel(const float* __restrict__ X, const int* __restrict__ batch,
    const int* __restrict__ gstart, const float* __restrict__ gsum,
    const float* __restrict__ gsq, const float* __restrict__ w,
    const float* __restrict__ b, const float* __restrict__ a,
    float* __restrict__ Y,
    const float* __restrict__ C, float* __restrict__ OC) {
  int blk = blockIdx.x;
  if (blk >= (NN_ * 32) / 256) {
    int i = (blk - (NN_ * 32) / 256) * 256 + threadIdx.x;
    if (i < NN_ * 3) OC[i] = C[i];
    return;
  }
  int idx = blk * 256 + threadIdx.x;
  int n = idx >> 5, c4 = (idx & 31) * 4;
  int g = batch[n];
  float cnt = fmaxf((float)(gstart[g + 1] - gstart[g]), 1.f);
  float inv = 1.f / cnt;
  float4 xv = *(const float4*)&X[(size_t)n * DIM + c4];
  float4 sm = *(const float4*)&gsum[g * DIM + c4];
  float4 sq = *(const float4*)&gsq[g * DIM + c4];
  float4 av = *(const float4*)&a[c4];
  float4 wv = *(const float4*)&w[c4];
  float4 bv = *(const float4*)&b[c4];
  float4 ov;
  {
    float mean = sm.x * inv, msq = sq.x * inv, am = av.x * mean;
    float var = msq - 2.f * am * mean + am * am;
    ov.x = wv.x * (xv.x - am) * rsqrtf(var + 1e-5f) + bv.x;
  }
  {
    float mean = sm.y * inv, msq = sq.y * inv, am = av.y * mean;
    float var = msq - 2.f * am * mean + am * am;
    ov.y = wv.y * (xv.y - am) * rsqrtf(var + 1e-5f) + bv.y;
  }
  {
    float mean = sm.z * inv, msq = sq.z * inv, am = av.z * mean;
    float var = msq - 2.f * am * mean + am * am;
    ov.z = wv.z * (xv.z - am) * rsqrtf(var + 1e-5f) + bv.z;
  }
  {
    float mean = sm.w * inv, msq = sq.w * inv, am = av.w * mean;
    float var = msq - 2.f * am * mean + am * am;
    ov.w = wv.w * (xv.w - am) * rsqrtf(var + 1e-5f) + bv.w;
  }
  *(float4*)&Y[(size_t)n * DIM + c4] = ov;
}

// ---------------- launcher ----------------
extern "C" void kernel_launch(void* const* d_in, const int* in_sizes, int n_in,
                              void* d_out, int out_size, void* d_ws, size_t ws_size,
                              hipStream_t stream) {
  (void)in_sizes; (void)n_in; (void)out_size; (void)ws_size;
  const float* node  = (const float*)d_in[0];
  const float* edgef = (const float*)d_in[1];
  const float* coords= (const float*)d_in[2];
  const float* Ws  = (const float*)d_in[3];  const float* bs  = (const float*)d_in[4];
  const float* Wd  = (const float*)d_in[5];  const float* bd  = (const float*)d_in[6];
  const float* Wv  = (const float*)d_in[7];  const float* bv  = (const float*)d_in[8];
  const float* We1 = (const float*)d_in[9];  const float* be1 = (const float*)d_in[10];
  const float* We2 = (const float*)d_in[11]; const float* be2 = (const float*)d_in[12];
  const float* Wun = (const float*)d_in[13]; const float* bun = (const float*)d_in[14];
  const float* Wue = (const float*)d_in[15]; const float* bue = (const float*)d_in[16];
  const float* Wg  = (const float*)d_in[17]; const float* bg  = (const float*)d_in[18];
  const float* Wf1 = (const float*)d_in[19]; const float* bf1 = (const float*)d_in[20];
  const float* Wf2 = (const float*)d_in[21]; const float* bf2 = (const float*)d_in[22];
  const float* g1w = (const float*)d_in[23]; const float* g1b = (const float*)d_in[24];
  const float* g1a = (const float*)d_in[25];
  const float* g2w = (const float*)d_in[26]; const float* g2b = (const float*)d_in[27];
  const float* g2a = (const float*)d_in[28];
  const int* EI    = (const int*)d_in[29];
  const int* batch = (const int*)d_in[30];
  float* out = (float*)d_out;

  int*   wsi = (int*)d_ws;
  float* wsf = (float*)d_ws;
  int* deg    = wsi + W_DEG;
  int* cur    = wsi + W_CUR;
  int* offs   = wsi + W_OFF;
  int* bsum   = wsi + W_BSUM;
  int* gstart = wsi + W_GSTART;
  int* eidb   = wsi + W_EID;
  int* jcsr   = wsi + W_JC;
  float* gsum1 = wsf + W_GSUM1; float* gsq1 = wsf + W_GSQ1;
  float* gsum2 = wsf + W_GSUM2; float* gsq2 = wsf + W_GSQ2;
  float* scores_ = wsf + W_SCORES;
  u16* srcb = (u16*)(wsf + W_SRCB);
  u16* dstb = (u16*)(wsf + W_DSTB);
  u16* valb = (u16*)(wsf + W_VALB);
  float* A = wsf + W_A;   // agg -> x1 -> x2
  float* B = wsf + W_B;   // g
  u16*   we2b  = (u16*)(wsf + W_WE2B);
  u16*   wfrag = (u16*)(wsf + W_WPROJ);

  float* outE = out + (size_t)NN_ * DIM;
  float* outC = out + (size_t)NN_ * DIM + (size_t)NE_ * EOUTF;

  // zero the counter/stat prefix via DMA
  hipMemsetAsync(d_ws, 0, (size_t)W_ZEND * sizeof(int), stream);
  // consolidated setup: gstart + we2b + all weight hi/lo fragments
  setup_kernel<<<1089, 256, 0, stream>>>(batch, gstart, Wg, We2, we2b,
                                         Ws, Wd, Wv, Wun, Wf1, Wf2, wfrag);
  // CSR build
  deg_kernel<<<(NE_ + 255) / 256, 256, 0, stream>>>(EI, deg);
  scanA_kernel<<<(NN_ + 255) / 256, 256, 0, stream>>>(deg, offs, bsum);
  scanB_kernel<<<1, 128, 0, stream>>>(bsum);
  scanC_kernel<<<(NN_ + 255) / 256, 256, 0, stream>>>(offs, bsum);
  fill_kernel<<<(NE_ + 255) / 256, 256, 0, stream>>>(EI, offs, cur, eidb, jcsr);
  // projections via MFMA (bf16x2)
  proj_kernel<<<(NN_ + 31) / 32, 256, 0, stream>>>(node, wfrag, bs, bd, bv,
                                                   srcb, dstb, valb);
  // edge pipeline in CSR order
  edge_kernel<<<NE_ / 32, 256, 0, stream>>>(edgef, coords, EI, eidb, We1, be1,
                                            be2, we2b, Wue, bue,
                                            srcb, dstb, scores_, outE);
  // A := agg
  agg_kernel<<<NN_ / 4, 256, 0, stream>>>(valb, scores_, offs, jcsr, A);
  // MFMA: nnew+gate; B := g, A := x1; gn1 stats accumulated
  nnew_gate_kernel<<<(NN_ + 31) / 32, 256, 0, stream>>>(A, node, batch, wfrag,
                                                        bun, bg, gsum1, gsq1, B, A);
  // MFMA: fix_node with inline GN1; A := x2; gn2 stats accumulated
  fx_kernel<<<(NN_ + 31) / 32, 256, 0, stream>>>(A, batch, gstart, gsum1, gsq1,
                                                 g1w, g1b, g1a, wfrag, bf1, bf2,
                                                 B, gsum2, gsq2, A);
  // final GN apply + coords copy (merged)
  gn_apply_kernel<<<(NN_ * 32) / 256 + (NN_ * 3 + 255) / 256, 256, 0, stream>>>(
      A, batch, gstart, gsum2, gsq2, g2w, g2b, g2a, out, coords, outC);
}

// Round 12
// 529.761 us; speedup vs baseline: 1.4596x; 1.0040x over previous
//
#include <hip/hip_runtime.h>
#include <hip/hip_bf16.h>

#define NN_ 30000
#define NE_ 480000
#define DIM 128
#define EINF 16
#define EOUTF 16
#define NG 64
#define RSQRT_DH 0.17677669529663687f

typedef unsigned short u16;
typedef __attribute__((ext_vector_type(8))) short short8;
typedef __attribute__((ext_vector_type(8))) unsigned short ushort8v;
typedef __attribute__((ext_vector_type(4))) float floatx4;

// ---------------- workspace layout (32-bit word offsets) ----------------
#define W_DEG     0
#define W_CUR     30000
#define W_GSUM1   60000
#define W_GSQ1    68192
#define W_GSUM2   76384
#define W_GSQ2    84576
#define W_ZEND    92768
#define W_OFF     92768
#define W_BSUM    122772
#define W_GSTART  122900
#define W_EID     122968
#define W_JC      602968
#define W_SCORES  1082968
#define W_SRCB    3002968
#define W_DSTB    4922968
#define W_VALB    6842968
#define W_A       8762968
#define W_B       12602968
#define W_C       16442968
#define W_WGC     20282968
#define W_WE2B    20315736
#define W_WPROJ   20323928
#define W_WUEB    20455000
// wfrag: 16 halves x 16384 u16 = 131072 words; wueb: 8192 u16 = 4096 words
// end 20459096 words = 81.8 MB (133 MB proven safe)

static __device__ __forceinline__ u16 f2bf(float x) {
  __hip_bfloat16 h = __float2bfloat16(x);
  return *reinterpret_cast<u16*>(&h);
}
static __device__ __forceinline__ float bf2f(u16 v) {
  unsigned int b = ((unsigned int)v) << 16;
  return __uint_as_float(b);
}

// per-tile column reduce of a 32-row LDS tile (stride ld) into per-graph stats
static __device__ __forceinline__ void tile_gn_stats(const float* xsb, int ld,
    const int* bg_s, int row0, int tid,
    float* __restrict__ gsum, float* __restrict__ gsq) {
  int c = tid & 127, half = tid >> 7;
  float sm = 0.f, sq = 0.f;
  int gcur = -1;
  for (int r = 0; r < 16; ++r) {
    int rl = half * 16 + r;
    int row = row0 + rl;
    if (row >= NN_) break;
    int g = bg_s[rl];
    float v = xsb[rl * ld + c];
    if (g != gcur) {
      if (gcur >= 0) {
        atomicAdd(&gsum[gcur * DIM + c], sm);
        atomicAdd(&gsq[gcur * DIM + c], sq);
      }
      gcur = g; sm = 0.f; sq = 0.f;
    }
    sm += v; sq += v * v;
  }
  if (gcur >= 0) {
    atomicAdd(&gsum[gcur * DIM + c], sm);
    atomicAdd(&gsq[gcur * DIM + c], sq);
  }
}

// ---------------- consolidated setup kernel ----------------
// b0: gstart; b1..64: we2b; b65..1088: weight hi/lo fragments; b1089..1120:
// Wue hi/lo fragments (N=16, K=128 -> 4 s-chunks x 64 lanes x 8).
// wfrag half index = mat*2 + lo; mats: 0 Ws, 1 Wd, 2 Wv, 3 Wun,
// 4 Wgc0(=Wg[k]+Wg[256+k]), 5 Wgc1(=Wg[128+k]-Wg[256+k]), 6 Wf1, 7 Wf2.
__global__ void setup_kernel(const int* __restrict__ batch, int* __restrict__ gstart,
                             const float* __restrict__ Wg,
                             const float* __restrict__ We2, u16* __restrict__ we2b,
                             const float* __restrict__ Ws, const float* __restrict__ Wd,
                             const float* __restrict__ Wv, const float* __restrict__ Wun,
                             const float* __restrict__ Wf1, const float* __restrict__ Wf2,
                             u16* __restrict__ wfrag,
                             const float* __restrict__ Wue, u16* __restrict__ wueb) {
  int b = blockIdx.x, tid = threadIdx.x;
  if (b == 0) {
    int g = tid;
    if (g <= NG) {
      int lo = 0, hi = NN_;
      while (lo < hi) { int mid = (lo + hi) >> 1; if (batch[mid] < g) lo = mid + 1; else hi = mid; }
      gstart[g] = lo;
    }
  } else if (b < 65) {
    int idx = (b - 1) * 256 + tid;   // 16384 elems
    int j = idx & 7, lane = (idx >> 3) & 63, s = (idx >> 9) & 3, T = idx >> 11;
    int k = s * 32 + ((lane >> 4) << 3) + j;
    int n = T * 16 + (lane & 15);
    we2b[idx] = f2bf(We2[(size_t)k * DIM + n]);
  } else if (b < 1089) {
    int idx = (b - 65) * 256 + tid;   // 262144 elems: 16 halves x 16384
    int which = idx >> 14;            // mat*2 + lo
    int sub = idx & 16383;
    int j = sub & 7, lane = (sub >> 3) & 63, s = (sub >> 9) & 3, T = sub >> 11;
    int k = s * 32 + ((lane >> 4) << 3) + j;
    int n = T * 16 + (lane & 15);
    int mat = which >> 1;
    float w;
    if (mat == 4) w = Wg[(size_t)k * DIM + n] + Wg[(size_t)(256 + k) * DIM + n];
    else if (mat == 5) w = Wg[(size_t)(128 + k) * DIM + n] - Wg[(size_t)(256 + k) * DIM + n];
    else {
      const float* Wsrc = (mat == 0) ? Ws : (mat == 1) ? Wd : (mat == 2) ? Wv
                        : (mat == 3) ? Wun : (mat == 6) ? Wf1 : Wf2;
      w = Wsrc[(size_t)k * DIM + n];
    }
    u16 h = f2bf(w);
    wfrag[(size_t)which * 16384 + sub] = (which & 1) ? f2bf(w - bf2f(h)) : h;
  } else {
    int idx = (b - 1089) * 256 + tid;   // 8192 elems: 2 halves x 4096
    int half = idx >> 12;               // 0 hi, 1 lo
    int sub = idx & 4095;
    int j = sub & 7, lane = (sub >> 3) & 63, sG = sub >> 9;   // sG 0..3
    int k = sG * 32 + ((lane >> 4) << 3) + j;
    int n = lane & 15;
    float w = Wue[(size_t)k * EOUTF + n];
    u16 h = f2bf(w);
    wueb[half * 4096 + sub] = half ? f2bf(w - bf2f(h)) : h;
  }
}

__global__ void deg_kernel(const int* __restrict__ EI, int* __restrict__ deg) {
  int e = blockIdx.x * 256 + threadIdx.x;
  if (e < NE_) atomicAdd(&deg[EI[e]], 1);
}

// ---------------- node projections via MFMA (bf16x2 split) --------------
__global__ void __launch_bounds__(256) proj_kernel(
    const float* __restrict__ node, const u16* __restrict__ wfrag,
    const float* __restrict__ bs, const float* __restrict__ bd,
    const float* __restrict__ bv,
    u16* __restrict__ srcb, u16* __restrict__ dstb, u16* __restrict__ valb) {
  __shared__ __align__(16) u16 ah[32 * 136];
  __shared__ __align__(16) u16 al[32 * 136];
  __shared__ __align__(16) float park[32 * 132];
  int tid = threadIdx.x, row0 = blockIdx.x * 32;
  int r2 = tid >> 3, c16 = (tid & 7) * 16;

  {
    int row = row0 + r2;
    float v[16];
    if (row < NN_) {
#pragma unroll
      for (int q = 0; q < 4; ++q) {
        float4 x = *(const float4*)&node[(size_t)row * DIM + c16 + q * 4];
        v[q * 4 + 0] = x.x; v[q * 4 + 1] = x.y;
        v[q * 4 + 2] = x.z; v[q * 4 + 3] = x.w;
      }
    } else {
#pragma unroll
      for (int q = 0; q < 16; ++q) v[q] = 0.f;
    }
#pragma unroll
    for (int h2 = 0; h2 < 2; ++h2) {
      ushort8v hh, ll;
#pragma unroll
      for (int q = 0; q < 8; ++q) {
        float x = v[h2 * 8 + q];
        u16 h = f2bf(x);
        hh[q] = h;
        ll[q] = f2bf(x - bf2f(h));
      }
      *(ushort8v*)&ah[r2 * 136 + c16 + h2 * 8] = hh;
      *(ushort8v*)&al[r2 * 136 + c16 + h2 * 8] = ll;
    }
  }
  __syncthreads();

  int wv_ = tid >> 6, lane = tid & 63;
  int mtile = wv_ & 1, nhalf = wv_ >> 1;
  int quad = lane >> 4, lrow = lane & 15;
  int m0 = mtile * 16;

  short8 afh[4], afl[4];
#pragma unroll
  for (int s = 0; s < 4; ++s) {
    afh[s] = *(const short8*)&ah[(m0 + lrow) * 136 + s * 32 + quad * 8];
    afl[s] = *(const short8*)&al[(m0 + lrow) * 136 + s * 32 + quad * 8];
  }

  const float* Bt[3] = {bs, bd, bv};
  u16* Yt[3] = {srcb, dstb, valb};
#pragma unroll 1
  for (int g3 = 0; g3 < 3; ++g3) {
    const u16* wh = wfrag + (size_t)(g3 * 2 + 0) * 16384;
    const u16* wl = wfrag + (size_t)(g3 * 2 + 1) * 16384;
    floatx4 dacc[4];
#pragma unroll
    for (int t = 0; t < 4; ++t) dacc[t] = (floatx4){0.f, 0.f, 0.f, 0.f};
#pragma unroll
    for (int s = 0; s < 4; ++s) {
#pragma unroll
      for (int t = 0; t < 4; ++t) {
        int T = nhalf * 4 + t;
        size_t off = (size_t)((T * 4 + s) * 64 + lane) * 8;
        short8 bh = *(const short8*)&wh[off];
        short8 bl = *(const short8*)&wl[off];
        dacc[t] = __builtin_amdgcn_mfma_f32_16x16x32_bf16(afh[s], bh, dacc[t], 0, 0, 0);
        dacc[t] = __builtin_amdgcn_mfma_f32_16x16x32_bf16(afl[s], bh, dacc[t], 0, 0, 0);
        dacc[t] = __builtin_amdgcn_mfma_f32_16x16x32_bf16(afh[s], bl, dacc[t], 0, 0, 0);
      }
    }
#pragma unroll
    for (int t = 0; t < 4; ++t) {
      int col = nhalf * 64 + t * 16 + lrow;
#pragma unroll
      for (int r = 0; r < 4; ++r)
        park[(m0 + quad * 4 + r) * 132 + col] = dacc[t][r];
    }
    __syncthreads();
    {
      int row = row0 + r2;
      if (row < NN_) {
#pragma unroll
        for (int h2 = 0; h2 < 2; ++h2) {
          ushort8v o;
#pragma unroll
          for (int q = 0; q < 8; ++q) {
            float pv = park[r2 * 132 + c16 + h2 * 8 + q] + Bt[g3][c16 + h2 * 8 + q];
            o[q] = f2bf(pv);
          }
          *(ushort8v*)&Yt[g3][(size_t)row * DIM + c16 + h2 * 8] = o;
        }
      }
    }
    __syncthreads();
  }
}

// ---------------- nnew+gate via MFMA + gn1 stats ----------------
__global__ void __launch_bounds__(256) nnew_gate_kernel(
    const float* __restrict__ AGG, const float* __restrict__ NODE,
    const int* __restrict__ batch, const u16* __restrict__ wfrag,
    const float* __restrict__ bun, const float* __restrict__ bg,
    float* __restrict__ gsum1, float* __restrict__ gsq1,
    float* __restrict__ G, float* __restrict__ X1) {
  __shared__ __align__(16) u16 a_h[32 * 136];   // AGG frags -> nnew frags
  __shared__ __align__(16) u16 a_l[32 * 136];
  __shared__ __align__(16) u16 n_h[32 * 136];   // NODE frags
  __shared__ __align__(16) u16 n_l[32 * 136];
  __shared__ __align__(16) float park[32 * 132]; // nnew(raw) -> x1
  __shared__ int bg_s[32];
  int tid = threadIdx.x, row0 = blockIdx.x * 32;
  int r2 = tid >> 3, c16 = (tid & 7) * 16;
  if (tid < 32) bg_s[tid] = (row0 + tid < NN_) ? batch[row0 + tid] : 0;

  {
    int row = row0 + r2;
    float va[16], vn[16];
    if (row < NN_) {
#pragma unroll
      for (int q = 0; q < 4; ++q) {
        float4 xa = *(const float4*)&AGG[(size_t)row * DIM + c16 + q * 4];
        float4 xn = *(const float4*)&NODE[(size_t)row * DIM + c16 + q * 4];
        va[q * 4 + 0] = xa.x; va[q * 4 + 1] = xa.y; va[q * 4 + 2] = xa.z; va[q * 4 + 3] = xa.w;
        vn[q * 4 + 0] = xn.x; vn[q * 4 + 1] = xn.y; vn[q * 4 + 2] = xn.z; vn[q * 4 + 3] = xn.w;
      }
    } else {
#pragma unroll
      for (int q = 0; q < 16; ++q) { va[q] = 0.f; vn[q] = 0.f; }
    }
#pragma unroll
    for (int h2 = 0; h2 < 2; ++h2) {
      ushort8v ah8, al8, nh8, nl8;
#pragma unroll
      for (int q = 0; q < 8; ++q) {
        float x = va[h2 * 8 + q];
        u16 h = f2bf(x); ah8[q] = h; al8[q] = f2bf(x - bf2f(h));
        float y = vn[h2 * 8 + q];
        u16 hy = f2bf(y); nh8[q] = hy; nl8[q] = f2bf(y - bf2f(hy));
      }
      *(ushort8v*)&a_h[r2 * 136 + c16 + h2 * 8] = ah8;
      *(ushort8v*)&a_l[r2 * 136 + c16 + h2 * 8] = al8;
      *(ushort8v*)&n_h[r2 * 136 + c16 + h2 * 8] = nh8;
      *(ushort8v*)&n_l[r2 * 136 + c16 + h2 * 8] = nl8;
    }
  }
  __syncthreads();

  int wv_ = tid >> 6, lane = tid & 63;
  int mtile = wv_ & 1, nhalf = wv_ >> 1;
  int quad = lane >> 4, lrow = lane & 15;
  int m0 = mtile * 16;

  const u16* WunH = wfrag + (size_t)6 * 16384;
  const u16* WunL = wfrag + (size_t)7 * 16384;
  const u16* G0H  = wfrag + (size_t)8 * 16384;
  const u16* G0L  = wfrag + (size_t)9 * 16384;
  const u16* G1H  = wfrag + (size_t)10 * 16384;
  const u16* G1L  = wfrag + (size_t)11 * 16384;

  // MFMA1: nnew = AGG @ Wun (raw, bias added later)
  {
    short8 fh[4], fl[4];
#pragma unroll
    for (int s = 0; s < 4; ++s) {
      fh[s] = *(const short8*)&a_h[(m0 + lrow) * 136 + s * 32 + quad * 8];
      fl[s] = *(const short8*)&a_l[(m0 + lrow) * 136 + s * 32 + quad * 8];
    }
    floatx4 d1[4];
#pragma unroll
    for (int t = 0; t < 4; ++t) d1[t] = (floatx4){0.f, 0.f, 0.f, 0.f};
#pragma unroll
    for (int s = 0; s < 4; ++s) {
#pragma unroll
      for (int t = 0; t < 4; ++t) {
        int T = nhalf * 4 + t;
        size_t off = (size_t)((T * 4 + s) * 64 + lane) * 8;
        short8 bh = *(const short8*)&WunH[off];
        short8 bl = *(const short8*)&WunL[off];
        d1[t] = __builtin_amdgcn_mfma_f32_16x16x32_bf16(fh[s], bh, d1[t], 0, 0, 0);
        d1[t] = __builtin_amdgcn_mfma_f32_16x16x32_bf16(fl[s], bh, d1[t], 0, 0, 0);
        d1[t] = __builtin_amdgcn_mfma_f32_16x16x32_bf16(fh[s], bl, d1[t], 0, 0, 0);
      }
    }
#pragma unroll
    for (int t = 0; t < 4; ++t) {
      int col = nhalf * 64 + t * 16 + lrow;
#pragma unroll
      for (int r = 0; r < 4; ++r)
        park[(m0 + quad * 4 + r) * 132 + col] = d1[t][r];
    }
  }
  __syncthreads();

  // re-split nnew+bun into the dead AGG-frag region (A layout for MFMA2)
  {
#pragma unroll
    for (int h2 = 0; h2 < 2; ++h2) {
      ushort8v hh, ll;
#pragma unroll
      for (int q = 0; q < 8; ++q) {
        float x = park[r2 * 132 + c16 + h2 * 8 + q] + bun[c16 + h2 * 8 + q];
        u16 h = f2bf(x); hh[q] = h; ll[q] = f2bf(x - bf2f(h));
      }
      *(ushort8v*)&a_h[r2 * 136 + c16 + h2 * 8] = hh;
      *(ushort8v*)&a_l[r2 * 136 + c16 + h2 * 8] = ll;
    }
  }
  __syncthreads();

  // MFMA2: z = nnew@Wgc0 + NODE@Wgc1; epilogue in C-layout
  {
    short8 mh[4], ml[4], ph[4], pl[4];
#pragma unroll
    for (int s = 0; s < 4; ++s) {
      mh[s] = *(const short8*)&a_h[(m0 + lrow) * 136 + s * 32 + quad * 8];
      ml[s] = *(const short8*)&a_l[(m0 + lrow) * 136 + s * 32 + quad * 8];
      ph[s] = *(const short8*)&n_h[(m0 + lrow) * 136 + s * 32 + quad * 8];
      pl[s] = *(const short8*)&n_l[(m0 + lrow) * 136 + s * 32 + quad * 8];
    }
    floatx4 d2[4];
#pragma unroll
    for (int t = 0; t < 4; ++t) d2[t] = (floatx4){0.f, 0.f, 0.f, 0.f};
#pragma unroll
    for (int s = 0; s < 4; ++s) {
#pragma unroll
      for (int t = 0; t < 4; ++t) {
        int T = nhalf * 4 + t;
        size_t off = (size_t)((T * 4 + s) * 64 + lane) * 8;
        short8 g0h = *(const short8*)&G0H[off];
        short8 g0l = *(const short8*)&G0L[off];
        short8 g1h = *(const short8*)&G1H[off];
        short8 g1l = *(const short8*)&G1L[off];
        d2[t] = __builtin_amdgcn_mfma_f32_16x16x32_bf16(mh[s], g0h, d2[t], 0, 0, 0);
        d2[t] = __builtin_amdgcn_mfma_f32_16x16x32_bf16(ml[s], g0h, d2[t], 0, 0, 0);
        d2[t] = __builtin_amdgcn_mfma_f32_16x16x32_bf16(mh[s], g0l, d2[t], 0, 0, 0);
        d2[t] = __builtin_amdgcn_mfma_f32_16x16x32_bf16(ph[s], g1h, d2[t], 0, 0, 0);
        d2[t] = __builtin_amdgcn_mfma_f32_16x16x32_bf16(pl[s], g1h, d2[t], 0, 0, 0);
        d2[t] = __builtin_amdgcn_mfma_f32_16x16x32_bf16(ph[s], g1l, d2[t], 0, 0, 0);
      }
    }
#pragma unroll
    for (int t = 0; t < 4; ++t) {
      int col = nhalf * 64 + t * 16 + lrow;
      float bgv = bg[col], bunv = bun[col];
#pragma unroll
      for (int r = 0; r < 4; ++r) {
        int erow = m0 + quad * 4 + r;
        int row = row0 + erow;
        float z = d2[t][r] + bgv;
        float gg = 1.f / (1.f + __expf(-z));
        float nn = park[erow * 132 + col] + bunv;
        float nodev = bf2f(n_h[erow * 136 + col]) + bf2f(n_l[erow * 136 + col]);
        float x1 = gg * nn + nodev;
        park[erow * 132 + col] = x1;
        if (row < NN_) {
          G[(size_t)row * DIM + col] = gg;
          X1[(size_t)row * DIM + col] = x1;
        }
      }
    }
  }
  __syncthreads();
  tile_gn_stats(park, 132, bg_s, row0, tid, gsum1, gsq1);
}

// ---------------- fix_node via MFMA + inline GN1 + gn2 stats ------------
__global__ void __launch_bounds__(256) fx_kernel(
    const float* __restrict__ X1, const int* __restrict__ batch,
    const int* __restrict__ gstart,
    const float* __restrict__ gsum1, const float* __restrict__ gsq1,
    const float* __restrict__ g1w, const float* __restrict__ g1b,
    const float* __restrict__ g1a, const u16* __restrict__ wfrag,
    const float* __restrict__ bf1, const float* __restrict__ bf2,
    const float* __restrict__ G,
    float* __restrict__ gsum2, float* __restrict__ gsq2,
    float* __restrict__ X2) {
  __shared__ __align__(16) u16 a_h[32 * 136];   // n1 frags -> t frags
  __shared__ __align__(16) u16 a_l[32 * 136];
  __shared__ __align__(16) float n1s[32 * 132]; // n1 -> x2
  __shared__ int bg_s[32];
  int tid = threadIdx.x, row0 = blockIdx.x * 32;
  int r2 = tid >> 3, c16 = (tid & 7) * 16;
  if (tid < 32) bg_s[tid] = (row0 + tid < NN_) ? batch[row0 + tid] : 0;

  // stage x1 + inline GN1 -> n1 (f32 tile + hi/lo frags)
  {
    int row = row0 + r2;
    int gi = (row < NN_) ? batch[row] : 0;
    float cnt = fmaxf((float)(gstart[gi + 1] - gstart[gi]), 1.f);
    float inv = 1.f / cnt;
    float v[16];
    if (row < NN_) {
#pragma unroll
      for (int q = 0; q < 4; ++q) {
        float4 x = *(const float4*)&X1[(size_t)row * DIM + c16 + q * 4];
        v[q * 4 + 0] = x.x; v[q * 4 + 1] = x.y;
        v[q * 4 + 2] = x.z; v[q * 4 + 3] = x.w;
      }
    } else {
#pragma unroll
      for (int q = 0; q < 16; ++q) v[q] = 0.f;
    }
#pragma unroll
    for (int q0 = 0; q0 < 16; ++q0) {
      int c = c16 + q0;
      float sm = gsum1[gi * DIM + c], sq = gsq1[gi * DIM + c];
      float mean = sm * inv, msq = sq * inv, am = g1a[c] * mean;
      float var = msq - 2.f * am * mean + am * am;
      v[q0] = g1w[c] * (v[q0] - am) * rsqrtf(var + 1e-5f) + g1b[c];
    }
#pragma unroll
    for (int q = 0; q < 4; ++q) {
      float4 o; o.x = v[q * 4 + 0]; o.y = v[q * 4 + 1];
      o.z = v[q * 4 + 2]; o.w = v[q * 4 + 3];
      *(float4*)&n1s[r2 * 132 + c16 + q * 4] = o;
    }
#pragma unroll
    for (int h2 = 0; h2 < 2; ++h2) {
      ushort8v hh, ll;
#pragma unroll
      for (int q = 0; q < 8; ++q) {
        float x = v[h2 * 8 + q];
        u16 h = f2bf(x); hh[q] = h; ll[q] = f2bf(x - bf2f(h));
      }
      *(ushort8v*)&a_h[r2 * 136 + c16 + h2 * 8] = hh;
      *(ushort8v*)&a_l[r2 * 136 + c16 + h2 * 8] = ll;
    }
  }
  __syncthreads();

  int wv_ = tid >> 6, lane = tid & 63;
  int mtile = wv_ & 1, nhalf = wv_ >> 1;
  int quad = lane >> 4, lrow = lane & 15;
  int m0 = mtile * 16;

  const u16* F1H = wfrag + (size_t)12 * 16384;
  const u16* F1L = wfrag + (size_t)13 * 16384;
  const u16* F2H = wfrag + (size_t)14 * 16384;
  const u16* F2L = wfrag + (size_t)15 * 16384;

  short8 fh[4], fl[4];
#pragma unroll
  for (int s = 0; s < 4; ++s) {
    fh[s] = *(const short8*)&a_h[(m0 + lrow) * 136 + s * 32 + quad * 8];
    fl[s] = *(const short8*)&a_l[(m0 + lrow) * 136 + s * 32 + quad * 8];
  }
  __syncthreads();   // all frags in regs before the t-scatter overwrites

  // MFMA1: t = leaky(n1 @ Wf1 + bf1); scatter hi/lo into a_h/a_l (C->A)
  {
    floatx4 d1[4];
#pragma unroll
    for (int t = 0; t < 4; ++t) d1[t] = (floatx4){0.f, 0.f, 0.f, 0.f};
#pragma unroll
    for (int s = 0; s < 4; ++s) {
#pragma unroll
      for (int t = 0; t < 4; ++t) {
        int T = nhalf * 4 + t;
        size_t off = (size_t)((T * 4 + s) * 64 + lane) * 8;
        short8 bh = *(const short8*)&F1H[off];
        short8 bl = *(const short8*)&F1L[off];
        d1[t] = __builtin_amdgcn_mfma_f32_16x16x32_bf16(fh[s], bh, d1[t], 0, 0, 0);
        d1[t] = __builtin_amdgcn_mfma_f32_16x16x32_bf16(fl[s], bh, d1[t], 0, 0, 0);
        d1[t] = __builtin_amdgcn_mfma_f32_16x16x32_bf16(fh[s], bl, d1[t], 0, 0, 0);
      }
    }
#pragma unroll
    for (int t = 0; t < 4; ++t) {
      int col = nhalf * 64 + t * 16 + lrow;
      float b1v = bf1[col];
#pragma unroll
      for (int r = 0; r < 4; ++r) {
        int erow = m0 + quad * 4 + r;
        float tt = d1[t][r] + b1v;
        tt = tt > 0.f ? tt : 0.01f * tt;
        u16 h = f2bf(tt);
        a_h[erow * 136 + col] = h;
        a_l[erow * 136 + col] = f2bf(tt - bf2f(h));
      }
    }
  }
  __syncthreads();

  // MFMA2: x2 = g*(t @ Wf2 + bf2) + n1
  {
    short8 th[4], tl[4];
#pragma unroll
    for (int s = 0; s < 4; ++s) {
      th[s] = *(const short8*)&a_h[(m0 + lrow) * 136 + s * 32 + quad * 8];
      tl[s] = *(const short8*)&a_l[(m0 + lrow) * 136 + s * 32 + quad * 8];
    }
    floatx4 d2[4];
#pragma unroll
    for (int t = 0; t < 4; ++t) d2[t] = (floatx4){0.f, 0.f, 0.f, 0.f};
#pragma unroll
    for (int s = 0; s < 4; ++s) {
#pragma unroll
      for (int t = 0; t < 4; ++t) {
        int T = nhalf * 4 + t;
        size_t off = (size_t)((T * 4 + s) * 64 + lane) * 8;
        short8 bh = *(const short8*)&F2H[off];
        short8 bl = *(const short8*)&F2L[off];
        d2[t] = __builtin_amdgcn_mfma_f32_16x16x32_bf16(th[s], bh, d2[t], 0, 0, 0);
        d2[t] = __builtin_amdgcn_mfma_f32_16x16x32_bf16(tl[s], bh, d2[t], 0, 0, 0);
        d2[t] = __builtin_amdgcn_mfma_f32_16x16x32_bf16(th[s], bl, d2[t], 0, 0, 0);
      }
    }
#pragma unroll
    for (int t = 0; t < 4; ++t) {
      int col = nhalf * 64 + t * 16 + lrow;
      float b2v = bf2[col];
#pragma unroll
      for (int r = 0; r < 4; ++r) {
        int erow = m0 + quad * 4 + r;
        int row = row0 + erow;
        float gg = (row < NN_) ? G[(size_t)row * DIM + col] : 0.f;
        float x2 = gg * (d2[t][r] + b2v) + n1s[erow * 132 + col];
        n1s[erow * 132 + col] = x2;
        if (row < NN_) X2[(size_t)row * DIM + col] = x2;
      }
    }
  }
  __syncthreads();
  tile_gn_stats(n1s, 132, bg_s, row0, tid, gsum2, gsq2);
}

// ---------------- CSR build ----------------
__global__ void scanA_kernel(const int* __restrict__ deg, int* __restrict__ off,
                             int* __restrict__ bsum) {
  __shared__ int buf[256];
  int tid = threadIdx.x;
  int i = blockIdx.x * 256 + tid;
  int v = (i < NN_) ? deg[i] : 0;
  buf[tid] = v;
  __syncthreads();
  for (int s = 1; s < 256; s <<= 1) {
    int t = (tid >= s) ? buf[tid - s] : 0;
    __syncthreads();
    buf[tid] += t;
    __syncthreads();
  }
  if (i < NN_) off[i] = buf[tid] - v;
  if (tid == 255) bsum[blockIdx.x] = buf[255];
}

__global__ void scanB_kernel(int* __restrict__ bsum) {
  const int NBLK = (NN_ + 255) / 256;
  __shared__ int buf[128];
  int tid = threadIdx.x;
  int v = (tid < NBLK) ? bsum[tid] : 0;
  buf[tid] = v;
  __syncthreads();
  for (int s = 1; s < 128; s <<= 1) {
    int t = (tid >= s) ? buf[tid - s] : 0;
    __syncthreads();
    buf[tid] += t;
    __syncthreads();
  }
  if (tid < NBLK) bsum[tid] = buf[tid] - v;
}

__global__ void scanC_kernel(int* __restrict__ off, const int* __restrict__ bsum) {
  int i = blockIdx.x * 256 + threadIdx.x;
  if (i < NN_) off[i] += bsum[i >> 8];
  if (i == 0) off[NN_] = NE_;
}

__global__ void fill_kernel(const int* __restrict__ EI, const int* __restrict__ off,
                            int* __restrict__ cur, int* __restrict__ eidb,
                            int* __restrict__ jcsr) {
  int e = blockIdx.x * 256 + threadIdx.x;
  if (e >= NE_) return;
  int i = EI[e];
  int p = atomicAdd(&cur[i], 1);
  int pos = off[i] + p;
  eidb[pos] = e;
  jcsr[pos] = EI[NE_ + e];
}

// ---------------- fused edge kernel, CSR order ----------------
// R12: edge_new (er @ Wue) via MFMA (bf16x2, waves = mtile x khalf, two
// partial parks summed in epilogue). Drops the wue_s staging + 256-fma VALU
// loop. LDS: sbuf 5504 floats = 22016 B -> 7 blocks/CU.
// Phase A: xs[0..640) + hbf as u16 at [640..2816). Phase B: parks[0..1280)
// + ers[1280..5504).
__global__ void __launch_bounds__(256, 7) edge_kernel(
    const float* __restrict__ edgef, const float* __restrict__ coords,
    const int* __restrict__ EI, const int* __restrict__ eidb,
    const float* __restrict__ We1, const float* __restrict__ be1,
    const float* __restrict__ be2, const u16* __restrict__ we2b,
    const u16* __restrict__ wueb, const float* __restrict__ bue,
    const u16* __restrict__ srcb, const u16* __restrict__ dstb,
    float* __restrict__ scores, float* __restrict__ outE) {
  __shared__ __align__(16) float sbuf[5504];
  __shared__ float bue_s[EOUTF];
  __shared__ int ii[32], jj[32], ee[32];

  float* xs   = sbuf;                 // [32][20], cols 0..16 used (phase A)
  u16*   hbf  = (u16*)(sbuf + 640);   // [32][136] (phase A)
  float* park = sbuf;                 // [2][32][20] (phase B)
  float* ers  = sbuf + 1280;          // [32][132] (phase B)

  int tid = threadIdx.x;
  int bid = blockIdx.x;
  int bswz = (bid & 7) * (NE_ / 32 / 8) + (bid >> 3);
  int p0 = bswz * 32;

  if (tid < 32) {
    int p = p0 + tid;
    int e = eidb[p];
    ee[tid] = e;
    int i = EI[e], j = EI[NE_ + e];
    ii[tid] = i; jj[tid] = j;
    float dx = coords[i * 3 + 0] - coords[j * 3 + 0];
    float dy = coords[i * 3 + 1] - coords[j * 3 + 1];
    float dz = coords[i * 3 + 2] - coords[j * 3 + 2];
    float dist = sqrtf(dx * dx + dy * dy + dz * dz + 1e-12f) * 0.1f;
    xs[tid * 20 + 16] = dist;
  }
  if (tid < EOUTF) bue_s[tid] = bue[tid];
  __syncthreads();

  if (tid < 128) {
    int r = tid >> 2, c4 = (tid & 3) * 4;
    *(float4*)&xs[r * 20 + c4] = *(const float4*)&edgef[(size_t)ee[r] * EINF + c4];
  }
  __syncthreads();

  int cg = tid & 31, rg = tid >> 5, c0 = cg * 4, r0 = rg * 4;

  // h = leaky(x @ We1 + be1), K=17 VALU; write bf16 to hbf
  {
    float acc[4][4] = {};
    for (int k = 0; k < 16; k += 4) {
      float4 w0 = *(const float4*)&We1[(size_t)(k + 0) * DIM + c0];
      float4 w1 = *(const float4*)&We1[(size_t)(k + 1) * DIM + c0];
      float4 w2 = *(const float4*)&We1[(size_t)(k + 2) * DIM + c0];
      float4 w3 = *(const float4*)&We1[(size_t)(k + 3) * DIM + c0];
#pragma unroll
      for (int u = 0; u < 4; ++u) {
        float4 xv = *(const float4*)&xs[(r0 + u) * 20 + k];
        acc[u][0] += xv.x * w0.x + xv.y * w1.x + xv.z * w2.x + xv.w * w3.x;
        acc[u][1] += xv.x * w0.y + xv.y * w1.y + xv.z * w2.y + xv.w * w3.y;
        acc[u][2] += xv.x * w0.z + xv.y * w1.z + xv.z * w2.z + xv.w * w3.z;
        acc[u][3] += xv.x * w0.w + xv.y * w1.w + xv.z * w2.w + xv.w * w3.w;
      }
    }
    {   // k = 16: the dist column
      float4 w4 = *(const float4*)&We1[(size_t)16 * DIM + c0];
#pragma unroll
      for (int u = 0; u < 4; ++u) {
        float xd = xs[(r0 + u) * 20 + 16];
        acc[u][0] += xd * w4.x; acc[u][1] += xd * w4.y;
        acc[u][2] += xd * w4.z; acc[u][3] += xd * w4.w;
      }
    }
    float4 b1 = *(const float4*)&be1[c0];
#pragma unroll
    for (int u = 0; u < 4; ++u) {
      float h0 = acc[u][0] + b1.x, h1 = acc[u][1] + b1.y;
      float h2 = acc[u][2] + b1.z, h3 = acc[u][3] + b1.w;
      h0 = h0 > 0.f ? h0 : 0.01f * h0; h1 = h1 > 0.f ? h1 : 0.01f * h1;
      h2 = h2 > 0.f ? h2 : 0.01f * h2; h3 = h3 > 0.f ? h3 : 0.01f * h3;
      ushort4 pk; pk.x = f2bf(h0); pk.y = f2bf(h1); pk.z = f2bf(h2); pk.w = f2bf(h3);
      *(ushort4*)&hbf[(r0 + u) * 136 + c0] = pk;
    }
  }
  __syncthreads();

  int wv = tid >> 6, lane = tid & 63;
  int mtile = wv & 1, nhalf = wv >> 1;   // nhalf doubles as khalf for MFMA2
  int quad = lane >> 4, lrow = lane & 15;
  int m0 = mtile * 16;

  short8 afrag[4];
#pragma unroll
  for (int s = 0; s < 4; ++s)
    afrag[s] = *(const short8*)&hbf[(m0 + lrow) * 136 + s * 32 + quad * 8];
  __syncthreads();   // xs/hbf dead -> phase B overlay begins

  // MFMA1: e2 = h @ We2
  floatx4 dacc[4];
#pragma unroll
  for (int t = 0; t < 4; ++t) dacc[t] = (floatx4){0.f, 0.f, 0.f, 0.f};
#pragma unroll
  for (int s = 0; s < 4; ++s) {
#pragma unroll
    for (int t = 0; t < 4; ++t) {
      int T = nhalf * 4 + t;
      short8 bfrg = *(const short8*)&we2b[(size_t)((T * 4 + s) * 64 + lane) * 8];
      dacc[t] = __builtin_amdgcn_mfma_f32_16x16x32_bf16(afrag[s], bfrg, dacc[t], 0, 0, 0);
    }
  }

#pragma unroll
  for (int t = 0; t < 4; ++t) {
    int col = nhalf * 64 + t * 16 + lrow;
    float b2v = be2[col];
#pragma unroll
    for (int r = 0; r < 4; ++r) {
      int erow = m0 + quad * 4 + r;
      ers[erow * 132 + col] = dacc[t][r] + b2v;
    }
  }
  __syncthreads();

  // pass 2: er = dst_i * src_j * e2 / sqrt(DH); gathers at use site
  {
    int el2 = tid >> 3, cb2 = tid & 7;
    int c0b = cb2 * 16;
    int irow = ii[el2], jrow = jj[el2];
    ushort8v dv8a = *(const ushort8v*)&dstb[(size_t)irow * DIM + c0b];
    ushort8v dv8b = *(const ushort8v*)&dstb[(size_t)irow * DIM + c0b + 8];
    ushort8v sv8a = *(const ushort8v*)&srcb[(size_t)jrow * DIM + c0b];
    ushort8v sv8b = *(const ushort8v*)&srcb[(size_t)jrow * DIM + c0b + 8];

    float ef[16];
#pragma unroll
    for (int q = 0; q < 4; ++q) {
      float4 v = *(const float4*)&ers[el2 * 132 + c0b + q * 4];
      ef[q * 4 + 0] = v.x; ef[q * 4 + 1] = v.y;
      ef[q * 4 + 2] = v.z; ef[q * 4 + 3] = v.w;
    }
    float asum = 0.f;
#pragma unroll
    for (int k = 0; k < 8; ++k) {
      float er = bf2f((u16)dv8a[k]) * bf2f((u16)sv8a[k]) * ef[k] * RSQRT_DH;
      ef[k] = er; asum += fabsf(er);
    }
#pragma unroll
    for (int k = 0; k < 8; ++k) {
      float er = bf2f((u16)dv8b[k]) * bf2f((u16)sv8b[k]) * ef[8 + k] * RSQRT_DH;
      ef[8 + k] = er; asum += fabsf(er);
    }
#pragma unroll
    for (int q = 0; q < 4; ++q) {
      float4 v; v.x = ef[q * 4 + 0]; v.y = ef[q * 4 + 1];
      v.z = ef[q * 4 + 2]; v.w = ef[q * 4 + 3];
      *(float4*)&ers[el2 * 132 + c0b + q * 4] = v;
    }
    asum += __shfl_xor(asum, 1);
    if ((cb2 & 1) == 0)
      scores[(size_t)(p0 + el2) * 4 + (cb2 >> 1)] = asum;
  }
  __syncthreads();

  // MFMA2: edge_new = er @ Wue. Wave (mtile, khalf=nhalf) computes its
  // K-half partial into park[khalf]; A-frags split bf16x2 from f32 ers.
  {
    floatx4 d3 = (floatx4){0.f, 0.f, 0.f, 0.f};
#pragma unroll
    for (int s = 0; s < 2; ++s) {
      int kbase = nhalf * 64 + s * 32 + quad * 8;
      const float* src = &ers[(m0 + lrow) * 132 + kbase];
      float4 e0 = *(const float4*)&src[0];
      float4 e1 = *(const float4*)&src[4];
      float ev[8] = {e0.x, e0.y, e0.z, e0.w, e1.x, e1.y, e1.z, e1.w};
      short8 ah8, al8;
#pragma unroll
      for (int q = 0; q < 8; ++q) {
        u16 h = f2bf(ev[q]);
        ah8[q] = (short)h;
        al8[q] = (short)f2bf(ev[q] - bf2f(h));
      }
      int sG = nhalf * 2 + s;
      size_t off = (size_t)(sG * 64 + lane) * 8;
      short8 bh = *(const short8*)&wueb[off];
      short8 bl = *(const short8*)&wueb[4096 + off];
      d3 = __builtin_amdgcn_mfma_f32_16x16x32_bf16(ah8, bh, d3, 0, 0, 0);
      d3 = __builtin_amdgcn_mfma_f32_16x16x32_bf16(al8, bh, d3, 0, 0, 0);
      d3 = __builtin_amdgcn_mfma_f32_16x16x32_bf16(ah8, bl, d3, 0, 0, 0);
    }
    // park partial: C layout for 16x16 tile -> row m0+quad*4+r, col lrow
#pragma unroll
    for (int r = 0; r < 4; ++r)
      park[nhalf * 640 + (m0 + quad * 4 + r) * 20 + lrow] = d3[r];
  }
  __syncthreads();

  // epilogue: sum K-half partials + bias -> scatter by original edge id
  {
    int el = tid >> 3, oc2 = (tid & 7) * 2;
    float a0 = park[el * 20 + oc2]     + park[640 + el * 20 + oc2]     + bue_s[oc2];
    float a1 = park[el * 20 + oc2 + 1] + park[640 + el * 20 + oc2 + 1] + bue_s[oc2 + 1];
    size_t ob = (size_t)ee[el] * EOUTF + oc2;
    float2 o2; o2.x = a0; o2.y = a1;
    *(float2*)&outE[ob] = o2;
  }
}

// ---------------- per-node softmax + aggregation (CSR gather) -----------
__global__ void __launch_bounds__(256) agg_kernel(
    const u16* __restrict__ valb, const float* __restrict__ scores,
    const int* __restrict__ off, const int* __restrict__ jcsr,
    float* __restrict__ agg) {
  int n = blockIdx.x * 4 + (threadIdx.x >> 6);
  int l = threadIdx.x & 63;
  if (n >= NN_) return;
  int s = off[n], e_end = off[n + 1];

  float m0 = -1e30f, m1 = -1e30f, m2 = -1e30f, m3 = -1e30f;
  for (int p = s + l; p < e_end; p += 64) {
    float4 sc = *(const float4*)&scores[(size_t)p * 4];
    m0 = fmaxf(m0, sc.x); m1 = fmaxf(m1, sc.y);
    m2 = fmaxf(m2, sc.z); m3 = fmaxf(m3, sc.w);
  }
#pragma unroll
  for (int d = 1; d < 64; d <<= 1) {
    m0 = fmaxf(m0, __shfl_xor(m0, d)); m1 = fmaxf(m1, __shfl_xor(m1, d));
    m2 = fmaxf(m2, __shfl_xor(m2, d)); m3 = fmaxf(m3, __shfl_xor(m3, d));
  }
  int hh = l >> 4;
  float mh = (hh == 0) ? m0 : (hh == 1) ? m1 : (hh == 2) ? m2 : m3;

  float acc0 = 0.f, acc1 = 0.f, den = 0.f;
  int p = s;
  for (; p + 4 <= e_end; p += 4) {
    int j0 = jcsr[p], j1 = jcsr[p + 1], j2 = jcsr[p + 2], j3 = jcsr[p + 3];
    float s0 = scores[(size_t)p * 4 + hh];
    float s1 = scores[(size_t)(p + 1) * 4 + hh];
    float s2 = scores[(size_t)(p + 2) * 4 + hh];
    float s3 = scores[(size_t)(p + 3) * 4 + hh];
    ushort2 u0 = *(const ushort2*)&valb[(size_t)j0 * DIM + 2 * l];
    ushort2 u1 = *(const ushort2*)&valb[(size_t)j1 * DIM + 2 * l];
    ushort2 u2 = *(const ushort2*)&valb[(size_t)j2 * DIM + 2 * l];
    ushort2 u3 = *(const ushort2*)&valb[(size_t)j3 * DIM + 2 * l];
    float e0 = __expf(s0 - mh), e1 = __expf(s1 - mh);
    float e2 = __expf(s2 - mh), e3 = __expf(s3 - mh);
    den += (e0 + e1) + (e2 + e3);
    acc0 += e0 * bf2f(u0.x) + e1 * bf2f(u1.x) + e2 * bf2f(u2.x) + e3 * bf2f(u3.x);
    acc1 += e0 * bf2f(u0.y) + e1 * bf2f(u1.y) + e2 * bf2f(u2.y) + e3 * bf2f(u3.y);
  }
  for (; p < e_end; ++p) {
    int j = jcsr[p];
    float s0 = scores[(size_t)p * 4 + hh];
    ushort2 u0 = *(const ushort2*)&valb[(size_t)j * DIM + 2 * l];
    float e0 = __expf(s0 - mh);
    den += e0;
    acc0 += e0 * bf2f(u0.x);
    acc1 += e0 * bf2f(u0.y);
  }
  float2 o;
  if (e_end > s) { o.x = acc0 / den; o.y = acc1 / den; }
  else { o.x = 0.f; o.y = 0.f; }
  *(float2*)&agg[(size_t)n * DIM + 2 * l] = o;
}

// ---------------- final GraphNorm apply + coords copy (merged) ----------
__global__ void gn_apply_kernel(const float* __restrict__ X, const int* __restrict__ batch,
    const int* __restrict__ gstart, const float* __restrict__ gsum,
    const float* __restrict__ gsq, const float* __restrict__ w,
    const float* __restrict__ b, const float* __restrict__ a,
    float* __restrict__ Y,
    const float* __restrict__ C, float* __restrict__ OC) {
  int blk = blockIdx.x;
  if (blk >= (NN_ * 32) / 256) {
    int i = (blk - (NN_ * 32) / 256) * 256 + threadIdx.x;
    if (i < NN_ * 3) OC[i] = C[i];
    return;
  }
  int idx = blk * 256 + threadIdx.x;
  int n = idx >> 5, c4 = (idx & 31) * 4;
  int g = batch[n];
  float cnt = fmaxf((float)(gstart[g + 1] - gstart[g]), 1.f);
  float inv = 1.f / cnt;
  float4 xv = *(const float4*)&X[(size_t)n * DIM + c4];
  float4 sm = *(const float4*)&gsum[g * DIM + c4];
  float4 sq = *(const float4*)&gsq[g * DIM + c4];
  float4 av = *(const float4*)&a[c4];
  float4 wv = *(const float4*)&w[c4];
  float4 bv = *(const float4*)&b[c4];
  float4 ov;
  {
    float mean = sm.x * inv, msq = sq.x * inv, am = av.x * mean;
    float var = msq - 2.f * am * mean + am * am;
    ov.x = wv.x * (xv.x - am) * rsqrtf(var + 1e-5f) + bv.x;
  }
  {
    float mean = sm.y * inv, msq = sq.y * inv, am = av.y * mean;
    float var = msq - 2.f * am * mean + am * am;
    ov.y = wv.y * (xv.y - am) * rsqrtf(var + 1e-5f) + bv.y;
  }
  {
    float mean = sm.z * inv, msq = sq.z * inv, am = av.z * mean;
    float var = msq - 2.f * am * mean + am * am;
    ov.z = wv.z * (xv.z - am) * rsqrtf(var + 1e-5f) + bv.z;
  }
  {
    float mean = sm.w * inv, msq = sq.w * inv, am = av.w * mean;
    float var = msq - 2.f * am * mean + am * am;
    ov.w = wv.w * (xv.w - am) * rsqrtf(var + 1e-5f) + bv.w;
  }
  *(float4*)&Y[(size_t)n * DIM + c4] = ov;
}

// ---------------- launcher ----------------
extern "C" void kernel_launch(void* const* d_in, const int* in_sizes, int n_in,
                              void* d_out, int out_size, void* d_ws, size_t ws_size,
                              hipStream_t stream) {
  (void)in_sizes; (void)n_in; (void)out_size; (void)ws_size;
  const float* node  = (const float*)d_in[0];
  const float* edgef = (const float*)d_in[1];
  const float* coords= (const float*)d_in[2];
  const float* Ws  = (const float*)d_in[3];  const float* bs  = (const float*)d_in[4];
  const float* Wd  = (const float*)d_in[5];  const float* bd  = (const float*)d_in[6];
  const float* Wv  = (const float*)d_in[7];  const float* bv  = (const float*)d_in[8];
  const float* We1 = (const float*)d_in[9];  const float* be1 = (const float*)d_in[10];
  const float* We2 = (const float*)d_in[11]; const float* be2 = (const float*)d_in[12];
  const float* Wun = (const float*)d_in[13]; const float* bun = (const float*)d_in[14];
  const float* Wue = (const float*)d_in[15]; const float* bue = (const float*)d_in[16];
  const float* Wg  = (const float*)d_in[17]; const float* bg  = (const float*)d_in[18];
  const float* Wf1 = (const float*)d_in[19]; const float* bf1 = (const float*)d_in[20];
  const float* Wf2 = (const float*)d_in[21]; const float* bf2 = (const float*)d_in[22];
  const float* g1w = (const float*)d_in[23]; const float* g1b = (const float*)d_in[24];
  const float* g1a = (const float*)d_in[25];
  const float* g2w = (const float*)d_in[26]; const float* g2b = (const float*)d_in[27];
  const float* g2a = (const float*)d_in[28];
  const int* EI    = (const int*)d_in[29];
  const int* batch = (const int*)d_in[30];
  float* out = (float*)d_out;

  int*   wsi = (int*)d_ws;
  float* wsf = (float*)d_ws;
  int* deg    = wsi + W_DEG;
  int* cur    = wsi + W_CUR;
  int* offs   = wsi + W_OFF;
  int* bsum   = wsi + W_BSUM;
  int* gstart = wsi + W_GSTART;
  int* eidb   = wsi + W_EID;
  int* jcsr   = wsi + W_JC;
  float* gsum1 = wsf + W_GSUM1; float* gsq1 = wsf + W_GSQ1;
  float* gsum2 = wsf + W_GSUM2; float* gsq2 = wsf + W_GSQ2;
  float* scores_ = wsf + W_SCORES;
  u16* srcb = (u16*)(wsf + W_SRCB);
  u16* dstb = (u16*)(wsf + W_DSTB);
  u16* valb = (u16*)(wsf + W_VALB);
  float* A = wsf + W_A;   // agg -> x1 -> x2
  float* B = wsf + W_B;   // g
  u16*   we2b  = (u16*)(wsf + W_WE2B);
  u16*   wfrag = (u16*)(wsf + W_WPROJ);
  u16*   wueb  = (u16*)(wsf + W_WUEB);

  float* outE = out + (size_t)NN_ * DIM;
  float* outC = out + (size_t)NN_ * DIM + (size_t)NE_ * EOUTF;

  // zero the counter/stat prefix via DMA
  hipMemsetAsync(d_ws, 0, (size_t)W_ZEND * sizeof(int), stream);
  // consolidated setup: gstart + we2b + weight hi/lo fragments + wue frags
  setup_kernel<<<1121, 256, 0, stream>>>(batch, gstart, Wg, We2, we2b,
                                         Ws, Wd, Wv, Wun, Wf1, Wf2, wfrag,
                                         Wue, wueb);
  // CSR build
  deg_kernel<<<(NE_ + 255) / 256, 256, 0, stream>>>(EI, deg);
  scanA_kernel<<<(NN_ + 255) / 256, 256, 0, stream>>>(deg, offs, bsum);
  scanB_kernel<<<1, 128, 0, stream>>>(bsum);
  scanC_kernel<<<(NN_ + 255) / 256, 256, 0, stream>>>(offs, bsum);
  fill_kernel<<<(NE_ + 255) / 256, 256, 0, stream>>>(EI, offs, cur, eidb, jcsr);
  // projections via MFMA (bf16x2)
  proj_kernel<<<(NN_ + 31) / 32, 256, 0, stream>>>(node, wfrag, bs, bd, bv,
                                                   srcb, dstb, valb);
  // edge pipeline in CSR order
  edge_kernel<<<NE_ / 32, 256, 0, stream>>>(edgef, coords, EI, eidb, We1, be1,
                                            be2, we2b, wueb, bue,
                                            srcb, dstb, scores_, outE);
  // A := agg
  agg_kernel<<<NN_ / 4, 256, 0, stream>>>(valb, scores_, offs, jcsr, A);
  // MFMA: nnew+gate; B := g, A := x1; gn1 stats accumulated
  nnew_gate_kernel<<<(NN_ + 31) / 32, 256, 0, stream>>>(A, node, batch, wfrag,
                                                        bun, bg, gsum1, gsq1, B, A);
  // MFMA: fix_node with inline GN1; A := x2; gn2 stats accumulated
  fx_kernel<<<(NN_ + 31) / 32, 256, 0, stream>>>(A, batch, gstart, gsum1, gsq1,
                                                 g1w, g1b, g1a, wfrag, bf1, bf2,
                                                 B, gsum2, gsq2, A);
  // final GN apply + coords copy (merged)
  gn_apply_kernel<<<(NN_ * 32) / 256 + (NN_ * 3 + 255) / 256, 256, 0, stream>>>(
      A, batch, gstart, gsum2, gsq2, g2w, g2b, g2a, out, coords, outC);
}

// Round 13
// 516.599 us; speedup vs baseline: 1.4968x; 1.0255x over previous
//
#include <hip/hip_runtime.h>
#include <hip/hip_bf16.h>

#define NN_ 30000
#define NE_ 480000
#define DIM 128
#define EINF 16
#define EOUTF 16
#define NG 64
#define RSQRT_DH 0.17677669529663687f

typedef unsigned short u16;
typedef __attribute__((ext_vector_type(8))) short short8;
typedef __attribute__((ext_vector_type(8))) unsigned short ushort8v;
typedef __attribute__((ext_vector_type(4))) float floatx4;

// ---------------- workspace layout (32-bit word offsets) ----------------
#define W_DEG     0
#define W_CUR     30000
#define W_GSUM1   60000
#define W_GSQ1    68192
#define W_GSUM2   76384
#define W_GSQ2    84576
#define W_ZEND    92768
#define W_OFF     92768
#define W_BSUM    122772
#define W_GSTART  122900
#define W_EID     122968
#define W_JC      602968
#define W_SCORES  1082968
#define W_SRCB    3002968
#define W_DSTB    4922968
#define W_VALB    6842968
#define W_A       8762968
#define W_B       12602968
#define W_C       16442968
#define W_WGC     20282968
#define W_WE2B    20315736
#define W_WPROJ   20323928
#define W_WUEB    20455000
// wfrag: 16 halves x 16384 u16 = 131072 words; wueb: 8192 u16 = 4096 words
// end 20459096 words = 81.8 MB (133 MB proven safe)

static __device__ __forceinline__ u16 f2bf(float x) {
  __hip_bfloat16 h = __float2bfloat16(x);
  return *reinterpret_cast<u16*>(&h);
}
static __device__ __forceinline__ float bf2f(u16 v) {
  unsigned int b = ((unsigned int)v) << 16;
  return __uint_as_float(b);
}

// per-tile column reduce of a 32-row LDS tile (stride ld) into per-graph stats
static __device__ __forceinline__ void tile_gn_stats(const float* xsb, int ld,
    const int* bg_s, int row0, int tid,
    float* __restrict__ gsum, float* __restrict__ gsq) {
  int c = tid & 127, half = tid >> 7;
  float sm = 0.f, sq = 0.f;
  int gcur = -1;
  for (int r = 0; r < 16; ++r) {
    int rl = half * 16 + r;
    int row = row0 + rl;
    if (row >= NN_) break;
    int g = bg_s[rl];
    float v = xsb[rl * ld + c];
    if (g != gcur) {
      if (gcur >= 0) {
        atomicAdd(&gsum[gcur * DIM + c], sm);
        atomicAdd(&gsq[gcur * DIM + c], sq);
      }
      gcur = g; sm = 0.f; sq = 0.f;
    }
    sm += v; sq += v * v;
  }
  if (gcur >= 0) {
    atomicAdd(&gsum[gcur * DIM + c], sm);
    atomicAdd(&gsq[gcur * DIM + c], sq);
  }
}

// ---------------- consolidated setup kernel ----------------
// b0: gstart; b1..64: we2b; b65..1088: weight hi/lo fragments; b1089..1120:
// Wue hi/lo fragments (N=16, K=128 -> 4 s-chunks x 64 lanes x 8).
// wfrag half index = mat*2 + lo; mats: 0 Ws, 1 Wd, 2 Wv, 3 Wun,
// 4 Wgc0(=Wg[k]+Wg[256+k]), 5 Wgc1(=Wg[128+k]-Wg[256+k]), 6 Wf1, 7 Wf2.
__global__ void setup_kernel(const int* __restrict__ batch, int* __restrict__ gstart,
                             const float* __restrict__ Wg,
                             const float* __restrict__ We2, u16* __restrict__ we2b,
                             const float* __restrict__ Ws, const float* __restrict__ Wd,
                             const float* __restrict__ Wv, const float* __restrict__ Wun,
                             const float* __restrict__ Wf1, const float* __restrict__ Wf2,
                             u16* __restrict__ wfrag,
                             const float* __restrict__ Wue, u16* __restrict__ wueb) {
  int b = blockIdx.x, tid = threadIdx.x;
  if (b == 0) {
    int g = tid;
    if (g <= NG) {
      int lo = 0, hi = NN_;
      while (lo < hi) { int mid = (lo + hi) >> 1; if (batch[mid] < g) lo = mid + 1; else hi = mid; }
      gstart[g] = lo;
    }
  } else if (b < 65) {
    int idx = (b - 1) * 256 + tid;   // 16384 elems
    int j = idx & 7, lane = (idx >> 3) & 63, s = (idx >> 9) & 3, T = idx >> 11;
    int k = s * 32 + ((lane >> 4) << 3) + j;
    int n = T * 16 + (lane & 15);
    we2b[idx] = f2bf(We2[(size_t)k * DIM + n]);
  } else if (b < 1089) {
    int idx = (b - 65) * 256 + tid;   // 262144 elems: 16 halves x 16384
    int which = idx >> 14;            // mat*2 + lo
    int sub = idx & 16383;
    int j = sub & 7, lane = (sub >> 3) & 63, s = (sub >> 9) & 3, T = sub >> 11;
    int k = s * 32 + ((lane >> 4) << 3) + j;
    int n = T * 16 + (lane & 15);
    int mat = which >> 1;
    float w;
    if (mat == 4) w = Wg[(size_t)k * DIM + n] + Wg[(size_t)(256 + k) * DIM + n];
    else if (mat == 5) w = Wg[(size_t)(128 + k) * DIM + n] - Wg[(size_t)(256 + k) * DIM + n];
    else {
      const float* Wsrc = (mat == 0) ? Ws : (mat == 1) ? Wd : (mat == 2) ? Wv
                        : (mat == 3) ? Wun : (mat == 6) ? Wf1 : Wf2;
      w = Wsrc[(size_t)k * DIM + n];
    }
    u16 h = f2bf(w);
    wfrag[(size_t)which * 16384 + sub] = (which & 1) ? f2bf(w - bf2f(h)) : h;
  } else {
    int idx = (b - 1089) * 256 + tid;   // 8192 elems: 2 halves x 4096
    int half = idx >> 12;               // 0 hi, 1 lo
    int sub = idx & 4095;
    int j = sub & 7, lane = (sub >> 3) & 63, sG = sub >> 9;   // sG 0..3
    int k = sG * 32 + ((lane >> 4) << 3) + j;
    int n = lane & 15;
    float w = Wue[(size_t)k * EOUTF + n];
    u16 h = f2bf(w);
    wueb[half * 4096 + sub] = half ? f2bf(w - bf2f(h)) : h;
  }
}

__global__ void deg_kernel(const int* __restrict__ EI, int* __restrict__ deg) {
  int e = blockIdx.x * 256 + threadIdx.x;
  if (e < NE_) atomicAdd(&deg[EI[e]], 1);
}

// ---------------- node projections via MFMA (bf16x2 split) --------------
__global__ void __launch_bounds__(256) proj_kernel(
    const float* __restrict__ node, const u16* __restrict__ wfrag,
    const float* __restrict__ bs, const float* __restrict__ bd,
    const float* __restrict__ bv,
    u16* __restrict__ srcb, u16* __restrict__ dstb, u16* __restrict__ valb) {
  __shared__ __align__(16) u16 ah[32 * 136];
  __shared__ __align__(16) u16 al[32 * 136];
  __shared__ __align__(16) float park[32 * 132];
  int tid = threadIdx.x, row0 = blockIdx.x * 32;
  int r2 = tid >> 3, c16 = (tid & 7) * 16;

  {
    int row = row0 + r2;
    float v[16];
    if (row < NN_) {
#pragma unroll
      for (int q = 0; q < 4; ++q) {
        float4 x = *(const float4*)&node[(size_t)row * DIM + c16 + q * 4];
        v[q * 4 + 0] = x.x; v[q * 4 + 1] = x.y;
        v[q * 4 + 2] = x.z; v[q * 4 + 3] = x.w;
      }
    } else {
#pragma unroll
      for (int q = 0; q < 16; ++q) v[q] = 0.f;
    }
#pragma unroll
    for (int h2 = 0; h2 < 2; ++h2) {
      ushort8v hh, ll;
#pragma unroll
      for (int q = 0; q < 8; ++q) {
        float x = v[h2 * 8 + q];
        u16 h = f2bf(x);
        hh[q] = h;
        ll[q] = f2bf(x - bf2f(h));
      }
      *(ushort8v*)&ah[r2 * 136 + c16 + h2 * 8] = hh;
      *(ushort8v*)&al[r2 * 136 + c16 + h2 * 8] = ll;
    }
  }
  __syncthreads();

  int wv_ = tid >> 6, lane = tid & 63;
  int mtile = wv_ & 1, nhalf = wv_ >> 1;
  int quad = lane >> 4, lrow = lane & 15;
  int m0 = mtile * 16;

  short8 afh[4], afl[4];
#pragma unroll
  for (int s = 0; s < 4; ++s) {
    afh[s] = *(const short8*)&ah[(m0 + lrow) * 136 + s * 32 + quad * 8];
    afl[s] = *(const short8*)&al[(m0 + lrow) * 136 + s * 32 + quad * 8];
  }

  const float* Bt[3] = {bs, bd, bv};
  u16* Yt[3] = {srcb, dstb, valb};
#pragma unroll 1
  for (int g3 = 0; g3 < 3; ++g3) {
    const u16* wh = wfrag + (size_t)(g3 * 2 + 0) * 16384;
    const u16* wl = wfrag + (size_t)(g3 * 2 + 1) * 16384;
    floatx4 dacc[4];
#pragma unroll
    for (int t = 0; t < 4; ++t) dacc[t] = (floatx4){0.f, 0.f, 0.f, 0.f};
#pragma unroll
    for (int s = 0; s < 4; ++s) {
#pragma unroll
      for (int t = 0; t < 4; ++t) {
        int T = nhalf * 4 + t;
        size_t off = (size_t)((T * 4 + s) * 64 + lane) * 8;
        short8 bh = *(const short8*)&wh[off];
        short8 bl = *(const short8*)&wl[off];
        dacc[t] = __builtin_amdgcn_mfma_f32_16x16x32_bf16(afh[s], bh, dacc[t], 0, 0, 0);
        dacc[t] = __builtin_amdgcn_mfma_f32_16x16x32_bf16(afl[s], bh, dacc[t], 0, 0, 0);
        dacc[t] = __builtin_amdgcn_mfma_f32_16x16x32_bf16(afh[s], bl, dacc[t], 0, 0, 0);
      }
    }
#pragma unroll
    for (int t = 0; t < 4; ++t) {
      int col = nhalf * 64 + t * 16 + lrow;
#pragma unroll
      for (int r = 0; r < 4; ++r)
        park[(m0 + quad * 4 + r) * 132 + col] = dacc[t][r];
    }
    __syncthreads();
    {
      int row = row0 + r2;
      if (row < NN_) {
#pragma unroll
        for (int h2 = 0; h2 < 2; ++h2) {
          ushort8v o;
#pragma unroll
          for (int q = 0; q < 8; ++q) {
            float pv = park[r2 * 132 + c16 + h2 * 8 + q] + Bt[g3][c16 + h2 * 8 + q];
            o[q] = f2bf(pv);
          }
          *(ushort8v*)&Yt[g3][(size_t)row * DIM + c16 + h2 * 8] = o;
        }
      }
    }
    __syncthreads();
  }
}

// ---------------- nnew+gate via MFMA + gn1 stats ----------------
__global__ void __launch_bounds__(256) nnew_gate_kernel(
    const float* __restrict__ AGG, const float* __restrict__ NODE,
    const int* __restrict__ batch, const u16* __restrict__ wfrag,
    const float* __restrict__ bun, const float* __restrict__ bg,
    float* __restrict__ gsum1, float* __restrict__ gsq1,
    float* __restrict__ G, float* __restrict__ X1) {
  __shared__ __align__(16) u16 a_h[32 * 136];   // AGG frags -> nnew frags
  __shared__ __align__(16) u16 a_l[32 * 136];
  __shared__ __align__(16) u16 n_h[32 * 136];   // NODE frags
  __shared__ __align__(16) u16 n_l[32 * 136];
  __shared__ __align__(16) float park[32 * 132]; // nnew(raw) -> x1
  __shared__ int bg_s[32];
  int tid = threadIdx.x, row0 = blockIdx.x * 32;
  int r2 = tid >> 3, c16 = (tid & 7) * 16;
  if (tid < 32) bg_s[tid] = (row0 + tid < NN_) ? batch[row0 + tid] : 0;

  {
    int row = row0 + r2;
    float va[16], vn[16];
    if (row < NN_) {
#pragma unroll
      for (int q = 0; q < 4; ++q) {
        float4 xa = *(const float4*)&AGG[(size_t)row * DIM + c16 + q * 4];
        float4 xn = *(const float4*)&NODE[(size_t)row * DIM + c16 + q * 4];
        va[q * 4 + 0] = xa.x; va[q * 4 + 1] = xa.y; va[q * 4 + 2] = xa.z; va[q * 4 + 3] = xa.w;
        vn[q * 4 + 0] = xn.x; vn[q * 4 + 1] = xn.y; vn[q * 4 + 2] = xn.z; vn[q * 4 + 3] = xn.w;
      }
    } else {
#pragma unroll
      for (int q = 0; q < 16; ++q) { va[q] = 0.f; vn[q] = 0.f; }
    }
#pragma unroll
    for (int h2 = 0; h2 < 2; ++h2) {
      ushort8v ah8, al8, nh8, nl8;
#pragma unroll
      for (int q = 0; q < 8; ++q) {
        float x = va[h2 * 8 + q];
        u16 h = f2bf(x); ah8[q] = h; al8[q] = f2bf(x - bf2f(h));
        float y = vn[h2 * 8 + q];
        u16 hy = f2bf(y); nh8[q] = hy; nl8[q] = f2bf(y - bf2f(hy));
      }
      *(ushort8v*)&a_h[r2 * 136 + c16 + h2 * 8] = ah8;
      *(ushort8v*)&a_l[r2 * 136 + c16 + h2 * 8] = al8;
      *(ushort8v*)&n_h[r2 * 136 + c16 + h2 * 8] = nh8;
      *(ushort8v*)&n_l[r2 * 136 + c16 + h2 * 8] = nl8;
    }
  }
  __syncthreads();

  int wv_ = tid >> 6, lane = tid & 63;
  int mtile = wv_ & 1, nhalf = wv_ >> 1;
  int quad = lane >> 4, lrow = lane & 15;
  int m0 = mtile * 16;

  const u16* WunH = wfrag + (size_t)6 * 16384;
  const u16* WunL = wfrag + (size_t)7 * 16384;
  const u16* G0H  = wfrag + (size_t)8 * 16384;
  const u16* G0L  = wfrag + (size_t)9 * 16384;
  const u16* G1H  = wfrag + (size_t)10 * 16384;
  const u16* G1L  = wfrag + (size_t)11 * 16384;

  // MFMA1: nnew = AGG @ Wun (raw, bias added later)
  {
    short8 fh[4], fl[4];
#pragma unroll
    for (int s = 0; s < 4; ++s) {
      fh[s] = *(const short8*)&a_h[(m0 + lrow) * 136 + s * 32 + quad * 8];
      fl[s] = *(const short8*)&a_l[(m0 + lrow) * 136 + s * 32 + quad * 8];
    }
    floatx4 d1[4];
#pragma unroll
    for (int t = 0; t < 4; ++t) d1[t] = (floatx4){0.f, 0.f, 0.f, 0.f};
#pragma unroll
    for (int s = 0; s < 4; ++s) {
#pragma unroll
      for (int t = 0; t < 4; ++t) {
        int T = nhalf * 4 + t;
        size_t off = (size_t)((T * 4 + s) * 64 + lane) * 8;
        short8 bh = *(const short8*)&WunH[off];
        short8 bl = *(const short8*)&WunL[off];
        d1[t] = __builtin_amdgcn_mfma_f32_16x16x32_bf16(fh[s], bh, d1[t], 0, 0, 0);
        d1[t] = __builtin_amdgcn_mfma_f32_16x16x32_bf16(fl[s], bh, d1[t], 0, 0, 0);
        d1[t] = __builtin_amdgcn_mfma_f32_16x16x32_bf16(fh[s], bl, d1[t], 0, 0, 0);
      }
    }
#pragma unroll
    for (int t = 0; t < 4; ++t) {
      int col = nhalf * 64 + t * 16 + lrow;
#pragma unroll
      for (int r = 0; r < 4; ++r)
        park[(m0 + quad * 4 + r) * 132 + col] = d1[t][r];
    }
  }
  __syncthreads();

  // re-split nnew+bun into the dead AGG-frag region (A layout for MFMA2)
  {
#pragma unroll
    for (int h2 = 0; h2 < 2; ++h2) {
      ushort8v hh, ll;
#pragma unroll
      for (int q = 0; q < 8; ++q) {
        float x = park[r2 * 132 + c16 + h2 * 8 + q] + bun[c16 + h2 * 8 + q];
        u16 h = f2bf(x); hh[q] = h; ll[q] = f2bf(x - bf2f(h));
      }
      *(ushort8v*)&a_h[r2 * 136 + c16 + h2 * 8] = hh;
      *(ushort8v*)&a_l[r2 * 136 + c16 + h2 * 8] = ll;
    }
  }
  __syncthreads();

  // MFMA2: z = nnew@Wgc0 + NODE@Wgc1; epilogue in C-layout
  {
    short8 mh[4], ml[4], ph[4], pl[4];
#pragma unroll
    for (int s = 0; s < 4; ++s) {
      mh[s] = *(const short8*)&a_h[(m0 + lrow) * 136 + s * 32 + quad * 8];
      ml[s] = *(const short8*)&a_l[(m0 + lrow) * 136 + s * 32 + quad * 8];
      ph[s] = *(const short8*)&n_h[(m0 + lrow) * 136 + s * 32 + quad * 8];
      pl[s] = *(const short8*)&n_l[(m0 + lrow) * 136 + s * 32 + quad * 8];
    }
    floatx4 d2[4];
#pragma unroll
    for (int t = 0; t < 4; ++t) d2[t] = (floatx4){0.f, 0.f, 0.f, 0.f};
#pragma unroll
    for (int s = 0; s < 4; ++s) {
#pragma unroll
      for (int t = 0; t < 4; ++t) {
        int T = nhalf * 4 + t;
        size_t off = (size_t)((T * 4 + s) * 64 + lane) * 8;
        short8 g0h = *(const short8*)&G0H[off];
        short8 g0l = *(const short8*)&G0L[off];
        short8 g1h = *(const short8*)&G1H[off];
        short8 g1l = *(const short8*)&G1L[off];
        d2[t] = __builtin_amdgcn_mfma_f32_16x16x32_bf16(mh[s], g0h, d2[t], 0, 0, 0);
        d2[t] = __builtin_amdgcn_mfma_f32_16x16x32_bf16(ml[s], g0h, d2[t], 0, 0, 0);
        d2[t] = __builtin_amdgcn_mfma_f32_16x16x32_bf16(mh[s], g0l, d2[t], 0, 0, 0);
        d2[t] = __builtin_amdgcn_mfma_f32_16x16x32_bf16(ph[s], g1h, d2[t], 0, 0, 0);
        d2[t] = __builtin_amdgcn_mfma_f32_16x16x32_bf16(pl[s], g1h, d2[t], 0, 0, 0);
        d2[t] = __builtin_amdgcn_mfma_f32_16x16x32_bf16(ph[s], g1l, d2[t], 0, 0, 0);
      }
    }
#pragma unroll
    for (int t = 0; t < 4; ++t) {
      int col = nhalf * 64 + t * 16 + lrow;
      float bgv = bg[col], bunv = bun[col];
#pragma unroll
      for (int r = 0; r < 4; ++r) {
        int erow = m0 + quad * 4 + r;
        int row = row0 + erow;
        float z = d2[t][r] + bgv;
        float gg = 1.f / (1.f + __expf(-z));
        float nn = park[erow * 132 + col] + bunv;
        float nodev = bf2f(n_h[erow * 136 + col]) + bf2f(n_l[erow * 136 + col]);
        float x1 = gg * nn + nodev;
        park[erow * 132 + col] = x1;
        if (row < NN_) {
          G[(size_t)row * DIM + col] = gg;
          X1[(size_t)row * DIM + col] = x1;
        }
      }
    }
  }
  __syncthreads();
  tile_gn_stats(park, 132, bg_s, row0, tid, gsum1, gsq1);
}

// ---------------- fix_node via MFMA + inline GN1 + gn2 stats ------------
__global__ void __launch_bounds__(256) fx_kernel(
    const float* __restrict__ X1, const int* __restrict__ batch,
    const int* __restrict__ gstart,
    const float* __restrict__ gsum1, const float* __restrict__ gsq1,
    const float* __restrict__ g1w, const float* __restrict__ g1b,
    const float* __restrict__ g1a, const u16* __restrict__ wfrag,
    const float* __restrict__ bf1, const float* __restrict__ bf2,
    const float* __restrict__ G,
    float* __restrict__ gsum2, float* __restrict__ gsq2,
    float* __restrict__ X2) {
  __shared__ __align__(16) u16 a_h[32 * 136];   // n1 frags -> t frags
  __shared__ __align__(16) u16 a_l[32 * 136];
  __shared__ __align__(16) float n1s[32 * 132]; // n1 -> x2
  __shared__ int bg_s[32];
  int tid = threadIdx.x, row0 = blockIdx.x * 32;
  int r2 = tid >> 3, c16 = (tid & 7) * 16;
  if (tid < 32) bg_s[tid] = (row0 + tid < NN_) ? batch[row0 + tid] : 0;

  // stage x1 + inline GN1 -> n1 (f32 tile + hi/lo frags)
  {
    int row = row0 + r2;
    int gi = (row < NN_) ? batch[row] : 0;
    float cnt = fmaxf((float)(gstart[gi + 1] - gstart[gi]), 1.f);
    float inv = 1.f / cnt;
    float v[16];
    if (row < NN_) {
#pragma unroll
      for (int q = 0; q < 4; ++q) {
        float4 x = *(const float4*)&X1[(size_t)row * DIM + c16 + q * 4];
        v[q * 4 + 0] = x.x; v[q * 4 + 1] = x.y;
        v[q * 4 + 2] = x.z; v[q * 4 + 3] = x.w;
      }
    } else {
#pragma unroll
      for (int q = 0; q < 16; ++q) v[q] = 0.f;
    }
#pragma unroll
    for (int q0 = 0; q0 < 16; ++q0) {
      int c = c16 + q0;
      float sm = gsum1[gi * DIM + c], sq = gsq1[gi * DIM + c];
      float mean = sm * inv, msq = sq * inv, am = g1a[c] * mean;
      float var = msq - 2.f * am * mean + am * am;
      v[q0] = g1w[c] * (v[q0] - am) * rsqrtf(var + 1e-5f) + g1b[c];
    }
#pragma unroll
    for (int q = 0; q < 4; ++q) {
      float4 o; o.x = v[q * 4 + 0]; o.y = v[q * 4 + 1];
      o.z = v[q * 4 + 2]; o.w = v[q * 4 + 3];
      *(float4*)&n1s[r2 * 132 + c16 + q * 4] = o;
    }
#pragma unroll
    for (int h2 = 0; h2 < 2; ++h2) {
      ushort8v hh, ll;
#pragma unroll
      for (int q = 0; q < 8; ++q) {
        float x = v[h2 * 8 + q];
        u16 h = f2bf(x); hh[q] = h; ll[q] = f2bf(x - bf2f(h));
      }
      *(ushort8v*)&a_h[r2 * 136 + c16 + h2 * 8] = hh;
      *(ushort8v*)&a_l[r2 * 136 + c16 + h2 * 8] = ll;
    }
  }
  __syncthreads();

  int wv_ = tid >> 6, lane = tid & 63;
  int mtile = wv_ & 1, nhalf = wv_ >> 1;
  int quad = lane >> 4, lrow = lane & 15;
  int m0 = mtile * 16;

  const u16* F1H = wfrag + (size_t)12 * 16384;
  const u16* F1L = wfrag + (size_t)13 * 16384;
  const u16* F2H = wfrag + (size_t)14 * 16384;
  const u16* F2L = wfrag + (size_t)15 * 16384;

  short8 fh[4], fl[4];
#pragma unroll
  for (int s = 0; s < 4; ++s) {
    fh[s] = *(const short8*)&a_h[(m0 + lrow) * 136 + s * 32 + quad * 8];
    fl[s] = *(const short8*)&a_l[(m0 + lrow) * 136 + s * 32 + quad * 8];
  }
  __syncthreads();   // all frags in regs before the t-scatter overwrites

  // MFMA1: t = leaky(n1 @ Wf1 + bf1); scatter hi/lo into a_h/a_l (C->A)
  {
    floatx4 d1[4];
#pragma unroll
    for (int t = 0; t < 4; ++t) d1[t] = (floatx4){0.f, 0.f, 0.f, 0.f};
#pragma unroll
    for (int s = 0; s < 4; ++s) {
#pragma unroll
      for (int t = 0; t < 4; ++t) {
        int T = nhalf * 4 + t;
        size_t off = (size_t)((T * 4 + s) * 64 + lane) * 8;
        short8 bh = *(const short8*)&F1H[off];
        short8 bl = *(const short8*)&F1L[off];
        d1[t] = __builtin_amdgcn_mfma_f32_16x16x32_bf16(fh[s], bh, d1[t], 0, 0, 0);
        d1[t] = __builtin_amdgcn_mfma_f32_16x16x32_bf16(fl[s], bh, d1[t], 0, 0, 0);
        d1[t] = __builtin_amdgcn_mfma_f32_16x16x32_bf16(fh[s], bl, d1[t], 0, 0, 0);
      }
    }
#pragma unroll
    for (int t = 0; t < 4; ++t) {
      int col = nhalf * 64 + t * 16 + lrow;
      float b1v = bf1[col];
#pragma unroll
      for (int r = 0; r < 4; ++r) {
        int erow = m0 + quad * 4 + r;
        float tt = d1[t][r] + b1v;
        tt = tt > 0.f ? tt : 0.01f * tt;
        u16 h = f2bf(tt);
        a_h[erow * 136 + col] = h;
        a_l[erow * 136 + col] = f2bf(tt - bf2f(h));
      }
    }
  }
  __syncthreads();

  // MFMA2: x2 = g*(t @ Wf2 + bf2) + n1
  {
    short8 th[4], tl[4];
#pragma unroll
    for (int s = 0; s < 4; ++s) {
      th[s] = *(const short8*)&a_h[(m0 + lrow) * 136 + s * 32 + quad * 8];
      tl[s] = *(const short8*)&a_l[(m0 + lrow) * 136 + s * 32 + quad * 8];
    }
    floatx4 d2[4];
#pragma unroll
    for (int t = 0; t < 4; ++t) d2[t] = (floatx4){0.f, 0.f, 0.f, 0.f};
#pragma unroll
    for (int s = 0; s < 4; ++s) {
#pragma unroll
      for (int t = 0; t < 4; ++t) {
        int T = nhalf * 4 + t;
        size_t off = (size_t)((T * 4 + s) * 64 + lane) * 8;
        short8 bh = *(const short8*)&F2H[off];
        short8 bl = *(const short8*)&F2L[off];
        d2[t] = __builtin_amdgcn_mfma_f32_16x16x32_bf16(th[s], bh, d2[t], 0, 0, 0);
        d2[t] = __builtin_amdgcn_mfma_f32_16x16x32_bf16(tl[s], bh, d2[t], 0, 0, 0);
        d2[t] = __builtin_amdgcn_mfma_f32_16x16x32_bf16(th[s], bl, d2[t], 0, 0, 0);
      }
    }
#pragma unroll
    for (int t = 0; t < 4; ++t) {
      int col = nhalf * 64 + t * 16 + lrow;
      float b2v = bf2[col];
#pragma unroll
      for (int r = 0; r < 4; ++r) {
        int erow = m0 + quad * 4 + r;
        int row = row0 + erow;
        float gg = (row < NN_) ? G[(size_t)row * DIM + col] : 0.f;
        float x2 = gg * (d2[t][r] + b2v) + n1s[erow * 132 + col];
        n1s[erow * 132 + col] = x2;
        if (row < NN_) X2[(size_t)row * DIM + col] = x2;
      }
    }
  }
  __syncthreads();
  tile_gn_stats(n1s, 132, bg_s, row0, tid, gsum2, gsq2);
}

// ---------------- CSR build ----------------
__global__ void scanA_kernel(const int* __restrict__ deg, int* __restrict__ off,
                             int* __restrict__ bsum) {
  __shared__ int buf[256];
  int tid = threadIdx.x;
  int i = blockIdx.x * 256 + tid;
  int v = (i < NN_) ? deg[i] : 0;
  buf[tid] = v;
  __syncthreads();
  for (int s = 1; s < 256; s <<= 1) {
    int t = (tid >= s) ? buf[tid - s] : 0;
    __syncthreads();
    buf[tid] += t;
    __syncthreads();
  }
  if (i < NN_) off[i] = buf[tid] - v;
  if (tid == 255) bsum[blockIdx.x] = buf[255];
}

__global__ void scanB_kernel(int* __restrict__ bsum) {
  const int NBLK = (NN_ + 255) / 256;
  __shared__ int buf[128];
  int tid = threadIdx.x;
  int v = (tid < NBLK) ? bsum[tid] : 0;
  buf[tid] = v;
  __syncthreads();
  for (int s = 1; s < 128; s <<= 1) {
    int t = (tid >= s) ? buf[tid - s] : 0;
    __syncthreads();
    buf[tid] += t;
    __syncthreads();
  }
  if (tid < NBLK) bsum[tid] = buf[tid] - v;
}

__global__ void scanC_kernel(int* __restrict__ off, const int* __restrict__ bsum) {
  int i = blockIdx.x * 256 + threadIdx.x;
  if (i < NN_) off[i] += bsum[i >> 8];
  if (i == 0) off[NN_] = NE_;
}

__global__ void fill_kernel(const int* __restrict__ EI, const int* __restrict__ off,
                            int* __restrict__ cur, int* __restrict__ eidb,
                            int* __restrict__ jcsr) {
  int e = blockIdx.x * 256 + threadIdx.x;
  if (e >= NE_) return;
  int i = EI[e];
  int p = atomicAdd(&cur[i], 1);
  int pos = off[i] + p;
  eidb[pos] = e;
  jcsr[pos] = EI[NE_ + e];
}

// ---------------- fused edge kernel, CSR order ----------------
// R13: launch_bounds (256,6) — R12's (256,7) capped VGPR at 36 and spilled
// ~4 regs/thread to scratch (+220MB HBM). Cap 85 lets the MFMA2 bf16x2
// split live in regs; LDS 22016 still admits up to 7 blocks if VGPR <= 73.
__global__ void __launch_bounds__(256, 6) edge_kernel(
    const float* __restrict__ edgef, const float* __restrict__ coords,
    const int* __restrict__ EI, const int* __restrict__ eidb,
    const float* __restrict__ We1, const float* __restrict__ be1,
    const float* __restrict__ be2, const u16* __restrict__ we2b,
    const u16* __restrict__ wueb, const float* __restrict__ bue,
    const u16* __restrict__ srcb, const u16* __restrict__ dstb,
    float* __restrict__ scores, float* __restrict__ outE) {
  __shared__ __align__(16) float sbuf[5504];
  __shared__ float bue_s[EOUTF];
  __shared__ int ii[32], jj[32], ee[32];

  float* xs   = sbuf;                 // [32][20], cols 0..16 used (phase A)
  u16*   hbf  = (u16*)(sbuf + 640);   // [32][136] (phase A)
  float* park = sbuf;                 // [2][32][20] (phase B)
  float* ers  = sbuf + 1280;          // [32][132] (phase B)

  int tid = threadIdx.x;
  int bid = blockIdx.x;
  int bswz = (bid & 7) * (NE_ / 32 / 8) + (bid >> 3);
  int p0 = bswz * 32;

  if (tid < 32) {
    int p = p0 + tid;
    int e = eidb[p];
    ee[tid] = e;
    int i = EI[e], j = EI[NE_ + e];
    ii[tid] = i; jj[tid] = j;
    float dx = coords[i * 3 + 0] - coords[j * 3 + 0];
    float dy = coords[i * 3 + 1] - coords[j * 3 + 1];
    float dz = coords[i * 3 + 2] - coords[j * 3 + 2];
    float dist = sqrtf(dx * dx + dy * dy + dz * dz + 1e-12f) * 0.1f;
    xs[tid * 20 + 16] = dist;
  }
  if (tid < EOUTF) bue_s[tid] = bue[tid];
  __syncthreads();

  if (tid < 128) {
    int r = tid >> 2, c4 = (tid & 3) * 4;
    *(float4*)&xs[r * 20 + c4] = *(const float4*)&edgef[(size_t)ee[r] * EINF + c4];
  }
  __syncthreads();

  int cg = tid & 31, rg = tid >> 5, c0 = cg * 4, r0 = rg * 4;

  // h = leaky(x @ We1 + be1), K=17 VALU; write bf16 to hbf
  {
    float acc[4][4] = {};
    for (int k = 0; k < 16; k += 4) {
      float4 w0 = *(const float4*)&We1[(size_t)(k + 0) * DIM + c0];
      float4 w1 = *(const float4*)&We1[(size_t)(k + 1) * DIM + c0];
      float4 w2 = *(const float4*)&We1[(size_t)(k + 2) * DIM + c0];
      float4 w3 = *(const float4*)&We1[(size_t)(k + 3) * DIM + c0];
#pragma unroll
      for (int u = 0; u < 4; ++u) {
        float4 xv = *(const float4*)&xs[(r0 + u) * 20 + k];
        acc[u][0] += xv.x * w0.x + xv.y * w1.x + xv.z * w2.x + xv.w * w3.x;
        acc[u][1] += xv.x * w0.y + xv.y * w1.y + xv.z * w2.y + xv.w * w3.y;
        acc[u][2] += xv.x * w0.z + xv.y * w1.z + xv.z * w2.z + xv.w * w3.z;
        acc[u][3] += xv.x * w0.w + xv.y * w1.w + xv.z * w2.w + xv.w * w3.w;
      }
    }
    {   // k = 16: the dist column
      float4 w4 = *(const float4*)&We1[(size_t)16 * DIM + c0];
#pragma unroll
      for (int u = 0; u < 4; ++u) {
        float xd = xs[(r0 + u) * 20 + 16];
        acc[u][0] += xd * w4.x; acc[u][1] += xd * w4.y;
        acc[u][2] += xd * w4.z; acc[u][3] += xd * w4.w;
      }
    }
    float4 b1 = *(const float4*)&be1[c0];
#pragma unroll
    for (int u = 0; u < 4; ++u) {
      float h0 = acc[u][0] + b1.x, h1 = acc[u][1] + b1.y;
      float h2 = acc[u][2] + b1.z, h3 = acc[u][3] + b1.w;
      h0 = h0 > 0.f ? h0 : 0.01f * h0; h1 = h1 > 0.f ? h1 : 0.01f * h1;
      h2 = h2 > 0.f ? h2 : 0.01f * h2; h3 = h3 > 0.f ? h3 : 0.01f * h3;
      ushort4 pk; pk.x = f2bf(h0); pk.y = f2bf(h1); pk.z = f2bf(h2); pk.w = f2bf(h3);
      *(ushort4*)&hbf[(r0 + u) * 136 + c0] = pk;
    }
  }
  __syncthreads();

  int wv = tid >> 6, lane = tid & 63;
  int mtile = wv & 1, nhalf = wv >> 1;   // nhalf doubles as khalf for MFMA2
  int quad = lane >> 4, lrow = lane & 15;
  int m0 = mtile * 16;

  short8 afrag[4];
#pragma unroll
  for (int s = 0; s < 4; ++s)
    afrag[s] = *(const short8*)&hbf[(m0 + lrow) * 136 + s * 32 + quad * 8];
  __syncthreads();   // xs/hbf dead -> phase B overlay begins

  // MFMA1: e2 = h @ We2
  floatx4 dacc[4];
#pragma unroll
  for (int t = 0; t < 4; ++t) dacc[t] = (floatx4){0.f, 0.f, 0.f, 0.f};
#pragma unroll
  for (int s = 0; s < 4; ++s) {
#pragma unroll
    for (int t = 0; t < 4; ++t) {
      int T = nhalf * 4 + t;
      short8 bfrg = *(const short8*)&we2b[(size_t)((T * 4 + s) * 64 + lane) * 8];
      dacc[t] = __builtin_amdgcn_mfma_f32_16x16x32_bf16(afrag[s], bfrg, dacc[t], 0, 0, 0);
    }
  }

#pragma unroll
  for (int t = 0; t < 4; ++t) {
    int col = nhalf * 64 + t * 16 + lrow;
    float b2v = be2[col];
#pragma unroll
    for (int r = 0; r < 4; ++r) {
      int erow = m0 + quad * 4 + r;
      ers[erow * 132 + col] = dacc[t][r] + b2v;
    }
  }
  __syncthreads();

  // pass 2: er = dst_i * src_j * e2 / sqrt(DH); gathers at use site
  {
    int el2 = tid >> 3, cb2 = tid & 7;
    int c0b = cb2 * 16;
    int irow = ii[el2], jrow = jj[el2];
    ushort8v dv8a = *(const ushort8v*)&dstb[(size_t)irow * DIM + c0b];
    ushort8v dv8b = *(const ushort8v*)&dstb[(size_t)irow * DIM + c0b + 8];
    ushort8v sv8a = *(const ushort8v*)&srcb[(size_t)jrow * DIM + c0b];
    ushort8v sv8b = *(const ushort8v*)&srcb[(size_t)jrow * DIM + c0b + 8];

    float ef[16];
#pragma unroll
    for (int q = 0; q < 4; ++q) {
      float4 v = *(const float4*)&ers[el2 * 132 + c0b + q * 4];
      ef[q * 4 + 0] = v.x; ef[q * 4 + 1] = v.y;
      ef[q * 4 + 2] = v.z; ef[q * 4 + 3] = v.w;
    }
    float asum = 0.f;
#pragma unroll
    for (int k = 0; k < 8; ++k) {
      float er = bf2f((u16)dv8a[k]) * bf2f((u16)sv8a[k]) * ef[k] * RSQRT_DH;
      ef[k] = er; asum += fabsf(er);
    }
#pragma unroll
    for (int k = 0; k < 8; ++k) {
      float er = bf2f((u16)dv8b[k]) * bf2f((u16)sv8b[k]) * ef[8 + k] * RSQRT_DH;
      ef[8 + k] = er; asum += fabsf(er);
    }
#pragma unroll
    for (int q = 0; q < 4; ++q) {
      float4 v; v.x = ef[q * 4 + 0]; v.y = ef[q * 4 + 1];
      v.z = ef[q * 4 + 2]; v.w = ef[q * 4 + 3];
      *(float4*)&ers[el2 * 132 + c0b + q * 4] = v;
    }
    asum += __shfl_xor(asum, 1);
    if ((cb2 & 1) == 0)
      scores[(size_t)(p0 + el2) * 4 + (cb2 >> 1)] = asum;
  }
  __syncthreads();

  // MFMA2: edge_new = er @ Wue. Wave (mtile, khalf=nhalf) computes its
  // K-half partial into park[khalf]; A-frags split bf16x2 from f32 ers.
  {
    floatx4 d3 = (floatx4){0.f, 0.f, 0.f, 0.f};
#pragma unroll
    for (int s = 0; s < 2; ++s) {
      int kbase = nhalf * 64 + s * 32 + quad * 8;
      const float* src = &ers[(m0 + lrow) * 132 + kbase];
      float4 e0 = *(const float4*)&src[0];
      float4 e1 = *(const float4*)&src[4];
      float ev[8] = {e0.x, e0.y, e0.z, e0.w, e1.x, e1.y, e1.z, e1.w};
      short8 ah8, al8;
#pragma unroll
      for (int q = 0; q < 8; ++q) {
        u16 h = f2bf(ev[q]);
        ah8[q] = (short)h;
        al8[q] = (short)f2bf(ev[q] - bf2f(h));
      }
      int sG = nhalf * 2 + s;
      size_t off = (size_t)(sG * 64 + lane) * 8;
      short8 bh = *(const short8*)&wueb[off];
      short8 bl = *(const short8*)&wueb[4096 + off];
      d3 = __builtin_amdgcn_mfma_f32_16x16x32_bf16(ah8, bh, d3, 0, 0, 0);
      d3 = __builtin_amdgcn_mfma_f32_16x16x32_bf16(al8, bh, d3, 0, 0, 0);
      d3 = __builtin_amdgcn_mfma_f32_16x16x32_bf16(ah8, bl, d3, 0, 0, 0);
    }
    // park partial: C layout for 16x16 tile -> row m0+quad*4+r, col lrow
#pragma unroll
    for (int r = 0; r < 4; ++r)
      park[nhalf * 640 + (m0 + quad * 4 + r) * 20 + lrow] = d3[r];
  }
  __syncthreads();

  // epilogue: sum K-half partials + bias -> scatter by original edge id
  {
    int el = tid >> 3, oc2 = (tid & 7) * 2;
    float a0 = park[el * 20 + oc2]     + park[640 + el * 20 + oc2]     + bue_s[oc2];
    float a1 = park[el * 20 + oc2 + 1] + park[640 + el * 20 + oc2 + 1] + bue_s[oc2 + 1];
    size_t ob = (size_t)ee[el] * EOUTF + oc2;
    float2 o2; o2.x = a0; o2.y = a1;
    *(float2*)&outE[ob] = o2;
  }
}

// ---------------- per-node softmax + aggregation (CSR gather) -----------
// 8-way unrolled serial loop (deeper MLP on jcsr -> valb gather chain)
__global__ void __launch_bounds__(256) agg_kernel(
    const u16* __restrict__ valb, const float* __restrict__ scores,
    const int* __restrict__ off, const int* __restrict__ jcsr,
    float* __restrict__ agg) {
  int n = blockIdx.x * 4 + (threadIdx.x >> 6);
  int l = threadIdx.x & 63;
  if (n >= NN_) return;
  int s = off[n], e_end = off[n + 1];

  float m0 = -1e30f, m1 = -1e30f, m2 = -1e30f, m3 = -1e30f;
  for (int p = s + l; p < e_end; p += 64) {
    float4 sc = *(const float4*)&scores[(size_t)p * 4];
    m0 = fmaxf(m0, sc.x); m1 = fmaxf(m1, sc.y);
    m2 = fmaxf(m2, sc.z); m3 = fmaxf(m3, sc.w);
  }
#pragma unroll
  for (int d = 1; d < 64; d <<= 1) {
    m0 = fmaxf(m0, __shfl_xor(m0, d)); m1 = fmaxf(m1, __shfl_xor(m1, d));
    m2 = fmaxf(m2, __shfl_xor(m2, d)); m3 = fmaxf(m3, __shfl_xor(m3, d));
  }
  int hh = l >> 4;
  float mh = (hh == 0) ? m0 : (hh == 1) ? m1 : (hh == 2) ? m2 : m3;

  float acc0 = 0.f, acc1 = 0.f, den = 0.f;
  int p = s;
  for (; p + 8 <= e_end; p += 8) {
    int jA[8];
    float sA[8];
    ushort2 uA[8];
#pragma unroll
    for (int q = 0; q < 8; ++q) jA[q] = jcsr[p + q];
#pragma unroll
    for (int q = 0; q < 8; ++q) sA[q] = scores[(size_t)(p + q) * 4 + hh];
#pragma unroll
    for (int q = 0; q < 8; ++q)
      uA[q] = *(const ushort2*)&valb[(size_t)jA[q] * DIM + 2 * l];
#pragma unroll
    for (int q = 0; q < 8; ++q) {
      float e = __expf(sA[q] - mh);
      den += e;
      acc0 += e * bf2f(uA[q].x);
      acc1 += e * bf2f(uA[q].y);
    }
  }
  for (; p + 2 <= e_end; p += 2) {
    int j0 = jcsr[p], j1 = jcsr[p + 1];
    float s0 = scores[(size_t)p * 4 + hh];
    float s1 = scores[(size_t)(p + 1) * 4 + hh];
    ushort2 u0 = *(const ushort2*)&valb[(size_t)j0 * DIM + 2 * l];
    ushort2 u1 = *(const ushort2*)&valb[(size_t)j1 * DIM + 2 * l];
    float e0 = __expf(s0 - mh), e1 = __expf(s1 - mh);
    den += e0 + e1;
    acc0 += e0 * bf2f(u0.x) + e1 * bf2f(u1.x);
    acc1 += e0 * bf2f(u0.y) + e1 * bf2f(u1.y);
  }
  if (p < e_end) {
    int j = jcsr[p];
    float s0 = scores[(size_t)p * 4 + hh];
    ushort2 u0 = *(const ushort2*)&valb[(size_t)j * DIM + 2 * l];
    float e0 = __expf(s0 - mh);
    den += e0;
    acc0 += e0 * bf2f(u0.x);
    acc1 += e0 * bf2f(u0.y);
  }
  float2 o;
  if (e_end > s) { o.x = acc0 / den; o.y = acc1 / den; }
  else { o.x = 0.f; o.y = 0.f; }
  *(float2*)&agg[(size_t)n * DIM + 2 * l] = o;
}

// ---------------- final GraphNorm apply + coords copy (merged) ----------
__global__ void gn_apply_kernel(const float* __restrict__ X, const int* __restrict__ batch,
    const int* __restrict__ gstart, const float* __restrict__ gsum,
    const float* __restrict__ gsq, const float* __restrict__ w,
    const float* __restrict__ b, const float* __restrict__ a,
    float* __restrict__ Y,
    const float* __restrict__ C, float* __restrict__ OC) {
  int blk = blockIdx.x;
  if (blk >= (NN_ * 32) / 256) {
    int i = (blk - (NN_ * 32) / 256) * 256 + threadIdx.x;
    if (i < NN_ * 3) OC[i] = C[i];
    return;
  }
  int idx = blk * 256 + threadIdx.x;
  int n = idx >> 5, c4 = (idx & 31) * 4;
  int g = batch[n];
  float cnt = fmaxf((float)(gstart[g + 1] - gstart[g]), 1.f);
  float inv = 1.f / cnt;
  float4 xv = *(const float4*)&X[(size_t)n * DIM + c4];
  float4 sm = *(const float4*)&gsum[g * DIM + c4];
  float4 sq = *(const float4*)&gsq[g * DIM + c4];
  float4 av = *(const float4*)&a[c4];
  float4 wv = *(const float4*)&w[c4];
  float4 bv = *(const float4*)&b[c4];
  float4 ov;
  {
    float mean = sm.x * inv, msq = sq.x * inv, am = av.x * mean;
    float var = msq - 2.f * am * mean + am * am;
    ov.x = wv.x * (xv.x - am) * rsqrtf(var + 1e-5f) + bv.x;
  }
  {
    float mean = sm.y * inv, msq = sq.y * inv, am = av.y * mean;
    float var = msq - 2.f * am * mean + am * am;
    ov.y = wv.y * (xv.y - am) * rsqrtf(var + 1e-5f) + bv.y;
  }
  {
    float mean = sm.z * inv, msq = sq.z * inv, am = av.z * mean;
    float var = msq - 2.f * am * mean + am * am;
    ov.z = wv.z * (xv.z - am) * rsqrtf(var + 1e-5f) + bv.z;
  }
  {
    float mean = sm.w * inv, msq = sq.w * inv, am = av.w * mean;
    float var = msq - 2.f * am * mean + am * am;
    ov.w = wv.w * (xv.w - am) * rsqrtf(var + 1e-5f) + bv.w;
  }
  *(float4*)&Y[(size_t)n * DIM + c4] = ov;
}

// ---------------- launcher ----------------
extern "C" void kernel_launch(void* const* d_in, const int* in_sizes, int n_in,
                              void* d_out, int out_size, void* d_ws, size_t ws_size,
                              hipStream_t stream) {
  (void)in_sizes; (void)n_in; (void)out_size; (void)ws_size;
  const float* node  = (const float*)d_in[0];
  const float* edgef = (const float*)d_in[1];
  const float* coords= (const float*)d_in[2];
  const float* Ws  = (const float*)d_in[3];  const float* bs  = (const float*)d_in[4];
  const float* Wd  = (const float*)d_in[5];  const float* bd  = (const float*)d_in[6];
  const float* Wv  = (const float*)d_in[7];  const float* bv  = (const float*)d_in[8];
  const float* We1 = (const float*)d_in[9];  const float* be1 = (const float*)d_in[10];
  const float* We2 = (const float*)d_in[11]; const float* be2 = (const float*)d_in[12];
  const float* Wun = (const float*)d_in[13]; const float* bun = (const float*)d_in[14];
  const float* Wue = (const float*)d_in[15]; const float* bue = (const float*)d_in[16];
  const float* Wg  = (const float*)d_in[17]; const float* bg  = (const float*)d_in[18];
  const float* Wf1 = (const float*)d_in[19]; const float* bf1 = (const float*)d_in[20];
  const float* Wf2 = (const float*)d_in[21]; const float* bf2 = (const float*)d_in[22];
  const float* g1w = (const float*)d_in[23]; const float* g1b = (const float*)d_in[24];
  const float* g1a = (const float*)d_in[25];
  const float* g2w = (const float*)d_in[26]; const float* g2b = (const float*)d_in[27];
  const float* g2a = (const float*)d_in[28];
  const int* EI    = (const int*)d_in[29];
  const int* batch = (const int*)d_in[30];
  float* out = (float*)d_out;

  int*   wsi = (int*)d_ws;
  float* wsf = (float*)d_ws;
  int* deg    = wsi + W_DEG;
  int* cur    = wsi + W_CUR;
  int* offs   = wsi + W_OFF;
  int* bsum   = wsi + W_BSUM;
  int* gstart = wsi + W_GSTART;
  int* eidb   = wsi + W_EID;
  int* jcsr   = wsi + W_JC;
  float* gsum1 = wsf + W_GSUM1; float* gsq1 = wsf + W_GSQ1;
  float* gsum2 = wsf + W_GSUM2; float* gsq2 = wsf + W_GSQ2;
  float* scores_ = wsf + W_SCORES;
  u16* srcb = (u16*)(wsf + W_SRCB);
  u16* dstb = (u16*)(wsf + W_DSTB);
  u16* valb = (u16*)(wsf + W_VALB);
  float* A = wsf + W_A;   // agg -> x1 -> x2
  float* B = wsf + W_B;   // g
  u16*   we2b  = (u16*)(wsf + W_WE2B);
  u16*   wfrag = (u16*)(wsf + W_WPROJ);
  u16*   wueb  = (u16*)(wsf + W_WUEB);

  float* outE = out + (size_t)NN_ * DIM;
  float* outC = out + (size_t)NN_ * DIM + (size_t)NE_ * EOUTF;

  // zero the counter/stat prefix via DMA
  hipMemsetAsync(d_ws, 0, (size_t)W_ZEND * sizeof(int), stream);
  // consolidated setup: gstart + we2b + weight hi/lo fragments + wue frags
  setup_kernel<<<1121, 256, 0, stream>>>(batch, gstart, Wg, We2, we2b,
                                         Ws, Wd, Wv, Wun, Wf1, Wf2, wfrag,
                                         Wue, wueb);
  // CSR build
  deg_kernel<<<(NE_ + 255) / 256, 256, 0, stream>>>(EI, deg);
  scanA_kernel<<<(NN_ + 255) / 256, 256, 0, stream>>>(deg, offs, bsum);
  scanB_kernel<<<1, 128, 0, stream>>>(bsum);
  scanC_kernel<<<(NN_ + 255) / 256, 256, 0, stream>>>(offs, bsum);
  fill_kernel<<<(NE_ + 255) / 256, 256, 0, stream>>>(EI, offs, cur, eidb, jcsr);
  // projections via MFMA (bf16x2)
  proj_kernel<<<(NN_ + 31) / 32, 256, 0, stream>>>(node, wfrag, bs, bd, bv,
                                                   srcb, dstb, valb);
  // edge pipeline in CSR order
  edge_kernel<<<NE_ / 32, 256, 0, stream>>>(edgef, coords, EI, eidb, We1, be1,
                                            be2, we2b, wueb, bue,
                                            srcb, dstb, scores_, outE);
  // A := agg
  agg_kernel<<<NN_ / 4, 256, 0, stream>>>(valb, scores_, offs, jcsr, A);
  // MFMA: nnew+gate; B := g, A := x1; gn1 stats accumulated
  nnew_gate_kernel<<<(NN_ + 31) / 32, 256, 0, stream>>>(A, node, batch, wfrag,
                                                        bun, bg, gsum1, gsq1, B, A);
  // MFMA: fix_node with inline GN1; A := x2; gn2 stats accumulated
  fx_kernel<<<(NN_ + 31) / 32, 256, 0, stream>>>(A, batch, gstart, gsum1, gsq1,
                                                 g1w, g1b, g1a, wfrag, bf1, bf2,
                                                 B, gsum2, gsq2, A);
  // final GN apply + coords copy (merged)
  gn_apply_kernel<<<(NN_ * 32) / 256 + (NN_ * 3 + 255) / 256, 256, 0, stream>>>(
      A, batch, gstart, gsum2, gsq2, g2w, g2b, g2a, out, coords, outC);
}

// Round 16
// 508.632 us; speedup vs baseline: 1.5203x; 1.0157x over previous
//
#include <hip/hip_runtime.h>
#include <hip/hip_bf16.h>

#define NN_ 30000
#define NE_ 480000
#define DIM 128
#define EINF 16
#define EOUTF 16
#define NG 64
#define RSQRT_DH 0.17677669529663687f

typedef unsigned short u16;
typedef __attribute__((ext_vector_type(8))) short short8;
typedef __attribute__((ext_vector_type(8))) unsigned short ushort8v;
typedef __attribute__((ext_vector_type(4))) float floatx4;

// ---------------- workspace layout (32-bit word offsets) ----------------
#define W_DEG     0
#define W_CUR     30000
#define W_GSUM1   60000
#define W_GSQ1    68192
#define W_GSUM2   76384
#define W_GSQ2    84576
#define W_ZEND    92768
#define W_OFF     92768
#define W_BSUM    122772
#define W_GSTART  122900
#define W_EID     122968
#define W_JC      602968
#define W_SCORES  1082968
#define W_SRCB    3002968
#define W_DSTB    4922968
#define W_VALB    6842968
#define W_A       8762968
#define W_B       12602968
#define W_C       16442968
#define W_WGC     20282968
#define W_WE2B    20315736
#define W_WPROJ   20323928
#define W_WUEB    20455000
// wfrag: 16 halves x 16384 u16 = 131072 words; wueb: 8192 u16 = 4096 words
// end 20459096 words = 81.8 MB (133 MB proven safe)

static __device__ __forceinline__ u16 f2bf(float x) {
  __hip_bfloat16 h = __float2bfloat16(x);
  return *reinterpret_cast<u16*>(&h);
}
static __device__ __forceinline__ float bf2f(u16 v) {
  unsigned int b = ((unsigned int)v) << 16;
  return __uint_as_float(b);
}

// per-tile column reduce of a 32-row LDS tile (stride ld) into per-graph stats
static __device__ __forceinline__ void tile_gn_stats(const float* xsb, int ld,
    const int* bg_s, int row0, int tid,
    float* __restrict__ gsum, float* __restrict__ gsq) {
  int c = tid & 127, half = tid >> 7;
  float sm = 0.f, sq = 0.f;
  int gcur = -1;
  for (int r = 0; r < 16; ++r) {
    int rl = half * 16 + r;
    int row = row0 + rl;
    if (row >= NN_) break;
    int g = bg_s[rl];
    float v = xsb[rl * ld + c];
    if (g != gcur) {
      if (gcur >= 0) {
        atomicAdd(&gsum[gcur * DIM + c], sm);
        atomicAdd(&gsq[gcur * DIM + c], sq);
      }
      gcur = g; sm = 0.f; sq = 0.f;
    }
    sm += v; sq += v * v;
  }
  if (gcur >= 0) {
    atomicAdd(&gsum[gcur * DIM + c], sm);
    atomicAdd(&gsq[gcur * DIM + c], sq);
  }
}

// ---------------- consolidated setup kernel ----------------
// b0: gstart; b1..64: we2b; b65..1088: weight hi/lo fragments; b1089..1120:
// Wue hi/lo fragments; b1121..: deg atomics (folded-in deg_kernel).
// wfrag half index = mat*2 + lo; mats: 0 Ws, 1 Wd, 2 Wv, 3 Wun,
// 4 Wgc0(=Wg[k]+Wg[256+k]), 5 Wgc1(=Wg[128+k]-Wg[256+k]), 6 Wf1, 7 Wf2.
__global__ void setup_kernel(const int* __restrict__ batch, int* __restrict__ gstart,
                             const float* __restrict__ Wg,
                             const float* __restrict__ We2, u16* __restrict__ we2b,
                             const float* __restrict__ Ws, const float* __restrict__ Wd,
                             const float* __restrict__ Wv, const float* __restrict__ Wun,
                             const float* __restrict__ Wf1, const float* __restrict__ Wf2,
                             u16* __restrict__ wfrag,
                             const float* __restrict__ Wue, u16* __restrict__ wueb,
                             const int* __restrict__ EI, int* __restrict__ deg) {
  int b = blockIdx.x, tid = threadIdx.x;
  if (b == 0) {
    int g = tid;
    if (g <= NG) {
      int lo = 0, hi = NN_;
      while (lo < hi) { int mid = (lo + hi) >> 1; if (batch[mid] < g) lo = mid + 1; else hi = mid; }
      gstart[g] = lo;
    }
  } else if (b < 65) {
    int idx = (b - 1) * 256 + tid;   // 16384 elems
    int j = idx & 7, lane = (idx >> 3) & 63, s = (idx >> 9) & 3, T = idx >> 11;
    int k = s * 32 + ((lane >> 4) << 3) + j;
    int n = T * 16 + (lane & 15);
    we2b[idx] = f2bf(We2[(size_t)k * DIM + n]);
  } else if (b < 1089) {
    int idx = (b - 65) * 256 + tid;   // 262144 elems: 16 halves x 16384
    int which = idx >> 14;            // mat*2 + lo
    int sub = idx & 16383;
    int j = sub & 7, lane = (sub >> 3) & 63, s = (sub >> 9) & 3, T = sub >> 11;
    int k = s * 32 + ((lane >> 4) << 3) + j;
    int n = T * 16 + (lane & 15);
    int mat = which >> 1;
    float w;
    if (mat == 4) w = Wg[(size_t)k * DIM + n] + Wg[(size_t)(256 + k) * DIM + n];
    else if (mat == 5) w = Wg[(size_t)(128 + k) * DIM + n] - Wg[(size_t)(256 + k) * DIM + n];
    else {
      const float* Wsrc = (mat == 0) ? Ws : (mat == 1) ? Wd : (mat == 2) ? Wv
                        : (mat == 3) ? Wun : (mat == 6) ? Wf1 : Wf2;
      w = Wsrc[(size_t)k * DIM + n];
    }
    u16 h = f2bf(w);
    wfrag[(size_t)which * 16384 + sub] = (which & 1) ? f2bf(w - bf2f(h)) : h;
  } else if (b < 1121) {
    int idx = (b - 1089) * 256 + tid;   // 8192 elems: 2 halves x 4096
    int half = idx >> 12;               // 0 hi, 1 lo
    int sub = idx & 4095;
    int j = sub & 7, lane = (sub >> 3) & 63, sG = sub >> 9;   // sG 0..3
    int k = sG * 32 + ((lane >> 4) << 3) + j;
    int n = lane & 15;
    float w = Wue[(size_t)k * EOUTF + n];
    u16 h = f2bf(w);
    wueb[half * 4096 + sub] = half ? f2bf(w - bf2f(h)) : h;
  } else {
    int e = (b - 1121) * 256 + tid;
    if (e < NE_) atomicAdd(&deg[EI[e]], 1);
  }
}

// ---------------- node projections via MFMA (bf16x2 split) --------------
__global__ void __launch_bounds__(256) proj_kernel(
    const float* __restrict__ node, const u16* __restrict__ wfrag,
    const float* __restrict__ bs, const float* __restrict__ bd,
    const float* __restrict__ bv,
    u16* __restrict__ srcb, u16* __restrict__ dstb, u16* __restrict__ valb) {
  __shared__ __align__(16) u16 ah[32 * 136];
  __shared__ __align__(16) u16 al[32 * 136];
  __shared__ __align__(16) float park[32 * 132];
  int tid = threadIdx.x, row0 = blockIdx.x * 32;
  int r2 = tid >> 3, c16 = (tid & 7) * 16;

  {
    int row = row0 + r2;
    float v[16];
    if (row < NN_) {
#pragma unroll
      for (int q = 0; q < 4; ++q) {
        float4 x = *(const float4*)&node[(size_t)row * DIM + c16 + q * 4];
        v[q * 4 + 0] = x.x; v[q * 4 + 1] = x.y;
        v[q * 4 + 2] = x.z; v[q * 4 + 3] = x.w;
      }
    } else {
#pragma unroll
      for (int q = 0; q < 16; ++q) v[q] = 0.f;
    }
#pragma unroll
    for (int h2 = 0; h2 < 2; ++h2) {
      ushort8v hh, ll;
#pragma unroll
      for (int q = 0; q < 8; ++q) {
        float x = v[h2 * 8 + q];
        u16 h = f2bf(x);
        hh[q] = h;
        ll[q] = f2bf(x - bf2f(h));
      }
      *(ushort8v*)&ah[r2 * 136 + c16 + h2 * 8] = hh;
      *(ushort8v*)&al[r2 * 136 + c16 + h2 * 8] = ll;
    }
  }
  __syncthreads();

  int wv_ = tid >> 6, lane = tid & 63;
  int mtile = wv_ & 1, nhalf = wv_ >> 1;
  int quad = lane >> 4, lrow = lane & 15;
  int m0 = mtile * 16;

  short8 afh[4], afl[4];
#pragma unroll
  for (int s = 0; s < 4; ++s) {
    afh[s] = *(const short8*)&ah[(m0 + lrow) * 136 + s * 32 + quad * 8];
    afl[s] = *(const short8*)&al[(m0 + lrow) * 136 + s * 32 + quad * 8];
  }

  const float* Bt[3] = {bs, bd, bv};
  u16* Yt[3] = {srcb, dstb, valb};
#pragma unroll 1
  for (int g3 = 0; g3 < 3; ++g3) {
    const u16* wh = wfrag + (size_t)(g3 * 2 + 0) * 16384;
    const u16* wl = wfrag + (size_t)(g3 * 2 + 1) * 16384;
    floatx4 dacc[4];
#pragma unroll
    for (int t = 0; t < 4; ++t) dacc[t] = (floatx4){0.f, 0.f, 0.f, 0.f};
#pragma unroll
    for (int s = 0; s < 4; ++s) {
#pragma unroll
      for (int t = 0; t < 4; ++t) {
        int T = nhalf * 4 + t;
        size_t off = (size_t)((T * 4 + s) * 64 + lane) * 8;
        short8 bh = *(const short8*)&wh[off];
        short8 bl = *(const short8*)&wl[off];
        dacc[t] = __builtin_amdgcn_mfma_f32_16x16x32_bf16(afh[s], bh, dacc[t], 0, 0, 0);
        dacc[t] = __builtin_amdgcn_mfma_f32_16x16x32_bf16(afl[s], bh, dacc[t], 0, 0, 0);
        dacc[t] = __builtin_amdgcn_mfma_f32_16x16x32_bf16(afh[s], bl, dacc[t], 0, 0, 0);
      }
    }
#pragma unroll
    for (int t = 0; t < 4; ++t) {
      int col = nhalf * 64 + t * 16 + lrow;
#pragma unroll
      for (int r = 0; r < 4; ++r)
        park[(m0 + quad * 4 + r) * 132 + col] = dacc[t][r];
    }
    __syncthreads();
    {
      int row = row0 + r2;
      if (row < NN_) {
#pragma unroll
        for (int h2 = 0; h2 < 2; ++h2) {
          ushort8v o;
#pragma unroll
          for (int q = 0; q < 8; ++q) {
            float pv = park[r2 * 132 + c16 + h2 * 8 + q] + Bt[g3][c16 + h2 * 8 + q];
            o[q] = f2bf(pv);
          }
          *(ushort8v*)&Yt[g3][(size_t)row * DIM + c16 + h2 * 8] = o;
        }
      }
    }
    __syncthreads();
  }
}

// ---------------- fused agg + nnew + gate via MFMA + gn1 stats ----------
// Phase 0: per-node softmax aggregation computed in-block (8 thr/node,
// 16 cols/thread, one head/thread) -> result split hi/lo straight into the
// A-frag region. Removes the standalone agg kernel + 30.7MB A round-trip.
// Then: MFMA1 nnew = agg@Wun; re-split; MFMA2 gate; x1; gn1 stats.
__global__ void __launch_bounds__(256) nnew_gate_kernel(
    const u16* __restrict__ valb, const float* __restrict__ scores,
    const int* __restrict__ off, const int* __restrict__ jcsr,
    const float* __restrict__ NODE,
    const int* __restrict__ batch, const u16* __restrict__ wfrag,
    const float* __restrict__ bun, const float* __restrict__ bg,
    float* __restrict__ gsum1, float* __restrict__ gsq1,
    float* __restrict__ G, float* __restrict__ X1) {
  __shared__ __align__(16) u16 a_h[32 * 136];   // agg frags -> nnew frags
  __shared__ __align__(16) u16 a_l[32 * 136];
  __shared__ __align__(16) u16 n_h[32 * 136];   // NODE frags
  __shared__ __align__(16) u16 n_l[32 * 136];
  __shared__ __align__(16) float park[32 * 132]; // nnew(raw) -> x1
  __shared__ int bg_s[32];
  int tid = threadIdx.x, row0 = blockIdx.x * 32;
  int r2 = tid >> 3, c16 = (tid & 7) * 16;
  if (tid < 32) bg_s[tid] = (row0 + tid < NN_) ? batch[row0 + tid] : 0;

  // Phase 0: agg for node row0+r2, cols c16..c16+15 (single head c16>>5)
  {
    int row = row0 + r2;
    float acc[16];
#pragma unroll
    for (int q = 0; q < 16; ++q) acc[q] = 0.f;
    if (row < NN_) {
      int s = off[row], e_end = off[row + 1];
      if (e_end > s) {
        int head = c16 >> 5;
        float m = -1e30f;
        for (int p = s; p < e_end; ++p)
          m = fmaxf(m, scores[(size_t)p * 4 + head]);
        float den = 0.f;
        int p = s;
        for (; p + 2 <= e_end; p += 2) {
          int j0 = jcsr[p], j1 = jcsr[p + 1];
          float s0 = scores[(size_t)p * 4 + head];
          float s1 = scores[(size_t)(p + 1) * 4 + head];
          ushort8v v00 = *(const ushort8v*)&valb[(size_t)j0 * DIM + c16];
          ushort8v v01 = *(const ushort8v*)&valb[(size_t)j0 * DIM + c16 + 8];
          ushort8v v10 = *(const ushort8v*)&valb[(size_t)j1 * DIM + c16];
          ushort8v v11 = *(const ushort8v*)&valb[(size_t)j1 * DIM + c16 + 8];
          float e0 = __expf(s0 - m), e1 = __expf(s1 - m);
          den += e0 + e1;
#pragma unroll
          for (int q = 0; q < 8; ++q) {
            acc[q]     += e0 * bf2f(v00[q]) + e1 * bf2f(v10[q]);
            acc[8 + q] += e0 * bf2f(v01[q]) + e1 * bf2f(v11[q]);
          }
        }
        if (p < e_end) {
          int j = jcsr[p];
          float s0 = scores[(size_t)p * 4 + head];
          ushort8v v0 = *(const ushort8v*)&valb[(size_t)j * DIM + c16];
          ushort8v v1 = *(const ushort8v*)&valb[(size_t)j * DIM + c16 + 8];
          float e0 = __expf(s0 - m);
          den += e0;
#pragma unroll
          for (int q = 0; q < 8; ++q) {
            acc[q]     += e0 * bf2f(v0[q]);
            acc[8 + q] += e0 * bf2f(v1[q]);
          }
        }
        float inv = 1.f / den;
#pragma unroll
        for (int q = 0; q < 16; ++q) acc[q] *= inv;
      }
    }
    // NODE staging + agg hi/lo split into A-frag region
    float vn[16];
    if (row < NN_) {
#pragma unroll
      for (int q = 0; q < 4; ++q) {
        float4 xn = *(const float4*)&NODE[(size_t)row * DIM + c16 + q * 4];
        vn[q * 4 + 0] = xn.x; vn[q * 4 + 1] = xn.y;
        vn[q * 4 + 2] = xn.z; vn[q * 4 + 3] = xn.w;
      }
    } else {
#pragma unroll
      for (int q = 0; q < 16; ++q) vn[q] = 0.f;
    }
#pragma unroll
    for (int h2 = 0; h2 < 2; ++h2) {
      ushort8v ah8, al8, nh8, nl8;
#pragma unroll
      for (int q = 0; q < 8; ++q) {
        float x = acc[h2 * 8 + q];
        u16 h = f2bf(x); ah8[q] = h; al8[q] = f2bf(x - bf2f(h));
        float y = vn[h2 * 8 + q];
        u16 hy = f2bf(y); nh8[q] = hy; nl8[q] = f2bf(y - bf2f(hy));
      }
      *(ushort8v*)&a_h[r2 * 136 + c16 + h2 * 8] = ah8;
      *(ushort8v*)&a_l[r2 * 136 + c16 + h2 * 8] = al8;
      *(ushort8v*)&n_h[r2 * 136 + c16 + h2 * 8] = nh8;
      *(ushort8v*)&n_l[r2 * 136 + c16 + h2 * 8] = nl8;
    }
  }
  __syncthreads();

  int wv_ = tid >> 6, lane = tid & 63;
  int mtile = wv_ & 1, nhalf = wv_ >> 1;
  int quad = lane >> 4, lrow = lane & 15;
  int m0 = mtile * 16;

  const u16* WunH = wfrag + (size_t)6 * 16384;
  const u16* WunL = wfrag + (size_t)7 * 16384;
  const u16* G0H  = wfrag + (size_t)8 * 16384;
  const u16* G0L  = wfrag + (size_t)9 * 16384;
  const u16* G1H  = wfrag + (size_t)10 * 16384;
  const u16* G1L  = wfrag + (size_t)11 * 16384;

  // MFMA1: nnew = agg @ Wun (raw, bias added later)
  {
    short8 fh[4], fl[4];
#pragma unroll
    for (int s = 0; s < 4; ++s) {
      fh[s] = *(const short8*)&a_h[(m0 + lrow) * 136 + s * 32 + quad * 8];
      fl[s] = *(const short8*)&a_l[(m0 + lrow) * 136 + s * 32 + quad * 8];
    }
    floatx4 d1[4];
#pragma unroll
    for (int t = 0; t < 4; ++t) d1[t] = (floatx4){0.f, 0.f, 0.f, 0.f};
#pragma unroll
    for (int s = 0; s < 4; ++s) {
#pragma unroll
      for (int t = 0; t < 4; ++t) {
        int T = nhalf * 4 + t;
        size_t off2 = (size_t)((T * 4 + s) * 64 + lane) * 8;
        short8 bh = *(const short8*)&WunH[off2];
        short8 bl = *(const short8*)&WunL[off2];
        d1[t] = __builtin_amdgcn_mfma_f32_16x16x32_bf16(fh[s], bh, d1[t], 0, 0, 0);
        d1[t] = __builtin_amdgcn_mfma_f32_16x16x32_bf16(fl[s], bh, d1[t], 0, 0, 0);
        d1[t] = __builtin_amdgcn_mfma_f32_16x16x32_bf16(fh[s], bl, d1[t], 0, 0, 0);
      }
    }
#pragma unroll
    for (int t = 0; t < 4; ++t) {
      int col = nhalf * 64 + t * 16 + lrow;
#pragma unroll
      for (int r = 0; r < 4; ++r)
        park[(m0 + quad * 4 + r) * 132 + col] = d1[t][r];
    }
  }
  __syncthreads();

  // re-split nnew+bun into the dead agg-frag region (A layout for MFMA2)
  {
#pragma unroll
    for (int h2 = 0; h2 < 2; ++h2) {
      ushort8v hh, ll;
#pragma unroll
      for (int q = 0; q < 8; ++q) {
        float x = park[r2 * 132 + c16 + h2 * 8 + q] + bun[c16 + h2 * 8 + q];
        u16 h = f2bf(x); hh[q] = h; ll[q] = f2bf(x - bf2f(h));
      }
      *(ushort8v*)&a_h[r2 * 136 + c16 + h2 * 8] = hh;
      *(ushort8v*)&a_l[r2 * 136 + c16 + h2 * 8] = ll;
    }
  }
  __syncthreads();

  // MFMA2: z = nnew@Wgc0 + NODE@Wgc1; epilogue in C-layout
  {
    short8 mh[4], ml[4], ph[4], pl[4];
#pragma unroll
    for (int s = 0; s < 4; ++s) {
      mh[s] = *(const short8*)&a_h[(m0 + lrow) * 136 + s * 32 + quad * 8];
      ml[s] = *(const short8*)&a_l[(m0 + lrow) * 136 + s * 32 + quad * 8];
      ph[s] = *(const short8*)&n_h[(m0 + lrow) * 136 + s * 32 + quad * 8];
      pl[s] = *(const short8*)&n_l[(m0 + lrow) * 136 + s * 32 + quad * 8];
    }
    floatx4 d2[4];
#pragma unroll
    for (int t = 0; t < 4; ++t) d2[t] = (floatx4){0.f, 0.f, 0.f, 0.f};
#pragma unroll
    for (int s = 0; s < 4; ++s) {
#pragma unroll
      for (int t = 0; t < 4; ++t) {
        int T = nhalf * 4 + t;
        size_t off2 = (size_t)((T * 4 + s) * 64 + lane) * 8;
        short8 g0h = *(const short8*)&G0H[off2];
        short8 g0l = *(const short8*)&G0L[off2];
        short8 g1h = *(const short8*)&G1H[off2];
        short8 g1l = *(const short8*)&G1L[off2];
        d2[t] = __builtin_amdgcn_mfma_f32_16x16x32_bf16(mh[s], g0h, d2[t], 0, 0, 0);
        d2[t] = __builtin_amdgcn_mfma_f32_16x16x32_bf16(ml[s], g0h, d2[t], 0, 0, 0);
        d2[t] = __builtin_amdgcn_mfma_f32_16x16x32_bf16(mh[s], g0l, d2[t], 0, 0, 0);
        d2[t] = __builtin_amdgcn_mfma_f32_16x16x32_bf16(ph[s], g1h, d2[t], 0, 0, 0);
        d2[t] = __builtin_amdgcn_mfma_f32_16x16x32_bf16(pl[s], g1h, d2[t], 0, 0, 0);
        d2[t] = __builtin_amdgcn_mfma_f32_16x16x32_bf16(ph[s], g1l, d2[t], 0, 0, 0);
      }
    }
#pragma unroll
    for (int t = 0; t < 4; ++t) {
      int col = nhalf * 64 + t * 16 + lrow;
      float bgv = bg[col], bunv = bun[col];
#pragma unroll
      for (int r = 0; r < 4; ++r) {
        int erow = m0 + quad * 4 + r;
        int row = row0 + erow;
        float z = d2[t][r] + bgv;
        float gg = 1.f / (1.f + __expf(-z));
        float nn = park[erow * 132 + col] + bunv;
        float nodev = bf2f(n_h[erow * 136 + col]) + bf2f(n_l[erow * 136 + col]);
        float x1 = gg * nn + nodev;
        park[erow * 132 + col] = x1;
        if (row < NN_) {
          G[(size_t)row * DIM + col] = gg;
          X1[(size_t)row * DIM + col] = x1;
        }
      }
    }
  }
  __syncthreads();
  tile_gn_stats(park, 132, bg_s, row0, tid, gsum1, gsq1);
}

// ---------------- fix_node via MFMA + inline GN1 + gn2 stats ------------
__global__ void __launch_bounds__(256) fx_kernel(
    const float* __restrict__ X1, const int* __restrict__ batch,
    const int* __restrict__ gstart,
    const float* __restrict__ gsum1, const float* __restrict__ gsq1,
    const float* __restrict__ g1w, const float* __restrict__ g1b,
    const float* __restrict__ g1a, const u16* __restrict__ wfrag,
    const float* __restrict__ bf1, const float* __restrict__ bf2,
    const float* __restrict__ G,
    float* __restrict__ gsum2, float* __restrict__ gsq2,
    float* __restrict__ X2) {
  __shared__ __align__(16) u16 a_h[32 * 136];   // n1 frags -> t frags
  __shared__ __align__(16) u16 a_l[32 * 136];
  __shared__ __align__(16) float n1s[32 * 132]; // n1 -> x2
  __shared__ int bg_s[32];
  int tid = threadIdx.x, row0 = blockIdx.x * 32;
  int r2 = tid >> 3, c16 = (tid & 7) * 16;
  if (tid < 32) bg_s[tid] = (row0 + tid < NN_) ? batch[row0 + tid] : 0;

  // stage x1 + inline GN1 -> n1 (f32 tile + hi/lo frags)
  {
    int row = row0 + r2;
    int gi = (row < NN_) ? batch[row] : 0;
    float cnt = fmaxf((float)(gstart[gi + 1] - gstart[gi]), 1.f);
    float inv = 1.f / cnt;
    float v[16];
    if (row < NN_) {
#pragma unroll
      for (int q = 0; q < 4; ++q) {
        float4 x = *(const float4*)&X1[(size_t)row * DIM + c16 + q * 4];
        v[q * 4 + 0] = x.x; v[q * 4 + 1] = x.y;
        v[q * 4 + 2] = x.z; v[q * 4 + 3] = x.w;
      }
    } else {
#pragma unroll
      for (int q = 0; q < 16; ++q) v[q] = 0.f;
    }
#pragma unroll
    for (int q0 = 0; q0 < 16; ++q0) {
      int c = c16 + q0;
      float sm = gsum1[gi * DIM + c], sq = gsq1[gi * DIM + c];
      float mean = sm * inv, msq = sq * inv, am = g1a[c] * mean;
      float var = msq - 2.f * am * mean + am * am;
      v[q0] = g1w[c] * (v[q0] - am) * rsqrtf(var + 1e-5f) + g1b[c];
    }
#pragma unroll
    for (int q = 0; q < 4; ++q) {
      float4 o; o.x = v[q * 4 + 0]; o.y = v[q * 4 + 1];
      o.z = v[q * 4 + 2]; o.w = v[q * 4 + 3];
      *(float4*)&n1s[r2 * 132 + c16 + q * 4] = o;
    }
#pragma unroll
    for (int h2 = 0; h2 < 2; ++h2) {
      ushort8v hh, ll;
#pragma unroll
      for (int q = 0; q < 8; ++q) {
        float x = v[h2 * 8 + q];
        u16 h = f2bf(x); hh[q] = h; ll[q] = f2bf(x - bf2f(h));
      }
      *(ushort8v*)&a_h[r2 * 136 + c16 + h2 * 8] = hh;
      *(ushort8v*)&a_l[r2 * 136 + c16 + h2 * 8] = ll;
    }
  }
  __syncthreads();

  int wv_ = tid >> 6, lane = tid & 63;
  int mtile = wv_ & 1, nhalf = wv_ >> 1;
  int quad = lane >> 4, lrow = lane & 15;
  int m0 = mtile * 16;

  const u16* F1H = wfrag + (size_t)12 * 16384;
  const u16* F1L = wfrag + (size_t)13 * 16384;
  const u16* F2H = wfrag + (size_t)14 * 16384;
  const u16* F2L = wfrag + (size_t)15 * 16384;

  short8 fh[4], fl[4];
#pragma unroll
  for (int s = 0; s < 4; ++s) {
    fh[s] = *(const short8*)&a_h[(m0 + lrow) * 136 + s * 32 + quad * 8];
    fl[s] = *(const short8*)&a_l[(m0 + lrow) * 136 + s * 32 + quad * 8];
  }
  __syncthreads();   // all frags in regs before the t-scatter overwrites

  // MFMA1: t = leaky(n1 @ Wf1 + bf1); scatter hi/lo into a_h/a_l (C->A)
  {
    floatx4 d1[4];
#pragma unroll
    for (int t = 0; t < 4; ++t) d1[t] = (floatx4){0.f, 0.f, 0.f, 0.f};
#pragma unroll
    for (int s = 0; s < 4; ++s) {
#pragma unroll
      for (int t = 0; t < 4; ++t) {
        int T = nhalf * 4 + t;
        size_t off2 = (size_t)((T * 4 + s) * 64 + lane) * 8;
        short8 bh = *(const short8*)&F1H[off2];
        short8 bl = *(const short8*)&F1L[off2];
        d1[t] = __builtin_amdgcn_mfma_f32_16x16x32_bf16(fh[s], bh, d1[t], 0, 0, 0);
        d1[t] = __builtin_amdgcn_mfma_f32_16x16x32_bf16(fl[s], bh, d1[t], 0, 0, 0);
        d1[t] = __builtin_amdgcn_mfma_f32_16x16x32_bf16(fh[s], bl, d1[t], 0, 0, 0);
      }
    }
#pragma unroll
    for (int t = 0; t < 4; ++t) {
      int col = nhalf * 64 + t * 16 + lrow;
      float b1v = bf1[col];
#pragma unroll
      for (int r = 0; r < 4; ++r) {
        int erow = m0 + quad * 4 + r;
        float tt = d1[t][r] + b1v;
        tt = tt > 0.f ? tt : 0.01f * tt;
        u16 h = f2bf(tt);
        a_h[erow * 136 + col] = h;
        a_l[erow * 136 + col] = f2bf(tt - bf2f(h));
      }
    }
  }
  __syncthreads();

  // MFMA2: x2 = g*(t @ Wf2 + bf2) + n1
  {
    short8 th[4], tl[4];
#pragma unroll
    for (int s = 0; s < 4; ++s) {
      th[s] = *(const short8*)&a_h[(m0 + lrow) * 136 + s * 32 + quad * 8];
      tl[s] = *(const short8*)&a_l[(m0 + lrow) * 136 + s * 32 + quad * 8];
    }
    floatx4 d2[4];
#pragma unroll
    for (int t = 0; t < 4; ++t) d2[t] = (floatx4){0.f, 0.f, 0.f, 0.f};
#pragma unroll
    for (int s = 0; s < 4; ++s) {
#pragma unroll
      for (int t = 0; t < 4; ++t) {
        int T = nhalf * 4 + t;
        size_t off2 = (size_t)((T * 4 + s) * 64 + lane) * 8;
        short8 bh = *(const short8*)&F2H[off2];
        short8 bl = *(const short8*)&F2L[off2];
        d2[t] = __builtin_amdgcn_mfma_f32_16x16x32_bf16(th[s], bh, d2[t], 0, 0, 0);
        d2[t] = __builtin_amdgcn_mfma_f32_16x16x32_bf16(tl[s], bh, d2[t], 0, 0, 0);
        d2[t] = __builtin_amdgcn_mfma_f32_16x16x32_bf16(th[s], bl, d2[t], 0, 0, 0);
      }
    }
#pragma unroll
    for (int t = 0; t < 4; ++t) {
      int col = nhalf * 64 + t * 16 + lrow;
      float b2v = bf2[col];
#pragma unroll
      for (int r = 0; r < 4; ++r) {
        int erow = m0 + quad * 4 + r;
        int row = row0 + erow;
        float gg = (row < NN_) ? G[(size_t)row * DIM + col] : 0.f;
        float x2 = gg * (d2[t][r] + b2v) + n1s[erow * 132 + col];
        n1s[erow * 132 + col] = x2;
        if (row < NN_) X2[(size_t)row * DIM + col] = x2;
      }
    }
  }
  __syncthreads();
  tile_gn_stats(n1s, 132, bg_s, row0, tid, gsum2, gsq2);
}

// ---------------- CSR build ----------------
__global__ void scanA_kernel(const int* __restrict__ deg, int* __restrict__ off,
                             int* __restrict__ bsum) {
  __shared__ int buf[256];
  int tid = threadIdx.x;
  int i = blockIdx.x * 256 + tid;
  int v = (i < NN_) ? deg[i] : 0;
  buf[tid] = v;
  __syncthreads();
  for (int s = 1; s < 256; s <<= 1) {
    int t = (tid >= s) ? buf[tid - s] : 0;
    __syncthreads();
    buf[tid] += t;
    __syncthreads();
  }
  if (i < NN_) off[i] = buf[tid] - v;
  if (tid == 255) bsum[blockIdx.x] = buf[255];
}

__global__ void scanB_kernel(int* __restrict__ bsum) {
  const int NBLK = (NN_ + 255) / 256;
  __shared__ int buf[128];
  int tid = threadIdx.x;
  int v = (tid < NBLK) ? bsum[tid] : 0;
  buf[tid] = v;
  __syncthreads();
  for (int s = 1; s < 128; s <<= 1) {
    int t = (tid >= s) ? buf[tid - s] : 0;
    __syncthreads();
    buf[tid] += t;
    __syncthreads();
  }
  if (tid < NBLK) bsum[tid] = buf[tid] - v;
}

__global__ void scanC_kernel(int* __restrict__ off, const int* __restrict__ bsum) {
  int i = blockIdx.x * 256 + threadIdx.x;
  if (i < NN_) off[i] += bsum[i >> 8];
  if (i == 0) off[NN_] = NE_;
}

__global__ void fill_kernel(const int* __restrict__ EI, const int* __restrict__ off,
                            int* __restrict__ cur, int* __restrict__ eidb,
                            int* __restrict__ jcsr) {
  int e = blockIdx.x * 256 + threadIdx.x;
  if (e >= NE_) return;
  int i = EI[e];
  int p = atomicAdd(&cur[i], 1);
  int pos = off[i] + p;
  eidb[pos] = e;
  jcsr[pos] = EI[NE_ + e];
}

// ---------------- fused edge kernel, CSR order (FROZEN from R13) --------
__global__ void __launch_bounds__(256, 6) edge_kernel(
    const float* __restrict__ edgef, const float* __restrict__ coords,
    const int* __restrict__ EI, const int* __restrict__ eidb,
    const float* __restrict__ We1, const float* __restrict__ be1,
    const float* __restrict__ be2, const u16* __restrict__ we2b,
    const u16* __restrict__ wueb, const float* __restrict__ bue,
    const u16* __restrict__ srcb, const u16* __restrict__ dstb,
    float* __restrict__ scores, float* __restrict__ outE) {
  __shared__ __align__(16) float sbuf[5504];
  __shared__ float bue_s[EOUTF];
  __shared__ int ii[32], jj[32], ee[32];

  float* xs   = sbuf;                 // [32][20], cols 0..16 used (phase A)
  u16*   hbf  = (u16*)(sbuf + 640);   // [32][136] (phase A)
  float* park = sbuf;                 // [2][32][20] (phase B)
  float* ers  = sbuf + 1280;          // [32][132] (phase B)

  int tid = threadIdx.x;
  int bid = blockIdx.x;
  int bswz = (bid & 7) * (NE_ / 32 / 8) + (bid >> 3);
  int p0 = bswz * 32;

  if (tid < 32) {
    int p = p0 + tid;
    int e = eidb[p];
    ee[tid] = e;
    int i = EI[e], j = EI[NE_ + e];
    ii[tid] = i; jj[tid] = j;
    float dx = coords[i * 3 + 0] - coords[j * 3 + 0];
    float dy = coords[i * 3 + 1] - coords[j * 3 + 1];
    float dz = coords[i * 3 + 2] - coords[j * 3 + 2];
    float dist = sqrtf(dx * dx + dy * dy + dz * dz + 1e-12f) * 0.1f;
    xs[tid * 20 + 16] = dist;
  }
  if (tid < EOUTF) bue_s[tid] = bue[tid];
  __syncthreads();

  if (tid < 128) {
    int r = tid >> 2, c4 = (tid & 3) * 4;
    *(float4*)&xs[r * 20 + c4] = *(const float4*)&edgef[(size_t)ee[r] * EINF + c4];
  }
  __syncthreads();

  int cg = tid & 31, rg = tid >> 5, c0 = cg * 4, r0 = rg * 4;

  // h = leaky(x @ We1 + be1), K=17 VALU; write bf16 to hbf
  {
    float acc[4][4] = {};
    for (int k = 0; k < 16; k += 4) {
      float4 w0 = *(const float4*)&We1[(size_t)(k + 0) * DIM + c0];
      float4 w1 = *(const float4*)&We1[(size_t)(k + 1) * DIM + c0];
      float4 w2 = *(const float4*)&We1[(size_t)(k + 2) * DIM + c0];
      float4 w3 = *(const float4*)&We1[(size_t)(k + 3) * DIM + c0];
#pragma unroll
      for (int u = 0; u < 4; ++u) {
        float4 xv = *(const float4*)&xs[(r0 + u) * 20 + k];
        acc[u][0] += xv.x * w0.x + xv.y * w1.x + xv.z * w2.x + xv.w * w3.x;
        acc[u][1] += xv.x * w0.y + xv.y * w1.y + xv.z * w2.y + xv.w * w3.y;
        acc[u][2] += xv.x * w0.z + xv.y * w1.z + xv.z * w2.z + xv.w * w3.z;
        acc[u][3] += xv.x * w0.w + xv.y * w1.w + xv.z * w2.w + xv.w * w3.w;
      }
    }
    {   // k = 16: the dist column
      float4 w4 = *(const float4*)&We1[(size_t)16 * DIM + c0];
#pragma unroll
      for (int u = 0; u < 4; ++u) {
        float xd = xs[(r0 + u) * 20 + 16];
        acc[u][0] += xd * w4.x; acc[u][1] += xd * w4.y;
        acc[u][2] += xd * w4.z; acc[u][3] += xd * w4.w;
      }
    }
    float4 b1 = *(const float4*)&be1[c0];
#pragma unroll
    for (int u = 0; u < 4; ++u) {
      float h0 = acc[u][0] + b1.x, h1 = acc[u][1] + b1.y;
      float h2 = acc[u][2] + b1.z, h3 = acc[u][3] + b1.w;
      h0 = h0 > 0.f ? h0 : 0.01f * h0; h1 = h1 > 0.f ? h1 : 0.01f * h1;
      h2 = h2 > 0.f ? h2 : 0.01f * h2; h3 = h3 > 0.f ? h3 : 0.01f * h3;
      ushort4 pk; pk.x = f2bf(h0); pk.y = f2bf(h1); pk.z = f2bf(h2); pk.w = f2bf(h3);
      *(ushort4*)&hbf[(r0 + u) * 136 + c0] = pk;
    }
  }
  __syncthreads();

  int wv = tid >> 6, lane = tid & 63;
  int mtile = wv & 1, nhalf = wv >> 1;   // nhalf doubles as khalf for MFMA2
  int quad = lane >> 4, lrow = lane & 15;
  int m0 = mtile * 16;

  short8 afrag[4];
#pragma unroll
  for (int s = 0; s < 4; ++s)
    afrag[s] = *(const short8*)&hbf[(m0 + lrow) * 136 + s * 32 + quad * 8];
  __syncthreads();   // xs/hbf dead -> phase B overlay begins

  // MFMA1: e2 = h @ We2
  floatx4 dacc[4];
#pragma unroll
  for (int t = 0; t < 4; ++t) dacc[t] = (floatx4){0.f, 0.f, 0.f, 0.f};
#pragma unroll
  for (int s = 0; s < 4; ++s) {
#pragma unroll
    for (int t = 0; t < 4; ++t) {
      int T = nhalf * 4 + t;
      short8 bfrg = *(const short8*)&we2b[(size_t)((T * 4 + s) * 64 + lane) * 8];
      dacc[t] = __builtin_amdgcn_mfma_f32_16x16x32_bf16(afrag[s], bfrg, dacc[t], 0, 0, 0);
    }
  }

#pragma unroll
  for (int t = 0; t < 4; ++t) {
    int col = nhalf * 64 + t * 16 + lrow;
    float b2v = be2[col];
#pragma unroll
    for (int r = 0; r < 4; ++r) {
      int erow = m0 + quad * 4 + r;
      ers[erow * 132 + col] = dacc[t][r] + b2v;
    }
  }
  __syncthreads();

  // pass 2: er = dst_i * src_j * e2 / sqrt(DH); gathers at use site
  {
    int el2 = tid >> 3, cb2 = tid & 7;
    int c0b = cb2 * 16;
    int irow = ii[el2], jrow = jj[el2];
    ushort8v dv8a = *(const ushort8v*)&dstb[(size_t)irow * DIM + c0b];
    ushort8v dv8b = *(const ushort8v*)&dstb[(size_t)irow * DIM + c0b + 8];
    ushort8v sv8a = *(const ushort8v*)&srcb[(size_t)jrow * DIM + c0b];
    ushort8v sv8b = *(const ushort8v*)&srcb[(size_t)jrow * DIM + c0b + 8];

    float ef[16];
#pragma unroll
    for (int q = 0; q < 4; ++q) {
      float4 v = *(const float4*)&ers[el2 * 132 + c0b + q * 4];
      ef[q * 4 + 0] = v.x; ef[q * 4 + 1] = v.y;
      ef[q * 4 + 2] = v.z; ef[q * 4 + 3] = v.w;
    }
    float asum = 0.f;
#pragma unroll
    for (int k = 0; k < 8; ++k) {
      float er = bf2f((u16)dv8a[k]) * bf2f((u16)sv8a[k]) * ef[k] * RSQRT_DH;
      ef[k] = er; asum += fabsf(er);
    }
#pragma unroll
    for (int k = 0; k < 8; ++k) {
      float er = bf2f((u16)dv8b[k]) * bf2f((u16)sv8b[k]) * ef[8 + k] * RSQRT_DH;
      ef[8 + k] = er; asum += fabsf(er);
    }
#pragma unroll
    for (int q = 0; q < 4; ++q) {
      float4 v; v.x = ef[q * 4 + 0]; v.y = ef[q * 4 + 1];
      v.z = ef[q * 4 + 2]; v.w = ef[q * 4 + 3];
      *(float4*)&ers[el2 * 132 + c0b + q * 4] = v;
    }
    asum += __shfl_xor(asum, 1);
    if ((cb2 & 1) == 0)
      scores[(size_t)(p0 + el2) * 4 + (cb2 >> 1)] = asum;
  }
  __syncthreads();

  // MFMA2: edge_new = er @ Wue. Wave (mtile, khalf=nhalf) computes its
  // K-half partial into park[khalf]; A-frags split bf16x2 from f32 ers.
  {
    floatx4 d3 = (floatx4){0.f, 0.f, 0.f, 0.f};
#pragma unroll
    for (int s = 0; s < 2; ++s) {
      int kbase = nhalf * 64 + s * 32 + quad * 8;
      const float* src = &ers[(m0 + lrow) * 132 + kbase];
      float4 e0 = *(const float4*)&src[0];
      float4 e1 = *(const float4*)&src[4];
      float ev[8] = {e0.x, e0.y, e0.z, e0.w, e1.x, e1.y, e1.z, e1.w};
      short8 ah8, al8;
#pragma unroll
      for (int q = 0; q < 8; ++q) {
        u16 h = f2bf(ev[q]);
        ah8[q] = (short)h;
        al8[q] = (short)f2bf(ev[q] - bf2f(h));
      }
      int sG = nhalf * 2 + s;
      size_t off = (size_t)(sG * 64 + lane) * 8;
      short8 bh = *(const short8*)&wueb[off];
      short8 bl = *(const short8*)&wueb[4096 + off];
      d3 = __builtin_amdgcn_mfma_f32_16x16x32_bf16(ah8, bh, d3, 0, 0, 0);
      d3 = __builtin_amdgcn_mfma_f32_16x16x32_bf16(al8, bh, d3, 0, 0, 0);
      d3 = __builtin_amdgcn_mfma_f32_16x16x32_bf16(ah8, bl, d3, 0, 0, 0);
    }
    // park partial: C layout for 16x16 tile -> row m0+quad*4+r, col lrow
#pragma unroll
    for (int r = 0; r < 4; ++r)
      park[nhalf * 640 + (m0 + quad * 4 + r) * 20 + lrow] = d3[r];
  }
  __syncthreads();

  // epilogue: sum K-half partials + bias -> scatter by original edge id
  {
    int el = tid >> 3, oc2 = (tid & 7) * 2;
    float a0 = park[el * 20 + oc2]     + park[640 + el * 20 + oc2]     + bue_s[oc2];
    float a1 = park[el * 20 + oc2 + 1] + park[640 + el * 20 + oc2 + 1] + bue_s[oc2 + 1];
    size_t ob = (size_t)ee[el] * EOUTF + oc2;
    float2 o2; o2.x = a0; o2.y = a1;
    *(float2*)&outE[ob] = o2;
  }
}

// ---------------- final GraphNorm apply + coords copy (merged) ----------
__global__ void gn_apply_kernel(const float* __restrict__ X, const int* __restrict__ batch,
    const int* __restrict__ gstart, const float* __restrict__ gsum,
    const float* __restrict__ gsq, const float* __restrict__ w,
    const float* __restrict__ b, const float* __restrict__ a,
    float* __restrict__ Y,
    const float* __restrict__ C, float* __restrict__ OC) {
  int blk = blockIdx.x;
  if (blk >= (NN_ * 32) / 256) {
    int i = (blk - (NN_ * 32) / 256) * 256 + threadIdx.x;
    if (i < NN_ * 3) OC[i] = C[i];
    return;
  }
  int idx = blk * 256 + threadIdx.x;
  int n = idx >> 5, c4 = (idx & 31) * 4;
  int g = batch[n];
  float cnt = fmaxf((float)(gstart[g + 1] - gstart[g]), 1.f);
  float inv = 1.f / cnt;
  float4 xv = *(const float4*)&X[(size_t)n * DIM + c4];
  float4 sm = *(const float4*)&gsum[g * DIM + c4];
  float4 sq = *(const float4*)&gsq[g * DIM + c4];
  float4 av = *(const float4*)&a[c4];
  float4 wv = *(const float4*)&w[c4];
  float4 bv = *(const float4*)&b[c4];
  float4 ov;
  {
    float mean = sm.x * inv, msq = sq.x * inv, am = av.x * mean;
    float var = msq - 2.f * am * mean + am * am;
    ov.x = wv.x * (xv.x - am) * rsqrtf(var + 1e-5f) + bv.x;
  }
  {
    float mean = sm.y * inv, msq = sq.y * inv, am = av.y * mean;
    float var = msq - 2.f * am * mean + am * am;
    ov.y = wv.y * (xv.y - am) * rsqrtf(var + 1e-5f) + bv.y;
  }
  {
    float mean = sm.z * inv, msq = sq.z * inv, am = av.z * mean;
    float var = msq - 2.f * am * mean + am * am;
    ov.z = wv.z * (xv.z - am) * rsqrtf(var + 1e-5f) + bv.z;
  }
  {
    float mean = sm.w * inv, msq = sq.w * inv, am = av.w * mean;
    float var = msq - 2.f * am * mean + am * am;
    ov.w = wv.w * (xv.w - am) * rsqrtf(var + 1e-5f) + bv.w;
  }
  *(float4*)&Y[(size_t)n * DIM + c4] = ov;
}

// ---------------- launcher ----------------
extern "C" void kernel_launch(void* const* d_in, const int* in_sizes, int n_in,
                              void* d_out, int out_size, void* d_ws, size_t ws_size,
                              hipStream_t stream) {
  (void)in_sizes; (void)n_in; (void)out_size; (void)ws_size;
  const float* node  = (const float*)d_in[0];
  const float* edgef = (const float*)d_in[1];
  const float* coords= (const float*)d_in[2];
  const float* Ws  = (const float*)d_in[3];  const float* bs  = (const float*)d_in[4];
  const float* Wd  = (const float*)d_in[5];  const float* bd  = (const float*)d_in[6];
  const float* Wv  = (const float*)d_in[7];  const float* bv  = (const float*)d_in[8];
  const float* We1 = (const float*)d_in[9];  const float* be1 = (const float*)d_in[10];
  const float* We2 = (const float*)d_in[11]; const float* be2 = (const float*)d_in[12];
  const float* Wun = (const float*)d_in[13]; const float* bun = (const float*)d_in[14];
  const float* Wue = (const float*)d_in[15]; const float* bue = (const float*)d_in[16];
  const float* Wg  = (const float*)d_in[17]; const float* bg  = (const float*)d_in[18];
  const float* Wf1 = (const float*)d_in[19]; const float* bf1 = (const float*)d_in[20];
  const float* Wf2 = (const float*)d_in[21]; const float* bf2 = (const float*)d_in[22];
  const float* g1w = (const float*)d_in[23]; const float* g1b = (const float*)d_in[24];
  const float* g1a = (const float*)d_in[25];
  const float* g2w = (const float*)d_in[26]; const float* g2b = (const float*)d_in[27];
  const float* g2a = (const float*)d_in[28];
  const int* EI    = (const int*)d_in[29];
  const int* batch = (const int*)d_in[30];
  float* out = (float*)d_out;

  int*   wsi = (int*)d_ws;
  float* wsf = (float*)d_ws;
  int* deg    = wsi + W_DEG;
  int* cur    = wsi + W_CUR;
  int* offs   = wsi + W_OFF;
  int* bsum   = wsi + W_BSUM;
  int* gstart = wsi + W_GSTART;
  int* eidb   = wsi + W_EID;
  int* jcsr   = wsi + W_JC;
  float* gsum1 = wsf + W_GSUM1; float* gsq1 = wsf + W_GSQ1;
  float* gsum2 = wsf + W_GSUM2; float* gsq2 = wsf + W_GSQ2;
  float* scores_ = wsf + W_SCORES;
  u16* srcb = (u16*)(wsf + W_SRCB);
  u16* dstb = (u16*)(wsf + W_DSTB);
  u16* valb = (u16*)(wsf + W_VALB);
  float* A = wsf + W_A;   // x1 -> x2
  float* B = wsf + W_B;   // g
  u16*   we2b  = (u16*)(wsf + W_WE2B);
  u16*   wfrag = (u16*)(wsf + W_WPROJ);
  u16*   wueb  = (u16*)(wsf + W_WUEB);

  float* outE = out + (size_t)NN_ * DIM;
  float* outC = out + (size_t)NN_ * DIM + (size_t)NE_ * EOUTF;

  // zero the counter/stat prefix via DMA
  hipMemsetAsync(d_ws, 0, (size_t)W_ZEND * sizeof(int), stream);
  // consolidated setup: gstart + we2b + weight frags + wue frags + deg
  setup_kernel<<<1121 + (NE_ + 255) / 256, 256, 0, stream>>>(
      batch, gstart, Wg, We2, we2b, Ws, Wd, Wv, Wun, Wf1, Wf2, wfrag,
      Wue, wueb, EI, deg);
  // CSR build
  scanA_kernel<<<(NN_ + 255) / 256, 256, 0, stream>>>(deg, offs, bsum);
  scanB_kernel<<<1, 128, 0, stream>>>(bsum);
  scanC_kernel<<<(NN_ + 255) / 256, 256, 0, stream>>>(offs, bsum);
  fill_kernel<<<(NE_ + 255) / 256, 256, 0, stream>>>(EI, offs, cur, eidb, jcsr);
  // projections via MFMA (bf16x2)
  proj_kernel<<<(NN_ + 31) / 32, 256, 0, stream>>>(node, wfrag, bs, bd, bv,
                                                   srcb, dstb, valb);
  // edge pipeline in CSR order
  edge_kernel<<<NE_ / 32, 256, 0, stream>>>(edgef, coords, EI, eidb, We1, be1,
                                            be2, we2b, wueb, bue,
                                            srcb, dstb, scores_, outE);
  // fused: agg (in-block) + MFMA nnew+gate; B := g, A := x1; gn1 stats
  nnew_gate_kernel<<<(NN_ + 31) / 32, 256, 0, stream>>>(
      valb, scores_, offs, jcsr, node, batch, wfrag, bun, bg,
      gsum1, gsq1, B, A);
  // MFMA: fix_node with inline GN1; A := x2; gn2 stats accumulated
  fx_kernel<<<(NN_ + 31) / 32, 256, 0, stream>>>(A, batch, gstart, gsum1, gsq1,
                                                 g1w, g1b, g1a, wfrag, bf1, bf2,
                                                 B, gsum2, gsq2, A);
  // final GN apply + coords copy (merged)
  gn_apply_kernel<<<(NN_ * 32) / 256 + (NN_ * 3 + 255) / 256, 256, 0, stream>>>(
      A, batch, gstart, gsum2, gsq2, g2w, g2b, g2a, out, coords, outC);
}

// Round 17
// 504.956 us; speedup vs baseline: 1.5313x; 1.0073x over previous
//
#include <hip/hip_runtime.h>
#include <hip/hip_bf16.h>

#define NN_ 30000
#define NE_ 480000
#define DIM 128
#define EINF 16
#define EOUTF 16
#define NG 64
#define RSQRT_DH 0.17677669529663687f

typedef unsigned short u16;
typedef __attribute__((ext_vector_type(8))) short short8;
typedef __attribute__((ext_vector_type(8))) unsigned short ushort8v;
typedef __attribute__((ext_vector_type(4))) float floatx4;

// ---------------- workspace layout (32-bit word offsets) ----------------
#define W_DEG     0
#define W_CUR     30000
#define W_GSUM1   60000
#define W_GSQ1    68192
#define W_GSUM2   76384
#define W_GSQ2    84576
#define W_ZEND    92768
#define W_OFF     92768
#define W_BSUM    122772
#define W_GSTART  122900
#define W_EID     122968
#define W_JC      602968
#define W_SCORES  1082968
#define W_SRCB    3002968
#define W_DSTB    4922968
#define W_VALB    6842968
#define W_A       8762968
#define W_B       12602968
#define W_C       16442968
#define W_WGC     20282968
#define W_WE2B    20315736
#define W_WPROJ   20323928
#define W_WUEB    20455000
// wfrag: 16 halves x 16384 u16 = 131072 words; wueb: 8192 u16 = 4096 words
// end 20459096 words = 81.8 MB (133 MB proven safe)

static __device__ __forceinline__ u16 f2bf(float x) {
  __hip_bfloat16 h = __float2bfloat16(x);
  return *reinterpret_cast<u16*>(&h);
}
static __device__ __forceinline__ float bf2f(u16 v) {
  unsigned int b = ((unsigned int)v) << 16;
  return __uint_as_float(b);
}

// per-tile column reduce of a 32-row LDS tile (stride ld) into per-graph stats
static __device__ __forceinline__ void tile_gn_stats(const float* xsb, int ld,
    const int* bg_s, int row0, int tid,
    float* __restrict__ gsum, float* __restrict__ gsq) {
  int c = tid & 127, half = tid >> 7;
  float sm = 0.f, sq = 0.f;
  int gcur = -1;
  for (int r = 0; r < 16; ++r) {
    int rl = half * 16 + r;
    int row = row0 + rl;
    if (row >= NN_) break;
    int g = bg_s[rl];
    float v = xsb[rl * ld + c];
    if (g != gcur) {
      if (gcur >= 0) {
        atomicAdd(&gsum[gcur * DIM + c], sm);
        atomicAdd(&gsq[gcur * DIM + c], sq);
      }
      gcur = g; sm = 0.f; sq = 0.f;
    }
    sm += v; sq += v * v;
  }
  if (gcur >= 0) {
    atomicAdd(&gsum[gcur * DIM + c], sm);
    atomicAdd(&gsq[gcur * DIM + c], sq);
  }
}

// ---------------- consolidated setup kernel ----------------
// b0: gstart; b1..64: we2b; b65..1088: weight hi/lo fragments; b1089..1120:
// Wue hi/lo fragments; b1121..: deg atomics (folded-in deg_kernel).
// wfrag half index = mat*2 + lo; mats: 0 Ws, 1 Wd, 2 Wv, 3 Wun,
// 4 Wgc0(=Wg[k]+Wg[256+k]), 5 Wgc1(=Wg[128+k]-Wg[256+k]), 6 Wf1, 7 Wf2.
__global__ void setup_kernel(const int* __restrict__ batch, int* __restrict__ gstart,
                             const float* __restrict__ Wg,
                             const float* __restrict__ We2, u16* __restrict__ we2b,
                             const float* __restrict__ Ws, const float* __restrict__ Wd,
                             const float* __restrict__ Wv, const float* __restrict__ Wun,
                             const float* __restrict__ Wf1, const float* __restrict__ Wf2,
                             u16* __restrict__ wfrag,
                             const float* __restrict__ Wue, u16* __restrict__ wueb,
                             const int* __restrict__ EI, int* __restrict__ deg) {
  int b = blockIdx.x, tid = threadIdx.x;
  if (b == 0) {
    int g = tid;
    if (g <= NG) {
      int lo = 0, hi = NN_;
      while (lo < hi) { int mid = (lo + hi) >> 1; if (batch[mid] < g) lo = mid + 1; else hi = mid; }
      gstart[g] = lo;
    }
  } else if (b < 65) {
    int idx = (b - 1) * 256 + tid;   // 16384 elems
    int j = idx & 7, lane = (idx >> 3) & 63, s = (idx >> 9) & 3, T = idx >> 11;
    int k = s * 32 + ((lane >> 4) << 3) + j;
    int n = T * 16 + (lane & 15);
    we2b[idx] = f2bf(We2[(size_t)k * DIM + n]);
  } else if (b < 1089) {
    int idx = (b - 65) * 256 + tid;   // 262144 elems: 16 halves x 16384
    int which = idx >> 14;            // mat*2 + lo
    int sub = idx & 16383;
    int j = sub & 7, lane = (sub >> 3) & 63, s = (sub >> 9) & 3, T = sub >> 11;
    int k = s * 32 + ((lane >> 4) << 3) + j;
    int n = T * 16 + (lane & 15);
    int mat = which >> 1;
    float w;
    if (mat == 4) w = Wg[(size_t)k * DIM + n] + Wg[(size_t)(256 + k) * DIM + n];
    else if (mat == 5) w = Wg[(size_t)(128 + k) * DIM + n] - Wg[(size_t)(256 + k) * DIM + n];
    else {
      const float* Wsrc = (mat == 0) ? Ws : (mat == 1) ? Wd : (mat == 2) ? Wv
                        : (mat == 3) ? Wun : (mat == 6) ? Wf1 : Wf2;
      w = Wsrc[(size_t)k * DIM + n];
    }
    u16 h = f2bf(w);
    wfrag[(size_t)which * 16384 + sub] = (which & 1) ? f2bf(w - bf2f(h)) : h;
  } else if (b < 1121) {
    int idx = (b - 1089) * 256 + tid;   // 8192 elems: 2 halves x 4096
    int half = idx >> 12;               // 0 hi, 1 lo
    int sub = idx & 4095;
    int j = sub & 7, lane = (sub >> 3) & 63, sG = sub >> 9;   // sG 0..3
    int k = sG * 32 + ((lane >> 4) << 3) + j;
    int n = lane & 15;
    float w = Wue[(size_t)k * EOUTF + n];
    u16 h = f2bf(w);
    wueb[half * 4096 + sub] = half ? f2bf(w - bf2f(h)) : h;
  } else {
    int e = (b - 1121) * 256 + tid;
    if (e < NE_) atomicAdd(&deg[EI[e]], 1);
  }
}

// ---------------- node projections via MFMA (bf16x2 split) --------------
__global__ void __launch_bounds__(256) proj_kernel(
    const float* __restrict__ node, const u16* __restrict__ wfrag,
    const float* __restrict__ bs, const float* __restrict__ bd,
    const float* __restrict__ bv,
    u16* __restrict__ srcb, u16* __restrict__ dstb, u16* __restrict__ valb) {
  __shared__ __align__(16) u16 ah[32 * 136];
  __shared__ __align__(16) u16 al[32 * 136];
  __shared__ __align__(16) float park[32 * 132];
  int tid = threadIdx.x, row0 = blockIdx.x * 32;
  int r2 = tid >> 3, c16 = (tid & 7) * 16;

  {
    int row = row0 + r2;
    float v[16];
    if (row < NN_) {
#pragma unroll
      for (int q = 0; q < 4; ++q) {
        float4 x = *(const float4*)&node[(size_t)row * DIM + c16 + q * 4];
        v[q * 4 + 0] = x.x; v[q * 4 + 1] = x.y;
        v[q * 4 + 2] = x.z; v[q * 4 + 3] = x.w;
      }
    } else {
#pragma unroll
      for (int q = 0; q < 16; ++q) v[q] = 0.f;
    }
#pragma unroll
    for (int h2 = 0; h2 < 2; ++h2) {
      ushort8v hh, ll;
#pragma unroll
      for (int q = 0; q < 8; ++q) {
        float x = v[h2 * 8 + q];
        u16 h = f2bf(x);
        hh[q] = h;
        ll[q] = f2bf(x - bf2f(h));
      }
      *(ushort8v*)&ah[r2 * 136 + c16 + h2 * 8] = hh;
      *(ushort8v*)&al[r2 * 136 + c16 + h2 * 8] = ll;
    }
  }
  __syncthreads();

  int wv_ = tid >> 6, lane = tid & 63;
  int mtile = wv_ & 1, nhalf = wv_ >> 1;
  int quad = lane >> 4, lrow = lane & 15;
  int m0 = mtile * 16;

  short8 afh[4], afl[4];
#pragma unroll
  for (int s = 0; s < 4; ++s) {
    afh[s] = *(const short8*)&ah[(m0 + lrow) * 136 + s * 32 + quad * 8];
    afl[s] = *(const short8*)&al[(m0 + lrow) * 136 + s * 32 + quad * 8];
  }

  const float* Bt[3] = {bs, bd, bv};
  u16* Yt[3] = {srcb, dstb, valb};
#pragma unroll 1
  for (int g3 = 0; g3 < 3; ++g3) {
    const u16* wh = wfrag + (size_t)(g3 * 2 + 0) * 16384;
    const u16* wl = wfrag + (size_t)(g3 * 2 + 1) * 16384;
    floatx4 dacc[4];
#pragma unroll
    for (int t = 0; t < 4; ++t) dacc[t] = (floatx4){0.f, 0.f, 0.f, 0.f};
#pragma unroll
    for (int s = 0; s < 4; ++s) {
#pragma unroll
      for (int t = 0; t < 4; ++t) {
        int T = nhalf * 4 + t;
        size_t off = (size_t)((T * 4 + s) * 64 + lane) * 8;
        short8 bh = *(const short8*)&wh[off];
        short8 bl = *(const short8*)&wl[off];
        dacc[t] = __builtin_amdgcn_mfma_f32_16x16x32_bf16(afh[s], bh, dacc[t], 0, 0, 0);
        dacc[t] = __builtin_amdgcn_mfma_f32_16x16x32_bf16(afl[s], bh, dacc[t], 0, 0, 0);
        dacc[t] = __builtin_amdgcn_mfma_f32_16x16x32_bf16(afh[s], bl, dacc[t], 0, 0, 0);
      }
    }
#pragma unroll
    for (int t = 0; t < 4; ++t) {
      int col = nhalf * 64 + t * 16 + lrow;
#pragma unroll
      for (int r = 0; r < 4; ++r)
        park[(m0 + quad * 4 + r) * 132 + col] = dacc[t][r];
    }
    __syncthreads();
    {
      int row = row0 + r2;
      if (row < NN_) {
#pragma unroll
        for (int h2 = 0; h2 < 2; ++h2) {
          ushort8v o;
#pragma unroll
          for (int q = 0; q < 8; ++q) {
            float pv = park[r2 * 132 + c16 + h2 * 8 + q] + Bt[g3][c16 + h2 * 8 + q];
            o[q] = f2bf(pv);
          }
          *(ushort8v*)&Yt[g3][(size_t)row * DIM + c16 + h2 * 8] = o;
        }
      }
    }
    __syncthreads();
  }
}

// ---------------- fused agg + nnew + gate via MFMA + gn1 stats ----------
// Phase 0: per-node softmax aggregation in-block (8 thr/node, 16 cols each,
// one head/thread); R17: 4-way unrolled gather loop (restores R13 agg MLP
// depth on the jcsr->valb dependent chain). Result -> A-frag hi/lo.
// Then: MFMA1 nnew = agg@Wun; re-split; MFMA2 gate; x1; gn1 stats.
__global__ void __launch_bounds__(256) nnew_gate_kernel(
    const u16* __restrict__ valb, const float* __restrict__ scores,
    const int* __restrict__ off, const int* __restrict__ jcsr,
    const float* __restrict__ NODE,
    const int* __restrict__ batch, const u16* __restrict__ wfrag,
    const float* __restrict__ bun, const float* __restrict__ bg,
    float* __restrict__ gsum1, float* __restrict__ gsq1,
    float* __restrict__ G, float* __restrict__ X1) {
  __shared__ __align__(16) u16 a_h[32 * 136];   // agg frags -> nnew frags
  __shared__ __align__(16) u16 a_l[32 * 136];
  __shared__ __align__(16) u16 n_h[32 * 136];   // NODE frags
  __shared__ __align__(16) u16 n_l[32 * 136];
  __shared__ __align__(16) float park[32 * 132]; // nnew(raw) -> x1
  __shared__ int bg_s[32];
  int tid = threadIdx.x, row0 = blockIdx.x * 32;
  int r2 = tid >> 3, c16 = (tid & 7) * 16;
  if (tid < 32) bg_s[tid] = (row0 + tid < NN_) ? batch[row0 + tid] : 0;

  // Phase 0: agg for node row0+r2, cols c16..c16+15 (single head c16>>5)
  {
    int row = row0 + r2;
    float acc[16];
#pragma unroll
    for (int q = 0; q < 16; ++q) acc[q] = 0.f;
    if (row < NN_) {
      int s = off[row], e_end = off[row + 1];
      if (e_end > s) {
        int head = c16 >> 5;
        float m = -1e30f;
        for (int p = s; p < e_end; ++p)
          m = fmaxf(m, scores[(size_t)p * 4 + head]);
        float den = 0.f;
        int p = s;
        for (; p + 4 <= e_end; p += 4) {
          int j0 = jcsr[p], j1 = jcsr[p + 1], j2 = jcsr[p + 2], j3 = jcsr[p + 3];
          float s0 = scores[(size_t)p * 4 + head];
          float s1 = scores[(size_t)(p + 1) * 4 + head];
          float s2 = scores[(size_t)(p + 2) * 4 + head];
          float s3 = scores[(size_t)(p + 3) * 4 + head];
          ushort8v v00 = *(const ushort8v*)&valb[(size_t)j0 * DIM + c16];
          ushort8v v01 = *(const ushort8v*)&valb[(size_t)j0 * DIM + c16 + 8];
          ushort8v v10 = *(const ushort8v*)&valb[(size_t)j1 * DIM + c16];
          ushort8v v11 = *(const ushort8v*)&valb[(size_t)j1 * DIM + c16 + 8];
          ushort8v v20 = *(const ushort8v*)&valb[(size_t)j2 * DIM + c16];
          ushort8v v21 = *(const ushort8v*)&valb[(size_t)j2 * DIM + c16 + 8];
          ushort8v v30 = *(const ushort8v*)&valb[(size_t)j3 * DIM + c16];
          ushort8v v31 = *(const ushort8v*)&valb[(size_t)j3 * DIM + c16 + 8];
          float e0 = __expf(s0 - m), e1 = __expf(s1 - m);
          float e2 = __expf(s2 - m), e3 = __expf(s3 - m);
          den += (e0 + e1) + (e2 + e3);
#pragma unroll
          for (int q = 0; q < 8; ++q) {
            acc[q]     += e0 * bf2f(v00[q]) + e1 * bf2f(v10[q])
                        + e2 * bf2f(v20[q]) + e3 * bf2f(v30[q]);
            acc[8 + q] += e0 * bf2f(v01[q]) + e1 * bf2f(v11[q])
                        + e2 * bf2f(v21[q]) + e3 * bf2f(v31[q]);
          }
        }
        for (; p < e_end; ++p) {
          int j = jcsr[p];
          float s0 = scores[(size_t)p * 4 + head];
          ushort8v v0 = *(const ushort8v*)&valb[(size_t)j * DIM + c16];
          ushort8v v1 = *(const ushort8v*)&valb[(size_t)j * DIM + c16 + 8];
          float e0 = __expf(s0 - m);
          den += e0;
#pragma unroll
          for (int q = 0; q < 8; ++q) {
            acc[q]     += e0 * bf2f(v0[q]);
            acc[8 + q] += e0 * bf2f(v1[q]);
          }
        }
        float inv = 1.f / den;
#pragma unroll
        for (int q = 0; q < 16; ++q) acc[q] *= inv;
      }
    }
    // NODE staging + agg hi/lo split into A-frag region
    float vn[16];
    if (row < NN_) {
#pragma unroll
      for (int q = 0; q < 4; ++q) {
        float4 xn = *(const float4*)&NODE[(size_t)row * DIM + c16 + q * 4];
        vn[q * 4 + 0] = xn.x; vn[q * 4 + 1] = xn.y;
        vn[q * 4 + 2] = xn.z; vn[q * 4 + 3] = xn.w;
      }
    } else {
#pragma unroll
      for (int q = 0; q < 16; ++q) vn[q] = 0.f;
    }
#pragma unroll
    for (int h2 = 0; h2 < 2; ++h2) {
      ushort8v ah8, al8, nh8, nl8;
#pragma unroll
      for (int q = 0; q < 8; ++q) {
        float x = acc[h2 * 8 + q];
        u16 h = f2bf(x); ah8[q] = h; al8[q] = f2bf(x - bf2f(h));
        float y = vn[h2 * 8 + q];
        u16 hy = f2bf(y); nh8[q] = hy; nl8[q] = f2bf(y - bf2f(hy));
      }
      *(ushort8v*)&a_h[r2 * 136 + c16 + h2 * 8] = ah8;
      *(ushort8v*)&a_l[r2 * 136 + c16 + h2 * 8] = al8;
      *(ushort8v*)&n_h[r2 * 136 + c16 + h2 * 8] = nh8;
      *(ushort8v*)&n_l[r2 * 136 + c16 + h2 * 8] = nl8;
    }
  }
  __syncthreads();

  int wv_ = tid >> 6, lane = tid & 63;
  int mtile = wv_ & 1, nhalf = wv_ >> 1;
  int quad = lane >> 4, lrow = lane & 15;
  int m0 = mtile * 16;

  const u16* WunH = wfrag + (size_t)6 * 16384;
  const u16* WunL = wfrag + (size_t)7 * 16384;
  const u16* G0H  = wfrag + (size_t)8 * 16384;
  const u16* G0L  = wfrag + (size_t)9 * 16384;
  const u16* G1H  = wfrag + (size_t)10 * 16384;
  const u16* G1L  = wfrag + (size_t)11 * 16384;

  // MFMA1: nnew = agg @ Wun (raw, bias added later)
  {
    short8 fh[4], fl[4];
#pragma unroll
    for (int s = 0; s < 4; ++s) {
      fh[s] = *(const short8*)&a_h[(m0 + lrow) * 136 + s * 32 + quad * 8];
      fl[s] = *(const short8*)&a_l[(m0 + lrow) * 136 + s * 32 + quad * 8];
    }
    floatx4 d1[4];
#pragma unroll
    for (int t = 0; t < 4; ++t) d1[t] = (floatx4){0.f, 0.f, 0.f, 0.f};
#pragma unroll
    for (int s = 0; s < 4; ++s) {
#pragma unroll
      for (int t = 0; t < 4; ++t) {
        int T = nhalf * 4 + t;
        size_t off2 = (size_t)((T * 4 + s) * 64 + lane) * 8;
        short8 bh = *(const short8*)&WunH[off2];
        short8 bl = *(const short8*)&WunL[off2];
        d1[t] = __builtin_amdgcn_mfma_f32_16x16x32_bf16(fh[s], bh, d1[t], 0, 0, 0);
        d1[t] = __builtin_amdgcn_mfma_f32_16x16x32_bf16(fl[s], bh, d1[t], 0, 0, 0);
        d1[t] = __builtin_amdgcn_mfma_f32_16x16x32_bf16(fh[s], bl, d1[t], 0, 0, 0);
      }
    }
#pragma unroll
    for (int t = 0; t < 4; ++t) {
      int col = nhalf * 64 + t * 16 + lrow;
#pragma unroll
      for (int r = 0; r < 4; ++r)
        park[(m0 + quad * 4 + r) * 132 + col] = d1[t][r];
    }
  }
  __syncthreads();

  // re-split nnew+bun into the dead agg-frag region (A layout for MFMA2)
  {
#pragma unroll
    for (int h2 = 0; h2 < 2; ++h2) {
      ushort8v hh, ll;
#pragma unroll
      for (int q = 0; q < 8; ++q) {
        float x = park[r2 * 132 + c16 + h2 * 8 + q] + bun[c16 + h2 * 8 + q];
        u16 h = f2bf(x); hh[q] = h; ll[q] = f2bf(x - bf2f(h));
      }
      *(ushort8v*)&a_h[r2 * 136 + c16 + h2 * 8] = hh;
      *(ushort8v*)&a_l[r2 * 136 + c16 + h2 * 8] = ll;
    }
  }
  __syncthreads();

  // MFMA2: z = nnew@Wgc0 + NODE@Wgc1; epilogue in C-layout
  {
    short8 mh[4], ml[4], ph[4], pl[4];
#pragma unroll
    for (int s = 0; s < 4; ++s) {
      mh[s] = *(const short8*)&a_h[(m0 + lrow) * 136 + s * 32 + quad * 8];
      ml[s] = *(const short8*)&a_l[(m0 + lrow) * 136 + s * 32 + quad * 8];
      ph[s] = *(const short8*)&n_h[(m0 + lrow) * 136 + s * 32 + quad * 8];
      pl[s] = *(const short8*)&n_l[(m0 + lrow) * 136 + s * 32 + quad * 8];
    }
    floatx4 d2[4];
#pragma unroll
    for (int t = 0; t < 4; ++t) d2[t] = (floatx4){0.f, 0.f, 0.f, 0.f};
#pragma unroll
    for (int s = 0; s < 4; ++s) {
#pragma unroll
      for (int t = 0; t < 4; ++t) {
        int T = nhalf * 4 + t;
        size_t off2 = (size_t)((T * 4 + s) * 64 + lane) * 8;
        short8 g0h = *(const short8*)&G0H[off2];
        short8 g0l = *(const short8*)&G0L[off2];
        short8 g1h = *(const short8*)&G1H[off2];
        short8 g1l = *(const short8*)&G1L[off2];
        d2[t] = __builtin_amdgcn_mfma_f32_16x16x32_bf16(mh[s], g0h, d2[t], 0, 0, 0);
        d2[t] = __builtin_amdgcn_mfma_f32_16x16x32_bf16(ml[s], g0h, d2[t], 0, 0, 0);
        d2[t] = __builtin_amdgcn_mfma_f32_16x16x32_bf16(mh[s], g0l, d2[t], 0, 0, 0);
        d2[t] = __builtin_amdgcn_mfma_f32_16x16x32_bf16(ph[s], g1h, d2[t], 0, 0, 0);
        d2[t] = __builtin_amdgcn_mfma_f32_16x16x32_bf16(pl[s], g1h, d2[t], 0, 0, 0);
        d2[t] = __builtin_amdgcn_mfma_f32_16x16x32_bf16(ph[s], g1l, d2[t], 0, 0, 0);
      }
    }
#pragma unroll
    for (int t = 0; t < 4; ++t) {
      int col = nhalf * 64 + t * 16 + lrow;
      float bgv = bg[col], bunv = bun[col];
#pragma unroll
      for (int r = 0; r < 4; ++r) {
        int erow = m0 + quad * 4 + r;
        int row = row0 + erow;
        float z = d2[t][r] + bgv;
        float gg = 1.f / (1.f + __expf(-z));
        float nn = park[erow * 132 + col] + bunv;
        float nodev = bf2f(n_h[erow * 136 + col]) + bf2f(n_l[erow * 136 + col]);
        float x1 = gg * nn + nodev;
        park[erow * 132 + col] = x1;
        if (row < NN_) {
          G[(size_t)row * DIM + col] = gg;
          X1[(size_t)row * DIM + col] = x1;
        }
      }
    }
  }
  __syncthreads();
  tile_gn_stats(park, 132, bg_s, row0, tid, gsum1, gsq1);
}

// ---------------- fix_node via MFMA + inline GN1 + gn2 stats ------------
__global__ void __launch_bounds__(256) fx_kernel(
    const float* __restrict__ X1, const int* __restrict__ batch,
    const int* __restrict__ gstart,
    const float* __restrict__ gsum1, const float* __restrict__ gsq1,
    const float* __restrict__ g1w, const float* __restrict__ g1b,
    const float* __restrict__ g1a, const u16* __restrict__ wfrag,
    const float* __restrict__ bf1, const float* __restrict__ bf2,
    const float* __restrict__ G,
    float* __restrict__ gsum2, float* __restrict__ gsq2,
    float* __restrict__ X2) {
  __shared__ __align__(16) u16 a_h[32 * 136];   // n1 frags -> t frags
  __shared__ __align__(16) u16 a_l[32 * 136];
  __shared__ __align__(16) float n1s[32 * 132]; // n1 -> x2
  __shared__ int bg_s[32];
  int tid = threadIdx.x, row0 = blockIdx.x * 32;
  int r2 = tid >> 3, c16 = (tid & 7) * 16;
  if (tid < 32) bg_s[tid] = (row0 + tid < NN_) ? batch[row0 + tid] : 0;

  // stage x1 + inline GN1 -> n1 (f32 tile + hi/lo frags)
  {
    int row = row0 + r2;
    int gi = (row < NN_) ? batch[row] : 0;
    float cnt = fmaxf((float)(gstart[gi + 1] - gstart[gi]), 1.f);
    float inv = 1.f / cnt;
    float v[16];
    if (row < NN_) {
#pragma unroll
      for (int q = 0; q < 4; ++q) {
        float4 x = *(const float4*)&X1[(size_t)row * DIM + c16 + q * 4];
        v[q * 4 + 0] = x.x; v[q * 4 + 1] = x.y;
        v[q * 4 + 2] = x.z; v[q * 4 + 3] = x.w;
      }
    } else {
#pragma unroll
      for (int q = 0; q < 16; ++q) v[q] = 0.f;
    }
#pragma unroll
    for (int q0 = 0; q0 < 16; ++q0) {
      int c = c16 + q0;
      float sm = gsum1[gi * DIM + c], sq = gsq1[gi * DIM + c];
      float mean = sm * inv, msq = sq * inv, am = g1a[c] * mean;
      float var = msq - 2.f * am * mean + am * am;
      v[q0] = g1w[c] * (v[q0] - am) * rsqrtf(var + 1e-5f) + g1b[c];
    }
#pragma unroll
    for (int q = 0; q < 4; ++q) {
      float4 o; o.x = v[q * 4 + 0]; o.y = v[q * 4 + 1];
      o.z = v[q * 4 + 2]; o.w = v[q * 4 + 3];
      *(float4*)&n1s[r2 * 132 + c16 + q * 4] = o;
    }
#pragma unroll
    for (int h2 = 0; h2 < 2; ++h2) {
      ushort8v hh, ll;
#pragma unroll
      for (int q = 0; q < 8; ++q) {
        float x = v[h2 * 8 + q];
        u16 h = f2bf(x); hh[q] = h; ll[q] = f2bf(x - bf2f(h));
      }
      *(ushort8v*)&a_h[r2 * 136 + c16 + h2 * 8] = hh;
      *(ushort8v*)&a_l[r2 * 136 + c16 + h2 * 8] = ll;
    }
  }
  __syncthreads();

  int wv_ = tid >> 6, lane = tid & 63;
  int mtile = wv_ & 1, nhalf = wv_ >> 1;
  int quad = lane >> 4, lrow = lane & 15;
  int m0 = mtile * 16;

  const u16* F1H = wfrag + (size_t)12 * 16384;
  const u16* F1L = wfrag + (size_t)13 * 16384;
  const u16* F2H = wfrag + (size_t)14 * 16384;
  const u16* F2L = wfrag + (size_t)15 * 16384;

  short8 fh[4], fl[4];
#pragma unroll
  for (int s = 0; s < 4; ++s) {
    fh[s] = *(const short8*)&a_h[(m0 + lrow) * 136 + s * 32 + quad * 8];
    fl[s] = *(const short8*)&a_l[(m0 + lrow) * 136 + s * 32 + quad * 8];
  }
  __syncthreads();   // all frags in regs before the t-scatter overwrites

  // MFMA1: t = leaky(n1 @ Wf1 + bf1); scatter hi/lo into a_h/a_l (C->A)
  {
    floatx4 d1[4];
#pragma unroll
    for (int t = 0; t < 4; ++t) d1[t] = (floatx4){0.f, 0.f, 0.f, 0.f};
#pragma unroll
    for (int s = 0; s < 4; ++s) {
#pragma unroll
      for (int t = 0; t < 4; ++t) {
        int T = nhalf * 4 + t;
        size_t off2 = (size_t)((T * 4 + s) * 64 + lane) * 8;
        short8 bh = *(const short8*)&F1H[off2];
        short8 bl = *(const short8*)&F1L[off2];
        d1[t] = __builtin_amdgcn_mfma_f32_16x16x32_bf16(fh[s], bh, d1[t], 0, 0, 0);
        d1[t] = __builtin_amdgcn_mfma_f32_16x16x32_bf16(fl[s], bh, d1[t], 0, 0, 0);
        d1[t] = __builtin_amdgcn_mfma_f32_16x16x32_bf16(fh[s], bl, d1[t], 0, 0, 0);
      }
    }
#pragma unroll
    for (int t = 0; t < 4; ++t) {
      int col = nhalf * 64 + t * 16 + lrow;
      float b1v = bf1[col];
#pragma unroll
      for (int r = 0; r < 4; ++r) {
        int erow = m0 + quad * 4 + r;
        float tt = d1[t][r] + b1v;
        tt = tt > 0.f ? tt : 0.01f * tt;
        u16 h = f2bf(tt);
        a_h[erow * 136 + col] = h;
        a_l[erow * 136 + col] = f2bf(tt - bf2f(h));
      }
    }
  }
  __syncthreads();

  // MFMA2: x2 = g*(t @ Wf2 + bf2) + n1
  {
    short8 th[4], tl[4];
#pragma unroll
    for (int s = 0; s < 4; ++s) {
      th[s] = *(const short8*)&a_h[(m0 + lrow) * 136 + s * 32 + quad * 8];
      tl[s] = *(const short8*)&a_l[(m0 + lrow) * 136 + s * 32 + quad * 8];
    }
    floatx4 d2[4];
#pragma unroll
    for (int t = 0; t < 4; ++t) d2[t] = (floatx4){0.f, 0.f, 0.f, 0.f};
#pragma unroll
    for (int s = 0; s < 4; ++s) {
#pragma unroll
      for (int t = 0; t < 4; ++t) {
        int T = nhalf * 4 + t;
        size_t off2 = (size_t)((T * 4 + s) * 64 + lane) * 8;
        short8 bh = *(const short8*)&F2H[off2];
        short8 bl = *(const short8*)&F2L[off2];
        d2[t] = __builtin_amdgcn_mfma_f32_16x16x32_bf16(th[s], bh, d2[t], 0, 0, 0);
        d2[t] = __builtin_amdgcn_mfma_f32_16x16x32_bf16(tl[s], bh, d2[t], 0, 0, 0);
        d2[t] = __builtin_amdgcn_mfma_f32_16x16x32_bf16(th[s], bl, d2[t], 0, 0, 0);
      }
    }
#pragma unroll
    for (int t = 0; t < 4; ++t) {
      int col = nhalf * 64 + t * 16 + lrow;
      float b2v = bf2[col];
#pragma unroll
      for (int r = 0; r < 4; ++r) {
        int erow = m0 + quad * 4 + r;
        int row = row0 + erow;
        float gg = (row < NN_) ? G[(size_t)row * DIM + col] : 0.f;
        float x2 = gg * (d2[t][r] + b2v) + n1s[erow * 132 + col];
        n1s[erow * 132 + col] = x2;
        if (row < NN_) X2[(size_t)row * DIM + col] = x2;
      }
    }
  }
  __syncthreads();
  tile_gn_stats(n1s, 132, bg_s, row0, tid, gsum2, gsq2);
}

// ---------------- CSR build ----------------
__global__ void scanA_kernel(const int* __restrict__ deg, int* __restrict__ off,
                             int* __restrict__ bsum) {
  __shared__ int buf[256];
  int tid = threadIdx.x;
  int i = blockIdx.x * 256 + tid;
  int v = (i < NN_) ? deg[i] : 0;
  buf[tid] = v;
  __syncthreads();
  for (int s = 1; s < 256; s <<= 1) {
    int t = (tid >= s) ? buf[tid - s] : 0;
    __syncthreads();
    buf[tid] += t;
    __syncthreads();
  }
  if (i < NN_) off[i] = buf[tid] - v;
  if (tid == 255) bsum[blockIdx.x] = buf[255];
}

__global__ void scanB_kernel(int* __restrict__ bsum) {
  const int NBLK = (NN_ + 255) / 256;
  __shared__ int buf[128];
  int tid = threadIdx.x;
  int v = (tid < NBLK) ? bsum[tid] : 0;
  buf[tid] = v;
  __syncthreads();
  for (int s = 1; s < 128; s <<= 1) {
    int t = (tid >= s) ? buf[tid - s] : 0;
    __syncthreads();
    buf[tid] += t;
    __syncthreads();
  }
  if (tid < NBLK) bsum[tid] = buf[tid] - v;
}

__global__ void scanC_kernel(int* __restrict__ off, const int* __restrict__ bsum) {
  int i = blockIdx.x * 256 + threadIdx.x;
  if (i < NN_) off[i] += bsum[i >> 8];
  if (i == 0) off[NN_] = NE_;
}

__global__ void fill_kernel(const int* __restrict__ EI, const int* __restrict__ off,
                            int* __restrict__ cur, int* __restrict__ eidb,
                            int* __restrict__ jcsr) {
  int e = blockIdx.x * 256 + threadIdx.x;
  if (e >= NE_) return;
  int i = EI[e];
  int p = atomicAdd(&cur[i], 1);
  int pos = off[i] + p;
  eidb[pos] = e;
  jcsr[pos] = EI[NE_ + e];
}

// ---------------- fused edge kernel, CSR order (FROZEN from R13) --------
__global__ void __launch_bounds__(256, 6) edge_kernel(
    const float* __restrict__ edgef, const float* __restrict__ coords,
    const int* __restrict__ EI, const int* __restrict__ eidb,
    const float* __restrict__ We1, const float* __restrict__ be1,
    const float* __restrict__ be2, const u16* __restrict__ we2b,
    const u16* __restrict__ wueb, const float* __restrict__ bue,
    const u16* __restrict__ srcb, const u16* __restrict__ dstb,
    float* __restrict__ scores, float* __restrict__ outE) {
  __shared__ __align__(16) float sbuf[5504];
  __shared__ float bue_s[EOUTF];
  __shared__ int ii[32], jj[32], ee[32];

  float* xs   = sbuf;                 // [32][20], cols 0..16 used (phase A)
  u16*   hbf  = (u16*)(sbuf + 640);   // [32][136] (phase A)
  float* park = sbuf;                 // [2][32][20] (phase B)
  float* ers  = sbuf + 1280;          // [32][132] (phase B)

  int tid = threadIdx.x;
  int bid = blockIdx.x;
  int bswz = (bid & 7) * (NE_ / 32 / 8) + (bid >> 3);
  int p0 = bswz * 32;

  if (tid < 32) {
    int p = p0 + tid;
    int e = eidb[p];
    ee[tid] = e;
    int i = EI[e], j = EI[NE_ + e];
    ii[tid] = i; jj[tid] = j;
    float dx = coords[i * 3 + 0] - coords[j * 3 + 0];
    float dy = coords[i * 3 + 1] - coords[j * 3 + 1];
    float dz = coords[i * 3 + 2] - coords[j * 3 + 2];
    float dist = sqrtf(dx * dx + dy * dy + dz * dz + 1e-12f) * 0.1f;
    xs[tid * 20 + 16] = dist;
  }
  if (tid < EOUTF) bue_s[tid] = bue[tid];
  __syncthreads();

  if (tid < 128) {
    int r = tid >> 2, c4 = (tid & 3) * 4;
    *(float4*)&xs[r * 20 + c4] = *(const float4*)&edgef[(size_t)ee[r] * EINF + c4];
  }
  __syncthreads();

  int cg = tid & 31, rg = tid >> 5, c0 = cg * 4, r0 = rg * 4;

  // h = leaky(x @ We1 + be1), K=17 VALU; write bf16 to hbf
  {
    float acc[4][4] = {};
    for (int k = 0; k < 16; k += 4) {
      float4 w0 = *(const float4*)&We1[(size_t)(k + 0) * DIM + c0];
      float4 w1 = *(const float4*)&We1[(size_t)(k + 1) * DIM + c0];
      float4 w2 = *(const float4*)&We1[(size_t)(k + 2) * DIM + c0];
      float4 w3 = *(const float4*)&We1[(size_t)(k + 3) * DIM + c0];
#pragma unroll
      for (int u = 0; u < 4; ++u) {
        float4 xv = *(const float4*)&xs[(r0 + u) * 20 + k];
        acc[u][0] += xv.x * w0.x + xv.y * w1.x + xv.z * w2.x + xv.w * w3.x;
        acc[u][1] += xv.x * w0.y + xv.y * w1.y + xv.z * w2.y + xv.w * w3.y;
        acc[u][2] += xv.x * w0.z + xv.y * w1.z + xv.z * w2.z + xv.w * w3.z;
        acc[u][3] += xv.x * w0.w + xv.y * w1.w + xv.z * w2.w + xv.w * w3.w;
      }
    }
    {   // k = 16: the dist column
      float4 w4 = *(const float4*)&We1[(size_t)16 * DIM + c0];
#pragma unroll
      for (int u = 0; u < 4; ++u) {
        float xd = xs[(r0 + u) * 20 + 16];
        acc[u][0] += xd * w4.x; acc[u][1] += xd * w4.y;
        acc[u][2] += xd * w4.z; acc[u][3] += xd * w4.w;
      }
    }
    float4 b1 = *(const float4*)&be1[c0];
#pragma unroll
    for (int u = 0; u < 4; ++u) {
      float h0 = acc[u][0] + b1.x, h1 = acc[u][1] + b1.y;
      float h2 = acc[u][2] + b1.z, h3 = acc[u][3] + b1.w;
      h0 = h0 > 0.f ? h0 : 0.01f * h0; h1 = h1 > 0.f ? h1 : 0.01f * h1;
      h2 = h2 > 0.f ? h2 : 0.01f * h2; h3 = h3 > 0.f ? h3 : 0.01f * h3;
      ushort4 pk; pk.x = f2bf(h0); pk.y = f2bf(h1); pk.z = f2bf(h2); pk.w = f2bf(h3);
      *(ushort4*)&hbf[(r0 + u) * 136 + c0] = pk;
    }
  }
  __syncthreads();

  int wv = tid >> 6, lane = tid & 63;
  int mtile = wv & 1, nhalf = wv >> 1;   // nhalf doubles as khalf for MFMA2
  int quad = lane >> 4, lrow = lane & 15;
  int m0 = mtile * 16;

  short8 afrag[4];
#pragma unroll
  for (int s = 0; s < 4; ++s)
    afrag[s] = *(const short8*)&hbf[(m0 + lrow) * 136 + s * 32 + quad * 8];
  __syncthreads();   // xs/hbf dead -> phase B overlay begins

  // MFMA1: e2 = h @ We2
  floatx4 dacc[4];
#pragma unroll
  for (int t = 0; t < 4; ++t) dacc[t] = (floatx4){0.f, 0.f, 0.f, 0.f};
#pragma unroll
  for (int s = 0; s < 4; ++s) {
#pragma unroll
    for (int t = 0; t < 4; ++t) {
      int T = nhalf * 4 + t;
      short8 bfrg = *(const short8*)&we2b[(size_t)((T * 4 + s) * 64 + lane) * 8];
      dacc[t] = __builtin_amdgcn_mfma_f32_16x16x32_bf16(afrag[s], bfrg, dacc[t], 0, 0, 0);
    }
  }

#pragma unroll
  for (int t = 0; t < 4; ++t) {
    int col = nhalf * 64 + t * 16 + lrow;
    float b2v = be2[col];
#pragma unroll
    for (int r = 0; r < 4; ++r) {
      int erow = m0 + quad * 4 + r;
      ers[erow * 132 + col] = dacc[t][r] + b2v;
    }
  }
  __syncthreads();

  // pass 2: er = dst_i * src_j * e2 / sqrt(DH); gathers at use site
  {
    int el2 = tid >> 3, cb2 = tid & 7;
    int c0b = cb2 * 16;
    int irow = ii[el2], jrow = jj[el2];
    ushort8v dv8a = *(const ushort8v*)&dstb[(size_t)irow * DIM + c0b];
    ushort8v dv8b = *(const ushort8v*)&dstb[(size_t)irow * DIM + c0b + 8];
    ushort8v sv8a = *(const ushort8v*)&srcb[(size_t)jrow * DIM + c0b];
    ushort8v sv8b = *(const ushort8v*)&srcb[(size_t)jrow * DIM + c0b + 8];

    float ef[16];
#pragma unroll
    for (int q = 0; q < 4; ++q) {
      float4 v = *(const float4*)&ers[el2 * 132 + c0b + q * 4];
      ef[q * 4 + 0] = v.x; ef[q * 4 + 1] = v.y;
      ef[q * 4 + 2] = v.z; ef[q * 4 + 3] = v.w;
    }
    float asum = 0.f;
#pragma unroll
    for (int k = 0; k < 8; ++k) {
      float er = bf2f((u16)dv8a[k]) * bf2f((u16)sv8a[k]) * ef[k] * RSQRT_DH;
      ef[k] = er; asum += fabsf(er);
    }
#pragma unroll
    for (int k = 0; k < 8; ++k) {
      float er = bf2f((u16)dv8b[k]) * bf2f((u16)sv8b[k]) * ef[8 + k] * RSQRT_DH;
      ef[8 + k] = er; asum += fabsf(er);
    }
#pragma unroll
    for (int q = 0; q < 4; ++q) {
      float4 v; v.x = ef[q * 4 + 0]; v.y = ef[q * 4 + 1];
      v.z = ef[q * 4 + 2]; v.w = ef[q * 4 + 3];
      *(float4*)&ers[el2 * 132 + c0b + q * 4] = v;
    }
    asum += __shfl_xor(asum, 1);
    if ((cb2 & 1) == 0)
      scores[(size_t)(p0 + el2) * 4 + (cb2 >> 1)] = asum;
  }
  __syncthreads();

  // MFMA2: edge_new = er @ Wue. Wave (mtile, khalf=nhalf) computes its
  // K-half partial into park[khalf]; A-frags split bf16x2 from f32 ers.
  {
    floatx4 d3 = (floatx4){0.f, 0.f, 0.f, 0.f};
#pragma unroll
    for (int s = 0; s < 2; ++s) {
      int kbase = nhalf * 64 + s * 32 + quad * 8;
      const float* src = &ers[(m0 + lrow) * 132 + kbase];
      float4 e0 = *(const float4*)&src[0];
      float4 e1 = *(const float4*)&src[4];
      float ev[8] = {e0.x, e0.y, e0.z, e0.w, e1.x, e1.y, e1.z, e1.w};
      short8 ah8, al8;
#pragma unroll
      for (int q = 0; q < 8; ++q) {
        u16 h = f2bf(ev[q]);
        ah8[q] = (short)h;
        al8[q] = (short)f2bf(ev[q] - bf2f(h));
      }
      int sG = nhalf * 2 + s;
      size_t off = (size_t)(sG * 64 + lane) * 8;
      short8 bh = *(const short8*)&wueb[off];
      short8 bl = *(const short8*)&wueb[4096 + off];
      d3 = __builtin_amdgcn_mfma_f32_16x16x32_bf16(ah8, bh, d3, 0, 0, 0);
      d3 = __builtin_amdgcn_mfma_f32_16x16x32_bf16(al8, bh, d3, 0, 0, 0);
      d3 = __builtin_amdgcn_mfma_f32_16x16x32_bf16(ah8, bl, d3, 0, 0, 0);
    }
    // park partial: C layout for 16x16 tile -> row m0+quad*4+r, col lrow
#pragma unroll
    for (int r = 0; r < 4; ++r)
      park[nhalf * 640 + (m0 + quad * 4 + r) * 20 + lrow] = d3[r];
  }
  __syncthreads();

  // epilogue: sum K-half partials + bias -> scatter by original edge id
  {
    int el = tid >> 3, oc2 = (tid & 7) * 2;
    float a0 = park[el * 20 + oc2]     + park[640 + el * 20 + oc2]     + bue_s[oc2];
    float a1 = park[el * 20 + oc2 + 1] + park[640 + el * 20 + oc2 + 1] + bue_s[oc2 + 1];
    size_t ob = (size_t)ee[el] * EOUTF + oc2;
    float2 o2; o2.x = a0; o2.y = a1;
    *(float2*)&outE[ob] = o2;
  }
}

// ---------------- final GraphNorm apply + coords copy (merged) ----------
__global__ void gn_apply_kernel(const float* __restrict__ X, const int* __restrict__ batch,
    const int* __restrict__ gstart, const float* __restrict__ gsum,
    const float* __restrict__ gsq, const float* __restrict__ w,
    const float* __restrict__ b, const float* __restrict__ a,
    float* __restrict__ Y,
    const float* __restrict__ C, float* __restrict__ OC) {
  int blk = blockIdx.x;
  if (blk >= (NN_ * 32) / 256) {
    int i = (blk - (NN_ * 32) / 256) * 256 + threadIdx.x;
    if (i < NN_ * 3) OC[i] = C[i];
    return;
  }
  int idx = blk * 256 + threadIdx.x;
  int n = idx >> 5, c4 = (idx & 31) * 4;
  int g = batch[n];
  float cnt = fmaxf((float)(gstart[g + 1] - gstart[g]), 1.f);
  float inv = 1.f / cnt;
  float4 xv = *(const float4*)&X[(size_t)n * DIM + c4];
  float4 sm = *(const float4*)&gsum[g * DIM + c4];
  float4 sq = *(const float4*)&gsq[g * DIM + c4];
  float4 av = *(const float4*)&a[c4];
  float4 wv = *(const float4*)&w[c4];
  float4 bv = *(const float4*)&b[c4];
  float4 ov;
  {
    float mean = sm.x * inv, msq = sq.x * inv, am = av.x * mean;
    float var = msq - 2.f * am * mean + am * am;
    ov.x = wv.x * (xv.x - am) * rsqrtf(var + 1e-5f) + bv.x;
  }
  {
    float mean = sm.y * inv, msq = sq.y * inv, am = av.y * mean;
    float var = msq - 2.f * am * mean + am * am;
    ov.y = wv.y * (xv.y - am) * rsqrtf(var + 1e-5f) + bv.y;
  }
  {
    float mean = sm.z * inv, msq = sq.z * inv, am = av.z * mean;
    float var = msq - 2.f * am * mean + am * am;
    ov.z = wv.z * (xv.z - am) * rsqrtf(var + 1e-5f) + bv.z;
  }
  {
    float mean = sm.w * inv, msq = sq.w * inv, am = av.w * mean;
    float var = msq - 2.f * am * mean + am * am;
    ov.w = wv.w * (xv.w - am) * rsqrtf(var + 1e-5f) + bv.w;
  }
  *(float4*)&Y[(size_t)n * DIM + c4] = ov;
}

// ---------------- launcher ----------------
extern "C" void kernel_launch(void* const* d_in, const int* in_sizes, int n_in,
                              void* d_out, int out_size, void* d_ws, size_t ws_size,
                              hipStream_t stream) {
  (void)in_sizes; (void)n_in; (void)out_size; (void)ws_size;
  const float* node  = (const float*)d_in[0];
  const float* edgef = (const float*)d_in[1];
  const float* coords= (const float*)d_in[2];
  const float* Ws  = (const float*)d_in[3];  const float* bs  = (const float*)d_in[4];
  const float* Wd  = (const float*)d_in[5];  const float* bd  = (const float*)d_in[6];
  const float* Wv  = (const float*)d_in[7];  const float* bv  = (const float*)d_in[8];
  const float* We1 = (const float*)d_in[9];  const float* be1 = (const float*)d_in[10];
  const float* We2 = (const float*)d_in[11]; const float* be2 = (const float*)d_in[12];
  const float* Wun = (const float*)d_in[13]; const float* bun = (const float*)d_in[14];
  const float* Wue = (const float*)d_in[15]; const float* bue = (const float*)d_in[16];
  const float* Wg  = (const float*)d_in[17]; const float* bg  = (const float*)d_in[18];
  const float* Wf1 = (const float*)d_in[19]; const float* bf1 = (const float*)d_in[20];
  const float* Wf2 = (const float*)d_in[21]; const float* bf2 = (const float*)d_in[22];
  const float* g1w = (const float*)d_in[23]; const float* g1b = (const float*)d_in[24];
  const float* g1a = (const float*)d_in[25];
  const float* g2w = (const float*)d_in[26]; const float* g2b = (const float*)d_in[27];
  const float* g2a = (const float*)d_in[28];
  const int* EI    = (const int*)d_in[29];
  const int* batch = (const int*)d_in[30];
  float* out = (float*)d_out;

  int*   wsi = (int*)d_ws;
  float* wsf = (float*)d_ws;
  int* deg    = wsi + W_DEG;
  int* cur    = wsi + W_CUR;
  int* offs   = wsi + W_OFF;
  int* bsum   = wsi + W_BSUM;
  int* gstart = wsi + W_GSTART;
  int* eidb   = wsi + W_EID;
  int* jcsr   = wsi + W_JC;
  float* gsum1 = wsf + W_GSUM1; float* gsq1 = wsf + W_GSQ1;
  float* gsum2 = wsf + W_GSUM2; float* gsq2 = wsf + W_GSQ2;
  float* scores_ = wsf + W_SCORES;
  u16* srcb = (u16*)(wsf + W_SRCB);
  u16* dstb = (u16*)(wsf + W_DSTB);
  u16* valb = (u16*)(wsf + W_VALB);
  float* A = wsf + W_A;   // x1 -> x2
  float* B = wsf + W_B;   // g
  u16*   we2b  = (u16*)(wsf + W_WE2B);
  u16*   wfrag = (u16*)(wsf + W_WPROJ);
  u16*   wueb  = (u16*)(wsf + W_WUEB);

  float* outE = out + (size_t)NN_ * DIM;
  float* outC = out + (size_t)NN_ * DIM + (size_t)NE_ * EOUTF;

  // zero the counter/stat prefix via DMA
  hipMemsetAsync(d_ws, 0, (size_t)W_ZEND * sizeof(int), stream);
  // consolidated setup: gstart + we2b + weight frags + wue frags + deg
  setup_kernel<<<1121 + (NE_ + 255) / 256, 256, 0, stream>>>(
      batch, gstart, Wg, We2, we2b, Ws, Wd, Wv, Wun, Wf1, Wf2, wfrag,
      Wue, wueb, EI, deg);
  // CSR build
  scanA_kernel<<<(NN_ + 255) / 256, 256, 0, stream>>>(deg, offs, bsum);
  scanB_kernel<<<1, 128, 0, stream>>>(bsum);
  scanC_kernel<<<(NN_ + 255) / 256, 256, 0, stream>>>(offs, bsum);
  fill_kernel<<<(NE_ + 255) / 256, 256, 0, stream>>>(EI, offs, cur, eidb, jcsr);
  // projections via MFMA (bf16x2)
  proj_kernel<<<(NN_ + 31) / 32, 256, 0, stream>>>(node, wfrag, bs, bd, bv,
                                                   srcb, dstb, valb);
  // edge pipeline in CSR order
  edge_kernel<<<NE_ / 32, 256, 0, stream>>>(edgef, coords, EI, eidb, We1, be1,
                                            be2, we2b, wueb, bue,
                                            srcb, dstb, scores_, outE);
  // fused: agg (in-block, 4-way unroll) + MFMA nnew+gate; B := g, A := x1
  nnew_gate_kernel<<<(NN_ + 31) / 32, 256, 0, stream>>>(
      valb, scores_, offs, jcsr, node, batch, wfrag, bun, bg,
      gsum1, gsq1, B, A);
  // MFMA: fix_node with inline GN1; A := x2; gn2 stats accumulated
  fx_kernel<<<(NN_ + 31) / 32, 256, 0, stream>>>(A, batch, gstart, gsum1, gsq1,
                                                 g1w, g1b, g1a, wfrag, bf1, bf2,
                                                 B, gsum2, gsq2, A);
  // final GN apply + coords copy (merged)
  gn_apply_kernel<<<(NN_ * 32) / 256 + (NN_ * 3 + 255) / 256, 256, 0, stream>>>(
      A, batch, gstart, gsum2, gsq2, g2w, g2b, g2a, out, coords, outC);
}